// Round 3
// baseline (469.233 us; speedup 1.0000x reference)
//
#include <hip/hip_runtime.h>

#define DEV __device__ __forceinline__

typedef _Float16 half8 __attribute__((ext_vector_type(8)));
typedef _Float16 half4_t __attribute__((ext_vector_type(4)));
typedef float f32x4 __attribute__((ext_vector_type(4)));

DEV float ftanh(float x){
  float ax = fabsf(x);
  float e = __expf(-2.f*ax);
  float t = (1.f - e)/(1.f + e);
  return x < 0.f ? -t : t;
}
DEV float fsigm(float x){ return 1.f/(1.f + expf(-x)); }
DEV float wredsum(float v){
  #pragma unroll
  for (int o=32;o;o>>=1) v += __shfl_xor(v,o,64);
  return v;
}
DEV f32x4 MF(half8 a, half8 b, f32x4 c){
  return __builtin_amdgcn_mfma_f32_16x16x32_f16(a,b,c,0,0,0);
}
DEV void split8(float4 a0, float4 a1, half8& h, half8& l){
  float f[8] = {a0.x,a0.y,a0.z,a0.w,a1.x,a1.y,a1.z,a1.w};
  #pragma unroll
  for (int e=0;e<8;++e){
    _Float16 hh = (_Float16)f[e];
    h[e] = hh;
    l[e] = (_Float16)(f[e] - (float)hh);
  }
}

// ---------------- graph prep ----------------
__global__ void k_zero_i32(int* __restrict__ p, int n){
  int i = blockIdx.x*256 + threadIdx.x; if (i<n) p[i]=0;
}

__global__ void k_hist2(const int* __restrict__ s1, const int* __restrict__ d1, int E1,
                        int* __restrict__ co1, int* __restrict__ ci1,
                        const int* __restrict__ s2, const int* __restrict__ d2, int E2,
                        int* __restrict__ co2, int* __restrict__ ci2){
  int e = blockIdx.x*256 + threadIdx.x;
  if (e < E1){ atomicAdd(&co1[s1[e]],1); atomicAdd(&ci1[d1[e]],1); }
  int f = e - E1;
  if (f >= 0 && f < E2){ atomicAdd(&co2[s2[f]],1); atomicAdd(&ci2[d2[f]],1); }
}

__global__ void k_scan2(const int* __restrict__ c1, int n1, int* __restrict__ r1,
                        const int* __restrict__ c2, int n2, int* __restrict__ r2){
  __shared__ int sm[1024];
  const int* cnt = blockIdx.x ? c2 : c1;
  int*       row = blockIdx.x ? r2 : r1;
  int n          = blockIdx.x ? n2 : n1;
  int t = threadIdx.x;
  int per = n/1024 + 1;
  int st = t*per;
  int s = 0;
  for (int i=st;i<st+per;++i) if (i<n) s += cnt[i];
  sm[t]=s; __syncthreads();
  for (int o=1;o<1024;o<<=1){
    int v = (t>=o)? sm[t-o]:0;
    __syncthreads();
    sm[t] += v;
    __syncthreads();
  }
  int base = sm[t]-s;
  for (int i=st;i<st+per;++i){
    if (i<=n) row[i]=base;
    if (i<n) base += cnt[i];
  }
}

__global__ void k_scale2(const int* __restrict__ co1, const int* __restrict__ ci1, int n1,
                         float* __restrict__ os1, float* __restrict__ is1,
                         const int* __restrict__ co2, const int* __restrict__ ci2, int n2,
                         float* __restrict__ os2, float* __restrict__ is2){
  int i = blockIdx.x*256+threadIdx.x;
  if (i<n1){
    int a = co1[i] > 1 ? co1[i] : 1;
    int b = ci1[i] > 1 ? ci1[i] : 1;
    os1[i] = 1.f/sqrtf((float)a);
    is1[i] = 1.f/sqrtf((float)b);
  }
  int j = i - n1;
  if (j>=0 && j<n2){
    int a = co2[j] > 1 ? co2[j] : 1;
    int b = ci2[j] > 1 ? ci2[j] : 1;
    os2[j] = 1.f/sqrtf((float)a);
    is2[j] = 1.f/sqrtf((float)b);
  }
}

__global__ void k_scatter2(const int* __restrict__ s1, const int* __restrict__ d1, int E1,
                           const int* __restrict__ row1, int* __restrict__ cur1, int* __restrict__ csr1,
                           const int* __restrict__ s2, const int* __restrict__ d2, int E2,
                           const int* __restrict__ row2, int* __restrict__ cur2, int* __restrict__ csr2){
  int e = blockIdx.x*256+threadIdx.x;
  if (e<E1){ int d=d1[e]; int p=atomicAdd(&cur1[d],1); csr1[row1[d]+p]=s1[e]; }
  int f = e - E1;
  if (f>=0 && f<E2){ int d=d2[f]; int p=atomicAdd(&cur2[d],1); csr2[row2[d]+p]=s2[f]; }
}

// goff binary search + packed-plane prefix (pb, 32-aligned) + group->graph map (gm)
__global__ void k_goff2(const int* __restrict__ g1, int n1, int* __restrict__ o1,
                        const int* __restrict__ g2, int n2, int* __restrict__ o2, int B,
                        int* __restrict__ pb1, int* __restrict__ gm1,
                        int* __restrict__ pb2, int* __restrict__ gm2){
  int t = threadIdx.x;
  const int* gid = (t>=256)? g2 : g1;
  int*      goff = (t>=256)? o2 : o1;
  int n          = (t>=256)? n2 : n1;
  int q = t & 255;
  if (q<=B){
    int lo=0, hi=n;
    while (lo<hi){ int mid=(lo+hi)>>1; if (gid[mid]<q) lo=mid+1; else hi=mid; }
    goff[q]=lo;
  }
  __syncthreads();
  if (t==0 || t==256){
    const int* go = t ? o2 : o1;
    int* pb = t ? pb2 : pb1;
    int* gm = t ? gm2 : gm1;
    int acc = 0;
    for (int g=0; g<B; ++g){
      pb[g] = acc;
      int c = go[g+1]-go[g]; if (c>128) c=128;
      int pc = (c+31)&~31;
      int nb = pc>>5;
      for (int k=0;k<nb;++k) gm[(acc>>5)+k] = g;
      acc += pc;
    }
    pb[B] = acc;
  }
}

// gather aggregation with split-f16 output planes:
// acc[node] = sum_{e in in(node)} x[src_e] * (osc? osc[src_e] : 1) ; oh=f16(acc), ol=f16(acc-oh)
__global__ void k_agg_h(const float* __restrict__ x, int ldx, const float* __restrict__ osc,
                        const int* __restrict__ row, const int* __restrict__ csr,
                        _Float16* __restrict__ oh, _Float16* __restrict__ ol, int n, int f4shift){
  int F4 = 1<<f4shift;
  int node = blockIdx.x*(256>>f4shift) + (threadIdx.x>>f4shift);
  if (node>=n) return;
  int fc = threadIdx.x & (F4-1);
  int F = F4<<2;
  int rs=row[node], re=row[node+1];
  float ax=0, ay=0, az=0, aw=0;
  if (osc){
    for (int e=rs;e<re;++e){
      int s = csr[e];
      float sc = osc[s];
      const float4 v = *(const float4*)(x + (size_t)s*ldx + (fc<<2));
      ax += sc*v.x; ay += sc*v.y; az += sc*v.z; aw += sc*v.w;
    }
  } else {
    int e = rs;
    for (; e+1<re; e+=2){
      int s0 = csr[e], s1 = csr[e+1];
      const float4 v0 = *(const float4*)(x + (size_t)s0*ldx + (fc<<2));
      const float4 v1 = *(const float4*)(x + (size_t)s1*ldx + (fc<<2));
      ax += v0.x+v1.x; ay += v0.y+v1.y; az += v0.z+v1.z; aw += v0.w+v1.w;
    }
    if (e<re){
      int s0 = csr[e];
      const float4 v0 = *(const float4*)(x + (size_t)s0*ldx + (fc<<2));
      ax += v0.x; ay += v0.y; az += v0.z; aw += v0.w;
    }
  }
  half4_t hv, lv;
  hv.x = (_Float16)ax; lv.x = (_Float16)(ax - (float)hv.x);
  hv.y = (_Float16)ay; lv.y = (_Float16)(ay - (float)hv.y);
  hv.z = (_Float16)az; lv.z = (_Float16)(az - (float)hv.z);
  hv.w = (_Float16)aw; lv.w = (_Float16)(aw - (float)hv.w);
  size_t o = (size_t)node*F + (fc<<2);
  *(half4_t*)(oh + o) = hv;
  *(half4_t*)(ol + o) = lv;
}

// pack 4 GraphConv weights (fp32 [K][N]) into split-f16 hi/lo, k8-packed layout:
// element (k,n) -> plane[ ((k>>3)*N + n)*8 + (k&7) ]
__global__ void k_wpack4(const float* __restrict__ W0, const float* __restrict__ W1,
                         const float* __restrict__ W2, const float* __restrict__ W3,
                         _Float16* __restrict__ h0, _Float16* __restrict__ l0,
                         _Float16* __restrict__ h1, _Float16* __restrict__ l1,
                         _Float16* __restrict__ h2, _Float16* __restrict__ l2,
                         _Float16* __restrict__ h3, _Float16* __restrict__ l3){
  int w = blockIdx.y;
  const float* W = (w==0)?W0:(w==1)?W1:(w==2)?W2:W3;
  _Float16* oh = (w==0)?h0:(w==1)?h1:(w==2)?h2:h3;
  _Float16* ol = (w==0)?l0:(w==1)?l1:(w==2)?l2:l3;
  int K   = (w&1)? 256 : 128;
  int nsh = (w&1)? 9 : 8;
  int i = blockIdx.x*256 + threadIdx.x;
  if (i >= (K<<nsh)) return;
  int k = i >> nsh, n = i & ((1<<nsh)-1);
  float v = W[i];
  _Float16 h = (_Float16)v;
  _Float16 l = (_Float16)(v - (float)h);
  size_t p = (((size_t)(k>>3)<<nsh) + n)*8 + (k&7);
  oh[p] = h; ol[p] = l;
}

// ------- k_gconv_mfma: dual-side split-f16 MFMA GEMM (see round-0 notes).
__global__ __launch_bounds__(256)
void k_gconv_mfma(const _Float16* __restrict__ Ah0, const _Float16* __restrict__ Al0,
                  const _Float16* __restrict__ Ah1, const _Float16* __restrict__ Al1,
                  const _Float16* __restrict__ Bh0, const _Float16* __restrict__ Bl0,
                  const _Float16* __restrict__ Bh1, const _Float16* __restrict__ Bl1,
                  float* __restrict__ C0, float* __restrict__ C1, int ldc,
                  int M0, int M1, int N, int K,
                  const float* __restrict__ rs0, const float* __restrict__ rs1,
                  const float* __restrict__ bi0, const float* __restrict__ bi1, int relu,
                  const float* __restrict__ po0, const float* __restrict__ po1)
{
  __shared__ __align__(16) _Float16 As[2][4096];   // [kb(4)][m(128)][8]
  __shared__ __align__(16) _Float16 Bs[2][4096];   // [kb(4)][n(128)][8]

  const int gx = gridDim.x, gxy = gridDim.x*gridDim.y;
  const int nwg = gxy*2;
  int fid = blockIdx.x + gx*blockIdx.y + gxy*blockIdx.z;
  int q = nwg>>3, r = nwg&7;
  int xcd = fid & 7, idx = fid >> 3;
  int sid = (xcd<r ? xcd*(q+1) : r*(q+1)+(xcd-r)*q) + idx;
  const int z  = sid / gxy;  int rem = sid - z*gxy;
  const int by = rem / gx,  bx = rem - by*gx;

  const _Float16* Ah = z ? Ah1 : Ah0;
  const _Float16* Al = z ? Al1 : Al0;
  const _Float16* Bh = z ? Bh1 : Bh0;
  const _Float16* Bl = z ? Bl1 : Bl0;
  float*       C  = z ? C1 : C0;
  const float* rsc = z ? rs1 : rs0;
  const float* bia = z ? bi1 : bi0;
  const float* po  = z ? po1 : po0;
  const int M = z ? M1 : M0;

  const int row0 = by << 7;
  const int col0 = bx << 7;
  if (row0 >= ((M+127)&~127)) return;

  const int tid = threadIdx.x;
  const int am  = tid >> 2;
  const int akb = tid & 3;
  const int bn  = tid & 127;
  const int bkb = tid >> 7;
  const int wid = tid >> 6, lane = tid & 63;
  const int wr = wid >> 1, wc = wid & 1;
  const int lr = lane & 15, lg = lane >> 4;

  const size_t ldb8 = (size_t)N * 8;
  f32x4 acc[4][4] = {};

  const int kpt = K >> 5;     // K-steps per term
  const int nt  = 3 * kpt;    // total K-steps (hi*hi, lo*hi, hi*lo)

  half8 ga0, ga1, gb0, gb1;
  {
    const _Float16* Ap = Ah + (size_t)(row0 + am) * K + (akb<<3);
    ga0 = *(const half8*)(Ap);
    ga1 = *(const half8*)(Ap + (size_t)64 * K);
    const _Float16* Bp = Bh + (size_t)bkb * ldb8 + (size_t)(col0 + bn) * 8;
    gb0 = *(const half8*)(Bp);
    gb1 = *(const half8*)(Bp + 2*ldb8);
  }
  *(half8*)&As[0][(akb*128 + am)*8]        = ga0;
  *(half8*)&As[0][(akb*128 + am + 64)*8]   = ga1;
  *(half8*)&Bs[0][(bkb*128 + bn)*8]        = gb0;
  *(half8*)&Bs[0][((bkb+2)*128 + bn)*8]    = gb1;
  __syncthreads();

  int term = 0, kk = 32;    // coordinates of the NEXT tile (t+1)
  if (kk == K){ kk = 0; term = 1; }
  for (int t = 0; t < nt; ++t){
    const int cb = t & 1;
    if (t + 1 < nt){
      const _Float16* Asrc = (term == 1) ? Al : Ah;
      const _Float16* Bsrc = (term == 2) ? Bl : Bh;
      const _Float16* Ap = Asrc + (size_t)(row0 + am) * K + kk + (akb<<3);
      ga0 = *(const half8*)(Ap);
      ga1 = *(const half8*)(Ap + (size_t)64 * K);
      const _Float16* Bp = Bsrc + (size_t)((kk>>3) + bkb) * ldb8 + (size_t)(col0 + bn) * 8;
      gb0 = *(const half8*)(Bp);
      gb1 = *(const half8*)(Bp + 2*ldb8);
      kk += 32; if (kk == K){ kk = 0; ++term; }
    }
    {
      const _Float16* Abase = &As[cb][((lg<<7) + (wr<<6) + lr)<<3];
      const _Float16* Bbase = &Bs[cb][((lg<<7) + (wc<<6) + lr)<<3];
      half8 af[4], bf[4];
      #pragma unroll
      for (int i=0;i<4;++i){
        af[i] = *(const half8*)(Abase + i*128);
        bf[i] = *(const half8*)(Bbase + i*128);
      }
      #pragma unroll
      for (int mi=0; mi<4; ++mi){
        #pragma unroll
        for (int ni=0; ni<4; ++ni){
          acc[mi][ni] = __builtin_amdgcn_mfma_f32_16x16x32_f16(af[mi], bf[ni], acc[mi][ni], 0, 0, 0);
        }
      }
    }
    if (t + 1 < nt){
      const int nb_ = cb ^ 1;
      *(half8*)&As[nb_][(akb*128 + am)*8]      = ga0;
      *(half8*)&As[nb_][(akb*128 + am + 64)*8] = ga1;
      *(half8*)&Bs[nb_][(bkb*128 + bn)*8]      = gb0;
      *(half8*)&Bs[nb_][((bkb+2)*128 + bn)*8]  = gb1;
    }
    __syncthreads();
  }

  // epilogue: D row = row0 + wr*64 + mi*16 + lg*4 + j ; col = col0 + wc*64 + ni*16 + lr
  #pragma unroll
  for (int ni = 0; ni < 4; ++ni){
    int cc = col0 + (wc<<6) + (ni<<4) + lr;
    float bv = bia ? bia[cc] : 0.f;
    #pragma unroll
    for (int mi = 0; mi < 4; ++mi){
      int rbase = row0 + (wr<<6) + (mi<<4) + (lg<<2);
      #pragma unroll
      for (int j = 0; j < 4; ++j){
        int rr = rbase + j;
        if (rr < M){
          float rs_ = rsc ? rsc[rr] : 1.f;
          float v = acc[mi][ni][j]*rs_ + bv;
          if (relu) v = fmaxf(v, 0.f);
          if (po) v *= po[rr];
          C[(size_t)rr*ldc + cc] = v;
        }
      }
    }
  }
}

// ------- k_pack: repack sf/vf[:, 0:512) into per-graph 32-aligned node-packed
// split-f16 planes: elem(node j, feat f) -> plane[(j>>3)*4096 + f*8 + (j&7)],
// node index = pb[g] + local; padding nodes written as ZERO.
__global__ __launch_bounds__(256)
void k_pack(const float* __restrict__ sf, const float* __restrict__ vf,
            const int* __restrict__ go1, const int* __restrict__ go2,
            const int* __restrict__ pb1, const int* __restrict__ pb2,
            const int* __restrict__ gm1, const int* __restrict__ gm2,
            _Float16* __restrict__ p1h, _Float16* __restrict__ p1l,
            _Float16* __restrict__ p2h, _Float16* __restrict__ p2l, int B)
{
  __shared__ float st[32][516];
  const int side = blockIdx.y;
  const float* x = side ? vf : sf;
  const int* go = side ? go2 : go1;
  const int* pb = side ? pb2 : pb1;
  const int* gm = side ? gm2 : gm1;
  _Float16* ph = side ? p2h : p1h;
  _Float16* pl = side ? p2l : p1l;
  const int u = blockIdx.x;
  if (u*32 >= pb[B]) return;
  const int g = gm[u];
  const int j0 = u*32 - pb[g];
  const int base = go[g];
  int cnt = go[g+1]-base; if (cnt>128) cnt=128;
  const int t = threadIdx.x;
  const int r = t>>3, f0 = (t&7)<<2;
  const bool valid = (j0 + r) < cnt;
  const float* src = x + (size_t)(base + j0 + r)*1024;
  #pragma unroll
  for (int q=0;q<16;++q){
    int f = f0 + (q<<5);
    float4 vv;
    if (valid) vv = *(const float4*)(src + f);
    else { vv.x=0.f; vv.y=0.f; vv.z=0.f; vv.w=0.f; }
    *(float4*)&st[r][f] = vv;
  }
  __syncthreads();
  #pragma unroll
  for (int q=0;q<8;++q){
    int u2 = t + (q<<8);
    int jg = u2>>9, f = u2&511;
    half8 h8, l8;
    #pragma unroll
    for (int e=0;e<8;++e){
      float vvv = st[(jg<<3)+e][f];
      _Float16 hh = (_Float16)vvv;
      h8[e]=hh; l8[e]=(_Float16)(vvv-(float)hh);
    }
    size_t a = ((size_t)((u<<2)+jg)<<12) + ((size_t)f<<3);
    *(half8*)(ph + a) = h8;
    *(half8*)(pl + a) = l8;
  }
}

// ------- k_T: per (side, graph, 64x64-quadrant) MFMA tanh-interaction tile.
// side 0: T0 = tanh(s.v^T); side 1: T1 = tanh(v.s^T) = T0^T (computed directly,
// so both sides get a row-major T for k_apply). Output split-f16 hi/lo,
// [side*B+g][128][128], masked to zero outside (cR,cO) -> downstream reads safe.
__global__ __launch_bounds__(256)
void k_T(const float* __restrict__ sf, const float* __restrict__ vf,
         const int* __restrict__ go1, const int* __restrict__ go2,
         _Float16* __restrict__ Th, _Float16* __restrict__ Tl)
{
  const int side = blockIdx.x, g = blockIdx.y, quad = blockIdx.z;
  const int qr = quad>>1, qc = quad&1;
  const float* own = side ? vf : sf;
  const float* oth = side ? sf : vf;
  const int* goR = side ? go2 : go1;
  const int* goO = side ? go1 : go2;
  int gR = goR[g]; int cR = goR[g+1]-gR; if (cR>128) cR=128;
  int gO = goO[g]; int cO = goO[g+1]-gO; if (cO>128) cO=128;
  const int r0q = qr<<6, c0q = qc<<6;
  if (r0q >= ((cR+63)&~63) || c0q >= ((cO+63)&~63)) return;
  const int tid = threadIdx.x, w = tid>>6, lane = tid&63;
  const int lr = lane&15, lg = lane>>4;
  const int rr = r0q + (w<<4) + lr;
  f32x4 acc[4];
  #pragma unroll
  for (int c=0;c<4;++c) acc[c]=(f32x4){0.f,0.f,0.f,0.f};
  const float* Arow = own + (size_t)(gR + rr)*1024 + (lg<<3);
  for (int k0=0;k0<512;k0+=32){
    half8 ah, al;
    split8(*(const float4*)(Arow + k0), *(const float4*)(Arow + k0 + 4), ah, al);
    #pragma unroll
    for (int cj=0;cj<4;++cj){
      const float* Brow = oth + (size_t)(gO + c0q + (cj<<4) + lr)*1024 + k0 + (lg<<3);
      half8 bh, bl;
      split8(*(const float4*)(Brow), *(const float4*)(Brow+4), bh, bl);
      acc[cj] = MF(ah, bh, acc[cj]);
      acc[cj] = MF(al, bh, acc[cj]);
      acc[cj] = MF(ah, bl, acc[cj]);
    }
  }
  _Float16* Tph = Th + ((size_t)(side*gridDim.y + g)<<14);
  _Float16* Tpl = Tl + ((size_t)(side*gridDim.y + g)<<14);
  #pragma unroll
  for (int cj=0;cj<4;++cj){
    int c = c0q + (cj<<4) + lr;
    #pragma unroll
    for (int qq=0;qq<4;++qq){
      int r = r0q + (w<<4) + (lg<<2) + qq;
      float t = (r<cR && c<cO) ? ftanh(acc[cj][qq]) : 0.f;
      _Float16 hh = (_Float16)t;
      Tph[(r<<7) + c] = hh;
      Tpl[(r<<7) + c] = (_Float16)(t - (float)hh);
    }
  }
}

// ------- k_apply: own'[r][f] = sum_o T[r][o]*oth[o][f] via MFMA.
// A-frag: row-major T (half8 contiguous). B-frag: node-packed oth plane
// (8 consecutive nodes contiguous at fixed feat). grid (2 sides, B, 2 feat halves).
__global__ __launch_bounds__(256)
void k_apply(const _Float16* __restrict__ Th, const _Float16* __restrict__ Tl,
             const _Float16* __restrict__ p1h, const _Float16* __restrict__ p1l,
             const _Float16* __restrict__ p2h, const _Float16* __restrict__ p2l,
             const int* __restrict__ go1, const int* __restrict__ go2,
             const int* __restrict__ pb1, const int* __restrict__ pb2,
             float* __restrict__ sf, float* __restrict__ vf, int B)
{
  const int side = blockIdx.x, g = blockIdx.y, ft = blockIdx.z;
  const int* goR = side ? go2 : go1;
  const int* goO = side ? go1 : go2;
  const int* pbO = side ? pb1 : pb2;
  const _Float16* oph = side ? p1h : p2h;
  const _Float16* opl = side ? p1l : p2l;
  float* outp = side ? vf : sf;
  int gR = goR[g]; int cR = goR[g+1]-gR; if (cR>128) cR=128;
  int gO = goO[g]; int cO = goO[g+1]-gO; if (cO>128) cO=128;
  if (cR <= 0) return;
  const int pO = pbO[g];
  const int cO32 = (cO+31)&~31;
  const int MR = ((cR+15)&~15)>>4;     // 1..8 row tiles (all within written T rows)
  const _Float16* Tph = Th + ((size_t)(side*B + g)<<14);
  const _Float16* Tpl = Tl + ((size_t)(side*B + g)<<14);
  const int tid = threadIdx.x, w = tid>>6, lane = tid&63;
  const int lr = lane&15, lg = lane>>4;
  const int f0 = (ft<<8) + (w<<6);     // 64 feats per wave
  for (int rc = 0; rc < MR; rc += 4){
    f32x4 acc[4][4];
    #pragma unroll
    for (int a_=0;a_<4;++a_)
      #pragma unroll
      for (int b_=0;b_<4;++b_) acc[a_][b_] = (f32x4){0.f,0.f,0.f,0.f};
    for (int k0=0; k0<cO32; k0+=32){
      half8 bh[4], bl[4];
      #pragma unroll
      for (int nj=0;nj<4;++nj){
        size_t a = ((size_t)((pO + k0)>>3) + lg)*4096 + (size_t)(f0 + (nj<<4) + lr)*8;
        bh[nj] = *(const half8*)(oph + a);
        bl[nj] = *(const half8*)(opl + a);
      }
      #pragma unroll
      for (int mi=0;mi<4;++mi){
        if (rc + mi < MR){
          int a = ((((rc+mi)<<4) + lr)<<7) + k0 + (lg<<3);
          half8 th_ = *(const half8*)&Tph[a];
          half8 tl_ = *(const half8*)&Tpl[a];
          #pragma unroll
          for (int nj=0;nj<4;++nj){
            acc[mi][nj] = MF(th_, bh[nj], acc[mi][nj]);
            acc[mi][nj] = MF(tl_, bh[nj], acc[mi][nj]);
            acc[mi][nj] = MF(th_, bl[nj], acc[mi][nj]);
          }
        }
      }
    }
    #pragma unroll
    for (int mi=0;mi<4;++mi){
      if (rc + mi < MR){
        #pragma unroll
        for (int nj=0;nj<4;++nj){
          #pragma unroll
          for (int qq=0;qq<4;++qq){
            int r = (((rc+mi)<<4)) + (lg<<2) + qq;
            if (r < cR)
              outp[(size_t)(gR + r)*1024 + 512 + f0 + (nj<<4) + lr] = acc[mi][nj][qq];
          }
        }
      }
    }
  }
}

// ------- k_gemmsk: skinny NT GEMM, M=128 x 64-col tile, dbuf LDS, split-K,
// optional dual-side via blockIdx.y. Partials P[(side*splits+z)][M][N].
__global__ __launch_bounds__(256)
void k_gemmsk(const float* __restrict__ Ab, size_t AsideOff, int lda,
              const float* __restrict__ Bm, int ldb,
              float* __restrict__ P, int M, int N, int kchunk)
{
  __shared__ float As[2][16][132];
  __shared__ float Bs[2][16][68];
  const int tid = threadIdx.x;
  const int col0 = (int)blockIdx.x << 6;
  const int kbeg = (int)blockIdx.z * kchunk;
  const float* A = Ab + (size_t)blockIdx.y * AsideOff;
  const int ar = tid >> 1, ak = (tid & 1) << 3;
  const int br = tid >> 2, bk = (tid & 3) << 2;
  const int tx = tid & 15, ty = tid >> 4;
  const float* Arow = A + (size_t)ar * lda + kbeg + ak;
  const float* Brow = Bm + (size_t)(col0 + br) * ldb + kbeg + bk;
  float acc[8][4] = {};
  float4 a0 = *(const float4*)(Arow);
  float4 a1 = *(const float4*)(Arow + 4);
  float4 b0 = *(const float4*)(Brow);
  As[0][ak+0][ar]=a0.x; As[0][ak+1][ar]=a0.y; As[0][ak+2][ar]=a0.z; As[0][ak+3][ar]=a0.w;
  As[0][ak+4][ar]=a1.x; As[0][ak+5][ar]=a1.y; As[0][ak+6][ar]=a1.z; As[0][ak+7][ar]=a1.w;
  Bs[0][bk+0][br]=b0.x; Bs[0][bk+1][br]=b0.y; Bs[0][bk+2][br]=b0.z; Bs[0][bk+3][br]=b0.w;
  __syncthreads();
  const int nt = kchunk >> 4;
  for (int t = 0; t < nt; ++t){
    const int cb = t & 1;
    if (t + 1 < nt){
      int k0 = (t + 1) << 4;
      a0 = *(const float4*)(Arow + k0);
      a1 = *(const float4*)(Arow + k0 + 4);
      b0 = *(const float4*)(Brow + k0);
    }
    #pragma unroll
    for (int kk = 0; kk < 16; ++kk){
      float4 b4 = *(const float4*)&Bs[cb][kk][tx << 2];
      float4 a4 = *(const float4*)&As[cb][kk][ty << 3];
      float4 a5 = *(const float4*)&As[cb][kk][(ty << 3) + 4];
      acc[0][0]+=a4.x*b4.x; acc[0][1]+=a4.x*b4.y; acc[0][2]+=a4.x*b4.z; acc[0][3]+=a4.x*b4.w;
      acc[1][0]+=a4.y*b4.x; acc[1][1]+=a4.y*b4.y; acc[1][2]+=a4.y*b4.z; acc[1][3]+=a4.y*b4.w;
      acc[2][0]+=a4.z*b4.x; acc[2][1]+=a4.z*b4.y; acc[2][2]+=a4.z*b4.z; acc[2][3]+=a4.z*b4.w;
      acc[3][0]+=a4.w*b4.x; acc[3][1]+=a4.w*b4.y; acc[3][2]+=a4.w*b4.z; acc[3][3]+=a4.w*b4.w;
      acc[4][0]+=a5.x*b4.x; acc[4][1]+=a5.x*b4.y; acc[4][2]+=a5.x*b4.z; acc[4][3]+=a5.x*b4.w;
      acc[5][0]+=a5.y*b4.x; acc[5][1]+=a5.y*b4.y; acc[5][2]+=a5.y*b4.z; acc[5][3]+=a5.y*b4.w;
      acc[6][0]+=a5.z*b4.x; acc[6][1]+=a5.z*b4.y; acc[6][2]+=a5.z*b4.z; acc[6][3]+=a5.z*b4.w;
      acc[7][0]+=a5.w*b4.x; acc[7][1]+=a5.w*b4.y; acc[7][2]+=a5.w*b4.z; acc[7][3]+=a5.w*b4.w;
    }
    if (t + 1 < nt){
      const int nb = cb ^ 1;
      As[nb][ak+0][ar]=a0.x; As[nb][ak+1][ar]=a0.y; As[nb][ak+2][ar]=a0.z; As[nb][ak+3][ar]=a0.w;
      As[nb][ak+4][ar]=a1.x; As[nb][ak+5][ar]=a1.y; As[nb][ak+6][ar]=a1.z; As[nb][ak+7][ar]=a1.w;
      Bs[nb][bk+0][br]=b0.x; Bs[nb][bk+1][br]=b0.y; Bs[nb][bk+2][br]=b0.z; Bs[nb][bk+3][br]=b0.w;
    }
    __syncthreads();
  }
  float* Pz = P + (size_t)(blockIdx.y*gridDim.z + blockIdx.z) * M * N;
  #pragma unroll
  for (int i = 0; i < 8; ++i){
    int rr = (ty << 3) + i;
    float4 v = {acc[i][0], acc[i][1], acc[i][2], acc[i][3]};
    *(float4*)(Pz + (size_t)rr*N + col0 + (tx<<2)) = v;
  }
}

// sum split partials + bias (+relu)
__global__ void k_red_bias(const float* __restrict__ P, int split, int MN, int N,
                           const float* __restrict__ bias, float* __restrict__ C, int relu){
  int i = blockIdx.x*256 + threadIdx.x;
  if (i >= MN) return;
  float v = bias[i & (N-1)];
  for (int s=0;s<split;++s) v += P[(size_t)s*MN + i];
  if (relu) v = fmaxf(v, 0.f);
  C[i] = v;
}

// ---------------- Set2Set ----------------
__global__ void k_lstm1(const float* __restrict__ bih, const float* __restrict__ bhh,
                        float* __restrict__ c1, float* __restrict__ h1){
  int j = blockIdx.x*256 + threadIdx.x;
  if (j >= 1024) return;
  float gi = bih[j]        + bhh[j];
  float gg = bih[j+2048]   + bhh[j+2048];
  float go = bih[j+3072]   + bhh[j+3072];
  float cc = fsigm(gi)*ftanh(gg);
  c1[j] = cc;
  h1[j] = fsigm(go)*ftanh(cc);
}

__global__ void k_gemv_u(const float* __restrict__ Wih, const float* __restrict__ Whh,
                         const float* __restrict__ bih, const float* __restrict__ bhh,
                         const float* __restrict__ h1, float* __restrict__ u){
  int w = (blockIdx.x*256 + threadIdx.x)>>6;
  int lane = threadIdx.x & 63;
  if (w >= 4096) return;
  const float* wi = Wih + (size_t)w*2048;
  const float* wh = Whh + (size_t)w*1024;
  float acc = 0.f;
  #pragma unroll
  for (int qq=0;qq<4;++qq){
    int o = qq*256 + (lane<<2);
    float4 hv = *(const float4*)(h1 + o);
    float4 a  = *(const float4*)(wi + o);
    float4 b  = *(const float4*)(wh + o);
    acc += hv.x*(a.x+b.x) + hv.y*(a.y+b.y) + hv.z*(a.z+b.z) + hv.w*(a.w+b.w);
  }
  acc = wredsum(acc);
  if (lane==0) u[w] = acc + bih[w] + bhh[w];
}

// fused attention, dual-side (blockIdx.y): online segment softmax + weighted sum
__global__ __launch_bounds__(256)
void k_attn(const float* __restrict__ sf, const float* __restrict__ vf,
            const int* __restrict__ go1, const int* __restrict__ go2,
            const float* __restrict__ hbase, size_t hSideOff, int hstride,
            float* __restrict__ outbase, size_t oSideOff, int ldout)
{
  __shared__ float hs[1024];
  __shared__ float ech[1024];
  __shared__ float red[8];
  int side = blockIdx.y;
  const float* x = side? vf : sf;
  const int* goff = side? go2 : go1;
  const float* hsrc = hbase + (size_t)side*hSideOff;
  float* outp = outbase + (size_t)side*oSideOff;
  int b = blockIdx.x, t = threadIdx.x;
  int i0 = goff[b], i1 = goff[b+1];
  int lane = t & 63, wv = t >> 6;
  { float4 hv = *(const float4*)(hsrc + (size_t)b*hstride + (t<<2));
    *(float4*)&hs[t<<2] = hv; }
  __syncthreads();
  float m = -3.0e38f, s = 0.f;
  float ax=0, ay=0, az=0, aw=0;
  for (int c = i0; c < i1; c += 1024){
    int ce = c + 1024; if (ce > i1) ce = i1;
    int n = ce - c;
    float wmax = -3.0e38f;
    for (int i = c + wv; i < ce; i += 4){
      const float* xr = x + (size_t)i*1024;
      float d = 0.f;
      #pragma unroll
      for (int qq=0;qq<4;++qq){
        int o = qq*256 + (lane<<2);
        float4 xv = *(const float4*)(xr+o);
        float4 h4 = *(const float4*)&hs[o];
        d += xv.x*h4.x + xv.y*h4.y + xv.z*h4.z + xv.w*h4.w;
      }
      d = wredsum(d);
      if (lane==0) ech[i-c] = d;
      wmax = fmaxf(wmax, d);
    }
    if (lane==0) red[wv] = wmax;
    __syncthreads();
    float cm = fmaxf(fmaxf(red[0],red[1]), fmaxf(red[2],red[3]));
    float nm = fmaxf(m, cm);
    float scale = __expf(m - nm);
    s *= scale; ax*=scale; ay*=scale; az*=scale; aw*=scale;
    float ps = 0.f;
    for (int k = t; k < n; k += 256) ps += __expf(ech[k]-nm);
    ps = wredsum(ps);
    __syncthreads();
    if (lane==0) red[wv] = ps;
    __syncthreads();
    s += red[0]+red[1]+red[2]+red[3];
    for (int k = 0; k < n; ++k){
      float w = __expf(ech[k]-nm);
      float4 xv = *(const float4*)(x + (size_t)(c+k)*1024 + (t<<2));
      ax += w*xv.x; ay += w*xv.y; az += w*xv.z; aw += w*xv.w;
    }
    m = nm;
    __syncthreads();
  }
  float inv = (i1>i0 && s>0.f) ? 1.f/s : 0.f;
  float4 o = {ax*inv, ay*inv, az*inv, aw*inv};
  *(float4*)(outp + (size_t)b*ldout + (t<<2)) = o;
}

// LSTM iter2 (dual-side via blockIdx.y): sum split gate partials + u, cell/hidden
__global__ void k_lstm2_red(const float* __restrict__ Pb, size_t PsideOff, int split,
                            const float* __restrict__ u, const float* __restrict__ c1,
                            float* __restrict__ z, int B){
  int idx = blockIdx.x*256 + threadIdx.x;
  if (idx >= B*1024) return;
  int side = blockIdx.y;
  const float* P = Pb + (size_t)side*PsideOff;
  int b = idx >> 10, j = idx & 1023;
  float gi=u[j], gf=u[j+1024], gg=u[j+2048], go=u[j+3072];
  const float* g = P + (size_t)b*4096;
  for (int s=0;s<split;++s){
    const float* gs = g + (size_t)s*B*4096;
    gi += gs[j]; gf += gs[j+1024]; gg += gs[j+2048]; go += gs[j+3072];
  }
  float cc = fsigm(gf)*c1[j] + fsigm(gi)*ftanh(gg);
  z[(size_t)b*4096 + side*2048 + j] = fsigm(go)*ftanh(cc);
}

__global__ void k_fc3(const float* __restrict__ z2, const float* __restrict__ w3,
                      const float* __restrict__ b3, float* __restrict__ out, int B){
  int wv = (blockIdx.x*256+threadIdx.x)>>6;
  int lane = threadIdx.x & 63;
  if (wv >= B) return;
  const float* zr = z2 + (size_t)wv*512;
  float acc=0.f;
  #pragma unroll
  for (int qq=0;qq<2;++qq){
    int o = qq*256 + (lane<<2);
    float4 a  = *(const float4*)(zr + o);
    float4 ww = *(const float4*)(w3 + o);
    acc += a.x*ww.x + a.y*ww.y + a.z*ww.z + a.w*ww.w;
  }
  acc = wredsum(acc);
  if (lane==0) out[wv] = acc + b3[0];
}

// ---------------- driver ----------------
extern "C" void kernel_launch(void* const* d_in, const int* in_sizes, int n_in,
                              void* d_out, int out_size, void* d_ws, size_t ws_size,
                              hipStream_t stream)
{
  const float* x1  = (const float*)d_in[0];
  const float* x2  = (const float*)d_in[1];
  const int* src1  = (const int*)d_in[2];
  const int* dst1  = (const int*)d_in[3];
  const int* src2  = (const int*)d_in[4];
  const int* dst2  = (const int*)d_in[5];
  const int* gid1  = (const int*)d_in[6];
  const int* gid2  = (const int*)d_in[7];
  const float* Wg1 = (const float*)d_in[8];  const float* bg1 = (const float*)d_in[9];
  const float* Wg2 = (const float*)d_in[10]; const float* bg2 = (const float*)d_in[11];
  const float* Wg3 = (const float*)d_in[12]; const float* bg3 = (const float*)d_in[13];
  const float* Wg4 = (const float*)d_in[14]; const float* bg4 = (const float*)d_in[15];
  const float* Wih = (const float*)d_in[16]; const float* Whh = (const float*)d_in[17];
  const float* bih = (const float*)d_in[18]; const float* bhh = (const float*)d_in[19];
  const float* Wf1 = (const float*)d_in[20]; const float* bf1 = (const float*)d_in[21];
  const float* Wf2 = (const float*)d_in[22]; const float* bf2 = (const float*)d_in[23];
  const float* Wf3 = (const float*)d_in[24]; const float* bf3 = (const float*)d_in[25];
  float* out = (float*)d_out;

  const int N1 = in_sizes[0]/128;
  const int N2 = in_sizes[1]/128;
  const int E1 = in_sizes[2];
  const int E2 = in_sizes[4];
  const int B  = out_size;            // 128
  const int NM = N1>N2?N1:N2;

  char* base = (char*)d_ws; size_t off=0;
  auto alloc = [&](size_t bytes)->void*{ void* p = base+off; off += (bytes+255)&~(size_t)255; return p; };

  int* zr   = (int*)alloc(sizeof(int)*(size_t)(3*N1+3*N2));
  int* co1=zr, *ci1=zr+N1, *cur1=zr+2*N1;
  int* co2=zr+3*N1, *ci2=zr+3*N1+N2, *cur2=zr+3*N1+2*N2;
  int* row1 = (int*)alloc(sizeof(int)*(size_t)(N1+1));
  int* row2 = (int*)alloc(sizeof(int)*(size_t)(N2+1));
  int* csr1 = (int*)alloc(sizeof(int)*(size_t)E1);
  int* csr2 = (int*)alloc(sizeof(int)*(size_t)E2);
  int* go1  = (int*)alloc(sizeof(int)*(size_t)(B+1));
  int* go2  = (int*)alloc(sizeof(int)*(size_t)(B+1));
  int* pb1  = (int*)alloc(sizeof(int)*(size_t)(B+1));
  int* pb2  = (int*)alloc(sizeof(int)*(size_t)(B+1));
  int* gm1  = (int*)alloc(sizeof(int)*1024);
  int* gm2  = (int*)alloc(sizeof(int)*1024);
  float* os1 = (float*)alloc(sizeof(float)*(size_t)N1);
  float* is1 = (float*)alloc(sizeof(float)*(size_t)N1);
  float* os2 = (float*)alloc(sizeof(float)*(size_t)N2);
  float* is2 = (float*)alloc(sizeof(float)*(size_t)N2);
  _Float16* a1h = (_Float16*)alloc(sizeof(_Float16)*(size_t)(NM+128)*256);
  _Float16* a1l = (_Float16*)alloc(sizeof(_Float16)*(size_t)(NM+128)*256);
  _Float16* a2h = (_Float16*)alloc(sizeof(_Float16)*(size_t)(NM+128)*256);
  _Float16* a2l = (_Float16*)alloc(sizeof(_Float16)*(size_t)(NM+128)*256);
  _Float16* wg1h = (_Float16*)alloc(sizeof(_Float16)*32768);
  _Float16* wg1l = (_Float16*)alloc(sizeof(_Float16)*32768);
  _Float16* wg2h = (_Float16*)alloc(sizeof(_Float16)*131072);
  _Float16* wg2l = (_Float16*)alloc(sizeof(_Float16)*131072);
  _Float16* wg3h = (_Float16*)alloc(sizeof(_Float16)*32768);
  _Float16* wg3l = (_Float16*)alloc(sizeof(_Float16)*32768);
  _Float16* wg4h = (_Float16*)alloc(sizeof(_Float16)*131072);
  _Float16* wg4l = (_Float16*)alloc(sizeof(_Float16)*131072);
  float* sf  = (float*)alloc(sizeof(float)*(size_t)(N1+128)*1024);
  float* vf  = (float*)alloc(sizeof(float)*(size_t)(N2+128)*1024);
  float* h1 = (float*)alloc(sizeof(float)*1024);
  float* c1 = (float*)alloc(sizeof(float)*1024);
  float* u  = (float*)alloc(sizeof(float)*4096);
  float* r1 = (float*)alloc(sizeof(float)*(size_t)2*B*1024);
  float* z1 = (float*)alloc(sizeof(float)*(size_t)B*1024);
  float* z2 = (float*)alloc(sizeof(float)*(size_t)B*512);
  float* z  = (float*)alloc(sizeof(float)*(size_t)B*4096);
  // T planes: [2 sides][B][128][128] split-f16 (16.8 MB total)
  _Float16* Tqh = (_Float16*)alloc(sizeof(_Float16)*(size_t)2*B*16384);
  _Float16* Tql = (_Float16*)alloc(sizeof(_Float16)*(size_t)2*B*16384);
  // union region: node-packed split-f16 planes (interact stage) / Pbuf partials (later stages)
  const int PN = ((NM + 32*B + 63)&~63) + 64;      // padded node capacity
  const size_t PE = (size_t)PN*512;                // elems per plane
  size_t packedBytes = 4*PE*sizeof(_Float16);
  size_t pbufBytes   = sizeof(float)*(size_t)16*B*1024*4;
  char* uni = (char*)alloc(packedBytes > pbufBytes ? packedBytes : pbufBytes);
  _Float16* p1h = (_Float16*)uni;
  _Float16* p1l = p1h + PE;
  _Float16* p2h = p1l + PE;
  _Float16* p2l = p2h + PE;
  float* Pbuf = (float*)uni;
  if (off > ws_size) return;

  // hbuf regions live inside sf/vf cols [512,768) (stride 1024), overwritten later by apply
  float* hb1 = sf + 512;
  float* hb2 = vf + 512;

  dim3 blk(256);

  // --- weight split-f16 pack (independent of graph prep) ---
  k_wpack4<<<dim3(512,4),blk,0,stream>>>(Wg1,Wg2,Wg3,Wg4,
                                         wg1h,wg1l, wg2h,wg2l, wg3h,wg3l, wg4h,wg4l);

  // --- prep ---
  k_zero_i32<<<(3*N1+3*N2+255)/256, blk, 0, stream>>>(zr, 3*N1+3*N2);
  k_hist2<<<(E1+E2+255)/256, blk, 0, stream>>>(src1,dst1,E1,co1,ci1, src2,dst2,E2,co2,ci2);
  k_scan2<<<2,1024,0,stream>>>(ci1,N1,row1, ci2,N2,row2);
  k_scale2<<<(N1+N2+255)/256,blk,0,stream>>>(co1,ci1,N1,os1,is1, co2,ci2,N2,os2,is2);
  k_scatter2<<<(E1+E2+255)/256,blk,0,stream>>>(src1,dst1,E1,row1,cur1,csr1, src2,dst2,E2,row2,cur2,csr2);
  k_goff2<<<1,512,0,stream>>>(gid1,N1,go1, gid2,N2,go2, B, pb1,gm1, pb2,gm2);

  // --- GraphConv: agg both sides (split-f16 out), dual MFMA GEMM L1 (post=os),
  //     agg (no scale), dual MFMA GEMM L2 ---
  int gy = (NM+127)/128;
  k_agg_h<<<(N1+7)/8,blk,0,stream>>>(x1,128, os1,row1,csr1, a1h,a1l, N1,5);
  k_agg_h<<<(N2+7)/8,blk,0,stream>>>(x2,128, os2,row2,csr2, a2h,a2l, N2,5);
  k_gconv_mfma<<<dim3(2,gy,2),blk,0,stream>>>(a1h,a1l, a2h,a2l,
                                              wg1h,wg1l, wg3h,wg3l,
                                              hb1,hb2,1024, N1,N2, 256,128,
                                              is1,is2, bg1,bg3, 1, os1,os2);
  k_agg_h<<<(N1+3)/4,blk,0,stream>>>(hb1,1024, nullptr,row1,csr1, a1h,a1l, N1,6);
  k_agg_h<<<(N2+3)/4,blk,0,stream>>>(hb2,1024, nullptr,row2,csr2, a2h,a2l, N2,6);
  k_gconv_mfma<<<dim3(4,gy,2),blk,0,stream>>>(a1h,a1l, a2h,a2l,
                                              wg2h,wg2l, wg4h,wg4l,
                                              sf,vf,1024, N1,N2, 512,256,
                                              is1,is2, bg2,bg4, 0, nullptr,nullptr);

  // --- block-diagonal interaction (MFMA, parallel quadrant/feature-sliced) ---
  const int GMAX = NM/32 + B + 2;
  k_pack<<<dim3(GMAX,2),blk,0,stream>>>(sf,vf, go1,go2, pb1,pb2, gm1,gm2,
                                        p1h,p1l, p2h,p2l, B);
  k_T<<<dim3(2,B,4),blk,0,stream>>>(sf,vf, go1,go2, Tqh,Tql);
  k_apply<<<dim3(2,B,2),blk,0,stream>>>(Tqh,Tql, p1h,p1l, p2h,p2l,
                                        go1,go2, pb1,pb2, sf,vf, B);

  // --- Set2Set (sides merged per stage) ---
  k_lstm1<<<4,blk,0,stream>>>(bih,bhh,c1,h1);
  k_gemv_u<<<1024,blk,0,stream>>>(Wih,Whh,bih,bhh,h1,u);

  // iter1 attention (shared h1), both sides
  k_attn<<<dim3(B,2),blk,0,stream>>>(sf,vf,go1,go2, h1,0,0, r1,(size_t)B*1024,1024);
  // gates = r1 @ Wih[:,1024:].T, both sides, split-K 4 x chunk 256
  k_gemmsk<<<dim3(64,2,4),blk,0,stream>>>(r1,(size_t)B*1024,1024, Wih+1024,2048, Pbuf, 128,4096,256);
  k_lstm2_red<<<dim3((B*1024+255)/256,2),blk,0,stream>>>(Pbuf,(size_t)4*B*4096,4, u,c1, z,B);
  // iter2 attention with per-graph h2 (in z), both sides
  k_attn<<<dim3(B,2),blk,0,stream>>>(sf,vf,go1,go2, z,2048,4096, z+1024,2048,4096);

  // --- MLP head ---
  k_gemmsk<<<dim3(16,1,16),blk,0,stream>>>(z,0,4096, Wf1,4096, Pbuf, 128,1024,256);
  k_red_bias<<<(B*1024+255)/256,blk,0,stream>>>(Pbuf,16,B*1024,1024,bf1,z1,1);
  k_gemmsk<<<dim3(8,1,8),blk,0,stream>>>(z1,0,1024, Wf2,1024, Pbuf, 128,512,128);
  k_red_bias<<<(B*512+255)/256,blk,0,stream>>>(Pbuf,8,B*512,512,bf2,z2,1);
  k_fc3<<<(B*64+255)/256,blk,0,stream>>>(z2,Wf3,bf3,out,B);
}

// Round 4
// 418.329 us; speedup vs baseline: 1.1217x; 1.1217x over previous
//
#include <hip/hip_runtime.h>

#define DEV __device__ __forceinline__

typedef _Float16 half8 __attribute__((ext_vector_type(8)));
typedef _Float16 half4_t __attribute__((ext_vector_type(4)));
typedef float f32x4 __attribute__((ext_vector_type(4)));

DEV float ftanh(float x){
  float ax = fabsf(x);
  float e = __expf(-2.f*ax);
  float t = (1.f - e)/(1.f + e);
  return x < 0.f ? -t : t;
}
DEV float fsigm(float x){ return 1.f/(1.f + expf(-x)); }
DEV float wredsum(float v){
  #pragma unroll
  for (int o=32;o;o>>=1) v += __shfl_xor(v,o,64);
  return v;
}
DEV f32x4 MF(half8 a, half8 b, f32x4 c){
  return __builtin_amdgcn_mfma_f32_16x16x32_f16(a,b,c,0,0,0);
}
DEV void split8(float4 a0, float4 a1, half8& h, half8& l){
  float f[8] = {a0.x,a0.y,a0.z,a0.w,a1.x,a1.y,a1.z,a1.w};
  #pragma unroll
  for (int e=0;e<8;++e){
    _Float16 hh = (_Float16)f[e];
    h[e] = hh;
    l[e] = (_Float16)(f[e] - (float)hh);
  }
}

// ---------------- graph prep ----------------
__global__ void k_zero_i32(int* __restrict__ p, int n){
  int i = blockIdx.x*256 + threadIdx.x; if (i<n) p[i]=0;
}

__global__ void k_hist2(const int* __restrict__ s1, const int* __restrict__ d1, int E1,
                        int* __restrict__ co1, int* __restrict__ ci1,
                        const int* __restrict__ s2, const int* __restrict__ d2, int E2,
                        int* __restrict__ co2, int* __restrict__ ci2){
  int e = blockIdx.x*256 + threadIdx.x;
  if (e < E1){ atomicAdd(&co1[s1[e]],1); atomicAdd(&ci1[d1[e]],1); }
  int f = e - E1;
  if (f >= 0 && f < E2){ atomicAdd(&co2[s2[f]],1); atomicAdd(&ci2[d2[f]],1); }
}

__global__ void k_scan2(const int* __restrict__ c1, int n1, int* __restrict__ r1,
                        const int* __restrict__ c2, int n2, int* __restrict__ r2){
  __shared__ int sm[1024];
  const int* cnt = blockIdx.x ? c2 : c1;
  int*       row = blockIdx.x ? r2 : r1;
  int n          = blockIdx.x ? n2 : n1;
  int t = threadIdx.x;
  int per = n/1024 + 1;
  int st = t*per;
  int s = 0;
  for (int i=st;i<st+per;++i) if (i<n) s += cnt[i];
  sm[t]=s; __syncthreads();
  for (int o=1;o<1024;o<<=1){
    int v = (t>=o)? sm[t-o]:0;
    __syncthreads();
    sm[t] += v;
    __syncthreads();
  }
  int base = sm[t]-s;
  for (int i=st;i<st+per;++i){
    if (i<=n) row[i]=base;
    if (i<n) base += cnt[i];
  }
}

__global__ void k_scale2(const int* __restrict__ co1, const int* __restrict__ ci1, int n1,
                         float* __restrict__ os1, float* __restrict__ is1,
                         const int* __restrict__ co2, const int* __restrict__ ci2, int n2,
                         float* __restrict__ os2, float* __restrict__ is2){
  int i = blockIdx.x*256+threadIdx.x;
  if (i<n1){
    int a = co1[i] > 1 ? co1[i] : 1;
    int b = ci1[i] > 1 ? ci1[i] : 1;
    os1[i] = 1.f/sqrtf((float)a);
    is1[i] = 1.f/sqrtf((float)b);
  }
  int j = i - n1;
  if (j>=0 && j<n2){
    int a = co2[j] > 1 ? co2[j] : 1;
    int b = ci2[j] > 1 ? ci2[j] : 1;
    os2[j] = 1.f/sqrtf((float)a);
    is2[j] = 1.f/sqrtf((float)b);
  }
}

__global__ void k_scatter2(const int* __restrict__ s1, const int* __restrict__ d1, int E1,
                           const int* __restrict__ row1, int* __restrict__ cur1, int* __restrict__ csr1,
                           const int* __restrict__ s2, const int* __restrict__ d2, int E2,
                           const int* __restrict__ row2, int* __restrict__ cur2, int* __restrict__ csr2){
  int e = blockIdx.x*256+threadIdx.x;
  if (e<E1){ int d=d1[e]; int p=atomicAdd(&cur1[d],1); csr1[row1[d]+p]=s1[e]; }
  int f = e - E1;
  if (f>=0 && f<E2){ int d=d2[f]; int p=atomicAdd(&cur2[d],1); csr2[row2[d]+p]=s2[f]; }
}

// goff binary search + packed-plane prefix (pb, 32-aligned) + group->graph map (gm)
__global__ void k_goff2(const int* __restrict__ g1, int n1, int* __restrict__ o1,
                        const int* __restrict__ g2, int n2, int* __restrict__ o2, int B,
                        int* __restrict__ pb1, int* __restrict__ gm1,
                        int* __restrict__ pb2, int* __restrict__ gm2){
  int t = threadIdx.x;
  const int* gid = (t>=256)? g2 : g1;
  int*      goff = (t>=256)? o2 : o1;
  int n          = (t>=256)? n2 : n1;
  int q = t & 255;
  if (q<=B){
    int lo=0, hi=n;
    while (lo<hi){ int mid=(lo+hi)>>1; if (gid[mid]<q) lo=mid+1; else hi=mid; }
    goff[q]=lo;
  }
  __syncthreads();
  if (t==0 || t==256){
    const int* go = t ? o2 : o1;
    int* pb = t ? pb2 : pb1;
    int* gm = t ? gm2 : gm1;
    int acc = 0;
    for (int g=0; g<B; ++g){
      pb[g] = acc;
      int c = go[g+1]-go[g]; if (c>128) c=128;
      int pc = (c+31)&~31;
      int nb = pc>>5;
      for (int k=0;k<nb;++k) gm[(acc>>5)+k] = g;
      acc += pc;
    }
    pb[B] = acc;
  }
}

// gather aggregation with split-f16 output planes:
// acc[node] = sum_{e in in(node)} x[src_e] * (osc? osc[src_e] : 1) ; oh=f16(acc), ol=f16(acc-oh)
__global__ void k_agg_h(const float* __restrict__ x, int ldx, const float* __restrict__ osc,
                        const int* __restrict__ row, const int* __restrict__ csr,
                        _Float16* __restrict__ oh, _Float16* __restrict__ ol, int n, int f4shift){
  int F4 = 1<<f4shift;
  int node = blockIdx.x*(256>>f4shift) + (threadIdx.x>>f4shift);
  if (node>=n) return;
  int fc = threadIdx.x & (F4-1);
  int F = F4<<2;
  int rs=row[node], re=row[node+1];
  float ax=0, ay=0, az=0, aw=0;
  if (osc){
    for (int e=rs;e<re;++e){
      int s = csr[e];
      float sc = osc[s];
      const float4 v = *(const float4*)(x + (size_t)s*ldx + (fc<<2));
      ax += sc*v.x; ay += sc*v.y; az += sc*v.z; aw += sc*v.w;
    }
  } else {
    int e = rs;
    for (; e+1<re; e+=2){
      int s0 = csr[e], s1 = csr[e+1];
      const float4 v0 = *(const float4*)(x + (size_t)s0*ldx + (fc<<2));
      const float4 v1 = *(const float4*)(x + (size_t)s1*ldx + (fc<<2));
      ax += v0.x+v1.x; ay += v0.y+v1.y; az += v0.z+v1.z; aw += v0.w+v1.w;
    }
    if (e<re){
      int s0 = csr[e];
      const float4 v0 = *(const float4*)(x + (size_t)s0*ldx + (fc<<2));
      ax += v0.x; ay += v0.y; az += v0.z; aw += v0.w;
    }
  }
  half4_t hv, lv;
  hv.x = (_Float16)ax; lv.x = (_Float16)(ax - (float)hv.x);
  hv.y = (_Float16)ay; lv.y = (_Float16)(ay - (float)hv.y);
  hv.z = (_Float16)az; lv.z = (_Float16)(az - (float)hv.z);
  hv.w = (_Float16)aw; lv.w = (_Float16)(aw - (float)hv.w);
  size_t o = (size_t)node*F + (fc<<2);
  *(half4_t*)(oh + o) = hv;
  *(half4_t*)(ol + o) = lv;
}

// pack 4 GraphConv weights (fp32 [K][N]) into split-f16 hi/lo, k8-packed layout:
// element (k,n) -> plane[ ((k>>3)*N + n)*8 + (k&7) ]
__global__ void k_wpack4(const float* __restrict__ W0, const float* __restrict__ W1,
                         const float* __restrict__ W2, const float* __restrict__ W3,
                         _Float16* __restrict__ h0, _Float16* __restrict__ l0,
                         _Float16* __restrict__ h1, _Float16* __restrict__ l1,
                         _Float16* __restrict__ h2, _Float16* __restrict__ l2,
                         _Float16* __restrict__ h3, _Float16* __restrict__ l3){
  int w = blockIdx.y;
  const float* W = (w==0)?W0:(w==1)?W1:(w==2)?W2:W3;
  _Float16* oh = (w==0)?h0:(w==1)?h1:(w==2)?h2:h3;
  _Float16* ol = (w==0)?l0:(w==1)?l1:(w==2)?l2:l3;
  int K   = (w&1)? 256 : 128;
  int nsh = (w&1)? 9 : 8;
  int i = blockIdx.x*256 + threadIdx.x;
  if (i >= (K<<nsh)) return;
  int k = i >> nsh, n = i & ((1<<nsh)-1);
  float v = W[i];
  _Float16 h = (_Float16)v;
  _Float16 l = (_Float16)(v - (float)h);
  size_t p = (((size_t)(k>>3)<<nsh) + n)*8 + (k&7);
  oh[p] = h; ol[p] = l;
}

// ------- k_gconv_mfma: dual-side split-f16 MFMA GEMM (see round-0 notes).
__global__ __launch_bounds__(256)
void k_gconv_mfma(const _Float16* __restrict__ Ah0, const _Float16* __restrict__ Al0,
                  const _Float16* __restrict__ Ah1, const _Float16* __restrict__ Al1,
                  const _Float16* __restrict__ Bh0, const _Float16* __restrict__ Bl0,
                  const _Float16* __restrict__ Bh1, const _Float16* __restrict__ Bl1,
                  float* __restrict__ C0, float* __restrict__ C1, int ldc,
                  int M0, int M1, int N, int K,
                  const float* __restrict__ rs0, const float* __restrict__ rs1,
                  const float* __restrict__ bi0, const float* __restrict__ bi1, int relu,
                  const float* __restrict__ po0, const float* __restrict__ po1)
{
  __shared__ __align__(16) _Float16 As[2][4096];   // [kb(4)][m(128)][8]
  __shared__ __align__(16) _Float16 Bs[2][4096];   // [kb(4)][n(128)][8]

  const int gx = gridDim.x, gxy = gridDim.x*gridDim.y;
  const int nwg = gxy*2;
  int fid = blockIdx.x + gx*blockIdx.y + gxy*blockIdx.z;
  int q = nwg>>3, r = nwg&7;
  int xcd = fid & 7, idx = fid >> 3;
  int sid = (xcd<r ? xcd*(q+1) : r*(q+1)+(xcd-r)*q) + idx;
  const int z  = sid / gxy;  int rem = sid - z*gxy;
  const int by = rem / gx,  bx = rem - by*gx;

  const _Float16* Ah = z ? Ah1 : Ah0;
  const _Float16* Al = z ? Al1 : Al0;
  const _Float16* Bh = z ? Bh1 : Bh0;
  const _Float16* Bl = z ? Bl1 : Bl0;
  float*       C  = z ? C1 : C0;
  const float* rsc = z ? rs1 : rs0;
  const float* bia = z ? bi1 : bi0;
  const float* po  = z ? po1 : po0;
  const int M = z ? M1 : M0;

  const int row0 = by << 7;
  const int col0 = bx << 7;
  if (row0 >= ((M+127)&~127)) return;

  const int tid = threadIdx.x;
  const int am  = tid >> 2;
  const int akb = tid & 3;
  const int bn  = tid & 127;
  const int bkb = tid >> 7;
  const int wid = tid >> 6, lane = tid & 63;
  const int wr = wid >> 1, wc = wid & 1;
  const int lr = lane & 15, lg = lane >> 4;

  const size_t ldb8 = (size_t)N * 8;
  f32x4 acc[4][4] = {};

  const int kpt = K >> 5;     // K-steps per term
  const int nt  = 3 * kpt;    // total K-steps (hi*hi, lo*hi, hi*lo)

  half8 ga0, ga1, gb0, gb1;
  {
    const _Float16* Ap = Ah + (size_t)(row0 + am) * K + (akb<<3);
    ga0 = *(const half8*)(Ap);
    ga1 = *(const half8*)(Ap + (size_t)64 * K);
    const _Float16* Bp = Bh + (size_t)bkb * ldb8 + (size_t)(col0 + bn) * 8;
    gb0 = *(const half8*)(Bp);
    gb1 = *(const half8*)(Bp + 2*ldb8);
  }
  *(half8*)&As[0][(akb*128 + am)*8]        = ga0;
  *(half8*)&As[0][(akb*128 + am + 64)*8]   = ga1;
  *(half8*)&Bs[0][(bkb*128 + bn)*8]        = gb0;
  *(half8*)&Bs[0][((bkb+2)*128 + bn)*8]    = gb1;
  __syncthreads();

  int term = 0, kk = 32;    // coordinates of the NEXT tile (t+1)
  if (kk == K){ kk = 0; term = 1; }
  for (int t = 0; t < nt; ++t){
    const int cb = t & 1;
    if (t + 1 < nt){
      const _Float16* Asrc = (term == 1) ? Al : Ah;
      const _Float16* Bsrc = (term == 2) ? Bl : Bh;
      const _Float16* Ap = Asrc + (size_t)(row0 + am) * K + kk + (akb<<3);
      ga0 = *(const half8*)(Ap);
      ga1 = *(const half8*)(Ap + (size_t)64 * K);
      const _Float16* Bp = Bsrc + (size_t)((kk>>3) + bkb) * ldb8 + (size_t)(col0 + bn) * 8;
      gb0 = *(const half8*)(Bp);
      gb1 = *(const half8*)(Bp + 2*ldb8);
      kk += 32; if (kk == K){ kk = 0; ++term; }
    }
    {
      const _Float16* Abase = &As[cb][((lg<<7) + (wr<<6) + lr)<<3];
      const _Float16* Bbase = &Bs[cb][((lg<<7) + (wc<<6) + lr)<<3];
      half8 af[4], bf[4];
      #pragma unroll
      for (int i=0;i<4;++i){
        af[i] = *(const half8*)(Abase + i*128);
        bf[i] = *(const half8*)(Bbase + i*128);
      }
      #pragma unroll
      for (int mi=0; mi<4; ++mi){
        #pragma unroll
        for (int ni=0; ni<4; ++ni){
          acc[mi][ni] = __builtin_amdgcn_mfma_f32_16x16x32_f16(af[mi], bf[ni], acc[mi][ni], 0, 0, 0);
        }
      }
    }
    if (t + 1 < nt){
      const int nb_ = cb ^ 1;
      *(half8*)&As[nb_][(akb*128 + am)*8]      = ga0;
      *(half8*)&As[nb_][(akb*128 + am + 64)*8] = ga1;
      *(half8*)&Bs[nb_][(bkb*128 + bn)*8]      = gb0;
      *(half8*)&Bs[nb_][((bkb+2)*128 + bn)*8]  = gb1;
    }
    __syncthreads();
  }

  // epilogue: D row = row0 + wr*64 + mi*16 + lg*4 + j ; col = col0 + wc*64 + ni*16 + lr
  #pragma unroll
  for (int ni = 0; ni < 4; ++ni){
    int cc = col0 + (wc<<6) + (ni<<4) + lr;
    float bv = bia ? bia[cc] : 0.f;
    #pragma unroll
    for (int mi = 0; mi < 4; ++mi){
      int rbase = row0 + (wr<<6) + (mi<<4) + (lg<<2);
      #pragma unroll
      for (int j = 0; j < 4; ++j){
        int rr = rbase + j;
        if (rr < M){
          float rs_ = rsc ? rsc[rr] : 1.f;
          float v = acc[mi][ni][j]*rs_ + bv;
          if (relu) v = fmaxf(v, 0.f);
          if (po) v *= po[rr];
          C[(size_t)rr*ldc + cc] = v;
        }
      }
    }
  }
}

// ------- k_pack: repack sf/vf[:, 0:512) into per-graph 32-aligned node-packed
// split-f16 planes: elem(node j, feat f) -> plane[(j>>3)*4096 + f*8 + (j&7)],
// node index = pb[g] + local; padding nodes written as ZERO.
__global__ __launch_bounds__(256)
void k_pack(const float* __restrict__ sf, const float* __restrict__ vf,
            const int* __restrict__ go1, const int* __restrict__ go2,
            const int* __restrict__ pb1, const int* __restrict__ pb2,
            const int* __restrict__ gm1, const int* __restrict__ gm2,
            _Float16* __restrict__ p1h, _Float16* __restrict__ p1l,
            _Float16* __restrict__ p2h, _Float16* __restrict__ p2l, int B)
{
  __shared__ float st[32][516];
  const int side = blockIdx.y;
  const float* x = side ? vf : sf;
  const int* go = side ? go2 : go1;
  const int* pb = side ? pb2 : pb1;
  const int* gm = side ? gm2 : gm1;
  _Float16* ph = side ? p2h : p1h;
  _Float16* pl = side ? p2l : p1l;
  const int u = blockIdx.x;
  if (u*32 >= pb[B]) return;
  const int g = gm[u];
  const int j0 = u*32 - pb[g];
  const int base = go[g];
  int cnt = go[g+1]-base; if (cnt>128) cnt=128;
  const int t = threadIdx.x;
  const int r = t>>3, f0 = (t&7)<<2;
  const bool valid = (j0 + r) < cnt;
  const float* src = x + (size_t)(base + j0 + r)*1024;
  #pragma unroll
  for (int q=0;q<16;++q){
    int f = f0 + (q<<5);
    float4 vv;
    if (valid) vv = *(const float4*)(src + f);
    else { vv.x=0.f; vv.y=0.f; vv.z=0.f; vv.w=0.f; }
    *(float4*)&st[r][f] = vv;
  }
  __syncthreads();
  #pragma unroll
  for (int q=0;q<8;++q){
    int u2 = t + (q<<8);
    int jg = u2>>9, f = u2&511;
    half8 h8, l8;
    #pragma unroll
    for (int e=0;e<8;++e){
      float vvv = st[(jg<<3)+e][f];
      _Float16 hh = (_Float16)vvv;
      h8[e]=hh; l8[e]=(_Float16)(vvv-(float)hh);
    }
    size_t a = ((size_t)((u<<2)+jg)<<12) + ((size_t)f<<3);
    *(half8*)(ph + a) = h8;
    *(half8*)(pl + a) = l8;
  }
}

// ------- k_T: LDS-staged split-f16 MFMA interaction tiles, one block per
// (graph, 16-row tile of T0). T0 = tanh(s.v^T) computed ONCE; T1 = T0^T written
// directly (transposed stores). Coalesced fp32 staging; frag reads from LDS.
// Coverage: rows [0, ceil32(c1)), cols [0, ceil32(c2)) — exactly what k_apply reads.
__global__ __launch_bounds__(256)
void k_T(const float* __restrict__ sf, const float* __restrict__ vf,
         const int* __restrict__ go1, const int* __restrict__ go2,
         _Float16* __restrict__ Th, _Float16* __restrict__ Tl, int B)
{
  __shared__ __align__(16) _Float16 Ahs[64*136 + 8];   // [fg64][r16][8], fg stride 136
  __shared__ __align__(16) _Float16 Als[64*136 + 8];
  __shared__ __align__(16) _Float16 Bhs[2][2048];      // [buf][fg4][c64][8], c XOR-swizzled
  __shared__ __align__(16) _Float16 Bls[2][2048];
  const int g = blockIdx.x, rt = blockIdx.y;
  int gR = go1[g]; int c1 = go1[g+1]-gR; if (c1>128) c1=128;
  int gO = go2[g]; int c2 = go2[g+1]-gO; if (c2>128) c2=128;
  const int c1_32 = (c1+31)&~31, c2_32 = (c2+31)&~31;
  if ((rt<<4) >= c1_32 || c2_32 == 0) return;
  const int tid = threadIdx.x;
  // ---- stage A: 16 rows x 512 feats, coalesced row reads, split-f16 to LDS
  {
    const int r = tid >> 4;               // 0..15
    const int f0 = (tid & 15) << 5;       // 0,32,..,480
    const int row = (rt<<4) + r;
    const bool val = row < c1;
    const float* src = sf + (size_t)(gR + row)*1024 + f0;
    #pragma unroll
    for (int q=0;q<4;++q){
      float4 v0, v1;
      if (val){
        v0 = *(const float4*)(src + (q<<3));
        v1 = *(const float4*)(src + (q<<3) + 4);
      } else {
        v0.x=0.f; v0.y=0.f; v0.z=0.f; v0.w=0.f; v1 = v0;
      }
      half8 h,l; split8(v0,v1,h,l);
      const int a = ((f0>>3) + q)*136 + (r<<3);
      *(half8*)&Ahs[a] = h; *(half8*)&Als[a] = l;
    }
  }
  const int w = tid>>6, lane = tid&63, lr = lane&15, lg = lane>>4;
  const int bc = tid>>2, bfg = tid&3, bf = bfg<<3;   // B stage: row-in-chunk, feat-group
  const int bwr = (bfg<<9) + ((bc ^ (bfg<<2))<<3);   // B LDS write addr (swizzled)
  const int ncc = (c2_32 + 63) >> 6;
  _Float16* T0h = Th + ((size_t)g<<14);
  _Float16* T0l = Tl + ((size_t)g<<14);
  _Float16* T1h = Th + ((size_t)(B + g)<<14);
  _Float16* T1l = Tl + ((size_t)(B + g)<<14);
  for (int cc=0; cc<ncc; ++cc){
    const int cbase = cc<<6;
    const int colr = cbase + bc;
    const bool bval = colr < c2;
    const float* bsrc = vf + (size_t)(gO + colr)*1024 + bf;
    // stage B chunk kc=0
    {
      float4 v0, v1;
      if (bval){ v0 = *(const float4*)(bsrc); v1 = *(const float4*)(bsrc + 4); }
      else { v0.x=0.f; v0.y=0.f; v0.z=0.f; v0.w=0.f; v1 = v0; }
      half8 h,l; split8(v0,v1,h,l);
      *(half8*)&Bhs[0][bwr] = h; *(half8*)&Bls[0][bwr] = l;
    }
    __syncthreads();
    f32x4 acc = {0.f,0.f,0.f,0.f};
    const int col_l = (w<<4) + lr;
    const int ba = (lg<<9) + ((col_l ^ (lg<<2))<<3);
    for (int kc=0; kc<16; ++kc){
      float4 p0, p1;
      if (kc+1<16){
        if (bval){
          const float* s = bsrc + ((kc+1)<<5);
          p0 = *(const float4*)s; p1 = *(const float4*)(s + 4);
        } else { p0.x=0.f; p0.y=0.f; p0.z=0.f; p0.w=0.f; p1 = p0; }
      }
      const int aa = ((kc<<2)+lg)*136 + (lr<<3);
      half8 ah = *(const half8*)&Ahs[aa];
      half8 al = *(const half8*)&Als[aa];
      half8 bh = *(const half8*)&Bhs[kc&1][ba];
      half8 bl = *(const half8*)&Bls[kc&1][ba];
      acc = MF(ah,bh,acc);
      acc = MF(al,bh,acc);
      acc = MF(ah,bl,acc);
      if (kc+1<16){
        half8 h,l; split8(p0,p1,h,l);
        *(half8*)&Bhs[(kc+1)&1][bwr] = h; *(half8*)&Bls[(kc+1)&1][bwr] = l;
      }
      __syncthreads();
    }
    // epilogue: masked tanh, write T0 (row-major) and T1 = T0^T
    const int col = cbase + col_l;
    if (col < c2_32){
      half4_t t1h, t1l;
      #pragma unroll
      for (int qq=0;qq<4;++qq){
        int r = (rt<<4) + (lg<<2) + qq;
        float t = (r < c1 && col < c2) ? ftanh(acc[qq]) : 0.f;
        _Float16 hh = (_Float16)t;
        _Float16 ll = (_Float16)(t - (float)hh);
        T0h[(r<<7) + col] = hh;
        T0l[(r<<7) + col] = ll;
        t1h[qq] = hh; t1l[qq] = ll;
      }
      const int r0 = (rt<<4) + (lg<<2);
      *(half4_t*)&T1h[(col<<7) + r0] = t1h;
      *(half4_t*)&T1l[(col<<7) + r0] = t1l;
    }
  }
}

// ------- k_apply: own'[r][f] = sum_o T[r][o]*oth[o][f] via MFMA.
// A-frag: row-major T (half8 contiguous). B-frag: node-packed oth plane
// (8 consecutive nodes contiguous at fixed feat). grid (2 sides, B, 2 feat halves).
__global__ __launch_bounds__(256)
void k_apply(const _Float16* __restrict__ Th, const _Float16* __restrict__ Tl,
             const _Float16* __restrict__ p1h, const _Float16* __restrict__ p1l,
             const _Float16* __restrict__ p2h, const _Float16* __restrict__ p2l,
             const int* __restrict__ go1, const int* __restrict__ go2,
             const int* __restrict__ pb1, const int* __restrict__ pb2,
             float* __restrict__ sf, float* __restrict__ vf, int B)
{
  const int side = blockIdx.x, g = blockIdx.y, ft = blockIdx.z;
  const int* goR = side ? go2 : go1;
  const int* goO = side ? go1 : go2;
  const int* pbO = side ? pb1 : pb2;
  const _Float16* oph = side ? p1h : p2h;
  const _Float16* opl = side ? p1l : p2l;
  float* outp = side ? vf : sf;
  int gR = goR[g]; int cR = goR[g+1]-gR; if (cR>128) cR=128;
  int gO = goO[g]; int cO = goO[g+1]-gO; if (cO>128) cO=128;
  if (cR <= 0) return;
  const int pO = pbO[g];
  const int cO32 = (cO+31)&~31;
  const int MR = ((cR+15)&~15)>>4;     // 1..8 row tiles (all within written T rows)
  const _Float16* Tph = Th + ((size_t)(side*B + g)<<14);
  const _Float16* Tpl = Tl + ((size_t)(side*B + g)<<14);
  const int tid = threadIdx.x, w = tid>>6, lane = tid&63;
  const int lr = lane&15, lg = lane>>4;
  const int f0 = (ft<<8) + (w<<6);     // 64 feats per wave
  for (int rc = 0; rc < MR; rc += 4){
    f32x4 acc[4][4];
    #pragma unroll
    for (int a_=0;a_<4;++a_)
      #pragma unroll
      for (int b_=0;b_<4;++b_) acc[a_][b_] = (f32x4){0.f,0.f,0.f,0.f};
    for (int k0=0; k0<cO32; k0+=32){
      half8 bh[4], bl[4];
      #pragma unroll
      for (int nj=0;nj<4;++nj){
        size_t a = ((size_t)((pO + k0)>>3) + lg)*4096 + (size_t)(f0 + (nj<<4) + lr)*8;
        bh[nj] = *(const half8*)(oph + a);
        bl[nj] = *(const half8*)(opl + a);
      }
      #pragma unroll
      for (int mi=0;mi<4;++mi){
        if (rc + mi < MR){
          int a = ((((rc+mi)<<4) + lr)<<7) + k0 + (lg<<3);
          half8 th_ = *(const half8*)&Tph[a];
          half8 tl_ = *(const half8*)&Tpl[a];
          #pragma unroll
          for (int nj=0;nj<4;++nj){
            acc[mi][nj] = MF(th_, bh[nj], acc[mi][nj]);
            acc[mi][nj] = MF(tl_, bh[nj], acc[mi][nj]);
            acc[mi][nj] = MF(th_, bl[nj], acc[mi][nj]);
          }
        }
      }
    }
    #pragma unroll
    for (int mi=0;mi<4;++mi){
      if (rc + mi < MR){
        #pragma unroll
        for (int nj=0;nj<4;++nj){
          #pragma unroll
          for (int qq=0;qq<4;++qq){
            int r = (((rc+mi)<<4)) + (lg<<2) + qq;
            if (r < cR)
              outp[(size_t)(gR + r)*1024 + 512 + f0 + (nj<<4) + lr] = acc[mi][nj][qq];
          }
        }
      }
    }
  }
}

// ------- k_gemmsk: skinny NT GEMM, M=128 x 64-col tile, dbuf LDS, split-K,
// optional dual-side via blockIdx.y. Partials P[(side*splits+z)][M][N].
__global__ __launch_bounds__(256)
void k_gemmsk(const float* __restrict__ Ab, size_t AsideOff, int lda,
              const float* __restrict__ Bm, int ldb,
              float* __restrict__ P, int M, int N, int kchunk)
{
  __shared__ float As[2][16][132];
  __shared__ float Bs[2][16][68];
  const int tid = threadIdx.x;
  const int col0 = (int)blockIdx.x << 6;
  const int kbeg = (int)blockIdx.z * kchunk;
  const float* A = Ab + (size_t)blockIdx.y * AsideOff;
  const int ar = tid >> 1, ak = (tid & 1) << 3;
  const int br = tid >> 2, bk = (tid & 3) << 2;
  const int tx = tid & 15, ty = tid >> 4;
  const float* Arow = A + (size_t)ar * lda + kbeg + ak;
  const float* Brow = Bm + (size_t)(col0 + br) * ldb + kbeg + bk;
  float acc[8][4] = {};
  float4 a0 = *(const float4*)(Arow);
  float4 a1 = *(const float4*)(Arow + 4);
  float4 b0 = *(const float4*)(Brow);
  As[0][ak+0][ar]=a0.x; As[0][ak+1][ar]=a0.y; As[0][ak+2][ar]=a0.z; As[0][ak+3][ar]=a0.w;
  As[0][ak+4][ar]=a1.x; As[0][ak+5][ar]=a1.y; As[0][ak+6][ar]=a1.z; As[0][ak+7][ar]=a1.w;
  Bs[0][bk+0][br]=b0.x; Bs[0][bk+1][br]=b0.y; Bs[0][bk+2][br]=b0.z; Bs[0][bk+3][br]=b0.w;
  __syncthreads();
  const int nt = kchunk >> 4;
  for (int t = 0; t < nt; ++t){
    const int cb = t & 1;
    if (t + 1 < nt){
      int k0 = (t + 1) << 4;
      a0 = *(const float4*)(Arow + k0);
      a1 = *(const float4*)(Arow + k0 + 4);
      b0 = *(const float4*)(Brow + k0);
    }
    #pragma unroll
    for (int kk = 0; kk < 16; ++kk){
      float4 b4 = *(const float4*)&Bs[cb][kk][tx << 2];
      float4 a4 = *(const float4*)&As[cb][kk][ty << 3];
      float4 a5 = *(const float4*)&As[cb][kk][(ty << 3) + 4];
      acc[0][0]+=a4.x*b4.x; acc[0][1]+=a4.x*b4.y; acc[0][2]+=a4.x*b4.z; acc[0][3]+=a4.x*b4.w;
      acc[1][0]+=a4.y*b4.x; acc[1][1]+=a4.y*b4.y; acc[1][2]+=a4.y*b4.z; acc[1][3]+=a4.y*b4.w;
      acc[2][0]+=a4.z*b4.x; acc[2][1]+=a4.z*b4.y; acc[2][2]+=a4.z*b4.z; acc[2][3]+=a4.z*b4.w;
      acc[3][0]+=a4.w*b4.x; acc[3][1]+=a4.w*b4.y; acc[3][2]+=a4.w*b4.z; acc[3][3]+=a4.w*b4.w;
      acc[4][0]+=a5.x*b4.x; acc[4][1]+=a5.x*b4.y; acc[4][2]+=a5.x*b4.z; acc[4][3]+=a5.x*b4.w;
      acc[5][0]+=a5.y*b4.x; acc[5][1]+=a5.y*b4.y; acc[5][2]+=a5.y*b4.z; acc[5][3]+=a5.y*b4.w;
      acc[6][0]+=a5.z*b4.x; acc[6][1]+=a5.z*b4.y; acc[6][2]+=a5.z*b4.z; acc[6][3]+=a5.z*b4.w;
      acc[7][0]+=a5.w*b4.x; acc[7][1]+=a5.w*b4.y; acc[7][2]+=a5.w*b4.z; acc[7][3]+=a5.w*b4.w;
    }
    if (t + 1 < nt){
      const int nb = cb ^ 1;
      As[nb][ak+0][ar]=a0.x; As[nb][ak+1][ar]=a0.y; As[nb][ak+2][ar]=a0.z; As[nb][ak+3][ar]=a0.w;
      As[nb][ak+4][ar]=a1.x; As[nb][ak+5][ar]=a1.y; As[nb][ak+6][ar]=a1.z; As[nb][ak+7][ar]=a1.w;
      Bs[nb][bk+0][br]=b0.x; Bs[nb][bk+1][br]=b0.y; Bs[nb][bk+2][br]=b0.z; Bs[nb][bk+3][br]=b0.w;
    }
    __syncthreads();
  }
  float* Pz = P + (size_t)(blockIdx.y*gridDim.z + blockIdx.z) * M * N;
  #pragma unroll
  for (int i = 0; i < 8; ++i){
    int rr = (ty << 3) + i;
    float4 v = {acc[i][0], acc[i][1], acc[i][2], acc[i][3]};
    *(float4*)(Pz + (size_t)rr*N + col0 + (tx<<2)) = v;
  }
}

// sum split partials + bias (+relu)
__global__ void k_red_bias(const float* __restrict__ P, int split, int MN, int N,
                           const float* __restrict__ bias, float* __restrict__ C, int relu){
  int i = blockIdx.x*256 + threadIdx.x;
  if (i >= MN) return;
  float v = bias[i & (N-1)];
  for (int s=0;s<split;++s) v += P[(size_t)s*MN + i];
  if (relu) v = fmaxf(v, 0.f);
  C[i] = v;
}

// ---------------- Set2Set ----------------
__global__ void k_lstm1(const float* __restrict__ bih, const float* __restrict__ bhh,
                        float* __restrict__ c1, float* __restrict__ h1){
  int j = blockIdx.x*256 + threadIdx.x;
  if (j >= 1024) return;
  float gi = bih[j]        + bhh[j];
  float gg = bih[j+2048]   + bhh[j+2048];
  float go = bih[j+3072]   + bhh[j+3072];
  float cc = fsigm(gi)*ftanh(gg);
  c1[j] = cc;
  h1[j] = fsigm(go)*ftanh(cc);
}

__global__ void k_gemv_u(const float* __restrict__ Wih, const float* __restrict__ Whh,
                         const float* __restrict__ bih, const float* __restrict__ bhh,
                         const float* __restrict__ h1, float* __restrict__ u){
  int w = (blockIdx.x*256 + threadIdx.x)>>6;
  int lane = threadIdx.x & 63;
  if (w >= 4096) return;
  const float* wi = Wih + (size_t)w*2048;
  const float* wh = Whh + (size_t)w*1024;
  float acc = 0.f;
  #pragma unroll
  for (int qq=0;qq<4;++qq){
    int o = qq*256 + (lane<<2);
    float4 hv = *(const float4*)(h1 + o);
    float4 a  = *(const float4*)(wi + o);
    float4 b  = *(const float4*)(wh + o);
    acc += hv.x*(a.x+b.x) + hv.y*(a.y+b.y) + hv.z*(a.z+b.z) + hv.w*(a.w+b.w);
  }
  acc = wredsum(acc);
  if (lane==0) u[w] = acc + bih[w] + bhh[w];
}

// fused attention, dual-side (blockIdx.y): online segment softmax + weighted sum
__global__ __launch_bounds__(256)
void k_attn(const float* __restrict__ sf, const float* __restrict__ vf,
            const int* __restrict__ go1, const int* __restrict__ go2,
            const float* __restrict__ hbase, size_t hSideOff, int hstride,
            float* __restrict__ outbase, size_t oSideOff, int ldout)
{
  __shared__ float hs[1024];
  __shared__ float ech[1024];
  __shared__ float red[8];
  int side = blockIdx.y;
  const float* x = side? vf : sf;
  const int* goff = side? go2 : go1;
  const float* hsrc = hbase + (size_t)side*hSideOff;
  float* outp = outbase + (size_t)side*oSideOff;
  int b = blockIdx.x, t = threadIdx.x;
  int i0 = goff[b], i1 = goff[b+1];
  int lane = t & 63, wv = t >> 6;
  { float4 hv = *(const float4*)(hsrc + (size_t)b*hstride + (t<<2));
    *(float4*)&hs[t<<2] = hv; }
  __syncthreads();
  float m = -3.0e38f, s = 0.f;
  float ax=0, ay=0, az=0, aw=0;
  for (int c = i0; c < i1; c += 1024){
    int ce = c + 1024; if (ce > i1) ce = i1;
    int n = ce - c;
    float wmax = -3.0e38f;
    for (int i = c + wv; i < ce; i += 4){
      const float* xr = x + (size_t)i*1024;
      float d = 0.f;
      #pragma unroll
      for (int qq=0;qq<4;++qq){
        int o = qq*256 + (lane<<2);
        float4 xv = *(const float4*)(xr+o);
        float4 h4 = *(const float4*)&hs[o];
        d += xv.x*h4.x + xv.y*h4.y + xv.z*h4.z + xv.w*h4.w;
      }
      d = wredsum(d);
      if (lane==0) ech[i-c] = d;
      wmax = fmaxf(wmax, d);
    }
    if (lane==0) red[wv] = wmax;
    __syncthreads();
    float cm = fmaxf(fmaxf(red[0],red[1]), fmaxf(red[2],red[3]));
    float nm = fmaxf(m, cm);
    float scale = __expf(m - nm);
    s *= scale; ax*=scale; ay*=scale; az*=scale; aw*=scale;
    float ps = 0.f;
    for (int k = t; k < n; k += 256) ps += __expf(ech[k]-nm);
    ps = wredsum(ps);
    __syncthreads();
    if (lane==0) red[wv] = ps;
    __syncthreads();
    s += red[0]+red[1]+red[2]+red[3];
    for (int k = 0; k < n; ++k){
      float w = __expf(ech[k]-nm);
      float4 xv = *(const float4*)(x + (size_t)(c+k)*1024 + (t<<2));
      ax += w*xv.x; ay += w*xv.y; az += w*xv.z; aw += w*xv.w;
    }
    m = nm;
    __syncthreads();
  }
  float inv = (i1>i0 && s>0.f) ? 1.f/s : 0.f;
  float4 o = {ax*inv, ay*inv, az*inv, aw*inv};
  *(float4*)(outp + (size_t)b*ldout + (t<<2)) = o;
}

// LSTM iter2 (dual-side via blockIdx.y): sum split gate partials + u, cell/hidden
__global__ void k_lstm2_red(const float* __restrict__ Pb, size_t PsideOff, int split,
                            const float* __restrict__ u, const float* __restrict__ c1,
                            float* __restrict__ z, int B){
  int idx = blockIdx.x*256 + threadIdx.x;
  if (idx >= B*1024) return;
  int side = blockIdx.y;
  const float* P = Pb + (size_t)side*PsideOff;
  int b = idx >> 10, j = idx & 1023;
  float gi=u[j], gf=u[j+1024], gg=u[j+2048], go=u[j+3072];
  const float* g = P + (size_t)b*4096;
  for (int s=0;s<split;++s){
    const float* gs = g + (size_t)s*B*4096;
    gi += gs[j]; gf += gs[j+1024]; gg += gs[j+2048]; go += gs[j+3072];
  }
  float cc = fsigm(gf)*c1[j] + fsigm(gi)*ftanh(gg);
  z[(size_t)b*4096 + side*2048 + j] = fsigm(go)*ftanh(cc);
}

__global__ void k_fc3(const float* __restrict__ z2, const float* __restrict__ w3,
                      const float* __restrict__ b3, float* __restrict__ out, int B){
  int wv = (blockIdx.x*256+threadIdx.x)>>6;
  int lane = threadIdx.x & 63;
  if (wv >= B) return;
  const float* zr = z2 + (size_t)wv*512;
  float acc=0.f;
  #pragma unroll
  for (int qq=0;qq<2;++qq){
    int o = qq*256 + (lane<<2);
    float4 a  = *(const float4*)(zr + o);
    float4 ww = *(const float4*)(w3 + o);
    acc += a.x*ww.x + a.y*ww.y + a.z*ww.z + a.w*ww.w;
  }
  acc = wredsum(acc);
  if (lane==0) out[wv] = acc + b3[0];
}

// ---------------- driver ----------------
extern "C" void kernel_launch(void* const* d_in, const int* in_sizes, int n_in,
                              void* d_out, int out_size, void* d_ws, size_t ws_size,
                              hipStream_t stream)
{
  const float* x1  = (const float*)d_in[0];
  const float* x2  = (const float*)d_in[1];
  const int* src1  = (const int*)d_in[2];
  const int* dst1  = (const int*)d_in[3];
  const int* src2  = (const int*)d_in[4];
  const int* dst2  = (const int*)d_in[5];
  const int* gid1  = (const int*)d_in[6];
  const int* gid2  = (const int*)d_in[7];
  const float* Wg1 = (const float*)d_in[8];  const float* bg1 = (const float*)d_in[9];
  const float* Wg2 = (const float*)d_in[10]; const float* bg2 = (const float*)d_in[11];
  const float* Wg3 = (const float*)d_in[12]; const float* bg3 = (const float*)d_in[13];
  const float* Wg4 = (const float*)d_in[14]; const float* bg4 = (const float*)d_in[15];
  const float* Wih = (const float*)d_in[16]; const float* Whh = (const float*)d_in[17];
  const float* bih = (const float*)d_in[18]; const float* bhh = (const float*)d_in[19];
  const float* Wf1 = (const float*)d_in[20]; const float* bf1 = (const float*)d_in[21];
  const float* Wf2 = (const float*)d_in[22]; const float* bf2 = (const float*)d_in[23];
  const float* Wf3 = (const float*)d_in[24]; const float* bf3 = (const float*)d_in[25];
  float* out = (float*)d_out;

  const int N1 = in_sizes[0]/128;
  const int N2 = in_sizes[1]/128;
  const int E1 = in_sizes[2];
  const int E2 = in_sizes[4];
  const int B  = out_size;            // 128
  const int NM = N1>N2?N1:N2;

  char* base = (char*)d_ws; size_t off=0;
  auto alloc = [&](size_t bytes)->void*{ void* p = base+off; off += (bytes+255)&~(size_t)255; return p; };

  int* zr   = (int*)alloc(sizeof(int)*(size_t)(3*N1+3*N2));
  int* co1=zr, *ci1=zr+N1, *cur1=zr+2*N1;
  int* co2=zr+3*N1, *ci2=zr+3*N1+N2, *cur2=zr+3*N1+2*N2;
  int* row1 = (int*)alloc(sizeof(int)*(size_t)(N1+1));
  int* row2 = (int*)alloc(sizeof(int)*(size_t)(N2+1));
  int* csr1 = (int*)alloc(sizeof(int)*(size_t)E1);
  int* csr2 = (int*)alloc(sizeof(int)*(size_t)E2);
  int* go1  = (int*)alloc(sizeof(int)*(size_t)(B+1));
  int* go2  = (int*)alloc(sizeof(int)*(size_t)(B+1));
  int* pb1  = (int*)alloc(sizeof(int)*(size_t)(B+1));
  int* pb2  = (int*)alloc(sizeof(int)*(size_t)(B+1));
  int* gm1  = (int*)alloc(sizeof(int)*1024);
  int* gm2  = (int*)alloc(sizeof(int)*1024);
  float* os1 = (float*)alloc(sizeof(float)*(size_t)N1);
  float* is1 = (float*)alloc(sizeof(float)*(size_t)N1);
  float* os2 = (float*)alloc(sizeof(float)*(size_t)N2);
  float* is2 = (float*)alloc(sizeof(float)*(size_t)N2);
  _Float16* a1h = (_Float16*)alloc(sizeof(_Float16)*(size_t)(NM+128)*256);
  _Float16* a1l = (_Float16*)alloc(sizeof(_Float16)*(size_t)(NM+128)*256);
  _Float16* a2h = (_Float16*)alloc(sizeof(_Float16)*(size_t)(NM+128)*256);
  _Float16* a2l = (_Float16*)alloc(sizeof(_Float16)*(size_t)(NM+128)*256);
  _Float16* wg1h = (_Float16*)alloc(sizeof(_Float16)*32768);
  _Float16* wg1l = (_Float16*)alloc(sizeof(_Float16)*32768);
  _Float16* wg2h = (_Float16*)alloc(sizeof(_Float16)*131072);
  _Float16* wg2l = (_Float16*)alloc(sizeof(_Float16)*131072);
  _Float16* wg3h = (_Float16*)alloc(sizeof(_Float16)*32768);
  _Float16* wg3l = (_Float16*)alloc(sizeof(_Float16)*32768);
  _Float16* wg4h = (_Float16*)alloc(sizeof(_Float16)*131072);
  _Float16* wg4l = (_Float16*)alloc(sizeof(_Float16)*131072);
  float* sf  = (float*)alloc(sizeof(float)*(size_t)(N1+128)*1024);
  float* vf  = (float*)alloc(sizeof(float)*(size_t)(N2+128)*1024);
  float* h1 = (float*)alloc(sizeof(float)*1024);
  float* c1 = (float*)alloc(sizeof(float)*1024);
  float* u  = (float*)alloc(sizeof(float)*4096);
  float* r1 = (float*)alloc(sizeof(float)*(size_t)2*B*1024);
  float* z1 = (float*)alloc(sizeof(float)*(size_t)B*1024);
  float* z2 = (float*)alloc(sizeof(float)*(size_t)B*512);
  float* z  = (float*)alloc(sizeof(float)*(size_t)B*4096);
  // T planes: [2 sides][B][128][128] split-f16 (16.8 MB total)
  _Float16* Tqh = (_Float16*)alloc(sizeof(_Float16)*(size_t)2*B*16384);
  _Float16* Tql = (_Float16*)alloc(sizeof(_Float16)*(size_t)2*B*16384);
  // union region: node-packed split-f16 planes (interact stage) / Pbuf partials (later stages)
  const int PN = ((NM + 32*B + 63)&~63) + 64;      // padded node capacity
  const size_t PE = (size_t)PN*512;                // elems per plane
  size_t packedBytes = 4*PE*sizeof(_Float16);
  size_t pbufBytes   = sizeof(float)*(size_t)16*B*1024*4;
  char* uni = (char*)alloc(packedBytes > pbufBytes ? packedBytes : pbufBytes);
  _Float16* p1h = (_Float16*)uni;
  _Float16* p1l = p1h + PE;
  _Float16* p2h = p1l + PE;
  _Float16* p2l = p2h + PE;
  float* Pbuf = (float*)uni;
  if (off > ws_size) return;

  // hbuf regions live inside sf/vf cols [512,768) (stride 1024), overwritten later by apply
  float* hb1 = sf + 512;
  float* hb2 = vf + 512;

  dim3 blk(256);

  // --- weight split-f16 pack (independent of graph prep) ---
  k_wpack4<<<dim3(512,4),blk,0,stream>>>(Wg1,Wg2,Wg3,Wg4,
                                         wg1h,wg1l, wg2h,wg2l, wg3h,wg3l, wg4h,wg4l);

  // --- prep ---
  k_zero_i32<<<(3*N1+3*N2+255)/256, blk, 0, stream>>>(zr, 3*N1+3*N2);
  k_hist2<<<(E1+E2+255)/256, blk, 0, stream>>>(src1,dst1,E1,co1,ci1, src2,dst2,E2,co2,ci2);
  k_scan2<<<2,1024,0,stream>>>(ci1,N1,row1, ci2,N2,row2);
  k_scale2<<<(N1+N2+255)/256,blk,0,stream>>>(co1,ci1,N1,os1,is1, co2,ci2,N2,os2,is2);
  k_scatter2<<<(E1+E2+255)/256,blk,0,stream>>>(src1,dst1,E1,row1,cur1,csr1, src2,dst2,E2,row2,cur2,csr2);
  k_goff2<<<1,512,0,stream>>>(gid1,N1,go1, gid2,N2,go2, B, pb1,gm1, pb2,gm2);

  // --- GraphConv: agg both sides (split-f16 out), dual MFMA GEMM L1 (post=os),
  //     agg (no scale), dual MFMA GEMM L2 ---
  int gy = (NM+127)/128;
  k_agg_h<<<(N1+7)/8,blk,0,stream>>>(x1,128, os1,row1,csr1, a1h,a1l, N1,5);
  k_agg_h<<<(N2+7)/8,blk,0,stream>>>(x2,128, os2,row2,csr2, a2h,a2l, N2,5);
  k_gconv_mfma<<<dim3(2,gy,2),blk,0,stream>>>(a1h,a1l, a2h,a2l,
                                              wg1h,wg1l, wg3h,wg3l,
                                              hb1,hb2,1024, N1,N2, 256,128,
                                              is1,is2, bg1,bg3, 1, os1,os2);
  k_agg_h<<<(N1+3)/4,blk,0,stream>>>(hb1,1024, nullptr,row1,csr1, a1h,a1l, N1,6);
  k_agg_h<<<(N2+3)/4,blk,0,stream>>>(hb2,1024, nullptr,row2,csr2, a2h,a2l, N2,6);
  k_gconv_mfma<<<dim3(4,gy,2),blk,0,stream>>>(a1h,a1l, a2h,a2l,
                                              wg2h,wg2l, wg4h,wg4l,
                                              sf,vf,1024, N1,N2, 512,256,
                                              is1,is2, bg2,bg4, 0, nullptr,nullptr);

  // --- block-diagonal interaction (MFMA; T computed once, transposed write) ---
  const int GMAX = NM/32 + B + 2;
  k_pack<<<dim3(GMAX,2),blk,0,stream>>>(sf,vf, go1,go2, pb1,pb2, gm1,gm2,
                                        p1h,p1l, p2h,p2l, B);
  k_T<<<dim3(B,8),blk,0,stream>>>(sf,vf, go1,go2, Tqh,Tql, B);
  k_apply<<<dim3(2,B,2),blk,0,stream>>>(Tqh,Tql, p1h,p1l, p2h,p2l,
                                        go1,go2, pb1,pb2, sf,vf, B);

  // --- Set2Set (sides merged per stage) ---
  k_lstm1<<<4,blk,0,stream>>>(bih,bhh,c1,h1);
  k_gemv_u<<<1024,blk,0,stream>>>(Wih,Whh,bih,bhh,h1,u);

  // iter1 attention (shared h1), both sides
  k_attn<<<dim3(B,2),blk,0,stream>>>(sf,vf,go1,go2, h1,0,0, r1,(size_t)B*1024,1024);
  // gates = r1 @ Wih[:,1024:].T, both sides, split-K 4 x chunk 256
  k_gemmsk<<<dim3(64,2,4),blk,0,stream>>>(r1,(size_t)B*1024,1024, Wih+1024,2048, Pbuf, 128,4096,256);
  k_lstm2_red<<<dim3((B*1024+255)/256,2),blk,0,stream>>>(Pbuf,(size_t)4*B*4096,4, u,c1, z,B);
  // iter2 attention with per-graph h2 (in z), both sides
  k_attn<<<dim3(B,2),blk,0,stream>>>(sf,vf,go1,go2, z,2048,4096, z+1024,2048,4096);

  // --- MLP head ---
  k_gemmsk<<<dim3(16,1,16),blk,0,stream>>>(z,0,4096, Wf1,4096, Pbuf, 128,1024,256);
  k_red_bias<<<(B*1024+255)/256,blk,0,stream>>>(Pbuf,16,B*1024,1024,bf1,z1,1);
  k_gemmsk<<<dim3(8,1,8),blk,0,stream>>>(z1,0,1024, Wf2,1024, Pbuf, 128,512,128);
  k_red_bias<<<(B*512+255)/256,blk,0,stream>>>(Pbuf,8,B*512,512,bf2,z2,1);
  k_fc3<<<(B*64+255)/256,blk,0,stream>>>(z2,Wf3,bf3,out,B);
}

// Round 5
// 385.615 us; speedup vs baseline: 1.2168x; 1.0848x over previous
//
#include <hip/hip_runtime.h>

#define DEV __device__ __forceinline__

typedef _Float16 half8 __attribute__((ext_vector_type(8)));
typedef _Float16 half4_t __attribute__((ext_vector_type(4)));
typedef float f32x4 __attribute__((ext_vector_type(4)));

DEV float ftanh(float x){
  float ax = fabsf(x);
  float e = __expf(-2.f*ax);
  float t = (1.f - e)/(1.f + e);
  return x < 0.f ? -t : t;
}
DEV float fsigm(float x){ return 1.f/(1.f + expf(-x)); }
DEV float wredsum(float v){
  #pragma unroll
  for (int o=32;o;o>>=1) v += __shfl_xor(v,o,64);
  return v;
}
DEV f32x4 MF(half8 a, half8 b, f32x4 c){
  return __builtin_amdgcn_mfma_f32_16x16x32_f16(a,b,c,0,0,0);
}
DEV void split8(float4 a0, float4 a1, half8& h, half8& l){
  float f[8] = {a0.x,a0.y,a0.z,a0.w,a1.x,a1.y,a1.z,a1.w};
  #pragma unroll
  for (int e=0;e<8;++e){
    _Float16 hh = (_Float16)f[e];
    h[e] = hh;
    l[e] = (_Float16)(f[e] - (float)hh);
  }
}

// ---------------- graph prep ----------------
__global__ void k_zero_i32(int* __restrict__ p, int n){
  int i = blockIdx.x*256 + threadIdx.x; if (i<n) p[i]=0;
}

__global__ void k_hist2(const int* __restrict__ s1, const int* __restrict__ d1, int E1,
                        int* __restrict__ co1, int* __restrict__ ci1,
                        const int* __restrict__ s2, const int* __restrict__ d2, int E2,
                        int* __restrict__ co2, int* __restrict__ ci2){
  int e = blockIdx.x*256 + threadIdx.x;
  if (e < E1){ atomicAdd(&co1[s1[e]],1); atomicAdd(&ci1[d1[e]],1); }
  int f = e - E1;
  if (f >= 0 && f < E2){ atomicAdd(&co2[s2[f]],1); atomicAdd(&ci2[d2[f]],1); }
}

__global__ void k_scan2(const int* __restrict__ c1, int n1, int* __restrict__ r1,
                        const int* __restrict__ c2, int n2, int* __restrict__ r2){
  __shared__ int sm[1024];
  const int* cnt = blockIdx.x ? c2 : c1;
  int*       row = blockIdx.x ? r2 : r1;
  int n          = blockIdx.x ? n2 : n1;
  int t = threadIdx.x;
  int per = n/1024 + 1;
  int st = t*per;
  int s = 0;
  for (int i=st;i<st+per;++i) if (i<n) s += cnt[i];
  sm[t]=s; __syncthreads();
  for (int o=1;o<1024;o<<=1){
    int v = (t>=o)? sm[t-o]:0;
    __syncthreads();
    sm[t] += v;
    __syncthreads();
  }
  int base = sm[t]-s;
  for (int i=st;i<st+per;++i){
    if (i<=n) row[i]=base;
    if (i<n) base += cnt[i];
  }
}

__global__ void k_scale2(const int* __restrict__ co1, const int* __restrict__ ci1, int n1,
                         float* __restrict__ os1, float* __restrict__ is1,
                         const int* __restrict__ co2, const int* __restrict__ ci2, int n2,
                         float* __restrict__ os2, float* __restrict__ is2){
  int i = blockIdx.x*256+threadIdx.x;
  if (i<n1){
    int a = co1[i] > 1 ? co1[i] : 1;
    int b = ci1[i] > 1 ? ci1[i] : 1;
    os1[i] = 1.f/sqrtf((float)a);
    is1[i] = 1.f/sqrtf((float)b);
  }
  int j = i - n1;
  if (j>=0 && j<n2){
    int a = co2[j] > 1 ? co2[j] : 1;
    int b = ci2[j] > 1 ? ci2[j] : 1;
    os2[j] = 1.f/sqrtf((float)a);
    is2[j] = 1.f/sqrtf((float)b);
  }
}

__global__ void k_scatter2(const int* __restrict__ s1, const int* __restrict__ d1, int E1,
                           const int* __restrict__ row1, int* __restrict__ cur1, int* __restrict__ csr1,
                           const int* __restrict__ s2, const int* __restrict__ d2, int E2,
                           const int* __restrict__ row2, int* __restrict__ cur2, int* __restrict__ csr2){
  int e = blockIdx.x*256+threadIdx.x;
  if (e<E1){ int d=d1[e]; int p=atomicAdd(&cur1[d],1); csr1[row1[d]+p]=s1[e]; }
  int f = e - E1;
  if (f>=0 && f<E2){ int d=d2[f]; int p=atomicAdd(&cur2[d],1); csr2[row2[d]+p]=s2[f]; }
}

// goff binary search + PARALLEL packed-plane prefix (pb, 32-aligned) + group->graph map (gm).
// Replaces the former serial per-side loop (was ~42 us of dependent-latency chain):
// per-thread padded count -> Hillis-Steele scan in LDS (both sides concurrently) ->
// per-thread pb write + <=4 gm writes.
__global__ void k_goff2(const int* __restrict__ g1, int n1, int* __restrict__ o1,
                        const int* __restrict__ g2, int n2, int* __restrict__ o2, int B,
                        int* __restrict__ pb1, int* __restrict__ gm1,
                        int* __restrict__ pb2, int* __restrict__ gm2){
  __shared__ int sc[2][256];
  int t = threadIdx.x;
  const int* gid = (t>=256)? g2 : g1;
  int*      goff = (t>=256)? o2 : o1;
  int n          = (t>=256)? n2 : n1;
  const int side = t>>8, q = t & 255;
  if (q<=B){
    int lo=0, hi=n;
    while (lo<hi){ int mid=(lo+hi)>>1; if (gid[mid]<q) lo=mid+1; else hi=mid; }
    goff[q]=lo;
  }
  __syncthreads();
  int pc = 0;
  if (q < B){
    const int* go = side ? o2 : o1;
    int c = go[q+1]-go[q]; if (c>128) c=128;
    pc = (c+31)&~31;
  }
  sc[side][q] = pc;
  __syncthreads();
  for (int o=1;o<B;o<<=1){
    int v = (q>=o && q<B) ? sc[side][q-o] : 0;
    __syncthreads();
    if (q<B) sc[side][q] += v;
    __syncthreads();
  }
  if (q < B){
    int incl = sc[side][q];
    int pbv  = incl - pc;
    int* pb = side ? pb2 : pb1;
    int* gm = side ? gm2 : gm1;
    pb[q] = pbv;
    if (q == B-1) pb[B] = incl;
    int nb = pc>>5, b0 = pbv>>5;
    for (int k=0;k<nb;++k) gm[b0+k] = q;
  }
}

// gather aggregation with split-f16 output planes:
// acc[node] = sum_{e in in(node)} x[src_e] * (osc? osc[src_e] : 1) ; oh=f16(acc), ol=f16(acc-oh)
__global__ void k_agg_h(const float* __restrict__ x, int ldx, const float* __restrict__ osc,
                        const int* __restrict__ row, const int* __restrict__ csr,
                        _Float16* __restrict__ oh, _Float16* __restrict__ ol, int n, int f4shift){
  int F4 = 1<<f4shift;
  int node = blockIdx.x*(256>>f4shift) + (threadIdx.x>>f4shift);
  if (node>=n) return;
  int fc = threadIdx.x & (F4-1);
  int F = F4<<2;
  int rs=row[node], re=row[node+1];
  float ax=0, ay=0, az=0, aw=0;
  if (osc){
    for (int e=rs;e<re;++e){
      int s = csr[e];
      float sc = osc[s];
      const float4 v = *(const float4*)(x + (size_t)s*ldx + (fc<<2));
      ax += sc*v.x; ay += sc*v.y; az += sc*v.z; aw += sc*v.w;
    }
  } else {
    int e = rs;
    for (; e+1<re; e+=2){
      int s0 = csr[e], s1 = csr[e+1];
      const float4 v0 = *(const float4*)(x + (size_t)s0*ldx + (fc<<2));
      const float4 v1 = *(const float4*)(x + (size_t)s1*ldx + (fc<<2));
      ax += v0.x+v1.x; ay += v0.y+v1.y; az += v0.z+v1.z; aw += v0.w+v1.w;
    }
    if (e<re){
      int s0 = csr[e];
      const float4 v0 = *(const float4*)(x + (size_t)s0*ldx + (fc<<2));
      ax += v0.x; ay += v0.y; az += v0.z; aw += v0.w;
    }
  }
  half4_t hv, lv;
  hv.x = (_Float16)ax; lv.x = (_Float16)(ax - (float)hv.x);
  hv.y = (_Float16)ay; lv.y = (_Float16)(ay - (float)hv.y);
  hv.z = (_Float16)az; lv.z = (_Float16)(az - (float)hv.z);
  hv.w = (_Float16)aw; lv.w = (_Float16)(aw - (float)hv.w);
  size_t o = (size_t)node*F + (fc<<2);
  *(half4_t*)(oh + o) = hv;
  *(half4_t*)(ol + o) = lv;
}

// pack 4 GraphConv weights (fp32 [K][N]) into split-f16 hi/lo, k8-packed layout:
// element (k,n) -> plane[ ((k>>3)*N + n)*8 + (k&7) ]
__global__ void k_wpack4(const float* __restrict__ W0, const float* __restrict__ W1,
                         const float* __restrict__ W2, const float* __restrict__ W3,
                         _Float16* __restrict__ h0, _Float16* __restrict__ l0,
                         _Float16* __restrict__ h1, _Float16* __restrict__ l1,
                         _Float16* __restrict__ h2, _Float16* __restrict__ l2,
                         _Float16* __restrict__ h3, _Float16* __restrict__ l3){
  int w = blockIdx.y;
  const float* W = (w==0)?W0:(w==1)?W1:(w==2)?W2:W3;
  _Float16* oh = (w==0)?h0:(w==1)?h1:(w==2)?h2:h3;
  _Float16* ol = (w==0)?l0:(w==1)?l1:(w==2)?l2:l3;
  int K   = (w&1)? 256 : 128;
  int nsh = (w&1)? 9 : 8;
  int i = blockIdx.x*256 + threadIdx.x;
  if (i >= (K<<nsh)) return;
  int k = i >> nsh, n = i & ((1<<nsh)-1);
  float v = W[i];
  _Float16 h = (_Float16)v;
  _Float16 l = (_Float16)(v - (float)h);
  size_t p = (((size_t)(k>>3)<<nsh) + n)*8 + (k&7);
  oh[p] = h; ol[p] = l;
}

// ------- k_gconv_mfma: dual-side split-f16 MFMA GEMM (see round-0 notes).
__global__ __launch_bounds__(256)
void k_gconv_mfma(const _Float16* __restrict__ Ah0, const _Float16* __restrict__ Al0,
                  const _Float16* __restrict__ Ah1, const _Float16* __restrict__ Al1,
                  const _Float16* __restrict__ Bh0, const _Float16* __restrict__ Bl0,
                  const _Float16* __restrict__ Bh1, const _Float16* __restrict__ Bl1,
                  float* __restrict__ C0, float* __restrict__ C1, int ldc,
                  int M0, int M1, int N, int K,
                  const float* __restrict__ rs0, const float* __restrict__ rs1,
                  const float* __restrict__ bi0, const float* __restrict__ bi1, int relu,
                  const float* __restrict__ po0, const float* __restrict__ po1)
{
  __shared__ __align__(16) _Float16 As[2][4096];   // [kb(4)][m(128)][8]
  __shared__ __align__(16) _Float16 Bs[2][4096];   // [kb(4)][n(128)][8]

  const int gx = gridDim.x, gxy = gridDim.x*gridDim.y;
  const int nwg = gxy*2;
  int fid = blockIdx.x + gx*blockIdx.y + gxy*blockIdx.z;
  int q = nwg>>3, r = nwg&7;
  int xcd = fid & 7, idx = fid >> 3;
  int sid = (xcd<r ? xcd*(q+1) : r*(q+1)+(xcd-r)*q) + idx;
  const int z  = sid / gxy;  int rem = sid - z*gxy;
  const int by = rem / gx,  bx = rem - by*gx;

  const _Float16* Ah = z ? Ah1 : Ah0;
  const _Float16* Al = z ? Al1 : Al0;
  const _Float16* Bh = z ? Bh1 : Bh0;
  const _Float16* Bl = z ? Bl1 : Bl0;
  float*       C  = z ? C1 : C0;
  const float* rsc = z ? rs1 : rs0;
  const float* bia = z ? bi1 : bi0;
  const float* po  = z ? po1 : po0;
  const int M = z ? M1 : M0;

  const int row0 = by << 7;
  const int col0 = bx << 7;
  if (row0 >= ((M+127)&~127)) return;

  const int tid = threadIdx.x;
  const int am  = tid >> 2;
  const int akb = tid & 3;
  const int bn  = tid & 127;
  const int bkb = tid >> 7;
  const int wid = tid >> 6, lane = tid & 63;
  const int wr = wid >> 1, wc = wid & 1;
  const int lr = lane & 15, lg = lane >> 4;

  const size_t ldb8 = (size_t)N * 8;
  f32x4 acc[4][4] = {};

  const int kpt = K >> 5;     // K-steps per term
  const int nt  = 3 * kpt;    // total K-steps (hi*hi, lo*hi, hi*lo)

  half8 ga0, ga1, gb0, gb1;
  {
    const _Float16* Ap = Ah + (size_t)(row0 + am) * K + (akb<<3);
    ga0 = *(const half8*)(Ap);
    ga1 = *(const half8*)(Ap + (size_t)64 * K);
    const _Float16* Bp = Bh + (size_t)bkb * ldb8 + (size_t)(col0 + bn) * 8;
    gb0 = *(const half8*)(Bp);
    gb1 = *(const half8*)(Bp + 2*ldb8);
  }
  *(half8*)&As[0][(akb*128 + am)*8]        = ga0;
  *(half8*)&As[0][(akb*128 + am + 64)*8]   = ga1;
  *(half8*)&Bs[0][(bkb*128 + bn)*8]        = gb0;
  *(half8*)&Bs[0][((bkb+2)*128 + bn)*8]    = gb1;
  __syncthreads();

  int term = 0, kk = 32;    // coordinates of the NEXT tile (t+1)
  if (kk == K){ kk = 0; term = 1; }
  for (int t = 0; t < nt; ++t){
    const int cb = t & 1;
    if (t + 1 < nt){
      const _Float16* Asrc = (term == 1) ? Al : Ah;
      const _Float16* Bsrc = (term == 2) ? Bl : Bh;
      const _Float16* Ap = Asrc + (size_t)(row0 + am) * K + kk + (akb<<3);
      ga0 = *(const half8*)(Ap);
      ga1 = *(const half8*)(Ap + (size_t)64 * K);
      const _Float16* Bp = Bsrc + (size_t)((kk>>3) + bkb) * ldb8 + (size_t)(col0 + bn) * 8;
      gb0 = *(const half8*)(Bp);
      gb1 = *(const half8*)(Bp + 2*ldb8);
      kk += 32; if (kk == K){ kk = 0; ++term; }
    }
    {
      const _Float16* Abase = &As[cb][((lg<<7) + (wr<<6) + lr)<<3];
      const _Float16* Bbase = &Bs[cb][((lg<<7) + (wc<<6) + lr)<<3];
      half8 af[4], bf[4];
      #pragma unroll
      for (int i=0;i<4;++i){
        af[i] = *(const half8*)(Abase + i*128);
        bf[i] = *(const half8*)(Bbase + i*128);
      }
      #pragma unroll
      for (int mi=0; mi<4; ++mi){
        #pragma unroll
        for (int ni=0; ni<4; ++ni){
          acc[mi][ni] = __builtin_amdgcn_mfma_f32_16x16x32_f16(af[mi], bf[ni], acc[mi][ni], 0, 0, 0);
        }
      }
    }
    if (t + 1 < nt){
      const int nb_ = cb ^ 1;
      *(half8*)&As[nb_][(akb*128 + am)*8]      = ga0;
      *(half8*)&As[nb_][(akb*128 + am + 64)*8] = ga1;
      *(half8*)&Bs[nb_][(bkb*128 + bn)*8]      = gb0;
      *(half8*)&Bs[nb_][((bkb+2)*128 + bn)*8]  = gb1;
    }
    __syncthreads();
  }

  // epilogue: D row = row0 + wr*64 + mi*16 + lg*4 + j ; col = col0 + wc*64 + ni*16 + lr
  #pragma unroll
  for (int ni = 0; ni < 4; ++ni){
    int cc = col0 + (wc<<6) + (ni<<4) + lr;
    float bv = bia ? bia[cc] : 0.f;
    #pragma unroll
    for (int mi = 0; mi < 4; ++mi){
      int rbase = row0 + (wr<<6) + (mi<<4) + (lg<<2);
      #pragma unroll
      for (int j = 0; j < 4; ++j){
        int rr = rbase + j;
        if (rr < M){
          float rs_ = rsc ? rsc[rr] : 1.f;
          float v = acc[mi][ni][j]*rs_ + bv;
          if (relu) v = fmaxf(v, 0.f);
          if (po) v *= po[rr];
          C[(size_t)rr*ldc + cc] = v;
        }
      }
    }
  }
}

// ------- k_pack: repack sf/vf[:, 0:512) into per-graph 32-aligned node-packed
// split-f16 planes: elem(node j, feat f) -> plane[(j>>3)*4096 + f*8 + (j&7)],
// node index = pb[g] + local; padding nodes written as ZERO.
__global__ __launch_bounds__(256)
void k_pack(const float* __restrict__ sf, const float* __restrict__ vf,
            const int* __restrict__ go1, const int* __restrict__ go2,
            const int* __restrict__ pb1, const int* __restrict__ pb2,
            const int* __restrict__ gm1, const int* __restrict__ gm2,
            _Float16* __restrict__ p1h, _Float16* __restrict__ p1l,
            _Float16* __restrict__ p2h, _Float16* __restrict__ p2l, int B)
{
  __shared__ float st[32][516];
  const int side = blockIdx.y;
  const float* x = side ? vf : sf;
  const int* go = side ? go2 : go1;
  const int* pb = side ? pb2 : pb1;
  const int* gm = side ? gm2 : gm1;
  _Float16* ph = side ? p2h : p1h;
  _Float16* pl = side ? p2l : p1l;
  const int u = blockIdx.x;
  if (u*32 >= pb[B]) return;
  const int g = gm[u];
  const int j0 = u*32 - pb[g];
  const int base = go[g];
  int cnt = go[g+1]-base; if (cnt>128) cnt=128;
  const int t = threadIdx.x;
  const int r = t>>3, f0 = (t&7)<<2;
  const bool valid = (j0 + r) < cnt;
  const float* src = x + (size_t)(base + j0 + r)*1024;
  #pragma unroll
  for (int q=0;q<16;++q){
    int f = f0 + (q<<5);
    float4 vv;
    if (valid) vv = *(const float4*)(src + f);
    else { vv.x=0.f; vv.y=0.f; vv.z=0.f; vv.w=0.f; }
    *(float4*)&st[r][f] = vv;
  }
  __syncthreads();
  #pragma unroll
  for (int q=0;q<8;++q){
    int u2 = t + (q<<8);
    int jg = u2>>9, f = u2&511;
    half8 h8, l8;
    #pragma unroll
    for (int e=0;e<8;++e){
      float vvv = st[(jg<<3)+e][f];
      _Float16 hh = (_Float16)vvv;
      h8[e]=hh; l8[e]=(_Float16)(vvv-(float)hh);
    }
    size_t a = ((size_t)((u<<2)+jg)<<12) + ((size_t)f<<3);
    *(half8*)(ph + a) = h8;
    *(half8*)(pl + a) = l8;
  }
}

// ------- k_T: LDS-staged split-f16 MFMA interaction tiles, one block per
// (graph, 16-row tile of T0). T0 = tanh(s.v^T) computed ONCE; T1 = T0^T written
// directly (transposed stores). Coalesced fp32 staging; frag reads from LDS.
// Coverage: rows [0, ceil32(c1)), cols [0, ceil32(c2)) — exactly what k_apply reads.
__global__ __launch_bounds__(256)
void k_T(const float* __restrict__ sf, const float* __restrict__ vf,
         const int* __restrict__ go1, const int* __restrict__ go2,
         _Float16* __restrict__ Th, _Float16* __restrict__ Tl, int B)
{
  __shared__ __align__(16) _Float16 Ahs[64*136 + 8];   // [fg64][r16][8], fg stride 136
  __shared__ __align__(16) _Float16 Als[64*136 + 8];
  __shared__ __align__(16) _Float16 Bhs[2][2048];      // [buf][fg4][c64][8], c XOR-swizzled
  __shared__ __align__(16) _Float16 Bls[2][2048];
  const int g = blockIdx.x, rt = blockIdx.y;
  int gR = go1[g]; int c1 = go1[g+1]-gR; if (c1>128) c1=128;
  int gO = go2[g]; int c2 = go2[g+1]-gO; if (c2>128) c2=128;
  const int c1_32 = (c1+31)&~31, c2_32 = (c2+31)&~31;
  if ((rt<<4) >= c1_32 || c2_32 == 0) return;
  const int tid = threadIdx.x;
  // ---- stage A: 16 rows x 512 feats, coalesced row reads, split-f16 to LDS
  {
    const int r = tid >> 4;               // 0..15
    const int f0 = (tid & 15) << 5;       // 0,32,..,480
    const int row = (rt<<4) + r;
    const bool val = row < c1;
    const float* src = sf + (size_t)(gR + row)*1024 + f0;
    #pragma unroll
    for (int q=0;q<4;++q){
      float4 v0, v1;
      if (val){
        v0 = *(const float4*)(src + (q<<3));
        v1 = *(const float4*)(src + (q<<3) + 4);
      } else {
        v0.x=0.f; v0.y=0.f; v0.z=0.f; v0.w=0.f; v1 = v0;
      }
      half8 h,l; split8(v0,v1,h,l);
      const int a = ((f0>>3) + q)*136 + (r<<3);
      *(half8*)&Ahs[a] = h; *(half8*)&Als[a] = l;
    }
  }
  const int w = tid>>6, lane = tid&63, lr = lane&15, lg = lane>>4;
  const int bc = tid>>2, bfg = tid&3, bf = bfg<<3;   // B stage: row-in-chunk, feat-group
  const int bwr = (bfg<<9) + ((bc ^ (bfg<<2))<<3);   // B LDS write addr (swizzled)
  const int ncc = (c2_32 + 63) >> 6;
  _Float16* T0h = Th + ((size_t)g<<14);
  _Float16* T0l = Tl + ((size_t)g<<14);
  _Float16* T1h = Th + ((size_t)(B + g)<<14);
  _Float16* T1l = Tl + ((size_t)(B + g)<<14);
  for (int cc=0; cc<ncc; ++cc){
    const int cbase = cc<<6;
    const int colr = cbase + bc;
    const bool bval = colr < c2;
    const float* bsrc = vf + (size_t)(gO + colr)*1024 + bf;
    // stage B chunk kc=0
    {
      float4 v0, v1;
      if (bval){ v0 = *(const float4*)(bsrc); v1 = *(const float4*)(bsrc + 4); }
      else { v0.x=0.f; v0.y=0.f; v0.z=0.f; v0.w=0.f; v1 = v0; }
      half8 h,l; split8(v0,v1,h,l);
      *(half8*)&Bhs[0][bwr] = h; *(half8*)&Bls[0][bwr] = l;
    }
    __syncthreads();
    f32x4 acc = {0.f,0.f,0.f,0.f};
    const int col_l = (w<<4) + lr;
    const int ba = (lg<<9) + ((col_l ^ (lg<<2))<<3);
    for (int kc=0; kc<16; ++kc){
      float4 p0, p1;
      if (kc+1<16){
        if (bval){
          const float* s = bsrc + ((kc+1)<<5);
          p0 = *(const float4*)s; p1 = *(const float4*)(s + 4);
        } else { p0.x=0.f; p0.y=0.f; p0.z=0.f; p0.w=0.f; p1 = p0; }
      }
      const int aa = ((kc<<2)+lg)*136 + (lr<<3);
      half8 ah = *(const half8*)&Ahs[aa];
      half8 al = *(const half8*)&Als[aa];
      half8 bh = *(const half8*)&Bhs[kc&1][ba];
      half8 bl = *(const half8*)&Bls[kc&1][ba];
      acc = MF(ah,bh,acc);
      acc = MF(al,bh,acc);
      acc = MF(ah,bl,acc);
      if (kc+1<16){
        half8 h,l; split8(p0,p1,h,l);
        *(half8*)&Bhs[(kc+1)&1][bwr] = h; *(half8*)&Bls[(kc+1)&1][bwr] = l;
      }
      __syncthreads();
    }
    // epilogue: masked tanh, write T0 (row-major) and T1 = T0^T
    const int col = cbase + col_l;
    if (col < c2_32){
      half4_t t1h, t1l;
      #pragma unroll
      for (int qq=0;qq<4;++qq){
        int r = (rt<<4) + (lg<<2) + qq;
        float t = (r < c1 && col < c2) ? ftanh(acc[qq]) : 0.f;
        _Float16 hh = (_Float16)t;
        _Float16 ll = (_Float16)(t - (float)hh);
        T0h[(r<<7) + col] = hh;
        T0l[(r<<7) + col] = ll;
        t1h[qq] = hh; t1l[qq] = ll;
      }
      const int r0 = (rt<<4) + (lg<<2);
      *(half4_t*)&T1h[(col<<7) + r0] = t1h;
      *(half4_t*)&T1l[(col<<7) + r0] = t1l;
    }
  }
}

// ------- k_apply: own'[r][f] = sum_o T[r][o]*oth[o][f] via MFMA.
// A-frag: row-major T (half8 contiguous). B-frag: node-packed oth plane
// (8 consecutive nodes contiguous at fixed feat). grid (2 sides, B, 2 feat halves).
__global__ __launch_bounds__(256)
void k_apply(const _Float16* __restrict__ Th, const _Float16* __restrict__ Tl,
             const _Float16* __restrict__ p1h, const _Float16* __restrict__ p1l,
             const _Float16* __restrict__ p2h, const _Float16* __restrict__ p2l,
             const int* __restrict__ go1, const int* __restrict__ go2,
             const int* __restrict__ pb1, const int* __restrict__ pb2,
             float* __restrict__ sf, float* __restrict__ vf, int B)
{
  const int side = blockIdx.x, g = blockIdx.y, ft = blockIdx.z;
  const int* goR = side ? go2 : go1;
  const int* goO = side ? go1 : go2;
  const int* pbO = side ? pb1 : pb2;
  const _Float16* oph = side ? p1h : p2h;
  const _Float16* opl = side ? p1l : p2l;
  float* outp = side ? vf : sf;
  int gR = goR[g]; int cR = goR[g+1]-gR; if (cR>128) cR=128;
  int gO = goO[g]; int cO = goO[g+1]-gO; if (cO>128) cO=128;
  if (cR <= 0) return;
  const int pO = pbO[g];
  const int cO32 = (cO+31)&~31;
  const int MR = ((cR+15)&~15)>>4;     // 1..8 row tiles (all within written T rows)
  const _Float16* Tph = Th + ((size_t)(side*B + g)<<14);
  const _Float16* Tpl = Tl + ((size_t)(side*B + g)<<14);
  const int tid = threadIdx.x, w = tid>>6, lane = tid&63;
  const int lr = lane&15, lg = lane>>4;
  const int f0 = (ft<<8) + (w<<6);     // 64 feats per wave
  for (int rc = 0; rc < MR; rc += 4){
    f32x4 acc[4][4];
    #pragma unroll
    for (int a_=0;a_<4;++a_)
      #pragma unroll
      for (int b_=0;b_<4;++b_) acc[a_][b_] = (f32x4){0.f,0.f,0.f,0.f};
    for (int k0=0; k0<cO32; k0+=32){
      half8 bh[4], bl[4];
      #pragma unroll
      for (int nj=0;nj<4;++nj){
        size_t a = ((size_t)((pO + k0)>>3) + lg)*4096 + (size_t)(f0 + (nj<<4) + lr)*8;
        bh[nj] = *(const half8*)(oph + a);
        bl[nj] = *(const half8*)(opl + a);
      }
      #pragma unroll
      for (int mi=0;mi<4;++mi){
        if (rc + mi < MR){
          int a = ((((rc+mi)<<4) + lr)<<7) + k0 + (lg<<3);
          half8 th_ = *(const half8*)&Tph[a];
          half8 tl_ = *(const half8*)&Tpl[a];
          #pragma unroll
          for (int nj=0;nj<4;++nj){
            acc[mi][nj] = MF(th_, bh[nj], acc[mi][nj]);
            acc[mi][nj] = MF(tl_, bh[nj], acc[mi][nj]);
            acc[mi][nj] = MF(th_, bl[nj], acc[mi][nj]);
          }
        }
      }
    }
    #pragma unroll
    for (int mi=0;mi<4;++mi){
      if (rc + mi < MR){
        #pragma unroll
        for (int nj=0;nj<4;++nj){
          #pragma unroll
          for (int qq=0;qq<4;++qq){
            int r = (((rc+mi)<<4)) + (lg<<2) + qq;
            if (r < cR)
              outp[(size_t)(gR + r)*1024 + 512 + f0 + (nj<<4) + lr] = acc[mi][nj][qq];
          }
        }
      }
    }
  }
}

// ------- k_gemmsk: skinny NT GEMM, M=128 x 64-col tile, dbuf LDS, split-K,
// optional dual-side via blockIdx.y. Partials P[(side*splits+z)][M][N].
__global__ __launch_bounds__(256)
void k_gemmsk(const float* __restrict__ Ab, size_t AsideOff, int lda,
              const float* __restrict__ Bm, int ldb,
              float* __restrict__ P, int M, int N, int kchunk)
{
  __shared__ float As[2][16][132];
  __shared__ float Bs[2][16][68];
  const int tid = threadIdx.x;
  const int col0 = (int)blockIdx.x << 6;
  const int kbeg = (int)blockIdx.z * kchunk;
  const float* A = Ab + (size_t)blockIdx.y * AsideOff;
  const int ar = tid >> 1, ak = (tid & 1) << 3;
  const int br = tid >> 2, bk = (tid & 3) << 2;
  const int tx = tid & 15, ty = tid >> 4;
  const float* Arow = A + (size_t)ar * lda + kbeg + ak;
  const float* Brow = Bm + (size_t)(col0 + br) * ldb + kbeg + bk;
  float acc[8][4] = {};
  float4 a0 = *(const float4*)(Arow);
  float4 a1 = *(const float4*)(Arow + 4);
  float4 b0 = *(const float4*)(Brow);
  As[0][ak+0][ar]=a0.x; As[0][ak+1][ar]=a0.y; As[0][ak+2][ar]=a0.z; As[0][ak+3][ar]=a0.w;
  As[0][ak+4][ar]=a1.x; As[0][ak+5][ar]=a1.y; As[0][ak+6][ar]=a1.z; As[0][ak+7][ar]=a1.w;
  Bs[0][bk+0][br]=b0.x; Bs[0][bk+1][br]=b0.y; Bs[0][bk+2][br]=b0.z; Bs[0][bk+3][br]=b0.w;
  __syncthreads();
  const int nt = kchunk >> 4;
  for (int t = 0; t < nt; ++t){
    const int cb = t & 1;
    if (t + 1 < nt){
      int k0 = (t + 1) << 4;
      a0 = *(const float4*)(Arow + k0);
      a1 = *(const float4*)(Arow + k0 + 4);
      b0 = *(const float4*)(Brow + k0);
    }
    #pragma unroll
    for (int kk = 0; kk < 16; ++kk){
      float4 b4 = *(const float4*)&Bs[cb][kk][tx << 2];
      float4 a4 = *(const float4*)&As[cb][kk][ty << 3];
      float4 a5 = *(const float4*)&As[cb][kk][(ty << 3) + 4];
      acc[0][0]+=a4.x*b4.x; acc[0][1]+=a4.x*b4.y; acc[0][2]+=a4.x*b4.z; acc[0][3]+=a4.x*b4.w;
      acc[1][0]+=a4.y*b4.x; acc[1][1]+=a4.y*b4.y; acc[1][2]+=a4.y*b4.z; acc[1][3]+=a4.y*b4.w;
      acc[2][0]+=a4.z*b4.x; acc[2][1]+=a4.z*b4.y; acc[2][2]+=a4.z*b4.z; acc[2][3]+=a4.z*b4.w;
      acc[3][0]+=a4.w*b4.x; acc[3][1]+=a4.w*b4.y; acc[3][2]+=a4.w*b4.z; acc[3][3]+=a4.w*b4.w;
      acc[4][0]+=a5.x*b4.x; acc[4][1]+=a5.x*b4.y; acc[4][2]+=a5.x*b4.z; acc[4][3]+=a5.x*b4.w;
      acc[5][0]+=a5.y*b4.x; acc[5][1]+=a5.y*b4.y; acc[5][2]+=a5.y*b4.z; acc[5][3]+=a5.y*b4.w;
      acc[6][0]+=a5.z*b4.x; acc[6][1]+=a5.z*b4.y; acc[6][2]+=a5.z*b4.z; acc[6][3]+=a5.z*b4.w;
      acc[7][0]+=a5.w*b4.x; acc[7][1]+=a5.w*b4.y; acc[7][2]+=a5.w*b4.z; acc[7][3]+=a5.w*b4.w;
    }
    if (t + 1 < nt){
      const int nb = cb ^ 1;
      As[nb][ak+0][ar]=a0.x; As[nb][ak+1][ar]=a0.y; As[nb][ak+2][ar]=a0.z; As[nb][ak+3][ar]=a0.w;
      As[nb][ak+4][ar]=a1.x; As[nb][ak+5][ar]=a1.y; As[nb][ak+6][ar]=a1.z; As[nb][ak+7][ar]=a1.w;
      Bs[nb][bk+0][br]=b0.x; Bs[nb][bk+1][br]=b0.y; Bs[nb][bk+2][br]=b0.z; Bs[nb][bk+3][br]=b0.w;
    }
    __syncthreads();
  }
  float* Pz = P + (size_t)(blockIdx.y*gridDim.z + blockIdx.z) * M * N;
  #pragma unroll
  for (int i = 0; i < 8; ++i){
    int rr = (ty << 3) + i;
    float4 v = {acc[i][0], acc[i][1], acc[i][2], acc[i][3]};
    *(float4*)(Pz + (size_t)rr*N + col0 + (tx<<2)) = v;
  }
}

// sum split partials + bias (+relu)
__global__ void k_red_bias(const float* __restrict__ P, int split, int MN, int N,
                           const float* __restrict__ bias, float* __restrict__ C, int relu){
  int i = blockIdx.x*256 + threadIdx.x;
  if (i >= MN) return;
  float v = bias[i & (N-1)];
  for (int s=0;s<split;++s) v += P[(size_t)s*MN + i];
  if (relu) v = fmaxf(v, 0.f);
  C[i] = v;
}

// ---------------- Set2Set ----------------
__global__ void k_lstm1(const float* __restrict__ bih, const float* __restrict__ bhh,
                        float* __restrict__ c1, float* __restrict__ h1){
  int j = blockIdx.x*256 + threadIdx.x;
  if (j >= 1024) return;
  float gi = bih[j]        + bhh[j];
  float gg = bih[j+2048]   + bhh[j+2048];
  float go = bih[j+3072]   + bhh[j+3072];
  float cc = fsigm(gi)*ftanh(gg);
  c1[j] = cc;
  h1[j] = fsigm(go)*ftanh(cc);
}

__global__ void k_gemv_u(const float* __restrict__ Wih, const float* __restrict__ Whh,
                         const float* __restrict__ bih, const float* __restrict__ bhh,
                         const float* __restrict__ h1, float* __restrict__ u){
  int w = (blockIdx.x*256 + threadIdx.x)>>6;
  int lane = threadIdx.x & 63;
  if (w >= 4096) return;
  const float* wi = Wih + (size_t)w*2048;
  const float* wh = Whh + (size_t)w*1024;
  float acc = 0.f;
  #pragma unroll
  for (int qq=0;qq<4;++qq){
    int o = qq*256 + (lane<<2);
    float4 hv = *(const float4*)(h1 + o);
    float4 a  = *(const float4*)(wi + o);
    float4 b  = *(const float4*)(wh + o);
    acc += hv.x*(a.x+b.x) + hv.y*(a.y+b.y) + hv.z*(a.z+b.z) + hv.w*(a.w+b.w);
  }
  acc = wredsum(acc);
  if (lane==0) u[w] = acc + bih[w] + bhh[w];
}

// fused attention, dual-side (blockIdx.y): online segment softmax + weighted sum
__global__ __launch_bounds__(256)
void k_attn(const float* __restrict__ sf, const float* __restrict__ vf,
            const int* __restrict__ go1, const int* __restrict__ go2,
            const float* __restrict__ hbase, size_t hSideOff, int hstride,
            float* __restrict__ outbase, size_t oSideOff, int ldout)
{
  __shared__ float hs[1024];
  __shared__ float ech[1024];
  __shared__ float red[8];
  int side = blockIdx.y;
  const float* x = side? vf : sf;
  const int* goff = side? go2 : go1;
  const float* hsrc = hbase + (size_t)side*hSideOff;
  float* outp = outbase + (size_t)side*oSideOff;
  int b = blockIdx.x, t = threadIdx.x;
  int i0 = goff[b], i1 = goff[b+1];
  int lane = t & 63, wv = t >> 6;
  { float4 hv = *(const float4*)(hsrc + (size_t)b*hstride + (t<<2));
    *(float4*)&hs[t<<2] = hv; }
  __syncthreads();
  float m = -3.0e38f, s = 0.f;
  float ax=0, ay=0, az=0, aw=0;
  for (int c = i0; c < i1; c += 1024){
    int ce = c + 1024; if (ce > i1) ce = i1;
    int n = ce - c;
    float wmax = -3.0e38f;
    for (int i = c + wv; i < ce; i += 4){
      const float* xr = x + (size_t)i*1024;
      float d = 0.f;
      #pragma unroll
      for (int qq=0;qq<4;++qq){
        int o = qq*256 + (lane<<2);
        float4 xv = *(const float4*)(xr+o);
        float4 h4 = *(const float4*)&hs[o];
        d += xv.x*h4.x + xv.y*h4.y + xv.z*h4.z + xv.w*h4.w;
      }
      d = wredsum(d);
      if (lane==0) ech[i-c] = d;
      wmax = fmaxf(wmax, d);
    }
    if (lane==0) red[wv] = wmax;
    __syncthreads();
    float cm = fmaxf(fmaxf(red[0],red[1]), fmaxf(red[2],red[3]));
    float nm = fmaxf(m, cm);
    float scale = __expf(m - nm);
    s *= scale; ax*=scale; ay*=scale; az*=scale; aw*=scale;
    float ps = 0.f;
    for (int k = t; k < n; k += 256) ps += __expf(ech[k]-nm);
    ps = wredsum(ps);
    __syncthreads();
    if (lane==0) red[wv] = ps;
    __syncthreads();
    s += red[0]+red[1]+red[2]+red[3];
    for (int k = 0; k < n; ++k){
      float w = __expf(ech[k]-nm);
      float4 xv = *(const float4*)(x + (size_t)(c+k)*1024 + (t<<2));
      ax += w*xv.x; ay += w*xv.y; az += w*xv.z; aw += w*xv.w;
    }
    m = nm;
    __syncthreads();
  }
  float inv = (i1>i0 && s>0.f) ? 1.f/s : 0.f;
  float4 o = {ax*inv, ay*inv, az*inv, aw*inv};
  *(float4*)(outp + (size_t)b*ldout + (t<<2)) = o;
}

// LSTM iter2 (dual-side via blockIdx.y): sum split gate partials + u, cell/hidden
__global__ void k_lstm2_red(const float* __restrict__ Pb, size_t PsideOff, int split,
                            const float* __restrict__ u, const float* __restrict__ c1,
                            float* __restrict__ z, int B){
  int idx = blockIdx.x*256 + threadIdx.x;
  if (idx >= B*1024) return;
  int side = blockIdx.y;
  const float* P = Pb + (size_t)side*PsideOff;
  int b = idx >> 10, j = idx & 1023;
  float gi=u[j], gf=u[j+1024], gg=u[j+2048], go=u[j+3072];
  const float* g = P + (size_t)b*4096;
  for (int s=0;s<split;++s){
    const float* gs = g + (size_t)s*B*4096;
    gi += gs[j]; gf += gs[j+1024]; gg += gs[j+2048]; go += gs[j+3072];
  }
  float cc = fsigm(gf)*c1[j] + fsigm(gi)*ftanh(gg);
  z[(size_t)b*4096 + side*2048 + j] = fsigm(go)*ftanh(cc);
}

__global__ void k_fc3(const float* __restrict__ z2, const float* __restrict__ w3,
                      const float* __restrict__ b3, float* __restrict__ out, int B){
  int wv = (blockIdx.x*256+threadIdx.x)>>6;
  int lane = threadIdx.x & 63;
  if (wv >= B) return;
  const float* zr = z2 + (size_t)wv*512;
  float acc=0.f;
  #pragma unroll
  for (int qq=0;qq<2;++qq){
    int o = qq*256 + (lane<<2);
    float4 a  = *(const float4*)(zr + o);
    float4 ww = *(const float4*)(w3 + o);
    acc += a.x*ww.x + a.y*ww.y + a.z*ww.z + a.w*ww.w;
  }
  acc = wredsum(acc);
  if (lane==0) out[wv] = acc + b3[0];
}

// ---------------- driver ----------------
extern "C" void kernel_launch(void* const* d_in, const int* in_sizes, int n_in,
                              void* d_out, int out_size, void* d_ws, size_t ws_size,
                              hipStream_t stream)
{
  const float* x1  = (const float*)d_in[0];
  const float* x2  = (const float*)d_in[1];
  const int* src1  = (const int*)d_in[2];
  const int* dst1  = (const int*)d_in[3];
  const int* src2  = (const int*)d_in[4];
  const int* dst2  = (const int*)d_in[5];
  const int* gid1  = (const int*)d_in[6];
  const int* gid2  = (const int*)d_in[7];
  const float* Wg1 = (const float*)d_in[8];  const float* bg1 = (const float*)d_in[9];
  const float* Wg2 = (const float*)d_in[10]; const float* bg2 = (const float*)d_in[11];
  const float* Wg3 = (const float*)d_in[12]; const float* bg3 = (const float*)d_in[13];
  const float* Wg4 = (const float*)d_in[14]; const float* bg4 = (const float*)d_in[15];
  const float* Wih = (const float*)d_in[16]; const float* Whh = (const float*)d_in[17];
  const float* bih = (const float*)d_in[18]; const float* bhh = (const float*)d_in[19];
  const float* Wf1 = (const float*)d_in[20]; const float* bf1 = (const float*)d_in[21];
  const float* Wf2 = (const float*)d_in[22]; const float* bf2 = (const float*)d_in[23];
  const float* Wf3 = (const float*)d_in[24]; const float* bf3 = (const float*)d_in[25];
  float* out = (float*)d_out;

  const int N1 = in_sizes[0]/128;
  const int N2 = in_sizes[1]/128;
  const int E1 = in_sizes[2];
  const int E2 = in_sizes[4];
  const int B  = out_size;            // 128
  const int NM = N1>N2?N1:N2;

  char* base = (char*)d_ws; size_t off=0;
  auto alloc = [&](size_t bytes)->void*{ void* p = base+off; off += (bytes+255)&~(size_t)255; return p; };

  int* zr   = (int*)alloc(sizeof(int)*(size_t)(3*N1+3*N2));
  int* co1=zr, *ci1=zr+N1, *cur1=zr+2*N1;
  int* co2=zr+3*N1, *ci2=zr+3*N1+N2, *cur2=zr+3*N1+2*N2;
  int* row1 = (int*)alloc(sizeof(int)*(size_t)(N1+1));
  int* row2 = (int*)alloc(sizeof(int)*(size_t)(N2+1));
  int* csr1 = (int*)alloc(sizeof(int)*(size_t)E1);
  int* csr2 = (int*)alloc(sizeof(int)*(size_t)E2);
  int* go1  = (int*)alloc(sizeof(int)*(size_t)(B+1));
  int* go2  = (int*)alloc(sizeof(int)*(size_t)(B+1));
  int* pb1  = (int*)alloc(sizeof(int)*(size_t)(B+1));
  int* pb2  = (int*)alloc(sizeof(int)*(size_t)(B+1));
  int* gm1  = (int*)alloc(sizeof(int)*1024);
  int* gm2  = (int*)alloc(sizeof(int)*1024);
  float* os1 = (float*)alloc(sizeof(float)*(size_t)N1);
  float* is1 = (float*)alloc(sizeof(float)*(size_t)N1);
  float* os2 = (float*)alloc(sizeof(float)*(size_t)N2);
  float* is2 = (float*)alloc(sizeof(float)*(size_t)N2);
  _Float16* a1h = (_Float16*)alloc(sizeof(_Float16)*(size_t)(NM+128)*256);
  _Float16* a1l = (_Float16*)alloc(sizeof(_Float16)*(size_t)(NM+128)*256);
  _Float16* a2h = (_Float16*)alloc(sizeof(_Float16)*(size_t)(NM+128)*256);
  _Float16* a2l = (_Float16*)alloc(sizeof(_Float16)*(size_t)(NM+128)*256);
  _Float16* wg1h = (_Float16*)alloc(sizeof(_Float16)*32768);
  _Float16* wg1l = (_Float16*)alloc(sizeof(_Float16)*32768);
  _Float16* wg2h = (_Float16*)alloc(sizeof(_Float16)*131072);
  _Float16* wg2l = (_Float16*)alloc(sizeof(_Float16)*131072);
  _Float16* wg3h = (_Float16*)alloc(sizeof(_Float16)*32768);
  _Float16* wg3l = (_Float16*)alloc(sizeof(_Float16)*32768);
  _Float16* wg4h = (_Float16*)alloc(sizeof(_Float16)*131072);
  _Float16* wg4l = (_Float16*)alloc(sizeof(_Float16)*131072);
  float* sf  = (float*)alloc(sizeof(float)*(size_t)(N1+128)*1024);
  float* vf  = (float*)alloc(sizeof(float)*(size_t)(N2+128)*1024);
  float* h1 = (float*)alloc(sizeof(float)*1024);
  float* c1 = (float*)alloc(sizeof(float)*1024);
  float* u  = (float*)alloc(sizeof(float)*4096);
  float* r1 = (float*)alloc(sizeof(float)*(size_t)2*B*1024);
  float* z1 = (float*)alloc(sizeof(float)*(size_t)B*1024);
  float* z2 = (float*)alloc(sizeof(float)*(size_t)B*512);
  float* z  = (float*)alloc(sizeof(float)*(size_t)B*4096);
  // T planes: [2 sides][B][128][128] split-f16 (16.8 MB total)
  _Float16* Tqh = (_Float16*)alloc(sizeof(_Float16)*(size_t)2*B*16384);
  _Float16* Tql = (_Float16*)alloc(sizeof(_Float16)*(size_t)2*B*16384);
  // union region: node-packed split-f16 planes (interact stage) / Pbuf partials (later stages)
  const int PN = ((NM + 32*B + 63)&~63) + 64;      // padded node capacity
  const size_t PE = (size_t)PN*512;                // elems per plane
  size_t packedBytes = 4*PE*sizeof(_Float16);
  size_t pbufBytes   = sizeof(float)*(size_t)16*B*1024*4;
  char* uni = (char*)alloc(packedBytes > pbufBytes ? packedBytes : pbufBytes);
  _Float16* p1h = (_Float16*)uni;
  _Float16* p1l = p1h + PE;
  _Float16* p2h = p1l + PE;
  _Float16* p2l = p2h + PE;
  float* Pbuf = (float*)uni;
  if (off > ws_size) return;

  // hbuf regions live inside sf/vf cols [512,768) (stride 1024), overwritten later by apply
  float* hb1 = sf + 512;
  float* hb2 = vf + 512;

  dim3 blk(256);

  // --- weight split-f16 pack (independent of graph prep) ---
  k_wpack4<<<dim3(512,4),blk,0,stream>>>(Wg1,Wg2,Wg3,Wg4,
                                         wg1h,wg1l, wg2h,wg2l, wg3h,wg3l, wg4h,wg4l);

  // --- prep ---
  k_zero_i32<<<(3*N1+3*N2+255)/256, blk, 0, stream>>>(zr, 3*N1+3*N2);
  k_hist2<<<(E1+E2+255)/256, blk, 0, stream>>>(src1,dst1,E1,co1,ci1, src2,dst2,E2,co2,ci2);
  k_scan2<<<2,1024,0,stream>>>(ci1,N1,row1, ci2,N2,row2);
  k_scale2<<<(N1+N2+255)/256,blk,0,stream>>>(co1,ci1,N1,os1,is1, co2,ci2,N2,os2,is2);
  k_scatter2<<<(E1+E2+255)/256,blk,0,stream>>>(src1,dst1,E1,row1,cur1,csr1, src2,dst2,E2,row2,cur2,csr2);
  k_goff2<<<1,512,0,stream>>>(gid1,N1,go1, gid2,N2,go2, B, pb1,gm1, pb2,gm2);

  // --- GraphConv: agg both sides (split-f16 out), dual MFMA GEMM L1 (post=os),
  //     agg (no scale), dual MFMA GEMM L2 ---
  int gy = (NM+127)/128;
  k_agg_h<<<(N1+7)/8,blk,0,stream>>>(x1,128, os1,row1,csr1, a1h,a1l, N1,5);
  k_agg_h<<<(N2+7)/8,blk,0,stream>>>(x2,128, os2,row2,csr2, a2h,a2l, N2,5);
  k_gconv_mfma<<<dim3(2,gy,2),blk,0,stream>>>(a1h,a1l, a2h,a2l,
                                              wg1h,wg1l, wg3h,wg3l,
                                              hb1,hb2,1024, N1,N2, 256,128,
                                              is1,is2, bg1,bg3, 1, os1,os2);
  k_agg_h<<<(N1+3)/4,blk,0,stream>>>(hb1,1024, nullptr,row1,csr1, a1h,a1l, N1,6);
  k_agg_h<<<(N2+3)/4,blk,0,stream>>>(hb2,1024, nullptr,row2,csr2, a2h,a2l, N2,6);
  k_gconv_mfma<<<dim3(4,gy,2),blk,0,stream>>>(a1h,a1l, a2h,a2l,
                                              wg2h,wg2l, wg4h,wg4l,
                                              sf,vf,1024, N1,N2, 512,256,
                                              is1,is2, bg2,bg4, 0, nullptr,nullptr);

  // --- block-diagonal interaction (MFMA; T computed once, transposed write) ---
  const int GMAX = NM/32 + B + 2;
  k_pack<<<dim3(GMAX,2),blk,0,stream>>>(sf,vf, go1,go2, pb1,pb2, gm1,gm2,
                                        p1h,p1l, p2h,p2l, B);
  k_T<<<dim3(B,8),blk,0,stream>>>(sf,vf, go1,go2, Tqh,Tql, B);
  k_apply<<<dim3(2,B,2),blk,0,stream>>>(Tqh,Tql, p1h,p1l, p2h,p2l,
                                        go1,go2, pb1,pb2, sf,vf, B);

  // --- Set2Set (sides merged per stage) ---
  k_lstm1<<<4,blk,0,stream>>>(bih,bhh,c1,h1);
  k_gemv_u<<<1024,blk,0,stream>>>(Wih,Whh,bih,bhh,h1,u);

  // iter1 attention (shared h1), both sides
  k_attn<<<dim3(B,2),blk,0,stream>>>(sf,vf,go1,go2, h1,0,0, r1,(size_t)B*1024,1024);
  // gates = r1 @ Wih[:,1024:].T, both sides, split-K 4 x chunk 256
  k_gemmsk<<<dim3(64,2,4),blk,0,stream>>>(r1,(size_t)B*1024,1024, Wih+1024,2048, Pbuf, 128,4096,256);
  k_lstm2_red<<<dim3((B*1024+255)/256,2),blk,0,stream>>>(Pbuf,(size_t)4*B*4096,4, u,c1, z,B);
  // iter2 attention with per-graph h2 (in z), both sides
  k_attn<<<dim3(B,2),blk,0,stream>>>(sf,vf,go1,go2, z,2048,4096, z+1024,2048,4096);

  // --- MLP head ---
  k_gemmsk<<<dim3(16,1,16),blk,0,stream>>>(z,0,4096, Wf1,4096, Pbuf, 128,1024,256);
  k_red_bias<<<(B*1024+255)/256,blk,0,stream>>>(Pbuf,16,B*1024,1024,bf1,z1,1);
  k_gemmsk<<<dim3(8,1,8),blk,0,stream>>>(z1,0,1024, Wf2,1024, Pbuf, 128,512,128);
  k_red_bias<<<(B*512+255)/256,blk,0,stream>>>(Pbuf,8,B*512,512,bf2,z2,1);
  k_fc3<<<(B*64+255)/256,blk,0,stream>>>(z2,Wf3,bf3,out,B);
}

// Round 6
// 384.529 us; speedup vs baseline: 1.2203x; 1.0028x over previous
//
#include <hip/hip_runtime.h>

#define DEV __device__ __forceinline__

typedef _Float16 half8 __attribute__((ext_vector_type(8)));
typedef _Float16 half4_t __attribute__((ext_vector_type(4)));
typedef float f32x4 __attribute__((ext_vector_type(4)));

DEV float ftanh(float x){
  float ax = fabsf(x);
  float e = __expf(-2.f*ax);
  float t = (1.f - e)/(1.f + e);
  return x < 0.f ? -t : t;
}
DEV float fsigm(float x){ return 1.f/(1.f + expf(-x)); }
DEV float wredsum(float v){
  #pragma unroll
  for (int o=32;o;o>>=1) v += __shfl_xor(v,o,64);
  return v;
}
DEV f32x4 MF(half8 a, half8 b, f32x4 c){
  return __builtin_amdgcn_mfma_f32_16x16x32_f16(a,b,c,0,0,0);
}
DEV void split8(float4 a0, float4 a1, half8& h, half8& l){
  float f[8] = {a0.x,a0.y,a0.z,a0.w,a1.x,a1.y,a1.z,a1.w};
  #pragma unroll
  for (int e=0;e<8;++e){
    _Float16 hh = (_Float16)f[e];
    h[e] = hh;
    l[e] = (_Float16)(f[e] - (float)hh);
  }
}

// ---------------- graph prep ----------------
__global__ void k_zero_i32(int* __restrict__ p, int n){
  int i = blockIdx.x*256 + threadIdx.x; if (i<n) p[i]=0;
}

__global__ void k_hist2(const int* __restrict__ s1, const int* __restrict__ d1, int E1,
                        int* __restrict__ co1, int* __restrict__ ci1,
                        const int* __restrict__ s2, const int* __restrict__ d2, int E2,
                        int* __restrict__ co2, int* __restrict__ ci2){
  int e = blockIdx.x*256 + threadIdx.x;
  if (e < E1){ atomicAdd(&co1[s1[e]],1); atomicAdd(&ci1[d1[e]],1); }
  int f = e - E1;
  if (f >= 0 && f < E2){ atomicAdd(&co2[s2[f]],1); atomicAdd(&ci2[d2[f]],1); }
}

__global__ void k_scan2(const int* __restrict__ c1, int n1, int* __restrict__ r1,
                        const int* __restrict__ c2, int n2, int* __restrict__ r2){
  __shared__ int sm[1024];
  const int* cnt = blockIdx.x ? c2 : c1;
  int*       row = blockIdx.x ? r2 : r1;
  int n          = blockIdx.x ? n2 : n1;
  int t = threadIdx.x;
  int per = n/1024 + 1;
  int st = t*per;
  int s = 0;
  for (int i=st;i<st+per;++i) if (i<n) s += cnt[i];
  sm[t]=s; __syncthreads();
  for (int o=1;o<1024;o<<=1){
    int v = (t>=o)? sm[t-o]:0;
    __syncthreads();
    sm[t] += v;
    __syncthreads();
  }
  int base = sm[t]-s;
  for (int i=st;i<st+per;++i){
    if (i<=n) row[i]=base;
    if (i<n) base += cnt[i];
  }
}

__global__ void k_scale2(const int* __restrict__ co1, const int* __restrict__ ci1, int n1,
                         float* __restrict__ os1, float* __restrict__ is1,
                         const int* __restrict__ co2, const int* __restrict__ ci2, int n2,
                         float* __restrict__ os2, float* __restrict__ is2){
  int i = blockIdx.x*256+threadIdx.x;
  if (i<n1){
    int a = co1[i] > 1 ? co1[i] : 1;
    int b = ci1[i] > 1 ? ci1[i] : 1;
    os1[i] = 1.f/sqrtf((float)a);
    is1[i] = 1.f/sqrtf((float)b);
  }
  int j = i - n1;
  if (j>=0 && j<n2){
    int a = co2[j] > 1 ? co2[j] : 1;
    int b = ci2[j] > 1 ? ci2[j] : 1;
    os2[j] = 1.f/sqrtf((float)a);
    is2[j] = 1.f/sqrtf((float)b);
  }
}

__global__ void k_scatter2(const int* __restrict__ s1, const int* __restrict__ d1, int E1,
                           const int* __restrict__ row1, int* __restrict__ cur1, int* __restrict__ csr1,
                           const int* __restrict__ s2, const int* __restrict__ d2, int E2,
                           const int* __restrict__ row2, int* __restrict__ cur2, int* __restrict__ csr2){
  int e = blockIdx.x*256+threadIdx.x;
  if (e<E1){ int d=d1[e]; int p=atomicAdd(&cur1[d],1); csr1[row1[d]+p]=s1[e]; }
  int f = e - E1;
  if (f>=0 && f<E2){ int d=d2[f]; int p=atomicAdd(&cur2[d],1); csr2[row2[d]+p]=s2[f]; }
}

// goff binary search + PARALLEL packed-plane prefix (pb, 32-aligned) + group->graph map (gm).
__global__ void k_goff2(const int* __restrict__ g1, int n1, int* __restrict__ o1,
                        const int* __restrict__ g2, int n2, int* __restrict__ o2, int B,
                        int* __restrict__ pb1, int* __restrict__ gm1,
                        int* __restrict__ pb2, int* __restrict__ gm2){
  __shared__ int sc[2][256];
  int t = threadIdx.x;
  const int* gid = (t>=256)? g2 : g1;
  int*      goff = (t>=256)? o2 : o1;
  int n          = (t>=256)? n2 : n1;
  const int side = t>>8, q = t & 255;
  if (q<=B){
    int lo=0, hi=n;
    while (lo<hi){ int mid=(lo+hi)>>1; if (gid[mid]<q) lo=mid+1; else hi=mid; }
    goff[q]=lo;
  }
  __syncthreads();
  int pc = 0;
  if (q < B){
    const int* go = side ? o2 : o1;
    int c = go[q+1]-go[q]; if (c>128) c=128;
    pc = (c+31)&~31;
  }
  sc[side][q] = pc;
  __syncthreads();
  for (int o=1;o<B;o<<=1){
    int v = (q>=o && q<B) ? sc[side][q-o] : 0;
    __syncthreads();
    if (q<B) sc[side][q] += v;
    __syncthreads();
  }
  if (q < B){
    int incl = sc[side][q];
    int pbv  = incl - pc;
    int* pb = side ? pb2 : pb1;
    int* gm = side ? gm2 : gm1;
    pb[q] = pbv;
    if (q == B-1) pb[B] = incl;
    int nb = pc>>5, b0 = pbv>>5;
    for (int k=0;k<nb;++k) gm[b0+k] = q;
  }
}

// gather aggregation with split-f16 output planes
__global__ void k_agg_h(const float* __restrict__ x, int ldx, const float* __restrict__ osc,
                        const int* __restrict__ row, const int* __restrict__ csr,
                        _Float16* __restrict__ oh, _Float16* __restrict__ ol, int n, int f4shift){
  int F4 = 1<<f4shift;
  int node = blockIdx.x*(256>>f4shift) + (threadIdx.x>>f4shift);
  if (node>=n) return;
  int fc = threadIdx.x & (F4-1);
  int F = F4<<2;
  int rs=row[node], re=row[node+1];
  float ax=0, ay=0, az=0, aw=0;
  if (osc){
    for (int e=rs;e<re;++e){
      int s = csr[e];
      float sc = osc[s];
      const float4 v = *(const float4*)(x + (size_t)s*ldx + (fc<<2));
      ax += sc*v.x; ay += sc*v.y; az += sc*v.z; aw += sc*v.w;
    }
  } else {
    int e = rs;
    for (; e+1<re; e+=2){
      int s0 = csr[e], s1 = csr[e+1];
      const float4 v0 = *(const float4*)(x + (size_t)s0*ldx + (fc<<2));
      const float4 v1 = *(const float4*)(x + (size_t)s1*ldx + (fc<<2));
      ax += v0.x+v1.x; ay += v0.y+v1.y; az += v0.z+v1.z; aw += v0.w+v1.w;
    }
    if (e<re){
      int s0 = csr[e];
      const float4 v0 = *(const float4*)(x + (size_t)s0*ldx + (fc<<2));
      ax += v0.x; ay += v0.y; az += v0.z; aw += v0.w;
    }
  }
  half4_t hv, lv;
  hv.x = (_Float16)ax; lv.x = (_Float16)(ax - (float)hv.x);
  hv.y = (_Float16)ay; lv.y = (_Float16)(ay - (float)hv.y);
  hv.z = (_Float16)az; lv.z = (_Float16)(az - (float)hv.z);
  hv.w = (_Float16)aw; lv.w = (_Float16)(aw - (float)hv.w);
  size_t o = (size_t)node*F + (fc<<2);
  *(half4_t*)(oh + o) = hv;
  *(half4_t*)(ol + o) = lv;
}

// pack 4 GraphConv weights (fp32 [K][N]) into split-f16 hi/lo, k8-packed layout
__global__ void k_wpack4(const float* __restrict__ W0, const float* __restrict__ W1,
                         const float* __restrict__ W2, const float* __restrict__ W3,
                         _Float16* __restrict__ h0, _Float16* __restrict__ l0,
                         _Float16* __restrict__ h1, _Float16* __restrict__ l1,
                         _Float16* __restrict__ h2, _Float16* __restrict__ l2,
                         _Float16* __restrict__ h3, _Float16* __restrict__ l3){
  int w = blockIdx.y;
  const float* W = (w==0)?W0:(w==1)?W1:(w==2)?W2:W3;
  _Float16* oh = (w==0)?h0:(w==1)?h1:(w==2)?h2:h3;
  _Float16* ol = (w==0)?l0:(w==1)?l1:(w==2)?l2:l3;
  int K   = (w&1)? 256 : 128;
  int nsh = (w&1)? 9 : 8;
  int i = blockIdx.x*256 + threadIdx.x;
  if (i >= (K<<nsh)) return;
  int k = i >> nsh, n = i & ((1<<nsh)-1);
  float v = W[i];
  _Float16 h = (_Float16)v;
  _Float16 l = (_Float16)(v - (float)h);
  size_t p = (((size_t)(k>>3)<<nsh) + n)*8 + (k&7);
  oh[p] = h; ol[p] = l;
}

// ------- k_wpackT: pack fp32 W (N rows x K cols used, row stride ldw; elem(n,k)=W[n*ldw+k])
// into split-f16 k8-packed planes: elem(n,k) -> plane[((k>>3)*N + n)*8 + (k&7)].
// Tile 32n x 256k via LDS so both global reads and writes are coalesced.
__global__ __launch_bounds__(256)
void k_wpackT(const float* __restrict__ W, int ldw, int N,
              _Float16* __restrict__ Bh, _Float16* __restrict__ Bl){
  __shared__ float st[32][260];
  const int k0 = (int)blockIdx.x << 8;
  const int n0 = (int)blockIdx.y << 5;
  const int t = threadIdx.x;
  const int r = t >> 3, la = t & 7;
  const float* src = W + (size_t)(n0 + r)*ldw + k0;
  #pragma unroll
  for (int q=0;q<8;++q){
    int f = (la<<2) + (q<<5);
    *(float4*)&st[r][f] = *(const float4*)(src + f);
  }
  __syncthreads();
  const int nl = t & 31;
  #pragma unroll
  for (int j=0;j<4;++j){
    int kbl = (t>>5) + (j<<3);
    half8 h8, l8;
    #pragma unroll
    for (int e=0;e<8;++e){
      float v = st[nl][(kbl<<3)+e];
      _Float16 hh = (_Float16)v;
      h8[e]=hh; l8[e]=(_Float16)(v-(float)hh);
    }
    size_t a = ((size_t)((k0>>3)+kbl)*N + n0 + nl)*8;
    *(half8*)(Bh + a) = h8;
    *(half8*)(Bl + a) = l8;
  }
}

// ------- k_gconv_mfma: dual-side split-f16 MFMA GEMM (see round-0 notes).
__global__ __launch_bounds__(256)
void k_gconv_mfma(const _Float16* __restrict__ Ah0, const _Float16* __restrict__ Al0,
                  const _Float16* __restrict__ Ah1, const _Float16* __restrict__ Al1,
                  const _Float16* __restrict__ Bh0, const _Float16* __restrict__ Bl0,
                  const _Float16* __restrict__ Bh1, const _Float16* __restrict__ Bl1,
                  float* __restrict__ C0, float* __restrict__ C1, int ldc,
                  int M0, int M1, int N, int K,
                  const float* __restrict__ rs0, const float* __restrict__ rs1,
                  const float* __restrict__ bi0, const float* __restrict__ bi1, int relu,
                  const float* __restrict__ po0, const float* __restrict__ po1)
{
  __shared__ __align__(16) _Float16 As[2][4096];   // [kb(4)][m(128)][8]
  __shared__ __align__(16) _Float16 Bs[2][4096];   // [kb(4)][n(128)][8]

  const int gx = gridDim.x, gxy = gridDim.x*gridDim.y;
  const int nwg = gxy*2;
  int fid = blockIdx.x + gx*blockIdx.y + gxy*blockIdx.z;
  int q = nwg>>3, r = nwg&7;
  int xcd = fid & 7, idx = fid >> 3;
  int sid = (xcd<r ? xcd*(q+1) : r*(q+1)+(xcd-r)*q) + idx;
  const int z  = sid / gxy;  int rem = sid - z*gxy;
  const int by = rem / gx,  bx = rem - by*gx;

  const _Float16* Ah = z ? Ah1 : Ah0;
  const _Float16* Al = z ? Al1 : Al0;
  const _Float16* Bh = z ? Bh1 : Bh0;
  const _Float16* Bl = z ? Bl1 : Bl0;
  float*       C  = z ? C1 : C0;
  const float* rsc = z ? rs1 : rs0;
  const float* bia = z ? bi1 : bi0;
  const float* po  = z ? po1 : po0;
  const int M = z ? M1 : M0;

  const int row0 = by << 7;
  const int col0 = bx << 7;
  if (row0 >= ((M+127)&~127)) return;

  const int tid = threadIdx.x;
  const int am  = tid >> 2;
  const int akb = tid & 3;
  const int bn  = tid & 127;
  const int bkb = tid >> 7;
  const int wid = tid >> 6, lane = tid & 63;
  const int wr = wid >> 1, wc = wid & 1;
  const int lr = lane & 15, lg = lane >> 4;

  const size_t ldb8 = (size_t)N * 8;
  f32x4 acc[4][4] = {};

  const int kpt = K >> 5;     // K-steps per term
  const int nt  = 3 * kpt;    // total K-steps (hi*hi, lo*hi, hi*lo)

  half8 ga0, ga1, gb0, gb1;
  {
    const _Float16* Ap = Ah + (size_t)(row0 + am) * K + (akb<<3);
    ga0 = *(const half8*)(Ap);
    ga1 = *(const half8*)(Ap + (size_t)64 * K);
    const _Float16* Bp = Bh + (size_t)bkb * ldb8 + (size_t)(col0 + bn) * 8;
    gb0 = *(const half8*)(Bp);
    gb1 = *(const half8*)(Bp + 2*ldb8);
  }
  *(half8*)&As[0][(akb*128 + am)*8]        = ga0;
  *(half8*)&As[0][(akb*128 + am + 64)*8]   = ga1;
  *(half8*)&Bs[0][(bkb*128 + bn)*8]        = gb0;
  *(half8*)&Bs[0][((bkb+2)*128 + bn)*8]    = gb1;
  __syncthreads();

  int term = 0, kk = 32;    // coordinates of the NEXT tile (t+1)
  if (kk == K){ kk = 0; term = 1; }
  for (int t = 0; t < nt; ++t){
    const int cb = t & 1;
    if (t + 1 < nt){
      const _Float16* Asrc = (term == 1) ? Al : Ah;
      const _Float16* Bsrc = (term == 2) ? Bl : Bh;
      const _Float16* Ap = Asrc + (size_t)(row0 + am) * K + kk + (akb<<3);
      ga0 = *(const half8*)(Ap);
      ga1 = *(const half8*)(Ap + (size_t)64 * K);
      const _Float16* Bp = Bsrc + (size_t)((kk>>3) + bkb) * ldb8 + (size_t)(col0 + bn) * 8;
      gb0 = *(const half8*)(Bp);
      gb1 = *(const half8*)(Bp + 2*ldb8);
      kk += 32; if (kk == K){ kk = 0; ++term; }
    }
    {
      const _Float16* Abase = &As[cb][((lg<<7) + (wr<<6) + lr)<<3];
      const _Float16* Bbase = &Bs[cb][((lg<<7) + (wc<<6) + lr)<<3];
      half8 af[4], bf[4];
      #pragma unroll
      for (int i=0;i<4;++i){
        af[i] = *(const half8*)(Abase + i*128);
        bf[i] = *(const half8*)(Bbase + i*128);
      }
      #pragma unroll
      for (int mi=0; mi<4; ++mi){
        #pragma unroll
        for (int ni=0; ni<4; ++ni){
          acc[mi][ni] = __builtin_amdgcn_mfma_f32_16x16x32_f16(af[mi], bf[ni], acc[mi][ni], 0, 0, 0);
        }
      }
    }
    if (t + 1 < nt){
      const int nb_ = cb ^ 1;
      *(half8*)&As[nb_][(akb*128 + am)*8]      = ga0;
      *(half8*)&As[nb_][(akb*128 + am + 64)*8] = ga1;
      *(half8*)&Bs[nb_][(bkb*128 + bn)*8]      = gb0;
      *(half8*)&Bs[nb_][((bkb+2)*128 + bn)*8]  = gb1;
    }
    __syncthreads();
  }

  // epilogue: D row = row0 + wr*64 + mi*16 + lg*4 + j ; col = col0 + wc*64 + ni*16 + lr
  #pragma unroll
  for (int ni = 0; ni < 4; ++ni){
    int cc = col0 + (wc<<6) + (ni<<4) + lr;
    float bv = bia ? bia[cc] : 0.f;
    #pragma unroll
    for (int mi = 0; mi < 4; ++mi){
      int rbase = row0 + (wr<<6) + (mi<<4) + (lg<<2);
      #pragma unroll
      for (int j = 0; j < 4; ++j){
        int rr = rbase + j;
        if (rr < M){
          float rs_ = rsc ? rsc[rr] : 1.f;
          float v = acc[mi][ni][j]*rs_ + bv;
          if (relu) v = fmaxf(v, 0.f);
          if (po) v *= po[rr];
          C[(size_t)rr*ldc + cc] = v;
        }
      }
    }
  }
}

// ------- k_pack: repack sf/vf[:, 0:512) into per-graph 32-aligned node-packed
// split-f16 planes; padding nodes written as ZERO.
__global__ __launch_bounds__(256)
void k_pack(const float* __restrict__ sf, const float* __restrict__ vf,
            const int* __restrict__ go1, const int* __restrict__ go2,
            const int* __restrict__ pb1, const int* __restrict__ pb2,
            const int* __restrict__ gm1, const int* __restrict__ gm2,
            _Float16* __restrict__ p1h, _Float16* __restrict__ p1l,
            _Float16* __restrict__ p2h, _Float16* __restrict__ p2l, int B)
{
  __shared__ float st[32][516];
  const int side = blockIdx.y;
  const float* x = side ? vf : sf;
  const int* go = side ? go2 : go1;
  const int* pb = side ? pb2 : pb1;
  const int* gm = side ? gm2 : gm1;
  _Float16* ph = side ? p2h : p1h;
  _Float16* pl = side ? p2l : p1l;
  const int u = blockIdx.x;
  if (u*32 >= pb[B]) return;
  const int g = gm[u];
  const int j0 = u*32 - pb[g];
  const int base = go[g];
  int cnt = go[g+1]-base; if (cnt>128) cnt=128;
  const int t = threadIdx.x;
  const int r = t>>3, f0 = (t&7)<<2;
  const bool valid = (j0 + r) < cnt;
  const float* src = x + (size_t)(base + j0 + r)*1024;
  #pragma unroll
  for (int q=0;q<16;++q){
    int f = f0 + (q<<5);
    float4 vv;
    if (valid) vv = *(const float4*)(src + f);
    else { vv.x=0.f; vv.y=0.f; vv.z=0.f; vv.w=0.f; }
    *(float4*)&st[r][f] = vv;
  }
  __syncthreads();
  #pragma unroll
  for (int q=0;q<8;++q){
    int u2 = t + (q<<8);
    int jg = u2>>9, f = u2&511;
    half8 h8, l8;
    #pragma unroll
    for (int e=0;e<8;++e){
      float vvv = st[(jg<<3)+e][f];
      _Float16 hh = (_Float16)vvv;
      h8[e]=hh; l8[e]=(_Float16)(vvv-(float)hh);
    }
    size_t a = ((size_t)((u<<2)+jg)<<12) + ((size_t)f<<3);
    *(half8*)(ph + a) = h8;
    *(half8*)(pl + a) = l8;
  }
}

// ------- k_T: LDS-staged split-f16 MFMA interaction tiles (see R3 notes).
__global__ __launch_bounds__(256)
void k_T(const float* __restrict__ sf, const float* __restrict__ vf,
         const int* __restrict__ go1, const int* __restrict__ go2,
         _Float16* __restrict__ Th, _Float16* __restrict__ Tl, int B)
{
  __shared__ __align__(16) _Float16 Ahs[64*136 + 8];   // [fg64][r16][8], fg stride 136
  __shared__ __align__(16) _Float16 Als[64*136 + 8];
  __shared__ __align__(16) _Float16 Bhs[2][2048];      // [buf][fg4][c64][8], c XOR-swizzled
  __shared__ __align__(16) _Float16 Bls[2][2048];
  const int g = blockIdx.x, rt = blockIdx.y;
  int gR = go1[g]; int c1 = go1[g+1]-gR; if (c1>128) c1=128;
  int gO = go2[g]; int c2 = go2[g+1]-gO; if (c2>128) c2=128;
  const int c1_32 = (c1+31)&~31, c2_32 = (c2+31)&~31;
  if ((rt<<4) >= c1_32 || c2_32 == 0) return;
  const int tid = threadIdx.x;
  {
    const int r = tid >> 4;
    const int f0 = (tid & 15) << 5;
    const int row = (rt<<4) + r;
    const bool val = row < c1;
    const float* src = sf + (size_t)(gR + row)*1024 + f0;
    #pragma unroll
    for (int q=0;q<4;++q){
      float4 v0, v1;
      if (val){
        v0 = *(const float4*)(src + (q<<3));
        v1 = *(const float4*)(src + (q<<3) + 4);
      } else {
        v0.x=0.f; v0.y=0.f; v0.z=0.f; v0.w=0.f; v1 = v0;
      }
      half8 h,l; split8(v0,v1,h,l);
      const int a = ((f0>>3) + q)*136 + (r<<3);
      *(half8*)&Ahs[a] = h; *(half8*)&Als[a] = l;
    }
  }
  const int w = tid>>6, lane = tid&63, lr = lane&15, lg = lane>>4;
  const int bc = tid>>2, bfg = tid&3, bf = bfg<<3;
  const int bwr = (bfg<<9) + ((bc ^ (bfg<<2))<<3);
  const int ncc = (c2_32 + 63) >> 6;
  _Float16* T0h = Th + ((size_t)g<<14);
  _Float16* T0l = Tl + ((size_t)g<<14);
  _Float16* T1h = Th + ((size_t)(B + g)<<14);
  _Float16* T1l = Tl + ((size_t)(B + g)<<14);
  for (int cc=0; cc<ncc; ++cc){
    const int cbase = cc<<6;
    const int colr = cbase + bc;
    const bool bval = colr < c2;
    const float* bsrc = vf + (size_t)(gO + colr)*1024 + bf;
    {
      float4 v0, v1;
      if (bval){ v0 = *(const float4*)(bsrc); v1 = *(const float4*)(bsrc + 4); }
      else { v0.x=0.f; v0.y=0.f; v0.z=0.f; v0.w=0.f; v1 = v0; }
      half8 h,l; split8(v0,v1,h,l);
      *(half8*)&Bhs[0][bwr] = h; *(half8*)&Bls[0][bwr] = l;
    }
    __syncthreads();
    f32x4 acc = {0.f,0.f,0.f,0.f};
    const int col_l = (w<<4) + lr;
    const int ba = (lg<<9) + ((col_l ^ (lg<<2))<<3);
    for (int kc=0; kc<16; ++kc){
      float4 p0, p1;
      if (kc+1<16){
        if (bval){
          const float* s = bsrc + ((kc+1)<<5);
          p0 = *(const float4*)s; p1 = *(const float4*)(s + 4);
        } else { p0.x=0.f; p0.y=0.f; p0.z=0.f; p0.w=0.f; p1 = p0; }
      }
      const int aa = ((kc<<2)+lg)*136 + (lr<<3);
      half8 ah = *(const half8*)&Ahs[aa];
      half8 al = *(const half8*)&Als[aa];
      half8 bh = *(const half8*)&Bhs[kc&1][ba];
      half8 bl = *(const half8*)&Bls[kc&1][ba];
      acc = MF(ah,bh,acc);
      acc = MF(al,bh,acc);
      acc = MF(ah,bl,acc);
      if (kc+1<16){
        half8 h,l; split8(p0,p1,h,l);
        *(half8*)&Bhs[(kc+1)&1][bwr] = h; *(half8*)&Bls[(kc+1)&1][bwr] = l;
      }
      __syncthreads();
    }
    const int col = cbase + col_l;
    if (col < c2_32){
      half4_t t1h, t1l;
      #pragma unroll
      for (int qq=0;qq<4;++qq){
        int r = (rt<<4) + (lg<<2) + qq;
        float t = (r < c1 && col < c2) ? ftanh(acc[qq]) : 0.f;
        _Float16 hh = (_Float16)t;
        _Float16 ll = (_Float16)(t - (float)hh);
        T0h[(r<<7) + col] = hh;
        T0l[(r<<7) + col] = ll;
        t1h[qq] = hh; t1l[qq] = ll;
      }
      const int r0 = (rt<<4) + (lg<<2);
      *(half4_t*)&T1h[(col<<7) + r0] = t1h;
      *(half4_t*)&T1l[(col<<7) + r0] = t1l;
    }
  }
}

// ------- k_apply: own'[r][f] = sum_o T[r][o]*oth[o][f] via MFMA.
__global__ __launch_bounds__(256)
void k_apply(const _Float16* __restrict__ Th, const _Float16* __restrict__ Tl,
             const _Float16* __restrict__ p1h, const _Float16* __restrict__ p1l,
             const _Float16* __restrict__ p2h, const _Float16* __restrict__ p2l,
             const int* __restrict__ go1, const int* __restrict__ go2,
             const int* __restrict__ pb1, const int* __restrict__ pb2,
             float* __restrict__ sf, float* __restrict__ vf, int B)
{
  const int side = blockIdx.x, g = blockIdx.y, ft = blockIdx.z;
  const int* goR = side ? go2 : go1;
  const int* goO = side ? go1 : go2;
  const int* pbO = side ? pb1 : pb2;
  const _Float16* oph = side ? p1h : p2h;
  const _Float16* opl = side ? p1l : p2l;
  float* outp = side ? vf : sf;
  int gR = goR[g]; int cR = goR[g+1]-gR; if (cR>128) cR=128;
  int gO = goO[g]; int cO = goO[g+1]-gO; if (cO>128) cO=128;
  if (cR <= 0) return;
  const int pO = pbO[g];
  const int cO32 = (cO+31)&~31;
  const int MR = ((cR+15)&~15)>>4;
  const _Float16* Tph = Th + ((size_t)(side*B + g)<<14);
  const _Float16* Tpl = Tl + ((size_t)(side*B + g)<<14);
  const int tid = threadIdx.x, w = tid>>6, lane = tid&63;
  const int lr = lane&15, lg = lane>>4;
  const int f0 = (ft<<8) + (w<<6);
  for (int rc = 0; rc < MR; rc += 4){
    f32x4 acc[4][4];
    #pragma unroll
    for (int a_=0;a_<4;++a_)
      #pragma unroll
      for (int b_=0;b_<4;++b_) acc[a_][b_] = (f32x4){0.f,0.f,0.f,0.f};
    for (int k0=0; k0<cO32; k0+=32){
      half8 bh[4], bl[4];
      #pragma unroll
      for (int nj=0;nj<4;++nj){
        size_t a = ((size_t)((pO + k0)>>3) + lg)*4096 + (size_t)(f0 + (nj<<4) + lr)*8;
        bh[nj] = *(const half8*)(oph + a);
        bl[nj] = *(const half8*)(opl + a);
      }
      #pragma unroll
      for (int mi=0;mi<4;++mi){
        if (rc + mi < MR){
          int a = ((((rc+mi)<<4) + lr)<<7) + k0 + (lg<<3);
          half8 th_ = *(const half8*)&Tph[a];
          half8 tl_ = *(const half8*)&Tpl[a];
          #pragma unroll
          for (int nj=0;nj<4;++nj){
            acc[mi][nj] = MF(th_, bh[nj], acc[mi][nj]);
            acc[mi][nj] = MF(tl_, bh[nj], acc[mi][nj]);
            acc[mi][nj] = MF(th_, bl[nj], acc[mi][nj]);
          }
        }
      }
    }
    #pragma unroll
    for (int mi=0;mi<4;++mi){
      if (rc + mi < MR){
        #pragma unroll
        for (int nj=0;nj<4;++nj){
          #pragma unroll
          for (int qq=0;qq<4;++qq){
            int r = (((rc+mi)<<4)) + (lg<<2) + qq;
            if (r < cR)
              outp[(size_t)(gR + r)*1024 + 512 + f0 + (nj<<4) + lr] = acc[mi][nj][qq];
          }
        }
      }
    }
  }
}

// ------- k_gemmsk: fp32 skinny NT GEMM (kept for fc2 only).
__global__ __launch_bounds__(256)
void k_gemmsk(const float* __restrict__ Ab, size_t AsideOff, int lda,
              const float* __restrict__ Bm, int ldb,
              float* __restrict__ P, int M, int N, int kchunk)
{
  __shared__ float As[2][16][132];
  __shared__ float Bs[2][16][68];
  const int tid = threadIdx.x;
  const int col0 = (int)blockIdx.x << 6;
  const int kbeg = (int)blockIdx.z * kchunk;
  const float* A = Ab + (size_t)blockIdx.y * AsideOff;
  const int ar = tid >> 1, ak = (tid & 1) << 3;
  const int br = tid >> 2, bk = (tid & 3) << 2;
  const int tx = tid & 15, ty = tid >> 4;
  const float* Arow = A + (size_t)ar * lda + kbeg + ak;
  const float* Brow = Bm + (size_t)(col0 + br) * ldb + kbeg + bk;
  float acc[8][4] = {};
  float4 a0 = *(const float4*)(Arow);
  float4 a1 = *(const float4*)(Arow + 4);
  float4 b0 = *(const float4*)(Brow);
  As[0][ak+0][ar]=a0.x; As[0][ak+1][ar]=a0.y; As[0][ak+2][ar]=a0.z; As[0][ak+3][ar]=a0.w;
  As[0][ak+4][ar]=a1.x; As[0][ak+5][ar]=a1.y; As[0][ak+6][ar]=a1.z; As[0][ak+7][ar]=a1.w;
  Bs[0][bk+0][br]=b0.x; Bs[0][bk+1][br]=b0.y; Bs[0][bk+2][br]=b0.z; Bs[0][bk+3][br]=b0.w;
  __syncthreads();
  const int nt = kchunk >> 4;
  for (int t = 0; t < nt; ++t){
    const int cb = t & 1;
    if (t + 1 < nt){
      int k0 = (t + 1) << 4;
      a0 = *(const float4*)(Arow + k0);
      a1 = *(const float4*)(Arow + k0 + 4);
      b0 = *(const float4*)(Brow + k0);
    }
    #pragma unroll
    for (int kk = 0; kk < 16; ++kk){
      float4 b4 = *(const float4*)&Bs[cb][kk][tx << 2];
      float4 a4 = *(const float4*)&As[cb][kk][ty << 3];
      float4 a5 = *(const float4*)&As[cb][kk][(ty << 3) + 4];
      acc[0][0]+=a4.x*b4.x; acc[0][1]+=a4.x*b4.y; acc[0][2]+=a4.x*b4.z; acc[0][3]+=a4.x*b4.w;
      acc[1][0]+=a4.y*b4.x; acc[1][1]+=a4.y*b4.y; acc[1][2]+=a4.y*b4.z; acc[1][3]+=a4.y*b4.w;
      acc[2][0]+=a4.z*b4.x; acc[2][1]+=a4.z*b4.y; acc[2][2]+=a4.z*b4.z; acc[2][3]+=a4.z*b4.w;
      acc[3][0]+=a4.w*b4.x; acc[3][1]+=a4.w*b4.y; acc[3][2]+=a4.w*b4.z; acc[3][3]+=a4.w*b4.w;
      acc[4][0]+=a5.x*b4.x; acc[4][1]+=a5.x*b4.y; acc[4][2]+=a5.x*b4.z; acc[4][3]+=a5.x*b4.w;
      acc[5][0]+=a5.y*b4.x; acc[5][1]+=a5.y*b4.y; acc[5][2]+=a5.y*b4.z; acc[5][3]+=a5.y*b4.w;
      acc[6][0]+=a5.z*b4.x; acc[6][1]+=a5.z*b4.y; acc[6][2]+=a5.z*b4.z; acc[6][3]+=a5.z*b4.w;
      acc[7][0]+=a5.w*b4.x; acc[7][1]+=a5.w*b4.y; acc[7][2]+=a5.w*b4.z; acc[7][3]+=a5.w*b4.w;
    }
    if (t + 1 < nt){
      const int nb = cb ^ 1;
      As[nb][ak+0][ar]=a0.x; As[nb][ak+1][ar]=a0.y; As[nb][ak+2][ar]=a0.z; As[nb][ak+3][ar]=a0.w;
      As[nb][ak+4][ar]=a1.x; As[nb][ak+5][ar]=a1.y; As[nb][ak+6][ar]=a1.z; As[nb][ak+7][ar]=a1.w;
      Bs[nb][bk+0][br]=b0.x; Bs[nb][bk+1][br]=b0.y; Bs[nb][bk+2][br]=b0.z; Bs[nb][bk+3][br]=b0.w;
    }
    __syncthreads();
  }
  float* Pz = P + (size_t)(blockIdx.y*gridDim.z + blockIdx.z) * M * N;
  #pragma unroll
  for (int i = 0; i < 8; ++i){
    int rr = (ty << 3) + i;
    float4 v = {acc[i][0], acc[i][1], acc[i][2], acc[i][3]};
    *(float4*)(Pz + (size_t)rr*N + col0 + (tx<<2)) = v;
  }
}

// ------- k_gemmsk_h: split-f16 MFMA skinny GEMM. C_partial[m][n] = sum_k A[m][k]*W[n][k].
// A fp32 [128][K] per side (staged+split to LDS, dbuf); B pre-packed split-f16 planes
// (k8-packed, read direct from global, contiguous half8). 128x128 tile, 4 waves,
// 3-term split per 32-k chunk (A staged once, reused by all terms).
// grid (N/128, sides, splits); partials P[(side*splits+z)][128][N].
__global__ __launch_bounds__(256)
void k_gemmsk_h(const float* __restrict__ Ab, size_t AsideOff, int lda,
                const _Float16* __restrict__ Bhp, const _Float16* __restrict__ Blp,
                float* __restrict__ P, int N, int kchunk)
{
  __shared__ __align__(16) _Float16 Ahs[2][4096];   // [kb(4)][m(128)][8]
  __shared__ __align__(16) _Float16 Als[2][4096];
  const int tid = threadIdx.x;
  const int col0 = (int)blockIdx.x << 7;
  const int kbeg = (int)blockIdx.z * kchunk;
  const float* A = Ab + (size_t)blockIdx.y * AsideOff;
  const int ar = tid >> 1, aq = (tid & 1) << 4;     // row, k-offset {0,16}
  const int wid = tid>>6, lane = tid&63;
  const int wr = wid>>1, wc = wid&1;
  const int lr = lane&15, lg = lane>>4;
  const float* Arow = A + (size_t)ar*lda + kbeg + aq;
  const int akb = aq>>3;                            // 0 or 2
  f32x4 acc[4][4] = {};
  const int nc = kchunk >> 5;
  float4 g0,g1,g2,g3;
  g0 = *(const float4*)(Arow);     g1 = *(const float4*)(Arow+4);
  g2 = *(const float4*)(Arow+8);   g3 = *(const float4*)(Arow+12);
  {
    half8 h,l;
    split8(g0,g1,h,l);
    *(half8*)&Ahs[0][(akb*128+ar)*8] = h;     *(half8*)&Als[0][(akb*128+ar)*8] = l;
    split8(g2,g3,h,l);
    *(half8*)&Ahs[0][((akb+1)*128+ar)*8] = h; *(half8*)&Als[0][((akb+1)*128+ar)*8] = l;
  }
  __syncthreads();
  for (int c=0;c<nc;++c){
    const int cb = c&1;
    if (c+1<nc){
      const float* p = Arow + ((c+1)<<5);
      g0 = *(const float4*)(p);    g1 = *(const float4*)(p+4);
      g2 = *(const float4*)(p+8);  g3 = *(const float4*)(p+12);
    }
    const size_t kb0 = (size_t)((kbeg + (c<<5)) >> 3) + lg;
    half8 bh[4], bl[4];
    #pragma unroll
    for (int ni=0;ni<4;++ni){
      size_t a = (kb0*N + col0 + (wc<<6) + (ni<<4) + lr)*8;
      bh[ni] = *(const half8*)(Bhp + a);
      bl[ni] = *(const half8*)(Blp + a);
    }
    #pragma unroll
    for (int mi=0;mi<4;++mi){
      int aa = ((lg<<7) + (wr<<6) + (mi<<4) + lr)<<3;
      half8 ah = *(const half8*)&Ahs[cb][aa];
      half8 al = *(const half8*)&Als[cb][aa];
      #pragma unroll
      for (int ni=0;ni<4;++ni){
        acc[mi][ni] = MF(ah,bh[ni],acc[mi][ni]);
        acc[mi][ni] = MF(al,bh[ni],acc[mi][ni]);
        acc[mi][ni] = MF(ah,bl[ni],acc[mi][ni]);
      }
    }
    if (c+1<nc){
      const int nb = cb^1;
      half8 h,l;
      split8(g0,g1,h,l);
      *(half8*)&Ahs[nb][(akb*128+ar)*8] = h;     *(half8*)&Als[nb][(akb*128+ar)*8] = l;
      split8(g2,g3,h,l);
      *(half8*)&Ahs[nb][((akb+1)*128+ar)*8] = h; *(half8*)&Als[nb][((akb+1)*128+ar)*8] = l;
    }
    __syncthreads();
  }
  float* Pz = P + (size_t)(blockIdx.y*gridDim.z + blockIdx.z)*128*N;
  #pragma unroll
  for (int mi=0;mi<4;++mi){
    #pragma unroll
    for (int ni=0;ni<4;++ni){
      int cc2 = col0 + (wc<<6) + (ni<<4) + lr;
      #pragma unroll
      for (int j=0;j<4;++j){
        int rr2 = (wr<<6) + (mi<<4) + (lg<<2) + j;
        Pz[(size_t)rr2*N + cc2] = acc[mi][ni][j];
      }
    }
  }
}

// sum split partials + bias (+relu)
__global__ void k_red_bias(const float* __restrict__ P, int split, int MN, int N,
                           const float* __restrict__ bias, float* __restrict__ C, int relu){
  int i = blockIdx.x*256 + threadIdx.x;
  if (i >= MN) return;
  float v = bias[i & (N-1)];
  for (int s=0;s<split;++s) v += P[(size_t)s*MN + i];
  if (relu) v = fmaxf(v, 0.f);
  C[i] = v;
}

// ---------------- Set2Set ----------------
__global__ void k_lstm1(const float* __restrict__ bih, const float* __restrict__ bhh,
                        float* __restrict__ c1, float* __restrict__ h1){
  int j = blockIdx.x*256 + threadIdx.x;
  if (j >= 1024) return;
  float gi = bih[j]        + bhh[j];
  float gg = bih[j+2048]   + bhh[j+2048];
  float go = bih[j+3072]   + bhh[j+3072];
  float cc = fsigm(gi)*ftanh(gg);
  c1[j] = cc;
  h1[j] = fsigm(go)*ftanh(cc);
}

__global__ void k_gemv_u(const float* __restrict__ Wih, const float* __restrict__ Whh,
                         const float* __restrict__ bih, const float* __restrict__ bhh,
                         const float* __restrict__ h1, float* __restrict__ u){
  int w = (blockIdx.x*256 + threadIdx.x)>>6;
  int lane = threadIdx.x & 63;
  if (w >= 4096) return;
  const float* wi = Wih + (size_t)w*2048;
  const float* wh = Whh + (size_t)w*1024;
  float acc = 0.f;
  #pragma unroll
  for (int qq=0;qq<4;++qq){
    int o = qq*256 + (lane<<2);
    float4 hv = *(const float4*)(h1 + o);
    float4 a  = *(const float4*)(wi + o);
    float4 b  = *(const float4*)(wh + o);
    acc += hv.x*(a.x+b.x) + hv.y*(a.y+b.y) + hv.z*(a.z+b.z) + hv.w*(a.w+b.w);
  }
  acc = wredsum(acc);
  if (lane==0) u[w] = acc + bih[w] + bhh[w];
}

// fused attention, dual-side (blockIdx.y): online segment softmax + weighted sum
__global__ __launch_bounds__(256)
void k_attn(const float* __restrict__ sf, const float* __restrict__ vf,
            const int* __restrict__ go1, const int* __restrict__ go2,
            const float* __restrict__ hbase, size_t hSideOff, int hstride,
            float* __restrict__ outbase, size_t oSideOff, int ldout)
{
  __shared__ float hs[1024];
  __shared__ float ech[1024];
  __shared__ float red[8];
  int side = blockIdx.y;
  const float* x = side? vf : sf;
  const int* goff = side? go2 : go1;
  const float* hsrc = hbase + (size_t)side*hSideOff;
  float* outp = outbase + (size_t)side*oSideOff;
  int b = blockIdx.x, t = threadIdx.x;
  int i0 = goff[b], i1 = goff[b+1];
  int lane = t & 63, wv = t >> 6;
  { float4 hv = *(const float4*)(hsrc + (size_t)b*hstride + (t<<2));
    *(float4*)&hs[t<<2] = hv; }
  __syncthreads();
  float m = -3.0e38f, s = 0.f;
  float ax=0, ay=0, az=0, aw=0;
  for (int c = i0; c < i1; c += 1024){
    int ce = c + 1024; if (ce > i1) ce = i1;
    int n = ce - c;
    float wmax = -3.0e38f;
    for (int i = c + wv; i < ce; i += 4){
      const float* xr = x + (size_t)i*1024;
      float d = 0.f;
      #pragma unroll
      for (int qq=0;qq<4;++qq){
        int o = qq*256 + (lane<<2);
        float4 xv = *(const float4*)(xr+o);
        float4 h4 = *(const float4*)&hs[o];
        d += xv.x*h4.x + xv.y*h4.y + xv.z*h4.z + xv.w*h4.w;
      }
      d = wredsum(d);
      if (lane==0) ech[i-c] = d;
      wmax = fmaxf(wmax, d);
    }
    if (lane==0) red[wv] = wmax;
    __syncthreads();
    float cm = fmaxf(fmaxf(red[0],red[1]), fmaxf(red[2],red[3]));
    float nm = fmaxf(m, cm);
    float scale = __expf(m - nm);
    s *= scale; ax*=scale; ay*=scale; az*=scale; aw*=scale;
    float ps = 0.f;
    for (int k = t; k < n; k += 256) ps += __expf(ech[k]-nm);
    ps = wredsum(ps);
    __syncthreads();
    if (lane==0) red[wv] = ps;
    __syncthreads();
    s += red[0]+red[1]+red[2]+red[3];
    for (int k = 0; k < n; ++k){
      float w = __expf(ech[k]-nm);
      float4 xv = *(const float4*)(x + (size_t)(c+k)*1024 + (t<<2));
      ax += w*xv.x; ay += w*xv.y; az += w*xv.z; aw += w*xv.w;
    }
    m = nm;
    __syncthreads();
  }
  float inv = (i1>i0 && s>0.f) ? 1.f/s : 0.f;
  float4 o = {ax*inv, ay*inv, az*inv, aw*inv};
  *(float4*)(outp + (size_t)b*ldout + (t<<2)) = o;
}

// LSTM iter2 (dual-side via blockIdx.y): sum split gate partials + u, cell/hidden
__global__ void k_lstm2_red(const float* __restrict__ Pb, size_t PsideOff, int split,
                            const float* __restrict__ u, const float* __restrict__ c1,
                            float* __restrict__ z, int B){
  int idx = blockIdx.x*256 + threadIdx.x;
  if (idx >= B*1024) return;
  int side = blockIdx.y;
  const float* P = Pb + (size_t)side*PsideOff;
  int b = idx >> 10, j = idx & 1023;
  float gi=u[j], gf=u[j+1024], gg=u[j+2048], go=u[j+3072];
  const float* g = P + (size_t)b*4096;
  for (int s=0;s<split;++s){
    const float* gs = g + (size_t)s*B*4096;
    gi += gs[j]; gf += gs[j+1024]; gg += gs[j+2048]; go += gs[j+3072];
  }
  float cc = fsigm(gf)*c1[j] + fsigm(gi)*ftanh(gg);
  z[(size_t)b*4096 + side*2048 + j] = fsigm(go)*ftanh(cc);
}

__global__ void k_fc3(const float* __restrict__ z2, const float* __restrict__ w3,
                      const float* __restrict__ b3, float* __restrict__ out, int B){
  int wv = (blockIdx.x*256+threadIdx.x)>>6;
  int lane = threadIdx.x & 63;
  if (wv >= B) return;
  const float* zr = z2 + (size_t)wv*512;
  float acc=0.f;
  #pragma unroll
  for (int qq=0;qq<2;++qq){
    int o = qq*256 + (lane<<2);
    float4 a  = *(const float4*)(zr + o);
    float4 ww = *(const float4*)(w3 + o);
    acc += a.x*ww.x + a.y*ww.y + a.z*ww.z + a.w*ww.w;
  }
  acc = wredsum(acc);
  if (lane==0) out[wv] = acc + b3[0];
}

// ---------------- driver ----------------
extern "C" void kernel_launch(void* const* d_in, const int* in_sizes, int n_in,
                              void* d_out, int out_size, void* d_ws, size_t ws_size,
                              hipStream_t stream)
{
  const float* x1  = (const float*)d_in[0];
  const float* x2  = (const float*)d_in[1];
  const int* src1  = (const int*)d_in[2];
  const int* dst1  = (const int*)d_in[3];
  const int* src2  = (const int*)d_in[4];
  const int* dst2  = (const int*)d_in[5];
  const int* gid1  = (const int*)d_in[6];
  const int* gid2  = (const int*)d_in[7];
  const float* Wg1 = (const float*)d_in[8];  const float* bg1 = (const float*)d_in[9];
  const float* Wg2 = (const float*)d_in[10]; const float* bg2 = (const float*)d_in[11];
  const float* Wg3 = (const float*)d_in[12]; const float* bg3 = (const float*)d_in[13];
  const float* Wg4 = (const float*)d_in[14]; const float* bg4 = (const float*)d_in[15];
  const float* Wih = (const float*)d_in[16]; const float* Whh = (const float*)d_in[17];
  const float* bih = (const float*)d_in[18]; const float* bhh = (const float*)d_in[19];
  const float* Wf1 = (const float*)d_in[20]; const float* bf1 = (const float*)d_in[21];
  const float* Wf2 = (const float*)d_in[22]; const float* bf2 = (const float*)d_in[23];
  const float* Wf3 = (const float*)d_in[24]; const float* bf3 = (const float*)d_in[25];
  float* out = (float*)d_out;

  const int N1 = in_sizes[0]/128;
  const int N2 = in_sizes[1]/128;
  const int E1 = in_sizes[2];
  const int E2 = in_sizes[4];
  const int B  = out_size;            // 128
  const int NM = N1>N2?N1:N2;

  char* base = (char*)d_ws; size_t off=0;
  auto alloc = [&](size_t bytes)->void*{ void* p = base+off; off += (bytes+255)&~(size_t)255; return p; };

  int* zr   = (int*)alloc(sizeof(int)*(size_t)(3*N1+3*N2));
  int* co1=zr, *ci1=zr+N1, *cur1=zr+2*N1;
  int* co2=zr+3*N1, *ci2=zr+3*N1+N2, *cur2=zr+3*N1+2*N2;
  int* row1 = (int*)alloc(sizeof(int)*(size_t)(N1+1));
  int* row2 = (int*)alloc(sizeof(int)*(size_t)(N2+1));
  int* csr1 = (int*)alloc(sizeof(int)*(size_t)E1);
  int* csr2 = (int*)alloc(sizeof(int)*(size_t)E2);
  int* go1  = (int*)alloc(sizeof(int)*(size_t)(B+1));
  int* go2  = (int*)alloc(sizeof(int)*(size_t)(B+1));
  int* pb1  = (int*)alloc(sizeof(int)*(size_t)(B+1));
  int* pb2  = (int*)alloc(sizeof(int)*(size_t)(B+1));
  int* gm1  = (int*)alloc(sizeof(int)*1024);
  int* gm2  = (int*)alloc(sizeof(int)*1024);
  float* os1 = (float*)alloc(sizeof(float)*(size_t)N1);
  float* is1 = (float*)alloc(sizeof(float)*(size_t)N1);
  float* os2 = (float*)alloc(sizeof(float)*(size_t)N2);
  float* is2 = (float*)alloc(sizeof(float)*(size_t)N2);
  _Float16* a1h = (_Float16*)alloc(sizeof(_Float16)*(size_t)(NM+128)*256);
  _Float16* a1l = (_Float16*)alloc(sizeof(_Float16)*(size_t)(NM+128)*256);
  _Float16* a2h = (_Float16*)alloc(sizeof(_Float16)*(size_t)(NM+128)*256);
  _Float16* a2l = (_Float16*)alloc(sizeof(_Float16)*(size_t)(NM+128)*256);
  _Float16* wg1h = (_Float16*)alloc(sizeof(_Float16)*32768);
  _Float16* wg1l = (_Float16*)alloc(sizeof(_Float16)*32768);
  _Float16* wg2h = (_Float16*)alloc(sizeof(_Float16)*131072);
  _Float16* wg2l = (_Float16*)alloc(sizeof(_Float16)*131072);
  _Float16* wg3h = (_Float16*)alloc(sizeof(_Float16)*32768);
  _Float16* wg3l = (_Float16*)alloc(sizeof(_Float16)*32768);
  _Float16* wg4h = (_Float16*)alloc(sizeof(_Float16)*131072);
  _Float16* wg4l = (_Float16*)alloc(sizeof(_Float16)*131072);
  // Set2Set gates + fc1 weight planes (split-f16, k8-packed)
  _Float16* wihh = (_Float16*)alloc(sizeof(_Float16)*(size_t)4096*1024);
  _Float16* wihl = (_Float16*)alloc(sizeof(_Float16)*(size_t)4096*1024);
  _Float16* wf1h = (_Float16*)alloc(sizeof(_Float16)*(size_t)1024*4096);
  _Float16* wf1l = (_Float16*)alloc(sizeof(_Float16)*(size_t)1024*4096);
  float* sf  = (float*)alloc(sizeof(float)*(size_t)(N1+128)*1024);
  float* vf  = (float*)alloc(sizeof(float)*(size_t)(N2+128)*1024);
  float* h1 = (float*)alloc(sizeof(float)*1024);
  float* c1 = (float*)alloc(sizeof(float)*1024);
  float* u  = (float*)alloc(sizeof(float)*4096);
  float* r1 = (float*)alloc(sizeof(float)*(size_t)2*B*1024);
  float* z1 = (float*)alloc(sizeof(float)*(size_t)B*1024);
  float* z2 = (float*)alloc(sizeof(float)*(size_t)B*512);
  float* z  = (float*)alloc(sizeof(float)*(size_t)B*4096);
  // T planes: [2 sides][B][128][128] split-f16 (16.8 MB total)
  _Float16* Tqh = (_Float16*)alloc(sizeof(_Float16)*(size_t)2*B*16384);
  _Float16* Tql = (_Float16*)alloc(sizeof(_Float16)*(size_t)2*B*16384);
  // union region: node-packed split-f16 planes (interact stage) / Pbuf partials (later stages)
  const int PN = ((NM + 32*B + 63)&~63) + 64;      // padded node capacity
  const size_t PE = (size_t)PN*512;                // elems per plane
  size_t packedBytes = 4*PE*sizeof(_Float16);
  size_t pbufBytes   = sizeof(float)*(size_t)32*B*1024*4;
  char* uni = (char*)alloc(packedBytes > pbufBytes ? packedBytes : pbufBytes);
  _Float16* p1h = (_Float16*)uni;
  _Float16* p1l = p1h + PE;
  _Float16* p2h = p1l + PE;
  _Float16* p2l = p2h + PE;
  float* Pbuf = (float*)uni;
  if (off > ws_size) return;

  // hbuf regions live inside sf/vf cols [512,768) (stride 1024), overwritten later by apply
  float* hb1 = sf + 512;
  float* hb2 = vf + 512;

  dim3 blk(256);

  // --- weight split-f16 packs (independent of graph prep) ---
  k_wpack4<<<dim3(512,4),blk,0,stream>>>(Wg1,Wg2,Wg3,Wg4,
                                         wg1h,wg1l, wg2h,wg2l, wg3h,wg3l, wg4h,wg4l);
  k_wpackT<<<dim3(4,128),blk,0,stream>>>(Wih+1024, 2048, 4096, wihh, wihl);  // gates W
  k_wpackT<<<dim3(16,32),blk,0,stream>>>(Wf1, 4096, 1024, wf1h, wf1l);       // fc1 W

  // --- prep ---
  k_zero_i32<<<(3*N1+3*N2+255)/256, blk, 0, stream>>>(zr, 3*N1+3*N2);
  k_hist2<<<(E1+E2+255)/256, blk, 0, stream>>>(src1,dst1,E1,co1,ci1, src2,dst2,E2,co2,ci2);
  k_scan2<<<2,1024,0,stream>>>(ci1,N1,row1, ci2,N2,row2);
  k_scale2<<<(N1+N2+255)/256,blk,0,stream>>>(co1,ci1,N1,os1,is1, co2,ci2,N2,os2,is2);
  k_scatter2<<<(E1+E2+255)/256,blk,0,stream>>>(src1,dst1,E1,row1,cur1,csr1, src2,dst2,E2,row2,cur2,csr2);
  k_goff2<<<1,512,0,stream>>>(gid1,N1,go1, gid2,N2,go2, B, pb1,gm1, pb2,gm2);

  // --- GraphConv: agg both sides (split-f16 out), dual MFMA GEMM L1 (post=os),
  //     agg (no scale), dual MFMA GEMM L2 ---
  int gy = (NM+127)/128;
  k_agg_h<<<(N1+7)/8,blk,0,stream>>>(x1,128, os1,row1,csr1, a1h,a1l, N1,5);
  k_agg_h<<<(N2+7)/8,blk,0,stream>>>(x2,128, os2,row2,csr2, a2h,a2l, N2,5);
  k_gconv_mfma<<<dim3(2,gy,2),blk,0,stream>>>(a1h,a1l, a2h,a2l,
                                              wg1h,wg1l, wg3h,wg3l,
                                              hb1,hb2,1024, N1,N2, 256,128,
                                              is1,is2, bg1,bg3, 1, os1,os2);
  k_agg_h<<<(N1+3)/4,blk,0,stream>>>(hb1,1024, nullptr,row1,csr1, a1h,a1l, N1,6);
  k_agg_h<<<(N2+3)/4,blk,0,stream>>>(hb2,1024, nullptr,row2,csr2, a2h,a2l, N2,6);
  k_gconv_mfma<<<dim3(4,gy,2),blk,0,stream>>>(a1h,a1l, a2h,a2l,
                                              wg2h,wg2l, wg4h,wg4l,
                                              sf,vf,1024, N1,N2, 512,256,
                                              is1,is2, bg2,bg4, 0, nullptr,nullptr);

  // --- block-diagonal interaction (MFMA; T computed once, transposed write) ---
  const int GMAX = NM/32 + B + 2;
  k_pack<<<dim3(GMAX,2),blk,0,stream>>>(sf,vf, go1,go2, pb1,pb2, gm1,gm2,
                                        p1h,p1l, p2h,p2l, B);
  k_T<<<dim3(B,8),blk,0,stream>>>(sf,vf, go1,go2, Tqh,Tql, B);
  k_apply<<<dim3(2,B,2),blk,0,stream>>>(Tqh,Tql, p1h,p1l, p2h,p2l,
                                        go1,go2, pb1,pb2, sf,vf, B);

  // --- Set2Set (sides merged per stage) ---
  k_lstm1<<<4,blk,0,stream>>>(bih,bhh,c1,h1);
  k_gemv_u<<<1024,blk,0,stream>>>(Wih,Whh,bih,bhh,h1,u);

  // iter1 attention (shared h1), both sides
  k_attn<<<dim3(B,2),blk,0,stream>>>(sf,vf,go1,go2, h1,0,0, r1,(size_t)B*1024,1024);
  // gates = r1 @ Wih[:,1024:].T via split-f16 MFMA, split-K 4 x chunk 256
  k_gemmsk_h<<<dim3(32,2,4),blk,0,stream>>>(r1,(size_t)B*1024,1024, wihh,wihl, Pbuf, 4096,256);
  k_lstm2_red<<<dim3((B*1024+255)/256,2),blk,0,stream>>>(Pbuf,(size_t)4*B*4096,4, u,c1, z,B);
  // iter2 attention with per-graph h2 (in z), both sides
  k_attn<<<dim3(B,2),blk,0,stream>>>(sf,vf,go1,go2, z,2048,4096, z+1024,2048,4096);

  // --- MLP head ---
  k_gemmsk_h<<<dim3(8,1,32),blk,0,stream>>>(z,0,4096, wf1h,wf1l, Pbuf, 1024,128);
  k_red_bias<<<(B*1024+255)/256,blk,0,stream>>>(Pbuf,32,B*1024,1024,bf1,z1,1);
  k_gemmsk<<<dim3(8,1,8),blk,0,stream>>>(z1,0,1024, Wf2,1024, Pbuf, 128,512,128);
  k_red_bias<<<(B*512+255)/256,blk,0,stream>>>(Pbuf,8,B*512,512,bf2,z2,1);
  k_fc3<<<(B*64+255)/256,blk,0,stream>>>(z2,Wf3,bf3,out,B);
}

// Round 7
// 381.409 us; speedup vs baseline: 1.2303x; 1.0082x over previous
//
#include <hip/hip_runtime.h>

#define DEV __device__ __forceinline__

typedef _Float16 half8 __attribute__((ext_vector_type(8)));
typedef _Float16 half4_t __attribute__((ext_vector_type(4)));
typedef float f32x4 __attribute__((ext_vector_type(4)));

DEV float ftanh(float x){
  float ax = fabsf(x);
  float e = __expf(-2.f*ax);
  float t = (1.f - e)/(1.f + e);
  return x < 0.f ? -t : t;
}
DEV float fsigm(float x){ return 1.f/(1.f + expf(-x)); }
DEV float wredsum(float v){
  #pragma unroll
  for (int o=32;o;o>>=1) v += __shfl_xor(v,o,64);
  return v;
}
DEV f32x4 MF(half8 a, half8 b, f32x4 c){
  return __builtin_amdgcn_mfma_f32_16x16x32_f16(a,b,c,0,0,0);
}
DEV void split8(float4 a0, float4 a1, half8& h, half8& l){
  float f[8] = {a0.x,a0.y,a0.z,a0.w,a1.x,a1.y,a1.z,a1.w};
  #pragma unroll
  for (int e=0;e<8;++e){
    _Float16 hh = (_Float16)f[e];
    h[e] = hh;
    l[e] = (_Float16)(f[e] - (float)hh);
  }
}

// ---------------- graph prep ----------------
__global__ void k_zero_i32(int* __restrict__ p, int n){
  int i = blockIdx.x*256 + threadIdx.x; if (i<n) p[i]=0;
}

__global__ void k_hist2(const int* __restrict__ s1, const int* __restrict__ d1, int E1,
                        int* __restrict__ co1, int* __restrict__ ci1,
                        const int* __restrict__ s2, const int* __restrict__ d2, int E2,
                        int* __restrict__ co2, int* __restrict__ ci2){
  int e = blockIdx.x*256 + threadIdx.x;
  if (e < E1){ atomicAdd(&co1[s1[e]],1); atomicAdd(&ci1[d1[e]],1); }
  int f = e - E1;
  if (f >= 0 && f < E2){ atomicAdd(&co2[s2[f]],1); atomicAdd(&ci2[d2[f]],1); }
}

__global__ void k_scan2(const int* __restrict__ c1, int n1, int* __restrict__ r1,
                        const int* __restrict__ c2, int n2, int* __restrict__ r2){
  __shared__ int sm[1024];
  const int* cnt = blockIdx.x ? c2 : c1;
  int*       row = blockIdx.x ? r2 : r1;
  int n          = blockIdx.x ? n2 : n1;
  int t = threadIdx.x;
  int per = n/1024 + 1;
  int st = t*per;
  int s = 0;
  for (int i=st;i<st+per;++i) if (i<n) s += cnt[i];
  sm[t]=s; __syncthreads();
  for (int o=1;o<1024;o<<=1){
    int v = (t>=o)? sm[t-o]:0;
    __syncthreads();
    sm[t] += v;
    __syncthreads();
  }
  int base = sm[t]-s;
  for (int i=st;i<st+per;++i){
    if (i<=n) row[i]=base;
    if (i<n) base += cnt[i];
  }
}

__global__ void k_scale2(const int* __restrict__ co1, const int* __restrict__ ci1, int n1,
                         float* __restrict__ os1, float* __restrict__ is1,
                         const int* __restrict__ co2, const int* __restrict__ ci2, int n2,
                         float* __restrict__ os2, float* __restrict__ is2){
  int i = blockIdx.x*256+threadIdx.x;
  if (i<n1){
    int a = co1[i] > 1 ? co1[i] : 1;
    int b = ci1[i] > 1 ? ci1[i] : 1;
    os1[i] = 1.f/sqrtf((float)a);
    is1[i] = 1.f/sqrtf((float)b);
  }
  int j = i - n1;
  if (j>=0 && j<n2){
    int a = co2[j] > 1 ? co2[j] : 1;
    int b = ci2[j] > 1 ? ci2[j] : 1;
    os2[j] = 1.f/sqrtf((float)a);
    is2[j] = 1.f/sqrtf((float)b);
  }
}

__global__ void k_scatter2(const int* __restrict__ s1, const int* __restrict__ d1, int E1,
                           const int* __restrict__ row1, int* __restrict__ cur1, int* __restrict__ csr1,
                           const int* __restrict__ s2, const int* __restrict__ d2, int E2,
                           const int* __restrict__ row2, int* __restrict__ cur2, int* __restrict__ csr2){
  int e = blockIdx.x*256+threadIdx.x;
  if (e<E1){ int d=d1[e]; int p=atomicAdd(&cur1[d],1); csr1[row1[d]+p]=s1[e]; }
  int f = e - E1;
  if (f>=0 && f<E2){ int d=d2[f]; int p=atomicAdd(&cur2[d],1); csr2[row2[d]+p]=s2[f]; }
}

// goff binary search + PARALLEL packed-plane prefix (pb, 32-aligned) + group->graph map (gm).
__global__ void k_goff2(const int* __restrict__ g1, int n1, int* __restrict__ o1,
                        const int* __restrict__ g2, int n2, int* __restrict__ o2, int B,
                        int* __restrict__ pb1, int* __restrict__ gm1,
                        int* __restrict__ pb2, int* __restrict__ gm2){
  __shared__ int sc[2][256];
  int t = threadIdx.x;
  const int* gid = (t>=256)? g2 : g1;
  int*      goff = (t>=256)? o2 : o1;
  int n          = (t>=256)? n2 : n1;
  const int side = t>>8, q = t & 255;
  if (q<=B){
    int lo=0, hi=n;
    while (lo<hi){ int mid=(lo+hi)>>1; if (gid[mid]<q) lo=mid+1; else hi=mid; }
    goff[q]=lo;
  }
  __syncthreads();
  int pc = 0;
  if (q < B){
    const int* go = side ? o2 : o1;
    int c = go[q+1]-go[q]; if (c>128) c=128;
    pc = (c+31)&~31;
  }
  sc[side][q] = pc;
  __syncthreads();
  for (int o=1;o<B;o<<=1){
    int v = (q>=o && q<B) ? sc[side][q-o] : 0;
    __syncthreads();
    if (q<B) sc[side][q] += v;
    __syncthreads();
  }
  if (q < B){
    int incl = sc[side][q];
    int pbv  = incl - pc;
    int* pb = side ? pb2 : pb1;
    int* gm = side ? gm2 : gm1;
    pb[q] = pbv;
    if (q == B-1) pb[B] = incl;
    int nb = pc>>5, b0 = pbv>>5;
    for (int k=0;k<nb;++k) gm[b0+k] = q;
  }
}

// gather aggregation with split-f16 output planes
__global__ void k_agg_h(const float* __restrict__ x, int ldx, const float* __restrict__ osc,
                        const int* __restrict__ row, const int* __restrict__ csr,
                        _Float16* __restrict__ oh, _Float16* __restrict__ ol, int n, int f4shift){
  int F4 = 1<<f4shift;
  int node = blockIdx.x*(256>>f4shift) + (threadIdx.x>>f4shift);
  if (node>=n) return;
  int fc = threadIdx.x & (F4-1);
  int F = F4<<2;
  int rs=row[node], re=row[node+1];
  float ax=0, ay=0, az=0, aw=0;
  if (osc){
    for (int e=rs;e<re;++e){
      int s = csr[e];
      float sc = osc[s];
      const float4 v = *(const float4*)(x + (size_t)s*ldx + (fc<<2));
      ax += sc*v.x; ay += sc*v.y; az += sc*v.z; aw += sc*v.w;
    }
  } else {
    int e = rs;
    for (; e+1<re; e+=2){
      int s0 = csr[e], s1 = csr[e+1];
      const float4 v0 = *(const float4*)(x + (size_t)s0*ldx + (fc<<2));
      const float4 v1 = *(const float4*)(x + (size_t)s1*ldx + (fc<<2));
      ax += v0.x+v1.x; ay += v0.y+v1.y; az += v0.z+v1.z; aw += v0.w+v1.w;
    }
    if (e<re){
      int s0 = csr[e];
      const float4 v0 = *(const float4*)(x + (size_t)s0*ldx + (fc<<2));
      ax += v0.x; ay += v0.y; az += v0.z; aw += v0.w;
    }
  }
  half4_t hv, lv;
  hv.x = (_Float16)ax; lv.x = (_Float16)(ax - (float)hv.x);
  hv.y = (_Float16)ay; lv.y = (_Float16)(ay - (float)hv.y);
  hv.z = (_Float16)az; lv.z = (_Float16)(az - (float)hv.z);
  hv.w = (_Float16)aw; lv.w = (_Float16)(aw - (float)hv.w);
  size_t o = (size_t)node*F + (fc<<2);
  *(half4_t*)(oh + o) = hv;
  *(half4_t*)(ol + o) = lv;
}

// pack 4 GraphConv weights (fp32 [K][N]) into split-f16 hi/lo, k8-packed layout
__global__ void k_wpack4(const float* __restrict__ W0, const float* __restrict__ W1,
                         const float* __restrict__ W2, const float* __restrict__ W3,
                         _Float16* __restrict__ h0, _Float16* __restrict__ l0,
                         _Float16* __restrict__ h1, _Float16* __restrict__ l1,
                         _Float16* __restrict__ h2, _Float16* __restrict__ l2,
                         _Float16* __restrict__ h3, _Float16* __restrict__ l3){
  int w = blockIdx.y;
  const float* W = (w==0)?W0:(w==1)?W1:(w==2)?W2:W3;
  _Float16* oh = (w==0)?h0:(w==1)?h1:(w==2)?h2:h3;
  _Float16* ol = (w==0)?l0:(w==1)?l1:(w==2)?l2:l3;
  int K   = (w&1)? 256 : 128;
  int nsh = (w&1)? 9 : 8;
  int i = blockIdx.x*256 + threadIdx.x;
  if (i >= (K<<nsh)) return;
  int k = i >> nsh, n = i & ((1<<nsh)-1);
  float v = W[i];
  _Float16 h = (_Float16)v;
  _Float16 l = (_Float16)(v - (float)h);
  size_t p = (((size_t)(k>>3)<<nsh) + n)*8 + (k&7);
  oh[p] = h; ol[p] = l;
}

// ------- k_wpackT: pack fp32 W (N rows x K cols used, row stride ldw; elem(n,k)=W[n*ldw+k])
// into split-f16 k8-packed planes: elem(n,k) -> plane[((k>>3)*N + n)*8 + (k&7)].
__global__ __launch_bounds__(256)
void k_wpackT(const float* __restrict__ W, int ldw, int N,
              _Float16* __restrict__ Bh, _Float16* __restrict__ Bl){
  __shared__ float st[32][260];
  const int k0 = (int)blockIdx.x << 8;
  const int n0 = (int)blockIdx.y << 5;
  const int t = threadIdx.x;
  const int r = t >> 3, la = t & 7;
  const float* src = W + (size_t)(n0 + r)*ldw + k0;
  #pragma unroll
  for (int q=0;q<8;++q){
    int f = (la<<2) + (q<<5);
    *(float4*)&st[r][f] = *(const float4*)(src + f);
  }
  __syncthreads();
  const int nl = t & 31;
  #pragma unroll
  for (int j=0;j<4;++j){
    int kbl = (t>>5) + (j<<3);
    half8 h8, l8;
    #pragma unroll
    for (int e=0;e<8;++e){
      float v = st[nl][(kbl<<3)+e];
      _Float16 hh = (_Float16)v;
      h8[e]=hh; l8[e]=(_Float16)(v-(float)hh);
    }
    size_t a = ((size_t)((k0>>3)+kbl)*N + n0 + nl)*8;
    *(half8*)(Bh + a) = h8;
    *(half8*)(Bl + a) = l8;
  }
}

// ------- k_gconv_mfma v2: dual-side split-f16 MFMA GEMM, gemmsk_h-style.
// Per 32-K chunk: stage Ah+Al ONCE to LDS (dbuf, 16KB), read B frags DIRECT from
// global k8-packed planes (weights L2-resident), run all 3 terms x 16 MFMA from the
// single stage. vs v1: 1 barrier/chunk instead of 3, 2/3 the staging bytes, no Bs LDS.
__global__ __launch_bounds__(256)
void k_gconv_mfma(const _Float16* __restrict__ Ah0, const _Float16* __restrict__ Al0,
                  const _Float16* __restrict__ Ah1, const _Float16* __restrict__ Al1,
                  const _Float16* __restrict__ Bh0, const _Float16* __restrict__ Bl0,
                  const _Float16* __restrict__ Bh1, const _Float16* __restrict__ Bl1,
                  float* __restrict__ C0, float* __restrict__ C1, int ldc,
                  int M0, int M1, int N, int K,
                  const float* __restrict__ rs0, const float* __restrict__ rs1,
                  const float* __restrict__ bi0, const float* __restrict__ bi1, int relu,
                  const float* __restrict__ po0, const float* __restrict__ po1)
{
  __shared__ __align__(16) _Float16 Ahs[2][4096];   // [kb(4)][m(128)][8]
  __shared__ __align__(16) _Float16 Als[2][4096];

  const int gx = gridDim.x, gxy = gridDim.x*gridDim.y;
  const int nwg = gxy*2;
  int fid = blockIdx.x + gx*blockIdx.y + gxy*blockIdx.z;
  int q = nwg>>3, r = nwg&7;
  int xcd = fid & 7, idx = fid >> 3;
  int sid = (xcd<r ? xcd*(q+1) : r*(q+1)+(xcd-r)*q) + idx;
  const int z  = sid / gxy;  int rem = sid - z*gxy;
  const int by = rem / gx,  bx = rem - by*gx;

  const _Float16* Ah = z ? Ah1 : Ah0;
  const _Float16* Al = z ? Al1 : Al0;
  const _Float16* Bh = z ? Bh1 : Bh0;
  const _Float16* Bl = z ? Bl1 : Bl0;
  float*       C  = z ? C1 : C0;
  const float* rsc = z ? rs1 : rs0;
  const float* bia = z ? bi1 : bi0;
  const float* po  = z ? po1 : po0;
  const int M = z ? M1 : M0;

  const int row0 = by << 7;
  const int col0 = bx << 7;
  if (row0 >= ((M+127)&~127)) return;

  const int tid = threadIdx.x;
  const int am  = tid >> 2;
  const int akb = tid & 3;
  const int wid = tid >> 6, lane = tid & 63;
  const int wr = wid >> 1, wc = wid & 1;
  const int lr = lane & 15, lg = lane >> 4;

  f32x4 acc[4][4] = {};
  const int nt = K >> 5;
  const size_t rowK64 = (size_t)64 * K;
  const _Float16* Aph = Ah + (size_t)(row0 + am) * K + (akb<<3);
  const _Float16* Apl = Al + (size_t)(row0 + am) * K + (akb<<3);

  half8 gh0 = *(const half8*)(Aph);
  half8 gh1 = *(const half8*)(Aph + rowK64);
  half8 gl0 = *(const half8*)(Apl);
  half8 gl1 = *(const half8*)(Apl + rowK64);
  *(half8*)&Ahs[0][(akb*128 + am)*8]      = gh0;
  *(half8*)&Ahs[0][(akb*128 + am + 64)*8] = gh1;
  *(half8*)&Als[0][(akb*128 + am)*8]      = gl0;
  *(half8*)&Als[0][(akb*128 + am + 64)*8] = gl1;
  __syncthreads();

  for (int c = 0; c < nt; ++c){
    const int cb = c & 1;
    if (c + 1 < nt){
      const int k0 = (c + 1) << 5;
      gh0 = *(const half8*)(Aph + k0);
      gh1 = *(const half8*)(Aph + k0 + rowK64);
      gl0 = *(const half8*)(Apl + k0);
      gl1 = *(const half8*)(Apl + k0 + rowK64);
    }
    // B frags direct from global packed planes (L2-resident weights)
    const size_t kb0 = (size_t)(c<<2) + lg;
    half8 bh[4], bl[4];
    #pragma unroll
    for (int ni=0;ni<4;++ni){
      size_t a = (kb0*N + col0 + (wc<<6) + (ni<<4) + lr)*8;
      bh[ni] = *(const half8*)(Bh + a);
      bl[ni] = *(const half8*)(Bl + a);
    }
    #pragma unroll
    for (int mi=0;mi<4;++mi){
      const int aa = ((lg<<7) + (wr<<6) + (mi<<4) + lr)<<3;
      half8 ah = *(const half8*)&Ahs[cb][aa];
      half8 al = *(const half8*)&Als[cb][aa];
      #pragma unroll
      for (int ni=0;ni<4;++ni){
        acc[mi][ni] = MF(ah, bh[ni], acc[mi][ni]);
        acc[mi][ni] = MF(al, bh[ni], acc[mi][ni]);
        acc[mi][ni] = MF(ah, bl[ni], acc[mi][ni]);
      }
    }
    if (c + 1 < nt){
      const int nb_ = cb ^ 1;
      *(half8*)&Ahs[nb_][(akb*128 + am)*8]      = gh0;
      *(half8*)&Ahs[nb_][(akb*128 + am + 64)*8] = gh1;
      *(half8*)&Als[nb_][(akb*128 + am)*8]      = gl0;
      *(half8*)&Als[nb_][(akb*128 + am + 64)*8] = gl1;
    }
    __syncthreads();
  }

  // epilogue: D row = row0 + wr*64 + mi*16 + lg*4 + j ; col = col0 + wc*64 + ni*16 + lr
  #pragma unroll
  for (int ni = 0; ni < 4; ++ni){
    int cc = col0 + (wc<<6) + (ni<<4) + lr;
    float bv = bia ? bia[cc] : 0.f;
    #pragma unroll
    for (int mi = 0; mi < 4; ++mi){
      int rbase = row0 + (wr<<6) + (mi<<4) + (lg<<2);
      #pragma unroll
      for (int j = 0; j < 4; ++j){
        int rr = rbase + j;
        if (rr < M){
          float rs_ = rsc ? rsc[rr] : 1.f;
          float v = acc[mi][ni][j]*rs_ + bv;
          if (relu) v = fmaxf(v, 0.f);
          if (po) v *= po[rr];
          C[(size_t)rr*ldc + cc] = v;
        }
      }
    }
  }
}

// ------- k_pack: repack sf/vf[:, 0:512) into per-graph 32-aligned node-packed
// split-f16 planes; padding nodes written as ZERO.
__global__ __launch_bounds__(256)
void k_pack(const float* __restrict__ sf, const float* __restrict__ vf,
            const int* __restrict__ go1, const int* __restrict__ go2,
            const int* __restrict__ pb1, const int* __restrict__ pb2,
            const int* __restrict__ gm1, const int* __restrict__ gm2,
            _Float16* __restrict__ p1h, _Float16* __restrict__ p1l,
            _Float16* __restrict__ p2h, _Float16* __restrict__ p2l, int B)
{
  __shared__ float st[32][516];
  const int side = blockIdx.y;
  const float* x = side ? vf : sf;
  const int* go = side ? go2 : go1;
  const int* pb = side ? pb2 : pb1;
  const int* gm = side ? gm2 : gm1;
  _Float16* ph = side ? p2h : p1h;
  _Float16* pl = side ? p2l : p1l;
  const int u = blockIdx.x;
  if (u*32 >= pb[B]) return;
  const int g = gm[u];
  const int j0 = u*32 - pb[g];
  const int base = go[g];
  int cnt = go[g+1]-base; if (cnt>128) cnt=128;
  const int t = threadIdx.x;
  const int r = t>>3, f0 = (t&7)<<2;
  const bool valid = (j0 + r) < cnt;
  const float* src = x + (size_t)(base + j0 + r)*1024;
  #pragma unroll
  for (int q=0;q<16;++q){
    int f = f0 + (q<<5);
    float4 vv;
    if (valid) vv = *(const float4*)(src + f);
    else { vv.x=0.f; vv.y=0.f; vv.z=0.f; vv.w=0.f; }
    *(float4*)&st[r][f] = vv;
  }
  __syncthreads();
  #pragma unroll
  for (int q=0;q<8;++q){
    int u2 = t + (q<<8);
    int jg = u2>>9, f = u2&511;
    half8 h8, l8;
    #pragma unroll
    for (int e=0;e<8;++e){
      float vvv = st[(jg<<3)+e][f];
      _Float16 hh = (_Float16)vvv;
      h8[e]=hh; l8[e]=(_Float16)(vvv-(float)hh);
    }
    size_t a = ((size_t)((u<<2)+jg)<<12) + ((size_t)f<<3);
    *(half8*)(ph + a) = h8;
    *(half8*)(pl + a) = l8;
  }
}

// ------- k_T: LDS-staged split-f16 MFMA interaction tiles (see R3 notes).
__global__ __launch_bounds__(256)
void k_T(const float* __restrict__ sf, const float* __restrict__ vf,
         const int* __restrict__ go1, const int* __restrict__ go2,
         _Float16* __restrict__ Th, _Float16* __restrict__ Tl, int B)
{
  __shared__ __align__(16) _Float16 Ahs[64*136 + 8];   // [fg64][r16][8], fg stride 136
  __shared__ __align__(16) _Float16 Als[64*136 + 8];
  __shared__ __align__(16) _Float16 Bhs[2][2048];      // [buf][fg4][c64][8], c XOR-swizzled
  __shared__ __align__(16) _Float16 Bls[2][2048];
  const int g = blockIdx.x, rt = blockIdx.y;
  int gR = go1[g]; int c1 = go1[g+1]-gR; if (c1>128) c1=128;
  int gO = go2[g]; int c2 = go2[g+1]-gO; if (c2>128) c2=128;
  const int c1_32 = (c1+31)&~31, c2_32 = (c2+31)&~31;
  if ((rt<<4) >= c1_32 || c2_32 == 0) return;
  const int tid = threadIdx.x;
  {
    const int r = tid >> 4;
    const int f0 = (tid & 15) << 5;
    const int row = (rt<<4) + r;
    const bool val = row < c1;
    const float* src = sf + (size_t)(gR + row)*1024 + f0;
    #pragma unroll
    for (int q=0;q<4;++q){
      float4 v0, v1;
      if (val){
        v0 = *(const float4*)(src + (q<<3));
        v1 = *(const float4*)(src + (q<<3) + 4);
      } else {
        v0.x=0.f; v0.y=0.f; v0.z=0.f; v0.w=0.f; v1 = v0;
      }
      half8 h,l; split8(v0,v1,h,l);
      const int a = ((f0>>3) + q)*136 + (r<<3);
      *(half8*)&Ahs[a] = h; *(half8*)&Als[a] = l;
    }
  }
  const int w = tid>>6, lane = tid&63, lr = lane&15, lg = lane>>4;
  const int bc = tid>>2, bfg = tid&3, bf = bfg<<3;
  const int bwr = (bfg<<9) + ((bc ^ (bfg<<2))<<3);
  const int ncc = (c2_32 + 63) >> 6;
  _Float16* T0h = Th + ((size_t)g<<14);
  _Float16* T0l = Tl + ((size_t)g<<14);
  _Float16* T1h = Th + ((size_t)(B + g)<<14);
  _Float16* T1l = Tl + ((size_t)(B + g)<<14);
  for (int cc=0; cc<ncc; ++cc){
    const int cbase = cc<<6;
    const int colr = cbase + bc;
    const bool bval = colr < c2;
    const float* bsrc = vf + (size_t)(gO + colr)*1024 + bf;
    {
      float4 v0, v1;
      if (bval){ v0 = *(const float4*)(bsrc); v1 = *(const float4*)(bsrc + 4); }
      else { v0.x=0.f; v0.y=0.f; v0.z=0.f; v0.w=0.f; v1 = v0; }
      half8 h,l; split8(v0,v1,h,l);
      *(half8*)&Bhs[0][bwr] = h; *(half8*)&Bls[0][bwr] = l;
    }
    __syncthreads();
    f32x4 acc = {0.f,0.f,0.f,0.f};
    const int col_l = (w<<4) + lr;
    const int ba = (lg<<9) + ((col_l ^ (lg<<2))<<3);
    for (int kc=0; kc<16; ++kc){
      float4 p0, p1;
      if (kc+1<16){
        if (bval){
          const float* s = bsrc + ((kc+1)<<5);
          p0 = *(const float4*)s; p1 = *(const float4*)(s + 4);
        } else { p0.x=0.f; p0.y=0.f; p0.z=0.f; p0.w=0.f; p1 = p0; }
      }
      const int aa = ((kc<<2)+lg)*136 + (lr<<3);
      half8 ah = *(const half8*)&Ahs[aa];
      half8 al = *(const half8*)&Als[aa];
      half8 bh = *(const half8*)&Bhs[kc&1][ba];
      half8 bl = *(const half8*)&Bls[kc&1][ba];
      acc = MF(ah,bh,acc);
      acc = MF(al,bh,acc);
      acc = MF(ah,bl,acc);
      if (kc+1<16){
        half8 h,l; split8(p0,p1,h,l);
        *(half8*)&Bhs[(kc+1)&1][bwr] = h; *(half8*)&Bls[(kc+1)&1][bwr] = l;
      }
      __syncthreads();
    }
    const int col = cbase + col_l;
    if (col < c2_32){
      half4_t t1h, t1l;
      #pragma unroll
      for (int qq=0;qq<4;++qq){
        int r = (rt<<4) + (lg<<2) + qq;
        float t = (r < c1 && col < c2) ? ftanh(acc[qq]) : 0.f;
        _Float16 hh = (_Float16)t;
        _Float16 ll = (_Float16)(t - (float)hh);
        T0h[(r<<7) + col] = hh;
        T0l[(r<<7) + col] = ll;
        t1h[qq] = hh; t1l[qq] = ll;
      }
      const int r0 = (rt<<4) + (lg<<2);
      *(half4_t*)&T1h[(col<<7) + r0] = t1h;
      *(half4_t*)&T1l[(col<<7) + r0] = t1l;
    }
  }
}

// ------- k_apply: own'[r][f] = sum_o T[r][o]*oth[o][f] via MFMA.
__global__ __launch_bounds__(256)
void k_apply(const _Float16* __restrict__ Th, const _Float16* __restrict__ Tl,
             const _Float16* __restrict__ p1h, const _Float16* __restrict__ p1l,
             const _Float16* __restrict__ p2h, const _Float16* __restrict__ p2l,
             const int* __restrict__ go1, const int* __restrict__ go2,
             const int* __restrict__ pb1, const int* __restrict__ pb2,
             float* __restrict__ sf, float* __restrict__ vf, int B)
{
  const int side = blockIdx.x, g = blockIdx.y, ft = blockIdx.z;
  const int* goR = side ? go2 : go1;
  const int* goO = side ? go1 : go2;
  const int* pbO = side ? pb1 : pb2;
  const _Float16* oph = side ? p1h : p2h;
  const _Float16* opl = side ? p1l : p2l;
  float* outp = side ? vf : sf;
  int gR = goR[g]; int cR = goR[g+1]-gR; if (cR>128) cR=128;
  int gO = goO[g]; int cO = goO[g+1]-gO; if (cO>128) cO=128;
  if (cR <= 0) return;
  const int pO = pbO[g];
  const int cO32 = (cO+31)&~31;
  const int MR = ((cR+15)&~15)>>4;
  const _Float16* Tph = Th + ((size_t)(side*B + g)<<14);
  const _Float16* Tpl = Tl + ((size_t)(side*B + g)<<14);
  const int tid = threadIdx.x, w = tid>>6, lane = tid&63;
  const int lr = lane&15, lg = lane>>4;
  const int f0 = (ft<<8) + (w<<6);
  for (int rc = 0; rc < MR; rc += 4){
    f32x4 acc[4][4];
    #pragma unroll
    for (int a_=0;a_<4;++a_)
      #pragma unroll
      for (int b_=0;b_<4;++b_) acc[a_][b_] = (f32x4){0.f,0.f,0.f,0.f};
    for (int k0=0; k0<cO32; k0+=32){
      half8 bh[4], bl[4];
      #pragma unroll
      for (int nj=0;nj<4;++nj){
        size_t a = ((size_t)((pO + k0)>>3) + lg)*4096 + (size_t)(f0 + (nj<<4) + lr)*8;
        bh[nj] = *(const half8*)(oph + a);
        bl[nj] = *(const half8*)(opl + a);
      }
      #pragma unroll
      for (int mi=0;mi<4;++mi){
        if (rc + mi < MR){
          int a = ((((rc+mi)<<4) + lr)<<7) + k0 + (lg<<3);
          half8 th_ = *(const half8*)&Tph[a];
          half8 tl_ = *(const half8*)&Tpl[a];
          #pragma unroll
          for (int nj=0;nj<4;++nj){
            acc[mi][nj] = MF(th_, bh[nj], acc[mi][nj]);
            acc[mi][nj] = MF(tl_, bh[nj], acc[mi][nj]);
            acc[mi][nj] = MF(th_, bl[nj], acc[mi][nj]);
          }
        }
      }
    }
    #pragma unroll
    for (int mi=0;mi<4;++mi){
      if (rc + mi < MR){
        #pragma unroll
        for (int nj=0;nj<4;++nj){
          #pragma unroll
          for (int qq=0;qq<4;++qq){
            int r = (((rc+mi)<<4)) + (lg<<2) + qq;
            if (r < cR)
              outp[(size_t)(gR + r)*1024 + 512 + f0 + (nj<<4) + lr] = acc[mi][nj][qq];
          }
        }
      }
    }
  }
}

// ------- k_gemmsk: fp32 skinny NT GEMM (kept for fc2 only).
__global__ __launch_bounds__(256)
void k_gemmsk(const float* __restrict__ Ab, size_t AsideOff, int lda,
              const float* __restrict__ Bm, int ldb,
              float* __restrict__ P, int M, int N, int kchunk)
{
  __shared__ float As[2][16][132];
  __shared__ float Bs[2][16][68];
  const int tid = threadIdx.x;
  const int col0 = (int)blockIdx.x << 6;
  const int kbeg = (int)blockIdx.z * kchunk;
  const float* A = Ab + (size_t)blockIdx.y * AsideOff;
  const int ar = tid >> 1, ak = (tid & 1) << 3;
  const int br = tid >> 2, bk = (tid & 3) << 2;
  const int tx = tid & 15, ty = tid >> 4;
  const float* Arow = A + (size_t)ar * lda + kbeg + ak;
  const float* Brow = Bm + (size_t)(col0 + br) * ldb + kbeg + bk;
  float acc[8][4] = {};
  float4 a0 = *(const float4*)(Arow);
  float4 a1 = *(const float4*)(Arow + 4);
  float4 b0 = *(const float4*)(Brow);
  As[0][ak+0][ar]=a0.x; As[0][ak+1][ar]=a0.y; As[0][ak+2][ar]=a0.z; As[0][ak+3][ar]=a0.w;
  As[0][ak+4][ar]=a1.x; As[0][ak+5][ar]=a1.y; As[0][ak+6][ar]=a1.z; As[0][ak+7][ar]=a1.w;
  Bs[0][bk+0][br]=b0.x; Bs[0][bk+1][br]=b0.y; Bs[0][bk+2][br]=b0.z; Bs[0][bk+3][br]=b0.w;
  __syncthreads();
  const int nt = kchunk >> 4;
  for (int t = 0; t < nt; ++t){
    const int cb = t & 1;
    if (t + 1 < nt){
      int k0 = (t + 1) << 4;
      a0 = *(const float4*)(Arow + k0);
      a1 = *(const float4*)(Arow + k0 + 4);
      b0 = *(const float4*)(Brow + k0);
    }
    #pragma unroll
    for (int kk = 0; kk < 16; ++kk){
      float4 b4 = *(const float4*)&Bs[cb][kk][tx << 2];
      float4 a4 = *(const float4*)&As[cb][kk][ty << 3];
      float4 a5 = *(const float4*)&As[cb][kk][(ty << 3) + 4];
      acc[0][0]+=a4.x*b4.x; acc[0][1]+=a4.x*b4.y; acc[0][2]+=a4.x*b4.z; acc[0][3]+=a4.x*b4.w;
      acc[1][0]+=a4.y*b4.x; acc[1][1]+=a4.y*b4.y; acc[1][2]+=a4.y*b4.z; acc[1][3]+=a4.y*b4.w;
      acc[2][0]+=a4.z*b4.x; acc[2][1]+=a4.z*b4.y; acc[2][2]+=a4.z*b4.z; acc[2][3]+=a4.z*b4.w;
      acc[3][0]+=a4.w*b4.x; acc[3][1]+=a4.w*b4.y; acc[3][2]+=a4.w*b4.z; acc[3][3]+=a4.w*b4.w;
      acc[4][0]+=a5.x*b4.x; acc[4][1]+=a5.x*b4.y; acc[4][2]+=a5.x*b4.z; acc[4][3]+=a5.x*b4.w;
      acc[5][0]+=a5.y*b4.x; acc[5][1]+=a5.y*b4.y; acc[5][2]+=a5.y*b4.z; acc[5][3]+=a5.y*b4.w;
      acc[6][0]+=a5.z*b4.x; acc[6][1]+=a5.z*b4.y; acc[6][2]+=a5.z*b4.z; acc[6][3]+=a5.z*b4.w;
      acc[7][0]+=a5.w*b4.x; acc[7][1]+=a5.w*b4.y; acc[7][2]+=a5.w*b4.z; acc[7][3]+=a5.w*b4.w;
    }
    if (t + 1 < nt){
      const int nb = cb ^ 1;
      As[nb][ak+0][ar]=a0.x; As[nb][ak+1][ar]=a0.y; As[nb][ak+2][ar]=a0.z; As[nb][ak+3][ar]=a0.w;
      As[nb][ak+4][ar]=a1.x; As[nb][ak+5][ar]=a1.y; As[nb][ak+6][ar]=a1.z; As[nb][ak+7][ar]=a1.w;
      Bs[nb][bk+0][br]=b0.x; Bs[nb][bk+1][br]=b0.y; Bs[nb][bk+2][br]=b0.z; Bs[nb][bk+3][br]=b0.w;
    }
    __syncthreads();
  }
  float* Pz = P + (size_t)(blockIdx.y*gridDim.z + blockIdx.z) * M * N;
  #pragma unroll
  for (int i = 0; i < 8; ++i){
    int rr = (ty << 3) + i;
    float4 v = {acc[i][0], acc[i][1], acc[i][2], acc[i][3]};
    *(float4*)(Pz + (size_t)rr*N + col0 + (tx<<2)) = v;
  }
}

// ------- k_gemmsk_h: split-f16 MFMA skinny GEMM (A fp32 staged, B packed planes).
__global__ __launch_bounds__(256)
void k_gemmsk_h(const float* __restrict__ Ab, size_t AsideOff, int lda,
                const _Float16* __restrict__ Bhp, const _Float16* __restrict__ Blp,
                float* __restrict__ P, int N, int kchunk)
{
  __shared__ __align__(16) _Float16 Ahs[2][4096];   // [kb(4)][m(128)][8]
  __shared__ __align__(16) _Float16 Als[2][4096];
  const int tid = threadIdx.x;
  const int col0 = (int)blockIdx.x << 7;
  const int kbeg = (int)blockIdx.z * kchunk;
  const float* A = Ab + (size_t)blockIdx.y * AsideOff;
  const int ar = tid >> 1, aq = (tid & 1) << 4;     // row, k-offset {0,16}
  const int wid = tid>>6, lane = tid&63;
  const int wr = wid>>1, wc = wid&1;
  const int lr = lane&15, lg = lane>>4;
  const float* Arow = A + (size_t)ar*lda + kbeg + aq;
  const int akb = aq>>3;                            // 0 or 2
  f32x4 acc[4][4] = {};
  const int nc = kchunk >> 5;
  float4 g0,g1,g2,g3;
  g0 = *(const float4*)(Arow);     g1 = *(const float4*)(Arow+4);
  g2 = *(const float4*)(Arow+8);   g3 = *(const float4*)(Arow+12);
  {
    half8 h,l;
    split8(g0,g1,h,l);
    *(half8*)&Ahs[0][(akb*128+ar)*8] = h;     *(half8*)&Als[0][(akb*128+ar)*8] = l;
    split8(g2,g3,h,l);
    *(half8*)&Ahs[0][((akb+1)*128+ar)*8] = h; *(half8*)&Als[0][((akb+1)*128+ar)*8] = l;
  }
  __syncthreads();
  for (int c=0;c<nc;++c){
    const int cb = c&1;
    if (c+1<nc){
      const float* p = Arow + ((c+1)<<5);
      g0 = *(const float4*)(p);    g1 = *(const float4*)(p+4);
      g2 = *(const float4*)(p+8);  g3 = *(const float4*)(p+12);
    }
    const size_t kb0 = (size_t)((kbeg + (c<<5)) >> 3) + lg;
    half8 bh[4], bl[4];
    #pragma unroll
    for (int ni=0;ni<4;++ni){
      size_t a = (kb0*N + col0 + (wc<<6) + (ni<<4) + lr)*8;
      bh[ni] = *(const half8*)(Bhp + a);
      bl[ni] = *(const half8*)(Blp + a);
    }
    #pragma unroll
    for (int mi=0;mi<4;++mi){
      int aa = ((lg<<7) + (wr<<6) + (mi<<4) + lr)<<3;
      half8 ah = *(const half8*)&Ahs[cb][aa];
      half8 al = *(const half8*)&Als[cb][aa];
      #pragma unroll
      for (int ni=0;ni<4;++ni){
        acc[mi][ni] = MF(ah,bh[ni],acc[mi][ni]);
        acc[mi][ni] = MF(al,bh[ni],acc[mi][ni]);
        acc[mi][ni] = MF(ah,bl[ni],acc[mi][ni]);
      }
    }
    if (c+1<nc){
      const int nb = cb^1;
      half8 h,l;
      split8(g0,g1,h,l);
      *(half8*)&Ahs[nb][(akb*128+ar)*8] = h;     *(half8*)&Als[nb][(akb*128+ar)*8] = l;
      split8(g2,g3,h,l);
      *(half8*)&Ahs[nb][((akb+1)*128+ar)*8] = h; *(half8*)&Als[nb][((akb+1)*128+ar)*8] = l;
    }
    __syncthreads();
  }
  float* Pz = P + (size_t)(blockIdx.y*gridDim.z + blockIdx.z)*128*N;
  #pragma unroll
  for (int mi=0;mi<4;++mi){
    #pragma unroll
    for (int ni=0;ni<4;++ni){
      int cc2 = col0 + (wc<<6) + (ni<<4) + lr;
      #pragma unroll
      for (int j=0;j<4;++j){
        int rr2 = (wr<<6) + (mi<<4) + (lg<<2) + j;
        Pz[(size_t)rr2*N + cc2] = acc[mi][ni][j];
      }
    }
  }
}

// sum split partials + bias (+relu)
__global__ void k_red_bias(const float* __restrict__ P, int split, int MN, int N,
                           const float* __restrict__ bias, float* __restrict__ C, int relu){
  int i = blockIdx.x*256 + threadIdx.x;
  if (i >= MN) return;
  float v = bias[i & (N-1)];
  for (int s=0;s<split;++s) v += P[(size_t)s*MN + i];
  if (relu) v = fmaxf(v, 0.f);
  C[i] = v;
}

// ---------------- Set2Set ----------------
__global__ void k_lstm1(const float* __restrict__ bih, const float* __restrict__ bhh,
                        float* __restrict__ c1, float* __restrict__ h1){
  int j = blockIdx.x*256 + threadIdx.x;
  if (j >= 1024) return;
  float gi = bih[j]        + bhh[j];
  float gg = bih[j+2048]   + bhh[j+2048];
  float go = bih[j+3072]   + bhh[j+3072];
  float cc = fsigm(gi)*ftanh(gg);
  c1[j] = cc;
  h1[j] = fsigm(go)*ftanh(cc);
}

__global__ void k_gemv_u(const float* __restrict__ Wih, const float* __restrict__ Whh,
                         const float* __restrict__ bih, const float* __restrict__ bhh,
                         const float* __restrict__ h1, float* __restrict__ u){
  int w = (blockIdx.x*256 + threadIdx.x)>>6;
  int lane = threadIdx.x & 63;
  if (w >= 4096) return;
  const float* wi = Wih + (size_t)w*2048;
  const float* wh = Whh + (size_t)w*1024;
  float acc = 0.f;
  #pragma unroll
  for (int qq=0;qq<4;++qq){
    int o = qq*256 + (lane<<2);
    float4 hv = *(const float4*)(h1 + o);
    float4 a  = *(const float4*)(wi + o);
    float4 b  = *(const float4*)(wh + o);
    acc += hv.x*(a.x+b.x) + hv.y*(a.y+b.y) + hv.z*(a.z+b.z) + hv.w*(a.w+b.w);
  }
  acc = wredsum(acc);
  if (lane==0) u[w] = acc + bih[w] + bhh[w];
}

// fused attention, dual-side (blockIdx.y): online segment softmax + weighted sum
__global__ __launch_bounds__(256)
void k_attn(const float* __restrict__ sf, const float* __restrict__ vf,
            const int* __restrict__ go1, const int* __restrict__ go2,
            const float* __restrict__ hbase, size_t hSideOff, int hstride,
            float* __restrict__ outbase, size_t oSideOff, int ldout)
{
  __shared__ float hs[1024];
  __shared__ float ech[1024];
  __shared__ float red[8];
  int side = blockIdx.y;
  const float* x = side? vf : sf;
  const int* goff = side? go2 : go1;
  const float* hsrc = hbase + (size_t)side*hSideOff;
  float* outp = outbase + (size_t)side*oSideOff;
  int b = blockIdx.x, t = threadIdx.x;
  int i0 = goff[b], i1 = goff[b+1];
  int lane = t & 63, wv = t >> 6;
  { float4 hv = *(const float4*)(hsrc + (size_t)b*hstride + (t<<2));
    *(float4*)&hs[t<<2] = hv; }
  __syncthreads();
  float m = -3.0e38f, s = 0.f;
  float ax=0, ay=0, az=0, aw=0;
  for (int c = i0; c < i1; c += 1024){
    int ce = c + 1024; if (ce > i1) ce = i1;
    int n = ce - c;
    float wmax = -3.0e38f;
    for (int i = c + wv; i < ce; i += 4){
      const float* xr = x + (size_t)i*1024;
      float d = 0.f;
      #pragma unroll
      for (int qq=0;qq<4;++qq){
        int o = qq*256 + (lane<<2);
        float4 xv = *(const float4*)(xr+o);
        float4 h4 = *(const float4*)&hs[o];
        d += xv.x*h4.x + xv.y*h4.y + xv.z*h4.z + xv.w*h4.w;
      }
      d = wredsum(d);
      if (lane==0) ech[i-c] = d;
      wmax = fmaxf(wmax, d);
    }
    if (lane==0) red[wv] = wmax;
    __syncthreads();
    float cm = fmaxf(fmaxf(red[0],red[1]), fmaxf(red[2],red[3]));
    float nm = fmaxf(m, cm);
    float scale = __expf(m - nm);
    s *= scale; ax*=scale; ay*=scale; az*=scale; aw*=scale;
    float ps = 0.f;
    for (int k = t; k < n; k += 256) ps += __expf(ech[k]-nm);
    ps = wredsum(ps);
    __syncthreads();
    if (lane==0) red[wv] = ps;
    __syncthreads();
    s += red[0]+red[1]+red[2]+red[3];
    for (int k = 0; k < n; ++k){
      float w = __expf(ech[k]-nm);
      float4 xv = *(const float4*)(x + (size_t)(c+k)*1024 + (t<<2));
      ax += w*xv.x; ay += w*xv.y; az += w*xv.z; aw += w*xv.w;
    }
    m = nm;
    __syncthreads();
  }
  float inv = (i1>i0 && s>0.f) ? 1.f/s : 0.f;
  float4 o = {ax*inv, ay*inv, az*inv, aw*inv};
  *(float4*)(outp + (size_t)b*ldout + (t<<2)) = o;
}

// LSTM iter2 (dual-side via blockIdx.y): sum split gate partials + u, cell/hidden
__global__ void k_lstm2_red(const float* __restrict__ Pb, size_t PsideOff, int split,
                            const float* __restrict__ u, const float* __restrict__ c1,
                            float* __restrict__ z, int B){
  int idx = blockIdx.x*256 + threadIdx.x;
  if (idx >= B*1024) return;
  int side = blockIdx.y;
  const float* P = Pb + (size_t)side*PsideOff;
  int b = idx >> 10, j = idx & 1023;
  float gi=u[j], gf=u[j+1024], gg=u[j+2048], go=u[j+3072];
  const float* g = P + (size_t)b*4096;
  for (int s=0;s<split;++s){
    const float* gs = g + (size_t)s*B*4096;
    gi += gs[j]; gf += gs[j+1024]; gg += gs[j+2048]; go += gs[j+3072];
  }
  float cc = fsigm(gf)*c1[j] + fsigm(gi)*ftanh(gg);
  z[(size_t)b*4096 + side*2048 + j] = fsigm(go)*ftanh(cc);
}

__global__ void k_fc3(const float* __restrict__ z2, const float* __restrict__ w3,
                      const float* __restrict__ b3, float* __restrict__ out, int B){
  int wv = (blockIdx.x*256+threadIdx.x)>>6;
  int lane = threadIdx.x & 63;
  if (wv >= B) return;
  const float* zr = z2 + (size_t)wv*512;
  float acc=0.f;
  #pragma unroll
  for (int qq=0;qq<2;++qq){
    int o = qq*256 + (lane<<2);
    float4 a  = *(const float4*)(zr + o);
    float4 ww = *(const float4*)(w3 + o);
    acc += a.x*ww.x + a.y*ww.y + a.z*ww.z + a.w*ww.w;
  }
  acc = wredsum(acc);
  if (lane==0) out[wv] = acc + b3[0];
}

// ---------------- driver ----------------
extern "C" void kernel_launch(void* const* d_in, const int* in_sizes, int n_in,
                              void* d_out, int out_size, void* d_ws, size_t ws_size,
                              hipStream_t stream)
{
  const float* x1  = (const float*)d_in[0];
  const float* x2  = (const float*)d_in[1];
  const int* src1  = (const int*)d_in[2];
  const int* dst1  = (const int*)d_in[3];
  const int* src2  = (const int*)d_in[4];
  const int* dst2  = (const int*)d_in[5];
  const int* gid1  = (const int*)d_in[6];
  const int* gid2  = (const int*)d_in[7];
  const float* Wg1 = (const float*)d_in[8];  const float* bg1 = (const float*)d_in[9];
  const float* Wg2 = (const float*)d_in[10]; const float* bg2 = (const float*)d_in[11];
  const float* Wg3 = (const float*)d_in[12]; const float* bg3 = (const float*)d_in[13];
  const float* Wg4 = (const float*)d_in[14]; const float* bg4 = (const float*)d_in[15];
  const float* Wih = (const float*)d_in[16]; const float* Whh = (const float*)d_in[17];
  const float* bih = (const float*)d_in[18]; const float* bhh = (const float*)d_in[19];
  const float* Wf1 = (const float*)d_in[20]; const float* bf1 = (const float*)d_in[21];
  const float* Wf2 = (const float*)d_in[22]; const float* bf2 = (const float*)d_in[23];
  const float* Wf3 = (const float*)d_in[24]; const float* bf3 = (const float*)d_in[25];
  float* out = (float*)d_out;

  const int N1 = in_sizes[0]/128;
  const int N2 = in_sizes[1]/128;
  const int E1 = in_sizes[2];
  const int E2 = in_sizes[4];
  const int B  = out_size;            // 128
  const int NM = N1>N2?N1:N2;

  char* base = (char*)d_ws; size_t off=0;
  auto alloc = [&](size_t bytes)->void*{ void* p = base+off; off += (bytes+255)&~(size_t)255; return p; };

  int* zr   = (int*)alloc(sizeof(int)*(size_t)(3*N1+3*N2));
  int* co1=zr, *ci1=zr+N1, *cur1=zr+2*N1;
  int* co2=zr+3*N1, *ci2=zr+3*N1+N2, *cur2=zr+3*N1+2*N2;
  int* row1 = (int*)alloc(sizeof(int)*(size_t)(N1+1));
  int* row2 = (int*)alloc(sizeof(int)*(size_t)(N2+1));
  int* csr1 = (int*)alloc(sizeof(int)*(size_t)E1);
  int* csr2 = (int*)alloc(sizeof(int)*(size_t)E2);
  int* go1  = (int*)alloc(sizeof(int)*(size_t)(B+1));
  int* go2  = (int*)alloc(sizeof(int)*(size_t)(B+1));
  int* pb1  = (int*)alloc(sizeof(int)*(size_t)(B+1));
  int* pb2  = (int*)alloc(sizeof(int)*(size_t)(B+1));
  int* gm1  = (int*)alloc(sizeof(int)*1024);
  int* gm2  = (int*)alloc(sizeof(int)*1024);
  float* os1 = (float*)alloc(sizeof(float)*(size_t)N1);
  float* is1 = (float*)alloc(sizeof(float)*(size_t)N1);
  float* os2 = (float*)alloc(sizeof(float)*(size_t)N2);
  float* is2 = (float*)alloc(sizeof(float)*(size_t)N2);
  _Float16* a1h = (_Float16*)alloc(sizeof(_Float16)*(size_t)(NM+128)*256);
  _Float16* a1l = (_Float16*)alloc(sizeof(_Float16)*(size_t)(NM+128)*256);
  _Float16* a2h = (_Float16*)alloc(sizeof(_Float16)*(size_t)(NM+128)*256);
  _Float16* a2l = (_Float16*)alloc(sizeof(_Float16)*(size_t)(NM+128)*256);
  _Float16* wg1h = (_Float16*)alloc(sizeof(_Float16)*32768);
  _Float16* wg1l = (_Float16*)alloc(sizeof(_Float16)*32768);
  _Float16* wg2h = (_Float16*)alloc(sizeof(_Float16)*131072);
  _Float16* wg2l = (_Float16*)alloc(sizeof(_Float16)*131072);
  _Float16* wg3h = (_Float16*)alloc(sizeof(_Float16)*32768);
  _Float16* wg3l = (_Float16*)alloc(sizeof(_Float16)*32768);
  _Float16* wg4h = (_Float16*)alloc(sizeof(_Float16)*131072);
  _Float16* wg4l = (_Float16*)alloc(sizeof(_Float16)*131072);
  // Set2Set gates + fc1 weight planes (split-f16, k8-packed)
  _Float16* wihh = (_Float16*)alloc(sizeof(_Float16)*(size_t)4096*1024);
  _Float16* wihl = (_Float16*)alloc(sizeof(_Float16)*(size_t)4096*1024);
  _Float16* wf1h = (_Float16*)alloc(sizeof(_Float16)*(size_t)1024*4096);
  _Float16* wf1l = (_Float16*)alloc(sizeof(_Float16)*(size_t)1024*4096);
  float* sf  = (float*)alloc(sizeof(float)*(size_t)(N1+128)*1024);
  float* vf  = (float*)alloc(sizeof(float)*(size_t)(N2+128)*1024);
  float* h1 = (float*)alloc(sizeof(float)*1024);
  float* c1 = (float*)alloc(sizeof(float)*1024);
  float* u  = (float*)alloc(sizeof(float)*4096);
  float* r1 = (float*)alloc(sizeof(float)*(size_t)2*B*1024);
  float* z1 = (float*)alloc(sizeof(float)*(size_t)B*1024);
  float* z2 = (float*)alloc(sizeof(float)*(size_t)B*512);
  float* z  = (float*)alloc(sizeof(float)*(size_t)B*4096);
  // T planes: [2 sides][B][128][128] split-f16 (16.8 MB total)
  _Float16* Tqh = (_Float16*)alloc(sizeof(_Float16)*(size_t)2*B*16384);
  _Float16* Tql = (_Float16*)alloc(sizeof(_Float16)*(size_t)2*B*16384);
  // union region: node-packed split-f16 planes (interact stage) / Pbuf partials (later stages)
  const int PN = ((NM + 32*B + 63)&~63) + 64;      // padded node capacity
  const size_t PE = (size_t)PN*512;                // elems per plane
  size_t packedBytes = 4*PE*sizeof(_Float16);
  size_t pbufBytes   = sizeof(float)*(size_t)32*B*1024*4;
  char* uni = (char*)alloc(packedBytes > pbufBytes ? packedBytes : pbufBytes);
  _Float16* p1h = (_Float16*)uni;
  _Float16* p1l = p1h + PE;
  _Float16* p2h = p1l + PE;
  _Float16* p2l = p2h + PE;
  float* Pbuf = (float*)uni;
  if (off > ws_size) return;

  // hbuf regions live inside sf/vf cols [512,768) (stride 1024), overwritten later by apply
  float* hb1 = sf + 512;
  float* hb2 = vf + 512;

  dim3 blk(256);

  // --- weight split-f16 packs (independent of graph prep) ---
  k_wpack4<<<dim3(512,4),blk,0,stream>>>(Wg1,Wg2,Wg3,Wg4,
                                         wg1h,wg1l, wg2h,wg2l, wg3h,wg3l, wg4h,wg4l);
  k_wpackT<<<dim3(4,128),blk,0,stream>>>(Wih+1024, 2048, 4096, wihh, wihl);  // gates W
  k_wpackT<<<dim3(16,32),blk,0,stream>>>(Wf1, 4096, 1024, wf1h, wf1l);       // fc1 W

  // --- prep ---
  k_zero_i32<<<(3*N1+3*N2+255)/256, blk, 0, stream>>>(zr, 3*N1+3*N2);
  k_hist2<<<(E1+E2+255)/256, blk, 0, stream>>>(src1,dst1,E1,co1,ci1, src2,dst2,E2,co2,ci2);
  k_scan2<<<2,1024,0,stream>>>(ci1,N1,row1, ci2,N2,row2);
  k_scale2<<<(N1+N2+255)/256,blk,0,stream>>>(co1,ci1,N1,os1,is1, co2,ci2,N2,os2,is2);
  k_scatter2<<<(E1+E2+255)/256,blk,0,stream>>>(src1,dst1,E1,row1,cur1,csr1, src2,dst2,E2,row2,cur2,csr2);
  k_goff2<<<1,512,0,stream>>>(gid1,N1,go1, gid2,N2,go2, B, pb1,gm1, pb2,gm2);

  // --- GraphConv: agg both sides (split-f16 out), dual MFMA GEMM L1 (post=os),
  //     agg (no scale), dual MFMA GEMM L2 ---
  int gy = (NM+127)/128;
  k_agg_h<<<(N1+7)/8,blk,0,stream>>>(x1,128, os1,row1,csr1, a1h,a1l, N1,5);
  k_agg_h<<<(N2+7)/8,blk,0,stream>>>(x2,128, os2,row2,csr2, a2h,a2l, N2,5);
  k_gconv_mfma<<<dim3(2,gy,2),blk,0,stream>>>(a1h,a1l, a2h,a2l,
                                              wg1h,wg1l, wg3h,wg3l,
                                              hb1,hb2,1024, N1,N2, 256,128,
                                              is1,is2, bg1,bg3, 1, os1,os2);
  k_agg_h<<<(N1+3)/4,blk,0,stream>>>(hb1,1024, nullptr,row1,csr1, a1h,a1l, N1,6);
  k_agg_h<<<(N2+3)/4,blk,0,stream>>>(hb2,1024, nullptr,row2,csr2, a2h,a2l, N2,6);
  k_gconv_mfma<<<dim3(4,gy,2),blk,0,stream>>>(a1h,a1l, a2h,a2l,
                                              wg2h,wg2l, wg4h,wg4l,
                                              sf,vf,1024, N1,N2, 512,256,
                                              is1,is2, bg2,bg4, 0, nullptr,nullptr);

  // --- block-diagonal interaction (MFMA; T computed once, transposed write) ---
  const int GMAX = NM/32 + B + 2;
  k_pack<<<dim3(GMAX,2),blk,0,stream>>>(sf,vf, go1,go2, pb1,pb2, gm1,gm2,
                                        p1h,p1l, p2h,p2l, B);
  k_T<<<dim3(B,8),blk,0,stream>>>(sf,vf, go1,go2, Tqh,Tql, B);
  k_apply<<<dim3(2,B,2),blk,0,stream>>>(Tqh,Tql, p1h,p1l, p2h,p2l,
                                        go1,go2, pb1,pb2, sf,vf, B);

  // --- Set2Set (sides merged per stage) ---
  k_lstm1<<<4,blk,0,stream>>>(bih,bhh,c1,h1);
  k_gemv_u<<<1024,blk,0,stream>>>(Wih,Whh,bih,bhh,h1,u);

  // iter1 attention (shared h1), both sides
  k_attn<<<dim3(B,2),blk,0,stream>>>(sf,vf,go1,go2, h1,0,0, r1,(size_t)B*1024,1024);
  // gates = r1 @ Wih[:,1024:].T via split-f16 MFMA, split-K 4 x chunk 256
  k_gemmsk_h<<<dim3(32,2,4),blk,0,stream>>>(r1,(size_t)B*1024,1024, wihh,wihl, Pbuf, 4096,256);
  k_lstm2_red<<<dim3((B*1024+255)/256,2),blk,0,stream>>>(Pbuf,(size_t)4*B*4096,4, u,c1, z,B);
  // iter2 attention with per-graph h2 (in z), both sides
  k_attn<<<dim3(B,2),blk,0,stream>>>(sf,vf,go1,go2, z,2048,4096, z+1024,2048,4096);

  // --- MLP head ---
  k_gemmsk_h<<<dim3(8,1,32),blk,0,stream>>>(z,0,4096, wf1h,wf1l, Pbuf, 1024,128);
  k_red_bias<<<(B*1024+255)/256,blk,0,stream>>>(Pbuf,32,B*1024,1024,bf1,z1,1);
  k_gemmsk<<<dim3(8,1,8),blk,0,stream>>>(z1,0,1024, Wf2,1024, Pbuf, 128,512,128);
  k_red_bias<<<(B*512+255)/256,blk,0,stream>>>(Pbuf,8,B*512,512,bf2,z2,1);
  k_fc3<<<(B*64+255)/256,blk,0,stream>>>(z2,Wf3,bf3,out,B);
}

// Round 8
// 369.501 us; speedup vs baseline: 1.2699x; 1.0322x over previous
//
#include <hip/hip_runtime.h>

#define DEV __device__ __forceinline__

typedef _Float16 half8 __attribute__((ext_vector_type(8)));
typedef _Float16 half4_t __attribute__((ext_vector_type(4)));
typedef float f32x4 __attribute__((ext_vector_type(4)));

DEV float ftanh(float x){
  float ax = fabsf(x);
  float e = __expf(-2.f*ax);
  float t = (1.f - e)/(1.f + e);
  return x < 0.f ? -t : t;
}
DEV float fsigm(float x){ return 1.f/(1.f + expf(-x)); }
DEV float wredsum(float v){
  #pragma unroll
  for (int o=32;o;o>>=1) v += __shfl_xor(v,o,64);
  return v;
}
DEV f32x4 MF(half8 a, half8 b, f32x4 c){
  return __builtin_amdgcn_mfma_f32_16x16x32_f16(a,b,c,0,0,0);
}
DEV void split8(float4 a0, float4 a1, half8& h, half8& l){
  float f[8] = {a0.x,a0.y,a0.z,a0.w,a1.x,a1.y,a1.z,a1.w};
  #pragma unroll
  for (int e=0;e<8;++e){
    _Float16 hh = (_Float16)f[e];
    h[e] = hh;
    l[e] = (_Float16)(f[e] - (float)hh);
  }
}

// ---------------- graph prep ----------------
__global__ void k_zero_i32(int* __restrict__ p, int n){
  int i = blockIdx.x*256 + threadIdx.x; if (i<n) p[i]=0;
}

__global__ void k_hist2(const int* __restrict__ s1, const int* __restrict__ d1, int E1,
                        int* __restrict__ co1, int* __restrict__ ci1,
                        const int* __restrict__ s2, const int* __restrict__ d2, int E2,
                        int* __restrict__ co2, int* __restrict__ ci2){
  int e = blockIdx.x*256 + threadIdx.x;
  if (e < E1){ atomicAdd(&co1[s1[e]],1); atomicAdd(&ci1[d1[e]],1); }
  int f = e - E1;
  if (f >= 0 && f < E2){ atomicAdd(&co2[s2[f]],1); atomicAdd(&ci2[d2[f]],1); }
}

__global__ void k_scan2(const int* __restrict__ c1, int n1, int* __restrict__ r1,
                        const int* __restrict__ c2, int n2, int* __restrict__ r2){
  __shared__ int sm[1024];
  const int* cnt = blockIdx.x ? c2 : c1;
  int*       row = blockIdx.x ? r2 : r1;
  int n          = blockIdx.x ? n2 : n1;
  int t = threadIdx.x;
  int per = n/1024 + 1;
  int st = t*per;
  int s = 0;
  for (int i=st;i<st+per;++i) if (i<n) s += cnt[i];
  sm[t]=s; __syncthreads();
  for (int o=1;o<1024;o<<=1){
    int v = (t>=o)? sm[t-o]:0;
    __syncthreads();
    sm[t] += v;
    __syncthreads();
  }
  int base = sm[t]-s;
  for (int i=st;i<st+per;++i){
    if (i<=n) row[i]=base;
    if (i<n) base += cnt[i];
  }
}

__global__ void k_scale2(const int* __restrict__ co1, const int* __restrict__ ci1, int n1,
                         float* __restrict__ os1, float* __restrict__ is1,
                         const int* __restrict__ co2, const int* __restrict__ ci2, int n2,
                         float* __restrict__ os2, float* __restrict__ is2){
  int i = blockIdx.x*256+threadIdx.x;
  if (i<n1){
    int a = co1[i] > 1 ? co1[i] : 1;
    int b = ci1[i] > 1 ? ci1[i] : 1;
    os1[i] = 1.f/sqrtf((float)a);
    is1[i] = 1.f/sqrtf((float)b);
  }
  int j = i - n1;
  if (j>=0 && j<n2){
    int a = co2[j] > 1 ? co2[j] : 1;
    int b = ci2[j] > 1 ? ci2[j] : 1;
    os2[j] = 1.f/sqrtf((float)a);
    is2[j] = 1.f/sqrtf((float)b);
  }
}

__global__ void k_scatter2(const int* __restrict__ s1, const int* __restrict__ d1, int E1,
                           const int* __restrict__ row1, int* __restrict__ cur1, int* __restrict__ csr1,
                           const int* __restrict__ s2, const int* __restrict__ d2, int E2,
                           const int* __restrict__ row2, int* __restrict__ cur2, int* __restrict__ csr2){
  int e = blockIdx.x*256+threadIdx.x;
  if (e<E1){ int d=d1[e]; int p=atomicAdd(&cur1[d],1); csr1[row1[d]+p]=s1[e]; }
  int f = e - E1;
  if (f>=0 && f<E2){ int d=d2[f]; int p=atomicAdd(&cur2[d],1); csr2[row2[d]+p]=s2[f]; }
}

// goff binary search + PARALLEL packed-plane prefix (pb, 32-aligned) + group->graph map (gm).
__global__ void k_goff2(const int* __restrict__ g1, int n1, int* __restrict__ o1,
                        const int* __restrict__ g2, int n2, int* __restrict__ o2, int B,
                        int* __restrict__ pb1, int* __restrict__ gm1,
                        int* __restrict__ pb2, int* __restrict__ gm2){
  __shared__ int sc[2][256];
  int t = threadIdx.x;
  const int* gid = (t>=256)? g2 : g1;
  int*      goff = (t>=256)? o2 : o1;
  int n          = (t>=256)? n2 : n1;
  const int side = t>>8, q = t & 255;
  if (q<=B){
    int lo=0, hi=n;
    while (lo<hi){ int mid=(lo+hi)>>1; if (gid[mid]<q) lo=mid+1; else hi=mid; }
    goff[q]=lo;
  }
  __syncthreads();
  int pc = 0;
  if (q < B){
    const int* go = side ? o2 : o1;
    int c = go[q+1]-go[q]; if (c>128) c=128;
    pc = (c+31)&~31;
  }
  sc[side][q] = pc;
  __syncthreads();
  for (int o=1;o<B;o<<=1){
    int v = (q>=o && q<B) ? sc[side][q-o] : 0;
    __syncthreads();
    if (q<B) sc[side][q] += v;
    __syncthreads();
  }
  if (q < B){
    int incl = sc[side][q];
    int pbv  = incl - pc;
    int* pb = side ? pb2 : pb1;
    int* gm = side ? gm2 : gm1;
    pb[q] = pbv;
    if (q == B-1) pb[B] = incl;
    int nb = pc>>5, b0 = pbv>>5;
    for (int k=0;k<nb;++k) gm[b0+k] = q;
  }
}

// gather aggregation with split-f16 output planes
__global__ void k_agg_h(const float* __restrict__ x, int ldx, const float* __restrict__ osc,
                        const int* __restrict__ row, const int* __restrict__ csr,
                        _Float16* __restrict__ oh, _Float16* __restrict__ ol, int n, int f4shift){
  int F4 = 1<<f4shift;
  int node = blockIdx.x*(256>>f4shift) + (threadIdx.x>>f4shift);
  if (node>=n) return;
  int fc = threadIdx.x & (F4-1);
  int F = F4<<2;
  int rs=row[node], re=row[node+1];
  float ax=0, ay=0, az=0, aw=0;
  if (osc){
    for (int e=rs;e<re;++e){
      int s = csr[e];
      float sc = osc[s];
      const float4 v = *(const float4*)(x + (size_t)s*ldx + (fc<<2));
      ax += sc*v.x; ay += sc*v.y; az += sc*v.z; aw += sc*v.w;
    }
  } else {
    int e = rs;
    for (; e+1<re; e+=2){
      int s0 = csr[e], s1 = csr[e+1];
      const float4 v0 = *(const float4*)(x + (size_t)s0*ldx + (fc<<2));
      const float4 v1 = *(const float4*)(x + (size_t)s1*ldx + (fc<<2));
      ax += v0.x+v1.x; ay += v0.y+v1.y; az += v0.z+v1.z; aw += v0.w+v1.w;
    }
    if (e<re){
      int s0 = csr[e];
      const float4 v0 = *(const float4*)(x + (size_t)s0*ldx + (fc<<2));
      ax += v0.x; ay += v0.y; az += v0.z; aw += v0.w;
    }
  }
  half4_t hv, lv;
  hv.x = (_Float16)ax; lv.x = (_Float16)(ax - (float)hv.x);
  hv.y = (_Float16)ay; lv.y = (_Float16)(ay - (float)hv.y);
  hv.z = (_Float16)az; lv.z = (_Float16)(az - (float)hv.z);
  hv.w = (_Float16)aw; lv.w = (_Float16)(aw - (float)hv.w);
  size_t o = (size_t)node*F + (fc<<2);
  *(half4_t*)(oh + o) = hv;
  *(half4_t*)(ol + o) = lv;
}

// pack 4 GraphConv weights (fp32 [K][N]) into split-f16 hi/lo, k8-packed layout
__global__ void k_wpack4(const float* __restrict__ W0, const float* __restrict__ W1,
                         const float* __restrict__ W2, const float* __restrict__ W3,
                         _Float16* __restrict__ h0, _Float16* __restrict__ l0,
                         _Float16* __restrict__ h1, _Float16* __restrict__ l1,
                         _Float16* __restrict__ h2, _Float16* __restrict__ l2,
                         _Float16* __restrict__ h3, _Float16* __restrict__ l3){
  int w = blockIdx.y;
  const float* W = (w==0)?W0:(w==1)?W1:(w==2)?W2:W3;
  _Float16* oh = (w==0)?h0:(w==1)?h1:(w==2)?h2:h3;
  _Float16* ol = (w==0)?l0:(w==1)?l1:(w==2)?l2:l3;
  int K   = (w&1)? 256 : 128;
  int nsh = (w&1)? 9 : 8;
  int i = blockIdx.x*256 + threadIdx.x;
  if (i >= (K<<nsh)) return;
  int k = i >> nsh, n = i & ((1<<nsh)-1);
  float v = W[i];
  _Float16 h = (_Float16)v;
  _Float16 l = (_Float16)(v - (float)h);
  size_t p = (((size_t)(k>>3)<<nsh) + n)*8 + (k&7);
  oh[p] = h; ol[p] = l;
}

// ------- k_wpackT: pack fp32 W (N rows x K cols used, row stride ldw; elem(n,k)=W[n*ldw+k])
// into split-f16 k8-packed planes: elem(n,k) -> plane[((k>>3)*N + n)*8 + (k&7)].
__global__ __launch_bounds__(256)
void k_wpackT(const float* __restrict__ W, int ldw, int N,
              _Float16* __restrict__ Bh, _Float16* __restrict__ Bl){
  __shared__ float st[32][260];
  const int k0 = (int)blockIdx.x << 8;
  const int n0 = (int)blockIdx.y << 5;
  const int t = threadIdx.x;
  const int r = t >> 3, la = t & 7;
  const float* src = W + (size_t)(n0 + r)*ldw + k0;
  #pragma unroll
  for (int q=0;q<8;++q){
    int f = (la<<2) + (q<<5);
    *(float4*)&st[r][f] = *(const float4*)(src + f);
  }
  __syncthreads();
  const int nl = t & 31;
  #pragma unroll
  for (int j=0;j<4;++j){
    int kbl = (t>>5) + (j<<3);
    half8 h8, l8;
    #pragma unroll
    for (int e=0;e<8;++e){
      float v = st[nl][(kbl<<3)+e];
      _Float16 hh = (_Float16)v;
      h8[e]=hh; l8[e]=(_Float16)(v-(float)hh);
    }
    size_t a = ((size_t)((k0>>3)+kbl)*N + n0 + nl)*8;
    *(half8*)(Bh + a) = h8;
    *(half8*)(Bl + a) = l8;
  }
}

// ------- k_gconv_mfma v2: dual-side split-f16 MFMA GEMM, gemmsk_h-style.
__global__ __launch_bounds__(256)
void k_gconv_mfma(const _Float16* __restrict__ Ah0, const _Float16* __restrict__ Al0,
                  const _Float16* __restrict__ Ah1, const _Float16* __restrict__ Al1,
                  const _Float16* __restrict__ Bh0, const _Float16* __restrict__ Bl0,
                  const _Float16* __restrict__ Bh1, const _Float16* __restrict__ Bl1,
                  float* __restrict__ C0, float* __restrict__ C1, int ldc,
                  int M0, int M1, int N, int K,
                  const float* __restrict__ rs0, const float* __restrict__ rs1,
                  const float* __restrict__ bi0, const float* __restrict__ bi1, int relu,
                  const float* __restrict__ po0, const float* __restrict__ po1)
{
  __shared__ __align__(16) _Float16 Ahs[2][4096];   // [kb(4)][m(128)][8]
  __shared__ __align__(16) _Float16 Als[2][4096];

  const int gx = gridDim.x, gxy = gridDim.x*gridDim.y;
  const int nwg = gxy*2;
  int fid = blockIdx.x + gx*blockIdx.y + gxy*blockIdx.z;
  int q = nwg>>3, r = nwg&7;
  int xcd = fid & 7, idx = fid >> 3;
  int sid = (xcd<r ? xcd*(q+1) : r*(q+1)+(xcd-r)*q) + idx;
  const int z  = sid / gxy;  int rem = sid - z*gxy;
  const int by = rem / gx,  bx = rem - by*gx;

  const _Float16* Ah = z ? Ah1 : Ah0;
  const _Float16* Al = z ? Al1 : Al0;
  const _Float16* Bh = z ? Bh1 : Bh0;
  const _Float16* Bl = z ? Bl1 : Bl0;
  float*       C  = z ? C1 : C0;
  const float* rsc = z ? rs1 : rs0;
  const float* bia = z ? bi1 : bi0;
  const float* po  = z ? po1 : po0;
  const int M = z ? M1 : M0;

  const int row0 = by << 7;
  const int col0 = bx << 7;
  if (row0 >= ((M+127)&~127)) return;

  const int tid = threadIdx.x;
  const int am  = tid >> 2;
  const int akb = tid & 3;
  const int wid = tid >> 6, lane = tid & 63;
  const int wr = wid >> 1, wc = wid & 1;
  const int lr = lane & 15, lg = lane >> 4;

  f32x4 acc[4][4] = {};
  const int nt = K >> 5;
  const size_t rowK64 = (size_t)64 * K;
  const _Float16* Aph = Ah + (size_t)(row0 + am) * K + (akb<<3);
  const _Float16* Apl = Al + (size_t)(row0 + am) * K + (akb<<3);

  half8 gh0 = *(const half8*)(Aph);
  half8 gh1 = *(const half8*)(Aph + rowK64);
  half8 gl0 = *(const half8*)(Apl);
  half8 gl1 = *(const half8*)(Apl + rowK64);
  *(half8*)&Ahs[0][(akb*128 + am)*8]      = gh0;
  *(half8*)&Ahs[0][(akb*128 + am + 64)*8] = gh1;
  *(half8*)&Als[0][(akb*128 + am)*8]      = gl0;
  *(half8*)&Als[0][(akb*128 + am + 64)*8] = gl1;
  __syncthreads();

  for (int c = 0; c < nt; ++c){
    const int cb = c & 1;
    if (c + 1 < nt){
      const int k0 = (c + 1) << 5;
      gh0 = *(const half8*)(Aph + k0);
      gh1 = *(const half8*)(Aph + k0 + rowK64);
      gl0 = *(const half8*)(Apl + k0);
      gl1 = *(const half8*)(Apl + k0 + rowK64);
    }
    const size_t kb0 = (size_t)(c<<2) + lg;
    half8 bh[4], bl[4];
    #pragma unroll
    for (int ni=0;ni<4;++ni){
      size_t a = (kb0*N + col0 + (wc<<6) + (ni<<4) + lr)*8;
      bh[ni] = *(const half8*)(Bh + a);
      bl[ni] = *(const half8*)(Bl + a);
    }
    #pragma unroll
    for (int mi=0;mi<4;++mi){
      const int aa = ((lg<<7) + (wr<<6) + (mi<<4) + lr)<<3;
      half8 ah = *(const half8*)&Ahs[cb][aa];
      half8 al = *(const half8*)&Als[cb][aa];
      #pragma unroll
      for (int ni=0;ni<4;++ni){
        acc[mi][ni] = MF(ah, bh[ni], acc[mi][ni]);
        acc[mi][ni] = MF(al, bh[ni], acc[mi][ni]);
        acc[mi][ni] = MF(ah, bl[ni], acc[mi][ni]);
      }
    }
    if (c + 1 < nt){
      const int nb_ = cb ^ 1;
      *(half8*)&Ahs[nb_][(akb*128 + am)*8]      = gh0;
      *(half8*)&Ahs[nb_][(akb*128 + am + 64)*8] = gh1;
      *(half8*)&Als[nb_][(akb*128 + am)*8]      = gl0;
      *(half8*)&Als[nb_][(akb*128 + am + 64)*8] = gl1;
    }
    __syncthreads();
  }

  #pragma unroll
  for (int ni = 0; ni < 4; ++ni){
    int cc = col0 + (wc<<6) + (ni<<4) + lr;
    float bv = bia ? bia[cc] : 0.f;
    #pragma unroll
    for (int mi = 0; mi < 4; ++mi){
      int rbase = row0 + (wr<<6) + (mi<<4) + (lg<<2);
      #pragma unroll
      for (int j = 0; j < 4; ++j){
        int rr = rbase + j;
        if (rr < M){
          float rs_ = rsc ? rsc[rr] : 1.f;
          float v = acc[mi][ni][j]*rs_ + bv;
          if (relu) v = fmaxf(v, 0.f);
          if (po) v *= po[rr];
          C[(size_t)rr*ldc + cc] = v;
        }
      }
    }
  }
}

// ------- k_pack: repack sf/vf[:, 0:512) into per-graph 32-aligned node-packed
// split-f16 planes; padding nodes written as ZERO.
__global__ __launch_bounds__(256)
void k_pack(const float* __restrict__ sf, const float* __restrict__ vf,
            const int* __restrict__ go1, const int* __restrict__ go2,
            const int* __restrict__ pb1, const int* __restrict__ pb2,
            const int* __restrict__ gm1, const int* __restrict__ gm2,
            _Float16* __restrict__ p1h, _Float16* __restrict__ p1l,
            _Float16* __restrict__ p2h, _Float16* __restrict__ p2l, int B)
{
  __shared__ float st[32][516];
  const int side = blockIdx.y;
  const float* x = side ? vf : sf;
  const int* go = side ? go2 : go1;
  const int* pb = side ? pb2 : pb1;
  const int* gm = side ? gm2 : gm1;
  _Float16* ph = side ? p2h : p1h;
  _Float16* pl = side ? p2l : p1l;
  const int u = blockIdx.x;
  if (u*32 >= pb[B]) return;
  const int g = gm[u];
  const int j0 = u*32 - pb[g];
  const int base = go[g];
  int cnt = go[g+1]-base; if (cnt>128) cnt=128;
  const int t = threadIdx.x;
  const int r = t>>3, f0 = (t&7)<<2;
  const bool valid = (j0 + r) < cnt;
  const float* src = x + (size_t)(base + j0 + r)*1024;
  #pragma unroll
  for (int q=0;q<16;++q){
    int f = f0 + (q<<5);
    float4 vv;
    if (valid) vv = *(const float4*)(src + f);
    else { vv.x=0.f; vv.y=0.f; vv.z=0.f; vv.w=0.f; }
    *(float4*)&st[r][f] = vv;
  }
  __syncthreads();
  #pragma unroll
  for (int q=0;q<8;++q){
    int u2 = t + (q<<8);
    int jg = u2>>9, f = u2&511;
    half8 h8, l8;
    #pragma unroll
    for (int e=0;e<8;++e){
      float vvv = st[(jg<<3)+e][f];
      _Float16 hh = (_Float16)vvv;
      h8[e]=hh; l8[e]=(_Float16)(vvv-(float)hh);
    }
    size_t a = ((size_t)((u<<2)+jg)<<12) + ((size_t)f<<3);
    *(half8*)(ph + a) = h8;
    *(half8*)(pl + a) = l8;
  }
}

// ------- k_T: LDS-staged split-f16 MFMA interaction tiles (see R3 notes).
__global__ __launch_bounds__(256)
void k_T(const float* __restrict__ sf, const float* __restrict__ vf,
         const int* __restrict__ go1, const int* __restrict__ go2,
         _Float16* __restrict__ Th, _Float16* __restrict__ Tl, int B)
{
  __shared__ __align__(16) _Float16 Ahs[64*136 + 8];   // [fg64][r16][8], fg stride 136
  __shared__ __align__(16) _Float16 Als[64*136 + 8];
  __shared__ __align__(16) _Float16 Bhs[2][2048];      // [buf][fg4][c64][8], c XOR-swizzled
  __shared__ __align__(16) _Float16 Bls[2][2048];
  const int g = blockIdx.x, rt = blockIdx.y;
  int gR = go1[g]; int c1 = go1[g+1]-gR; if (c1>128) c1=128;
  int gO = go2[g]; int c2 = go2[g+1]-gO; if (c2>128) c2=128;
  const int c1_32 = (c1+31)&~31, c2_32 = (c2+31)&~31;
  if ((rt<<4) >= c1_32 || c2_32 == 0) return;
  const int tid = threadIdx.x;
  {
    const int r = tid >> 4;
    const int f0 = (tid & 15) << 5;
    const int row = (rt<<4) + r;
    const bool val = row < c1;
    const float* src = sf + (size_t)(gR + row)*1024 + f0;
    #pragma unroll
    for (int q=0;q<4;++q){
      float4 v0, v1;
      if (val){
        v0 = *(const float4*)(src + (q<<3));
        v1 = *(const float4*)(src + (q<<3) + 4);
      } else {
        v0.x=0.f; v0.y=0.f; v0.z=0.f; v0.w=0.f; v1 = v0;
      }
      half8 h,l; split8(v0,v1,h,l);
      const int a = ((f0>>3) + q)*136 + (r<<3);
      *(half8*)&Ahs[a] = h; *(half8*)&Als[a] = l;
    }
  }
  const int w = tid>>6, lane = tid&63, lr = lane&15, lg = lane>>4;
  const int bc = tid>>2, bfg = tid&3, bf = bfg<<3;
  const int bwr = (bfg<<9) + ((bc ^ (bfg<<2))<<3);
  const int ncc = (c2_32 + 63) >> 6;
  _Float16* T0h = Th + ((size_t)g<<14);
  _Float16* T0l = Tl + ((size_t)g<<14);
  _Float16* T1h = Th + ((size_t)(B + g)<<14);
  _Float16* T1l = Tl + ((size_t)(B + g)<<14);
  for (int cc=0; cc<ncc; ++cc){
    const int cbase = cc<<6;
    const int colr = cbase + bc;
    const bool bval = colr < c2;
    const float* bsrc = vf + (size_t)(gO + colr)*1024 + bf;
    {
      float4 v0, v1;
      if (bval){ v0 = *(const float4*)(bsrc); v1 = *(const float4*)(bsrc + 4); }
      else { v0.x=0.f; v0.y=0.f; v0.z=0.f; v0.w=0.f; v1 = v0; }
      half8 h,l; split8(v0,v1,h,l);
      *(half8*)&Bhs[0][bwr] = h; *(half8*)&Bls[0][bwr] = l;
    }
    __syncthreads();
    f32x4 acc = {0.f,0.f,0.f,0.f};
    const int col_l = (w<<4) + lr;
    const int ba = (lg<<9) + ((col_l ^ (lg<<2))<<3);
    for (int kc=0; kc<16; ++kc){
      float4 p0, p1;
      if (kc+1<16){
        if (bval){
          const float* s = bsrc + ((kc+1)<<5);
          p0 = *(const float4*)s; p1 = *(const float4*)(s + 4);
        } else { p0.x=0.f; p0.y=0.f; p0.z=0.f; p0.w=0.f; p1 = p0; }
      }
      const int aa = ((kc<<2)+lg)*136 + (lr<<3);
      half8 ah = *(const half8*)&Ahs[aa];
      half8 al = *(const half8*)&Als[aa];
      half8 bh = *(const half8*)&Bhs[kc&1][ba];
      half8 bl = *(const half8*)&Bls[kc&1][ba];
      acc = MF(ah,bh,acc);
      acc = MF(al,bh,acc);
      acc = MF(ah,bl,acc);
      if (kc+1<16){
        half8 h,l; split8(p0,p1,h,l);
        *(half8*)&Bhs[(kc+1)&1][bwr] = h; *(half8*)&Bls[(kc+1)&1][bwr] = l;
      }
      __syncthreads();
    }
    const int col = cbase + col_l;
    if (col < c2_32){
      half4_t t1h, t1l;
      #pragma unroll
      for (int qq=0;qq<4;++qq){
        int r = (rt<<4) + (lg<<2) + qq;
        float t = (r < c1 && col < c2) ? ftanh(acc[qq]) : 0.f;
        _Float16 hh = (_Float16)t;
        _Float16 ll = (_Float16)(t - (float)hh);
        T0h[(r<<7) + col] = hh;
        T0l[(r<<7) + col] = ll;
        t1h[qq] = hh; t1l[qq] = ll;
      }
      const int r0 = (rt<<4) + (lg<<2);
      *(half4_t*)&T1h[(col<<7) + r0] = t1h;
      *(half4_t*)&T1l[(col<<7) + r0] = t1l;
    }
  }
}

// ------- k_apply: own'[r][f] = sum_o T[r][o]*oth[o][f] via MFMA.
__global__ __launch_bounds__(256)
void k_apply(const _Float16* __restrict__ Th, const _Float16* __restrict__ Tl,
             const _Float16* __restrict__ p1h, const _Float16* __restrict__ p1l,
             const _Float16* __restrict__ p2h, const _Float16* __restrict__ p2l,
             const int* __restrict__ go1, const int* __restrict__ go2,
             const int* __restrict__ pb1, const int* __restrict__ pb2,
             float* __restrict__ sf, float* __restrict__ vf, int B)
{
  const int side = blockIdx.x, g = blockIdx.y, ft = blockIdx.z;
  const int* goR = side ? go2 : go1;
  const int* goO = side ? go1 : go2;
  const int* pbO = side ? pb1 : pb2;
  const _Float16* oph = side ? p1h : p2h;
  const _Float16* opl = side ? p1l : p2l;
  float* outp = side ? vf : sf;
  int gR = goR[g]; int cR = goR[g+1]-gR; if (cR>128) cR=128;
  int gO = goO[g]; int cO = goO[g+1]-gO; if (cO>128) cO=128;
  if (cR <= 0) return;
  const int pO = pbO[g];
  const int cO32 = (cO+31)&~31;
  const int MR = ((cR+15)&~15)>>4;
  const _Float16* Tph = Th + ((size_t)(side*B + g)<<14);
  const _Float16* Tpl = Tl + ((size_t)(side*B + g)<<14);
  const int tid = threadIdx.x, w = tid>>6, lane = tid&63;
  const int lr = lane&15, lg = lane>>4;
  const int f0 = (ft<<8) + (w<<6);
  for (int rc = 0; rc < MR; rc += 4){
    f32x4 acc[4][4];
    #pragma unroll
    for (int a_=0;a_<4;++a_)
      #pragma unroll
      for (int b_=0;b_<4;++b_) acc[a_][b_] = (f32x4){0.f,0.f,0.f,0.f};
    for (int k0=0; k0<cO32; k0+=32){
      half8 bh[4], bl[4];
      #pragma unroll
      for (int nj=0;nj<4;++nj){
        size_t a = ((size_t)((pO + k0)>>3) + lg)*4096 + (size_t)(f0 + (nj<<4) + lr)*8;
        bh[nj] = *(const half8*)(oph + a);
        bl[nj] = *(const half8*)(opl + a);
      }
      #pragma unroll
      for (int mi=0;mi<4;++mi){
        if (rc + mi < MR){
          int a = ((((rc+mi)<<4) + lr)<<7) + k0 + (lg<<3);
          half8 th_ = *(const half8*)&Tph[a];
          half8 tl_ = *(const half8*)&Tpl[a];
          #pragma unroll
          for (int nj=0;nj<4;++nj){
            acc[mi][nj] = MF(th_, bh[nj], acc[mi][nj]);
            acc[mi][nj] = MF(tl_, bh[nj], acc[mi][nj]);
            acc[mi][nj] = MF(th_, bl[nj], acc[mi][nj]);
          }
        }
      }
    }
    #pragma unroll
    for (int mi=0;mi<4;++mi){
      if (rc + mi < MR){
        #pragma unroll
        for (int nj=0;nj<4;++nj){
          #pragma unroll
          for (int qq=0;qq<4;++qq){
            int r = (((rc+mi)<<4)) + (lg<<2) + qq;
            if (r < cR)
              outp[(size_t)(gR + r)*1024 + 512 + f0 + (nj<<4) + lr] = acc[mi][nj][qq];
          }
        }
      }
    }
  }
}

// ------- k_gemmsk: fp32 skinny NT GEMM (kept for fc2 only).
__global__ __launch_bounds__(256)
void k_gemmsk(const float* __restrict__ Ab, size_t AsideOff, int lda,
              const float* __restrict__ Bm, int ldb,
              float* __restrict__ P, int M, int N, int kchunk)
{
  __shared__ float As[2][16][132];
  __shared__ float Bs[2][16][68];
  const int tid = threadIdx.x;
  const int col0 = (int)blockIdx.x << 6;
  const int kbeg = (int)blockIdx.z * kchunk;
  const float* A = Ab + (size_t)blockIdx.y * AsideOff;
  const int ar = tid >> 1, ak = (tid & 1) << 3;
  const int br = tid >> 2, bk = (tid & 3) << 2;
  const int tx = tid & 15, ty = tid >> 4;
  const float* Arow = A + (size_t)ar * lda + kbeg + ak;
  const float* Brow = Bm + (size_t)(col0 + br) * ldb + kbeg + bk;
  float acc[8][4] = {};
  float4 a0 = *(const float4*)(Arow);
  float4 a1 = *(const float4*)(Arow + 4);
  float4 b0 = *(const float4*)(Brow);
  As[0][ak+0][ar]=a0.x; As[0][ak+1][ar]=a0.y; As[0][ak+2][ar]=a0.z; As[0][ak+3][ar]=a0.w;
  As[0][ak+4][ar]=a1.x; As[0][ak+5][ar]=a1.y; As[0][ak+6][ar]=a1.z; As[0][ak+7][ar]=a1.w;
  Bs[0][bk+0][br]=b0.x; Bs[0][bk+1][br]=b0.y; Bs[0][bk+2][br]=b0.z; Bs[0][bk+3][br]=b0.w;
  __syncthreads();
  const int nt = kchunk >> 4;
  for (int t = 0; t < nt; ++t){
    const int cb = t & 1;
    if (t + 1 < nt){
      int k0 = (t + 1) << 4;
      a0 = *(const float4*)(Arow + k0);
      a1 = *(const float4*)(Arow + k0 + 4);
      b0 = *(const float4*)(Brow + k0);
    }
    #pragma unroll
    for (int kk = 0; kk < 16; ++kk){
      float4 b4 = *(const float4*)&Bs[cb][kk][tx << 2];
      float4 a4 = *(const float4*)&As[cb][kk][ty << 3];
      float4 a5 = *(const float4*)&As[cb][kk][(ty << 3) + 4];
      acc[0][0]+=a4.x*b4.x; acc[0][1]+=a4.x*b4.y; acc[0][2]+=a4.x*b4.z; acc[0][3]+=a4.x*b4.w;
      acc[1][0]+=a4.y*b4.x; acc[1][1]+=a4.y*b4.y; acc[1][2]+=a4.y*b4.z; acc[1][3]+=a4.y*b4.w;
      acc[2][0]+=a4.z*b4.x; acc[2][1]+=a4.z*b4.y; acc[2][2]+=a4.z*b4.z; acc[2][3]+=a4.z*b4.w;
      acc[3][0]+=a4.w*b4.x; acc[3][1]+=a4.w*b4.y; acc[3][2]+=a4.w*b4.z; acc[3][3]+=a4.w*b4.w;
      acc[4][0]+=a5.x*b4.x; acc[4][1]+=a5.x*b4.y; acc[4][2]+=a5.x*b4.z; acc[4][3]+=a5.x*b4.w;
      acc[5][0]+=a5.y*b4.x; acc[5][1]+=a5.y*b4.y; acc[5][2]+=a5.y*b4.z; acc[5][3]+=a5.y*b4.w;
      acc[6][0]+=a5.z*b4.x; acc[6][1]+=a5.z*b4.y; acc[6][2]+=a5.z*b4.z; acc[6][3]+=a5.z*b4.w;
      acc[7][0]+=a5.w*b4.x; acc[7][1]+=a5.w*b4.y; acc[7][2]+=a5.w*b4.z; acc[7][3]+=a5.w*b4.w;
    }
    if (t + 1 < nt){
      const int nb = cb ^ 1;
      As[nb][ak+0][ar]=a0.x; As[nb][ak+1][ar]=a0.y; As[nb][ak+2][ar]=a0.z; As[nb][ak+3][ar]=a0.w;
      As[nb][ak+4][ar]=a1.x; As[nb][ak+5][ar]=a1.y; As[nb][ak+6][ar]=a1.z; As[nb][ak+7][ar]=a1.w;
      Bs[nb][bk+0][br]=b0.x; Bs[nb][bk+1][br]=b0.y; Bs[nb][bk+2][br]=b0.z; Bs[nb][bk+3][br]=b0.w;
    }
    __syncthreads();
  }
  float* Pz = P + (size_t)(blockIdx.y*gridDim.z + blockIdx.z) * M * N;
  #pragma unroll
  for (int i = 0; i < 8; ++i){
    int rr = (ty << 3) + i;
    float4 v = {acc[i][0], acc[i][1], acc[i][2], acc[i][3]};
    *(float4*)(Pz + (size_t)rr*N + col0 + (tx<<2)) = v;
  }
}

// ------- k_gemmsk_h: split-f16 MFMA skinny GEMM (A fp32 staged, B packed planes).
__global__ __launch_bounds__(256)
void k_gemmsk_h(const float* __restrict__ Ab, size_t AsideOff, int lda,
                const _Float16* __restrict__ Bhp, const _Float16* __restrict__ Blp,
                float* __restrict__ P, int N, int kchunk)
{
  __shared__ __align__(16) _Float16 Ahs[2][4096];   // [kb(4)][m(128)][8]
  __shared__ __align__(16) _Float16 Als[2][4096];
  const int tid = threadIdx.x;
  const int col0 = (int)blockIdx.x << 7;
  const int kbeg = (int)blockIdx.z * kchunk;
  const float* A = Ab + (size_t)blockIdx.y * AsideOff;
  const int ar = tid >> 1, aq = (tid & 1) << 4;     // row, k-offset {0,16}
  const int wid = tid>>6, lane = tid&63;
  const int wr = wid>>1, wc = wid&1;
  const int lr = lane&15, lg = lane>>4;
  const float* Arow = A + (size_t)ar*lda + kbeg + aq;
  const int akb = aq>>3;                            // 0 or 2
  f32x4 acc[4][4] = {};
  const int nc = kchunk >> 5;
  float4 g0,g1,g2,g3;
  g0 = *(const float4*)(Arow);     g1 = *(const float4*)(Arow+4);
  g2 = *(const float4*)(Arow+8);   g3 = *(const float4*)(Arow+12);
  {
    half8 h,l;
    split8(g0,g1,h,l);
    *(half8*)&Ahs[0][(akb*128+ar)*8] = h;     *(half8*)&Als[0][(akb*128+ar)*8] = l;
    split8(g2,g3,h,l);
    *(half8*)&Ahs[0][((akb+1)*128+ar)*8] = h; *(half8*)&Als[0][((akb+1)*128+ar)*8] = l;
  }
  __syncthreads();
  for (int c=0;c<nc;++c){
    const int cb = c&1;
    if (c+1<nc){
      const float* p = Arow + ((c+1)<<5);
      g0 = *(const float4*)(p);    g1 = *(const float4*)(p+4);
      g2 = *(const float4*)(p+8);  g3 = *(const float4*)(p+12);
    }
    const size_t kb0 = (size_t)((kbeg + (c<<5)) >> 3) + lg;
    half8 bh[4], bl[4];
    #pragma unroll
    for (int ni=0;ni<4;++ni){
      size_t a = (kb0*N + col0 + (wc<<6) + (ni<<4) + lr)*8;
      bh[ni] = *(const half8*)(Bhp + a);
      bl[ni] = *(const half8*)(Blp + a);
    }
    #pragma unroll
    for (int mi=0;mi<4;++mi){
      int aa = ((lg<<7) + (wr<<6) + (mi<<4) + lr)<<3;
      half8 ah = *(const half8*)&Ahs[cb][aa];
      half8 al = *(const half8*)&Als[cb][aa];
      #pragma unroll
      for (int ni=0;ni<4;++ni){
        acc[mi][ni] = MF(ah,bh[ni],acc[mi][ni]);
        acc[mi][ni] = MF(al,bh[ni],acc[mi][ni]);
        acc[mi][ni] = MF(ah,bl[ni],acc[mi][ni]);
      }
    }
    if (c+1<nc){
      const int nb = cb^1;
      half8 h,l;
      split8(g0,g1,h,l);
      *(half8*)&Ahs[nb][(akb*128+ar)*8] = h;     *(half8*)&Als[nb][(akb*128+ar)*8] = l;
      split8(g2,g3,h,l);
      *(half8*)&Ahs[nb][((akb+1)*128+ar)*8] = h; *(half8*)&Als[nb][((akb+1)*128+ar)*8] = l;
    }
    __syncthreads();
  }
  float* Pz = P + (size_t)(blockIdx.y*gridDim.z + blockIdx.z)*128*N;
  #pragma unroll
  for (int mi=0;mi<4;++mi){
    #pragma unroll
    for (int ni=0;ni<4;++ni){
      int cc2 = col0 + (wc<<6) + (ni<<4) + lr;
      #pragma unroll
      for (int j=0;j<4;++j){
        int rr2 = (wr<<6) + (mi<<4) + (lg<<2) + j;
        Pz[(size_t)rr2*N + cc2] = acc[mi][ni][j];
      }
    }
  }
}

// sum split partials + bias (+relu)
__global__ void k_red_bias(const float* __restrict__ P, int split, int MN, int N,
                           const float* __restrict__ bias, float* __restrict__ C, int relu){
  int i = blockIdx.x*256 + threadIdx.x;
  if (i >= MN) return;
  float v = bias[i & (N-1)];
  for (int s=0;s<split;++s) v += P[(size_t)s*MN + i];
  if (relu) v = fmaxf(v, 0.f);
  C[i] = v;
}

// ---------------- Set2Set ----------------
// gemv for u = Wih[:,:1024] h1 + Whh h1 + biases. h1 computed IN-KERNEL from biases
// (LSTM iter1 with zero q_star/h/c); block 0 also writes h1 to global for k_attn.
__global__ void k_gemv_u(const float* __restrict__ Wih, const float* __restrict__ Whh,
                         const float* __restrict__ bih, const float* __restrict__ bhh,
                         float* __restrict__ h1, float* __restrict__ u){
  __shared__ float hsv[1024];
  int t = threadIdx.x;
  #pragma unroll
  for (int j=t; j<1024; j+=256){
    float gi = bih[j]        + bhh[j];
    float gg = bih[j+2048]   + bhh[j+2048];
    float go = bih[j+3072]   + bhh[j+3072];
    float cc = fsigm(gi)*ftanh(gg);
    float hv = fsigm(go)*ftanh(cc);
    hsv[j] = hv;
    if (blockIdx.x==0) h1[j] = hv;
  }
  __syncthreads();
  int w = (blockIdx.x*256 + t)>>6;
  int lane = t & 63;
  if (w >= 4096) return;
  const float* wi = Wih + (size_t)w*2048;
  const float* wh = Whh + (size_t)w*1024;
  float acc = 0.f;
  #pragma unroll
  for (int qq=0;qq<4;++qq){
    int o = qq*256 + (lane<<2);
    float4 hv = *(const float4*)&hsv[o];
    float4 a  = *(const float4*)(wi + o);
    float4 b  = *(const float4*)(wh + o);
    acc += hv.x*(a.x+b.x) + hv.y*(a.y+b.y) + hv.z*(a.z+b.z) + hv.w*(a.w+b.w);
  }
  acc = wredsum(acc);
  if (lane==0) u[w] = acc + bih[w] + bhh[w];
}

// fused attention, dual-side (blockIdx.y): SINGLE-PASS online segment softmax.
// Each wave owns every-4th node; lane l holds cols {l*4 + qq*256} of the running
// weighted sum (the same cols it loads for the dot product -> zero re-read).
// Cross-wave merge via LDS at the end.
__global__ __launch_bounds__(256)
void k_attn(const float* __restrict__ sf, const float* __restrict__ vf,
            const int* __restrict__ go1, const int* __restrict__ go2,
            const float* __restrict__ hbase, size_t hSideOff, int hstride,
            float* __restrict__ outbase, size_t oSideOff, int ldout)
{
  __shared__ float hs[1024];
  __shared__ float part[4][1024];
  __shared__ float redm[4], reds[4];
  int side = blockIdx.y;
  const float* x = side? vf : sf;
  const int* goff = side? go2 : go1;
  const float* hsrc = hbase + (size_t)side*hSideOff;
  float* outp = outbase + (size_t)side*oSideOff;
  int b = blockIdx.x, t = threadIdx.x;
  int i0 = goff[b], i1 = goff[b+1];
  int lane = t & 63, wv = t >> 6;
  { float4 hv = *(const float4*)(hsrc + (size_t)b*hstride + (t<<2));
    *(float4*)&hs[t<<2] = hv; }
  __syncthreads();
  float m = -3.0e38f, s = 0.f;
  float4 acc[4];
  #pragma unroll
  for (int qq=0;qq<4;++qq){ acc[qq].x=0.f; acc[qq].y=0.f; acc[qq].z=0.f; acc[qq].w=0.f; }
  for (int i = i0 + wv; i < i1; i += 4){
    const float* xr = x + (size_t)i*1024;
    float4 xv[4];
    float d = 0.f;
    #pragma unroll
    for (int qq=0;qq<4;++qq){
      int o = qq*256 + (lane<<2);
      xv[qq] = *(const float4*)(xr+o);
      float4 h4 = *(const float4*)&hs[o];
      d += xv[qq].x*h4.x + xv[qq].y*h4.y + xv[qq].z*h4.z + xv[qq].w*h4.w;
    }
    d = wredsum(d);
    if (d > m){
      float sc = __expf(m - d);
      s = s*sc + 1.f;
      #pragma unroll
      for (int qq=0;qq<4;++qq){
        acc[qq].x = acc[qq].x*sc + xv[qq].x;
        acc[qq].y = acc[qq].y*sc + xv[qq].y;
        acc[qq].z = acc[qq].z*sc + xv[qq].z;
        acc[qq].w = acc[qq].w*sc + xv[qq].w;
      }
      m = d;
    } else {
      float ww = __expf(d - m);
      s += ww;
      #pragma unroll
      for (int qq=0;qq<4;++qq){
        acc[qq].x += ww*xv[qq].x;
        acc[qq].y += ww*xv[qq].y;
        acc[qq].z += ww*xv[qq].z;
        acc[qq].w += ww*xv[qq].w;
      }
    }
  }
  if (lane==0){ redm[wv]=m; reds[wv]=s; }
  __syncthreads();
  float gm = fmaxf(fmaxf(redm[0],redm[1]), fmaxf(redm[2],redm[3]));
  float gs = reds[0]*__expf(redm[0]-gm) + reds[1]*__expf(redm[1]-gm)
           + reds[2]*__expf(redm[2]-gm) + reds[3]*__expf(redm[3]-gm);
  float wsc = __expf(m - gm);
  #pragma unroll
  for (int qq=0;qq<4;++qq){
    float4 v = acc[qq];
    v.x*=wsc; v.y*=wsc; v.z*=wsc; v.w*=wsc;
    *(float4*)&part[wv][qq*256 + (lane<<2)] = v;
  }
  __syncthreads();
  float inv = (i1>i0 && gs>0.f) ? 1.f/gs : 0.f;
  int col = t<<2;
  float4 p0 = *(float4*)&part[0][col];
  float4 p1 = *(float4*)&part[1][col];
  float4 p2 = *(float4*)&part[2][col];
  float4 p3 = *(float4*)&part[3][col];
  float4 o;
  o.x = (p0.x+p1.x+p2.x+p3.x)*inv;
  o.y = (p0.y+p1.y+p2.y+p3.y)*inv;
  o.z = (p0.z+p1.z+p2.z+p3.z)*inv;
  o.w = (p0.w+p1.w+p2.w+p3.w)*inv;
  *(float4*)(outp + (size_t)b*ldout + col) = o;
}

// LSTM iter2 (dual-side via blockIdx.y): sum split gate partials + u; c1 recomputed
// inline from biases (iter1 cell with zero inputs).
__global__ void k_lstm2_red(const float* __restrict__ Pb, size_t PsideOff, int split,
                            const float* __restrict__ u,
                            const float* __restrict__ bih, const float* __restrict__ bhh,
                            float* __restrict__ z, int B){
  int idx = blockIdx.x*256 + threadIdx.x;
  if (idx >= B*1024) return;
  int side = blockIdx.y;
  const float* P = Pb + (size_t)side*PsideOff;
  int b = idx >> 10, j = idx & 1023;
  float gi=u[j], gf=u[j+1024], gg=u[j+2048], go=u[j+3072];
  const float* g = P + (size_t)b*4096;
  for (int s=0;s<split;++s){
    const float* gs = g + (size_t)s*B*4096;
    gi += gs[j]; gf += gs[j+1024]; gg += gs[j+2048]; go += gs[j+3072];
  }
  float b_i = bih[j] + bhh[j];
  float b_g = bih[j+2048] + bhh[j+2048];
  float c1v = fsigm(b_i)*ftanh(b_g);
  float cc = fsigm(gf)*c1v + fsigm(gi)*ftanh(gg);
  z[(size_t)b*4096 + side*2048 + j] = fsigm(go)*ftanh(cc);
}

__global__ void k_fc3(const float* __restrict__ z2, const float* __restrict__ w3,
                      const float* __restrict__ b3, float* __restrict__ out, int B){
  int wv = (blockIdx.x*256+threadIdx.x)>>6;
  int lane = threadIdx.x & 63;
  if (wv >= B) return;
  const float* zr = z2 + (size_t)wv*512;
  float acc=0.f;
  #pragma unroll
  for (int qq=0;qq<2;++qq){
    int o = qq*256 + (lane<<2);
    float4 a  = *(const float4*)(zr + o);
    float4 ww = *(const float4*)(w3 + o);
    acc += a.x*ww.x + a.y*ww.y + a.z*ww.z + a.w*ww.w;
  }
  acc = wredsum(acc);
  if (lane==0) out[wv] = acc + b3[0];
}

// ---------------- driver ----------------
extern "C" void kernel_launch(void* const* d_in, const int* in_sizes, int n_in,
                              void* d_out, int out_size, void* d_ws, size_t ws_size,
                              hipStream_t stream)
{
  const float* x1  = (const float*)d_in[0];
  const float* x2  = (const float*)d_in[1];
  const int* src1  = (const int*)d_in[2];
  const int* dst1  = (const int*)d_in[3];
  const int* src2  = (const int*)d_in[4];
  const int* dst2  = (const int*)d_in[5];
  const int* gid1  = (const int*)d_in[6];
  const int* gid2  = (const int*)d_in[7];
  const float* Wg1 = (const float*)d_in[8];  const float* bg1 = (const float*)d_in[9];
  const float* Wg2 = (const float*)d_in[10]; const float* bg2 = (const float*)d_in[11];
  const float* Wg3 = (const float*)d_in[12]; const float* bg3 = (const float*)d_in[13];
  const float* Wg4 = (const float*)d_in[14]; const float* bg4 = (const float*)d_in[15];
  const float* Wih = (const float*)d_in[16]; const float* Whh = (const float*)d_in[17];
  const float* bih = (const float*)d_in[18]; const float* bhh = (const float*)d_in[19];
  const float* Wf1 = (const float*)d_in[20]; const float* bf1 = (const float*)d_in[21];
  const float* Wf2 = (const float*)d_in[22]; const float* bf2 = (const float*)d_in[23];
  const float* Wf3 = (const float*)d_in[24]; const float* bf3 = (const float*)d_in[25];
  float* out = (float*)d_out;

  const int N1 = in_sizes[0]/128;
  const int N2 = in_sizes[1]/128;
  const int E1 = in_sizes[2];
  const int E2 = in_sizes[4];
  const int B  = out_size;            // 128
  const int NM = N1>N2?N1:N2;

  char* base = (char*)d_ws; size_t off=0;
  auto alloc = [&](size_t bytes)->void*{ void* p = base+off; off += (bytes+255)&~(size_t)255; return p; };

  int* zr   = (int*)alloc(sizeof(int)*(size_t)(3*N1+3*N2));
  int* co1=zr, *ci1=zr+N1, *cur1=zr+2*N1;
  int* co2=zr+3*N1, *ci2=zr+3*N1+N2, *cur2=zr+3*N1+2*N2;
  int* row1 = (int*)alloc(sizeof(int)*(size_t)(N1+1));
  int* row2 = (int*)alloc(sizeof(int)*(size_t)(N2+1));
  int* csr1 = (int*)alloc(sizeof(int)*(size_t)E1);
  int* csr2 = (int*)alloc(sizeof(int)*(size_t)E2);
  int* go1  = (int*)alloc(sizeof(int)*(size_t)(B+1));
  int* go2  = (int*)alloc(sizeof(int)*(size_t)(B+1));
  int* pb1  = (int*)alloc(sizeof(int)*(size_t)(B+1));
  int* pb2  = (int*)alloc(sizeof(int)*(size_t)(B+1));
  int* gm1  = (int*)alloc(sizeof(int)*1024);
  int* gm2  = (int*)alloc(sizeof(int)*1024);
  float* os1 = (float*)alloc(sizeof(float)*(size_t)N1);
  float* is1 = (float*)alloc(sizeof(float)*(size_t)N1);
  float* os2 = (float*)alloc(sizeof(float)*(size_t)N2);
  float* is2 = (float*)alloc(sizeof(float)*(size_t)N2);
  _Float16* a1h = (_Float16*)alloc(sizeof(_Float16)*(size_t)(NM+128)*256);
  _Float16* a1l = (_Float16*)alloc(sizeof(_Float16)*(size_t)(NM+128)*256);
  _Float16* a2h = (_Float16*)alloc(sizeof(_Float16)*(size_t)(NM+128)*256);
  _Float16* a2l = (_Float16*)alloc(sizeof(_Float16)*(size_t)(NM+128)*256);
  _Float16* wg1h = (_Float16*)alloc(sizeof(_Float16)*32768);
  _Float16* wg1l = (_Float16*)alloc(sizeof(_Float16)*32768);
  _Float16* wg2h = (_Float16*)alloc(sizeof(_Float16)*131072);
  _Float16* wg2l = (_Float16*)alloc(sizeof(_Float16)*131072);
  _Float16* wg3h = (_Float16*)alloc(sizeof(_Float16)*32768);
  _Float16* wg3l = (_Float16*)alloc(sizeof(_Float16)*32768);
  _Float16* wg4h = (_Float16*)alloc(sizeof(_Float16)*131072);
  _Float16* wg4l = (_Float16*)alloc(sizeof(_Float16)*131072);
  // Set2Set gates + fc1 weight planes (split-f16, k8-packed)
  _Float16* wihh = (_Float16*)alloc(sizeof(_Float16)*(size_t)4096*1024);
  _Float16* wihl = (_Float16*)alloc(sizeof(_Float16)*(size_t)4096*1024);
  _Float16* wf1h = (_Float16*)alloc(sizeof(_Float16)*(size_t)1024*4096);
  _Float16* wf1l = (_Float16*)alloc(sizeof(_Float16)*(size_t)1024*4096);
  float* sf  = (float*)alloc(sizeof(float)*(size_t)(N1+128)*1024);
  float* vf  = (float*)alloc(sizeof(float)*(size_t)(N2+128)*1024);
  float* h1 = (float*)alloc(sizeof(float)*1024);
  float* u  = (float*)alloc(sizeof(float)*4096);
  float* r1 = (float*)alloc(sizeof(float)*(size_t)2*B*1024);
  float* z1 = (float*)alloc(sizeof(float)*(size_t)B*1024);
  float* z2 = (float*)alloc(sizeof(float)*(size_t)B*512);
  float* z  = (float*)alloc(sizeof(float)*(size_t)B*4096);
  // T planes: [2 sides][B][128][128] split-f16 (16.8 MB total)
  _Float16* Tqh = (_Float16*)alloc(sizeof(_Float16)*(size_t)2*B*16384);
  _Float16* Tql = (_Float16*)alloc(sizeof(_Float16)*(size_t)2*B*16384);
  // union region: node-packed split-f16 planes (interact stage) / Pbuf partials (later stages)
  const int PN = ((NM + 32*B + 63)&~63) + 64;      // padded node capacity
  const size_t PE = (size_t)PN*512;                // elems per plane
  size_t packedBytes = 4*PE*sizeof(_Float16);
  size_t pbufBytes   = sizeof(float)*(size_t)32*B*1024*4;
  char* uni = (char*)alloc(packedBytes > pbufBytes ? packedBytes : pbufBytes);
  _Float16* p1h = (_Float16*)uni;
  _Float16* p1l = p1h + PE;
  _Float16* p2h = p1l + PE;
  _Float16* p2l = p2h + PE;
  float* Pbuf = (float*)uni;
  if (off > ws_size) return;

  // hbuf regions live inside sf/vf cols [512,768) (stride 1024), overwritten later by apply
  float* hb1 = sf + 512;
  float* hb2 = vf + 512;

  dim3 blk(256);

  // --- weight split-f16 packs (independent of graph prep) ---
  k_wpack4<<<dim3(512,4),blk,0,stream>>>(Wg1,Wg2,Wg3,Wg4,
                                         wg1h,wg1l, wg2h,wg2l, wg3h,wg3l, wg4h,wg4l);
  k_wpackT<<<dim3(4,128),blk,0,stream>>>(Wih+1024, 2048, 4096, wihh, wihl);  // gates W
  k_wpackT<<<dim3(16,32),blk,0,stream>>>(Wf1, 4096, 1024, wf1h, wf1l);       // fc1 W

  // --- prep ---
  k_zero_i32<<<(3*N1+3*N2+255)/256, blk, 0, stream>>>(zr, 3*N1+3*N2);
  k_hist2<<<(E1+E2+255)/256, blk, 0, stream>>>(src1,dst1,E1,co1,ci1, src2,dst2,E2,co2,ci2);
  k_scan2<<<2,1024,0,stream>>>(ci1,N1,row1, ci2,N2,row2);
  k_scale2<<<(N1+N2+255)/256,blk,0,stream>>>(co1,ci1,N1,os1,is1, co2,ci2,N2,os2,is2);
  k_scatter2<<<(E1+E2+255)/256,blk,0,stream>>>(src1,dst1,E1,row1,cur1,csr1, src2,dst2,E2,row2,cur2,csr2);
  k_goff2<<<1,512,0,stream>>>(gid1,N1,go1, gid2,N2,go2, B, pb1,gm1, pb2,gm2);

  // --- GraphConv: agg both sides (split-f16 out), dual MFMA GEMM L1 (post=os),
  //     agg (no scale), dual MFMA GEMM L2 ---
  int gy = (NM+127)/128;
  k_agg_h<<<(N1+7)/8,blk,0,stream>>>(x1,128, os1,row1,csr1, a1h,a1l, N1,5);
  k_agg_h<<<(N2+7)/8,blk,0,stream>>>(x2,128, os2,row2,csr2, a2h,a2l, N2,5);
  k_gconv_mfma<<<dim3(2,gy,2),blk,0,stream>>>(a1h,a1l, a2h,a2l,
                                              wg1h,wg1l, wg3h,wg3l,
                                              hb1,hb2,1024, N1,N2, 256,128,
                                              is1,is2, bg1,bg3, 1, os1,os2);
  k_agg_h<<<(N1+3)/4,blk,0,stream>>>(hb1,1024, nullptr,row1,csr1, a1h,a1l, N1,6);
  k_agg_h<<<(N2+3)/4,blk,0,stream>>>(hb2,1024, nullptr,row2,csr2, a2h,a2l, N2,6);
  k_gconv_mfma<<<dim3(4,gy,2),blk,0,stream>>>(a1h,a1l, a2h,a2l,
                                              wg2h,wg2l, wg4h,wg4l,
                                              sf,vf,1024, N1,N2, 512,256,
                                              is1,is2, bg2,bg4, 0, nullptr,nullptr);

  // --- block-diagonal interaction (MFMA; T computed once, transposed write) ---
  const int GMAX = NM/32 + B + 2;
  k_pack<<<dim3(GMAX,2),blk,0,stream>>>(sf,vf, go1,go2, pb1,pb2, gm1,gm2,
                                        p1h,p1l, p2h,p2l, B);
  k_T<<<dim3(B,8),blk,0,stream>>>(sf,vf, go1,go2, Tqh,Tql, B);
  k_apply<<<dim3(2,B,2),blk,0,stream>>>(Tqh,Tql, p1h,p1l, p2h,p2l,
                                        go1,go2, pb1,pb2, sf,vf, B);

  // --- Set2Set (sides merged per stage; h1/c1 derived from biases in-kernel) ---
  k_gemv_u<<<1024,blk,0,stream>>>(Wih,Whh,bih,bhh,h1,u);

  // iter1 attention (shared h1), both sides — single-pass online softmax
  k_attn<<<dim3(B,2),blk,0,stream>>>(sf,vf,go1,go2, h1,0,0, r1,(size_t)B*1024,1024);
  // gates = r1 @ Wih[:,1024:].T via split-f16 MFMA, split-K 4 x chunk 256
  k_gemmsk_h<<<dim3(32,2,4),blk,0,stream>>>(r1,(size_t)B*1024,1024, wihh,wihl, Pbuf, 4096,256);
  k_lstm2_red<<<dim3((B*1024+255)/256,2),blk,0,stream>>>(Pbuf,(size_t)4*B*4096,4, u, bih,bhh, z,B);
  // iter2 attention with per-graph h2 (in z), both sides
  k_attn<<<dim3(B,2),blk,0,stream>>>(sf,vf,go1,go2, z,2048,4096, z+1024,2048,4096);

  // --- MLP head ---
  k_gemmsk_h<<<dim3(8,1,32),blk,0,stream>>>(z,0,4096, wf1h,wf1l, Pbuf, 1024,128);
  k_red_bias<<<(B*1024+255)/256,blk,0,stream>>>(Pbuf,32,B*1024,1024,bf1,z1,1);
  k_gemmsk<<<dim3(8,1,8),blk,0,stream>>>(z1,0,1024, Wf2,1024, Pbuf, 128,512,128);
  k_red_bias<<<(B*512+255)/256,blk,0,stream>>>(Pbuf,8,B*512,512,bf2,z2,1);
  k_fc3<<<(B*64+255)/256,blk,0,stream>>>(z2,Wf3,bf3,out,B);
}

// Round 9
// 353.135 us; speedup vs baseline: 1.3288x; 1.0463x over previous
//
#include <hip/hip_runtime.h>

#define DEV __device__ __forceinline__

typedef _Float16 half8 __attribute__((ext_vector_type(8)));
typedef _Float16 half4_t __attribute__((ext_vector_type(4)));
typedef float f32x4 __attribute__((ext_vector_type(4)));

DEV float ftanh(float x){
  float ax = fabsf(x);
  float e = __expf(-2.f*ax);
  float t = (1.f - e)/(1.f + e);
  return x < 0.f ? -t : t;
}
DEV float fsigm(float x){ return 1.f/(1.f + expf(-x)); }
DEV float wredsum(float v){
  #pragma unroll
  for (int o=32;o;o>>=1) v += __shfl_xor(v,o,64);
  return v;
}
DEV f32x4 MF(half8 a, half8 b, f32x4 c){
  return __builtin_amdgcn_mfma_f32_16x16x32_f16(a,b,c,0,0,0);
}
DEV void split8(float4 a0, float4 a1, half8& h, half8& l){
  float f[8] = {a0.x,a0.y,a0.z,a0.w,a1.x,a1.y,a1.z,a1.w};
  #pragma unroll
  for (int e=0;e<8;++e){
    _Float16 hh = (_Float16)f[e];
    h[e] = hh;
    l[e] = (_Float16)(f[e] - (float)hh);
  }
}

// ---------------- fused pre-pass: zero counters + all weight packs ----------------
// blockIdx.y: 0..3 = wpack4 tasks, 4 = zero counters, 5 = wpackT gates, 6 = wpackT fc1
__global__ __launch_bounds__(256)
void k_pre(const float* __restrict__ W0, const float* __restrict__ W1,
           const float* __restrict__ W2, const float* __restrict__ W3,
           _Float16* __restrict__ h0, _Float16* __restrict__ l0,
           _Float16* __restrict__ h1, _Float16* __restrict__ l1,
           _Float16* __restrict__ h2, _Float16* __restrict__ l2,
           _Float16* __restrict__ h3, _Float16* __restrict__ l3,
           const float* __restrict__ Wg, _Float16* __restrict__ gh, _Float16* __restrict__ gl,
           const float* __restrict__ Wf, _Float16* __restrict__ fh, _Float16* __restrict__ fl,
           int* __restrict__ zr, int nz)
{
  __shared__ float st[32][260];
  const int y = blockIdx.y, t = threadIdx.x;
  if (y < 4){
    const float* W = (y==0)?W0:(y==1)?W1:(y==2)?W2:W3;
    _Float16* oh = (y==0)?h0:(y==1)?h1:(y==2)?h2:h3;
    _Float16* ol = (y==0)?l0:(y==1)?l1:(y==2)?l2:l3;
    int K   = (y&1)? 256 : 128;
    int nsh = (y&1)? 9 : 8;
    int i = blockIdx.x*256 + t;
    if (i >= (K<<nsh)) return;
    int k = i >> nsh, n = i & ((1<<nsh)-1);
    float v = W[i];
    _Float16 h = (_Float16)v;
    _Float16 l = (_Float16)(v - (float)h);
    size_t p = (((size_t)(k>>3)<<nsh) + n)*8 + (k&7);
    oh[p] = h; ol[p] = l;
    return;
  }
  if (y == 4){
    int i = blockIdx.x*256 + t;
    if (i < nz) zr[i] = 0;
    return;
  }
  // wpackT: tile decomposition over blockIdx.x
  const float* W; _Float16* Bh; _Float16* Bl; int ldw, N, k0, n0;
  if (y == 5){
    int tile = blockIdx.x; if (tile >= 512) return;
    W = Wg; Bh = gh; Bl = gl; ldw = 2048; N = 4096;
    k0 = (tile & 3) << 8; n0 = (tile >> 2) << 5;
  } else {
    int tile = blockIdx.x; if (tile >= 512) return;
    W = Wf; Bh = fh; Bl = fl; ldw = 4096; N = 1024;
    k0 = (tile & 15) << 8; n0 = (tile >> 4) << 5;
  }
  const int r = t >> 3, la = t & 7;
  const float* src = W + (size_t)(n0 + r)*ldw + k0;
  #pragma unroll
  for (int q=0;q<8;++q){
    int f = (la<<2) + (q<<5);
    *(float4*)&st[r][f] = *(const float4*)(src + f);
  }
  __syncthreads();
  const int nl = t & 31;
  #pragma unroll
  for (int j=0;j<4;++j){
    int kbl = (t>>5) + (j<<3);
    half8 h8, l8;
    #pragma unroll
    for (int e=0;e<8;++e){
      float v = st[nl][(kbl<<3)+e];
      _Float16 hh = (_Float16)v;
      h8[e]=hh; l8[e]=(_Float16)(v-(float)hh);
    }
    size_t a = ((size_t)((k0>>3)+kbl)*N + n0 + nl)*8;
    *(half8*)(Bh + a) = h8;
    *(half8*)(Bl + a) = l8;
  }
}

// ---------------- graph prep ----------------
__global__ void k_hist2(const int* __restrict__ s1, const int* __restrict__ d1, int E1,
                        int* __restrict__ co1, int* __restrict__ ci1,
                        const int* __restrict__ s2, const int* __restrict__ d2, int E2,
                        int* __restrict__ co2, int* __restrict__ ci2){
  int e = blockIdx.x*256 + threadIdx.x;
  if (e < E1){ atomicAdd(&co1[s1[e]],1); atomicAdd(&ci1[d1[e]],1); }
  int f = e - E1;
  if (f >= 0 && f < E2){ atomicAdd(&co2[s2[f]],1); atomicAdd(&ci2[d2[f]],1); }
}

// fused: blocks 0,1 = CSR row scans; block 2 = goff+pb+gm; blocks 3+ = degree scales.
__global__ __launch_bounds__(1024)
void k_prep2(const int* __restrict__ ci1, int n1, int* __restrict__ row1,
             const int* __restrict__ ci2, int n2, int* __restrict__ row2,
             const int* __restrict__ co1, float* __restrict__ os1, float* __restrict__ is1,
             const int* __restrict__ co2, float* __restrict__ os2, float* __restrict__ is2,
             const int* __restrict__ g1, int* __restrict__ o1,
             const int* __restrict__ g2, int* __restrict__ o2, int B,
             int* __restrict__ pb1, int* __restrict__ gm1,
             int* __restrict__ pb2, int* __restrict__ gm2)
{
  const int bid = blockIdx.x, t = threadIdx.x;
  if (bid < 2){
    __shared__ int sm[1024];
    const int* cnt = bid ? ci2 : ci1;
    int*       row = bid ? row2 : row1;
    int n          = bid ? n2 : n1;
    int per = n/1024 + 1;
    int st = t*per;
    int s = 0;
    for (int i=st;i<st+per;++i) if (i<n) s += cnt[i];
    sm[t]=s; __syncthreads();
    for (int o=1;o<1024;o<<=1){
      int v = (t>=o)? sm[t-o]:0;
      __syncthreads();
      sm[t] += v;
      __syncthreads();
    }
    int base = sm[t]-s;
    for (int i=st;i<st+per;++i){
      if (i<=n) row[i]=base;
      if (i<n) base += cnt[i];
    }
    return;
  }
  if (bid == 2){
    __shared__ int sc[2][256];
    const bool act = t < 512;
    const int side = (t>>8)&1, q = t & 255;
    if (act && q<=B){
      const int* gid = side ? g2 : g1;
      int n = side ? n2 : n1;
      int lo=0, hi=n;
      while (lo<hi){ int mid=(lo+hi)>>1; if (gid[mid]<q) lo=mid+1; else hi=mid; }
      (side ? o2 : o1)[q]=lo;
    }
    __syncthreads();
    int pc = 0;
    if (act && q < B){
      const int* go = side ? o2 : o1;
      int c = go[q+1]-go[q]; if (c>128) c=128;
      pc = (c+31)&~31;
    }
    if (act) sc[side][q] = pc;
    __syncthreads();
    for (int o=1;o<B;o<<=1){
      int v = (act && q>=o && q<B) ? sc[side][q-o] : 0;
      __syncthreads();
      if (act && q<B) sc[side][q] += v;
      __syncthreads();
    }
    if (act && q < B){
      int incl = sc[side][q];
      int pbv  = incl - pc;
      int* pb = side ? pb2 : pb1;
      int* gm = side ? gm2 : gm1;
      pb[q] = pbv;
      if (q == B-1) pb[B] = incl;
      int nb = pc>>5, b0 = pbv>>5;
      for (int k=0;k<nb;++k) gm[b0+k] = q;
    }
    return;
  }
  int i = (bid-3)*1024 + t;
  if (i<n1){
    int a = co1[i] > 1 ? co1[i] : 1;
    int b = ci1[i] > 1 ? ci1[i] : 1;
    os1[i] = 1.f/sqrtf((float)a);
    is1[i] = 1.f/sqrtf((float)b);
  }
  int j = i - n1;
  if (j>=0 && j<n2){
    int a = co2[j] > 1 ? co2[j] : 1;
    int b = ci2[j] > 1 ? ci2[j] : 1;
    os2[j] = 1.f/sqrtf((float)a);
    is2[j] = 1.f/sqrtf((float)b);
  }
}

__global__ void k_scatter2(const int* __restrict__ s1, const int* __restrict__ d1, int E1,
                           const int* __restrict__ row1, int* __restrict__ cur1, int* __restrict__ csr1,
                           const int* __restrict__ s2, const int* __restrict__ d2, int E2,
                           const int* __restrict__ row2, int* __restrict__ cur2, int* __restrict__ csr2){
  int e = blockIdx.x*256+threadIdx.x;
  if (e<E1){ int d=d1[e]; int p=atomicAdd(&cur1[d],1); csr1[row1[d]+p]=s1[e]; }
  int f = e - E1;
  if (f>=0 && f<E2){ int d=d2[f]; int p=atomicAdd(&cur2[d],1); csr2[row2[d]+p]=s2[f]; }
}

// gather aggregation with split-f16 output planes
__global__ void k_agg_h(const float* __restrict__ x, int ldx, const float* __restrict__ osc,
                        const int* __restrict__ row, const int* __restrict__ csr,
                        _Float16* __restrict__ oh, _Float16* __restrict__ ol, int n, int f4shift){
  int F4 = 1<<f4shift;
  int node = blockIdx.x*(256>>f4shift) + (threadIdx.x>>f4shift);
  if (node>=n) return;
  int fc = threadIdx.x & (F4-1);
  int F = F4<<2;
  int rs=row[node], re=row[node+1];
  float ax=0, ay=0, az=0, aw=0;
  if (osc){
    for (int e=rs;e<re;++e){
      int s = csr[e];
      float sc = osc[s];
      const float4 v = *(const float4*)(x + (size_t)s*ldx + (fc<<2));
      ax += sc*v.x; ay += sc*v.y; az += sc*v.z; aw += sc*v.w;
    }
  } else {
    int e = rs;
    for (; e+1<re; e+=2){
      int s0 = csr[e], s1 = csr[e+1];
      const float4 v0 = *(const float4*)(x + (size_t)s0*ldx + (fc<<2));
      const float4 v1 = *(const float4*)(x + (size_t)s1*ldx + (fc<<2));
      ax += v0.x+v1.x; ay += v0.y+v1.y; az += v0.z+v1.z; aw += v0.w+v1.w;
    }
    if (e<re){
      int s0 = csr[e];
      const float4 v0 = *(const float4*)(x + (size_t)s0*ldx + (fc<<2));
      ax += v0.x; ay += v0.y; az += v0.z; aw += v0.w;
    }
  }
  half4_t hv, lv;
  hv.x = (_Float16)ax; lv.x = (_Float16)(ax - (float)hv.x);
  hv.y = (_Float16)ay; lv.y = (_Float16)(ay - (float)hv.y);
  hv.z = (_Float16)az; lv.z = (_Float16)(az - (float)hv.z);
  hv.w = (_Float16)aw; lv.w = (_Float16)(aw - (float)hv.w);
  size_t o = (size_t)node*F + (fc<<2);
  *(half4_t*)(oh + o) = hv;
  *(half4_t*)(ol + o) = lv;
}

// ------- k_gconv_mfma v2: dual-side split-f16 MFMA GEMM, gemmsk_h-style.
__global__ __launch_bounds__(256)
void k_gconv_mfma(const _Float16* __restrict__ Ah0, const _Float16* __restrict__ Al0,
                  const _Float16* __restrict__ Ah1, const _Float16* __restrict__ Al1,
                  const _Float16* __restrict__ Bh0, const _Float16* __restrict__ Bl0,
                  const _Float16* __restrict__ Bh1, const _Float16* __restrict__ Bl1,
                  float* __restrict__ C0, float* __restrict__ C1, int ldc,
                  int M0, int M1, int N, int K,
                  const float* __restrict__ rs0, const float* __restrict__ rs1,
                  const float* __restrict__ bi0, const float* __restrict__ bi1, int relu,
                  const float* __restrict__ po0, const float* __restrict__ po1)
{
  __shared__ __align__(16) _Float16 Ahs[2][4096];   // [kb(4)][m(128)][8]
  __shared__ __align__(16) _Float16 Als[2][4096];

  const int gx = gridDim.x, gxy = gridDim.x*gridDim.y;
  const int nwg = gxy*2;
  int fid = blockIdx.x + gx*blockIdx.y + gxy*blockIdx.z;
  int q = nwg>>3, r = nwg&7;
  int xcd = fid & 7, idx = fid >> 3;
  int sid = (xcd<r ? xcd*(q+1) : r*(q+1)+(xcd-r)*q) + idx;
  const int z  = sid / gxy;  int rem = sid - z*gxy;
  const int by = rem / gx,  bx = rem - by*gx;

  const _Float16* Ah = z ? Ah1 : Ah0;
  const _Float16* Al = z ? Al1 : Al0;
  const _Float16* Bh = z ? Bh1 : Bh0;
  const _Float16* Bl = z ? Bl1 : Bl0;
  float*       C  = z ? C1 : C0;
  const float* rsc = z ? rs1 : rs0;
  const float* bia = z ? bi1 : bi0;
  const float* po  = z ? po1 : po0;
  const int M = z ? M1 : M0;

  const int row0 = by << 7;
  const int col0 = bx << 7;
  if (row0 >= ((M+127)&~127)) return;

  const int tid = threadIdx.x;
  const int am  = tid >> 2;
  const int akb = tid & 3;
  const int wid = tid >> 6, lane = tid & 63;
  const int wr = wid >> 1, wc = wid & 1;
  const int lr = lane & 15, lg = lane >> 4;

  f32x4 acc[4][4] = {};
  const int nt = K >> 5;
  const size_t rowK64 = (size_t)64 * K;
  const _Float16* Aph = Ah + (size_t)(row0 + am) * K + (akb<<3);
  const _Float16* Apl = Al + (size_t)(row0 + am) * K + (akb<<3);

  half8 gh0 = *(const half8*)(Aph);
  half8 gh1 = *(const half8*)(Aph + rowK64);
  half8 gl0 = *(const half8*)(Apl);
  half8 gl1 = *(const half8*)(Apl + rowK64);
  *(half8*)&Ahs[0][(akb*128 + am)*8]      = gh0;
  *(half8*)&Ahs[0][(akb*128 + am + 64)*8] = gh1;
  *(half8*)&Als[0][(akb*128 + am)*8]      = gl0;
  *(half8*)&Als[0][(akb*128 + am + 64)*8] = gl1;
  __syncthreads();

  for (int c = 0; c < nt; ++c){
    const int cb = c & 1;
    if (c + 1 < nt){
      const int k0 = (c + 1) << 5;
      gh0 = *(const half8*)(Aph + k0);
      gh1 = *(const half8*)(Aph + k0 + rowK64);
      gl0 = *(const half8*)(Apl + k0);
      gl1 = *(const half8*)(Apl + k0 + rowK64);
    }
    const size_t kb0 = (size_t)(c<<2) + lg;
    half8 bh[4], bl[4];
    #pragma unroll
    for (int ni=0;ni<4;++ni){
      size_t a = (kb0*N + col0 + (wc<<6) + (ni<<4) + lr)*8;
      bh[ni] = *(const half8*)(Bh + a);
      bl[ni] = *(const half8*)(Bl + a);
    }
    #pragma unroll
    for (int mi=0;mi<4;++mi){
      const int aa = ((lg<<7) + (wr<<6) + (mi<<4) + lr)<<3;
      half8 ah = *(const half8*)&Ahs[cb][aa];
      half8 al = *(const half8*)&Als[cb][aa];
      #pragma unroll
      for (int ni=0;ni<4;++ni){
        acc[mi][ni] = MF(ah, bh[ni], acc[mi][ni]);
        acc[mi][ni] = MF(al, bh[ni], acc[mi][ni]);
        acc[mi][ni] = MF(ah, bl[ni], acc[mi][ni]);
      }
    }
    if (c + 1 < nt){
      const int nb_ = cb ^ 1;
      *(half8*)&Ahs[nb_][(akb*128 + am)*8]      = gh0;
      *(half8*)&Ahs[nb_][(akb*128 + am + 64)*8] = gh1;
      *(half8*)&Als[nb_][(akb*128 + am)*8]      = gl0;
      *(half8*)&Als[nb_][(akb*128 + am + 64)*8] = gl1;
    }
    __syncthreads();
  }

  #pragma unroll
  for (int ni = 0; ni < 4; ++ni){
    int cc = col0 + (wc<<6) + (ni<<4) + lr;
    float bv = bia ? bia[cc] : 0.f;
    #pragma unroll
    for (int mi = 0; mi < 4; ++mi){
      int rbase = row0 + (wr<<6) + (mi<<4) + (lg<<2);
      #pragma unroll
      for (int j = 0; j < 4; ++j){
        int rr = rbase + j;
        if (rr < M){
          float rs_ = rsc ? rsc[rr] : 1.f;
          float v = acc[mi][ni][j]*rs_ + bv;
          if (relu) v = fmaxf(v, 0.f);
          if (po) v *= po[rr];
          C[(size_t)rr*ldc + cc] = v;
        }
      }
    }
  }
}

// ------- k_pack: repack sf/vf[:, 0:512) into per-graph 32-aligned node-packed
// split-f16 planes; padding nodes written as ZERO.
__global__ __launch_bounds__(256)
void k_pack(const float* __restrict__ sf, const float* __restrict__ vf,
            const int* __restrict__ go1, const int* __restrict__ go2,
            const int* __restrict__ pb1, const int* __restrict__ pb2,
            const int* __restrict__ gm1, const int* __restrict__ gm2,
            _Float16* __restrict__ p1h, _Float16* __restrict__ p1l,
            _Float16* __restrict__ p2h, _Float16* __restrict__ p2l, int B)
{
  __shared__ float st[32][516];
  const int side = blockIdx.y;
  const float* x = side ? vf : sf;
  const int* go = side ? go2 : go1;
  const int* pb = side ? pb2 : pb1;
  const int* gm = side ? gm2 : gm1;
  _Float16* ph = side ? p2h : p1h;
  _Float16* pl = side ? p2l : p1l;
  const int u = blockIdx.x;
  if (u*32 >= pb[B]) return;
  const int g = gm[u];
  const int j0 = u*32 - pb[g];
  const int base = go[g];
  int cnt = go[g+1]-base; if (cnt>128) cnt=128;
  const int t = threadIdx.x;
  const int r = t>>3, f0 = (t&7)<<2;
  const bool valid = (j0 + r) < cnt;
  const float* src = x + (size_t)(base + j0 + r)*1024;
  #pragma unroll
  for (int q=0;q<16;++q){
    int f = f0 + (q<<5);
    float4 vv;
    if (valid) vv = *(const float4*)(src + f);
    else { vv.x=0.f; vv.y=0.f; vv.z=0.f; vv.w=0.f; }
    *(float4*)&st[r][f] = vv;
  }
  __syncthreads();
  #pragma unroll
  for (int q=0;q<8;++q){
    int u2 = t + (q<<8);
    int jg = u2>>9, f = u2&511;
    half8 h8, l8;
    #pragma unroll
    for (int e=0;e<8;++e){
      float vvv = st[(jg<<3)+e][f];
      _Float16 hh = (_Float16)vvv;
      h8[e]=hh; l8[e]=(_Float16)(vvv-(float)hh);
    }
    size_t a = ((size_t)((u<<2)+jg)<<12) + ((size_t)f<<3);
    *(half8*)(ph + a) = h8;
    *(half8*)(pl + a) = l8;
  }
}

// ------- k_T: LDS-staged split-f16 MFMA interaction tiles (see R3 notes).
__global__ __launch_bounds__(256)
void k_T(const float* __restrict__ sf, const float* __restrict__ vf,
         const int* __restrict__ go1, const int* __restrict__ go2,
         _Float16* __restrict__ Th, _Float16* __restrict__ Tl, int B)
{
  __shared__ __align__(16) _Float16 Ahs[64*136 + 8];   // [fg64][r16][8], fg stride 136
  __shared__ __align__(16) _Float16 Als[64*136 + 8];
  __shared__ __align__(16) _Float16 Bhs[2][2048];      // [buf][fg4][c64][8], c XOR-swizzled
  __shared__ __align__(16) _Float16 Bls[2][2048];
  const int g = blockIdx.x, rt = blockIdx.y;
  int gR = go1[g]; int c1 = go1[g+1]-gR; if (c1>128) c1=128;
  int gO = go2[g]; int c2 = go2[g+1]-gO; if (c2>128) c2=128;
  const int c1_32 = (c1+31)&~31, c2_32 = (c2+31)&~31;
  if ((rt<<4) >= c1_32 || c2_32 == 0) return;
  const int tid = threadIdx.x;
  {
    const int r = tid >> 4;
    const int f0 = (tid & 15) << 5;
    const int row = (rt<<4) + r;
    const bool val = row < c1;
    const float* src = sf + (size_t)(gR + row)*1024 + f0;
    #pragma unroll
    for (int q=0;q<4;++q){
      float4 v0, v1;
      if (val){
        v0 = *(const float4*)(src + (q<<3));
        v1 = *(const float4*)(src + (q<<3) + 4);
      } else {
        v0.x=0.f; v0.y=0.f; v0.z=0.f; v0.w=0.f; v1 = v0;
      }
      half8 h,l; split8(v0,v1,h,l);
      const int a = ((f0>>3) + q)*136 + (r<<3);
      *(half8*)&Ahs[a] = h; *(half8*)&Als[a] = l;
    }
  }
  const int w = tid>>6, lane = tid&63, lr = lane&15, lg = lane>>4;
  const int bc = tid>>2, bfg = tid&3, bf = bfg<<3;
  const int bwr = (bfg<<9) + ((bc ^ (bfg<<2))<<3);
  const int ncc = (c2_32 + 63) >> 6;
  _Float16* T0h = Th + ((size_t)g<<14);
  _Float16* T0l = Tl + ((size_t)g<<14);
  _Float16* T1h = Th + ((size_t)(B + g)<<14);
  _Float16* T1l = Tl + ((size_t)(B + g)<<14);
  for (int cc=0; cc<ncc; ++cc){
    const int cbase = cc<<6;
    const int colr = cbase + bc;
    const bool bval = colr < c2;
    const float* bsrc = vf + (size_t)(gO + colr)*1024 + bf;
    {
      float4 v0, v1;
      if (bval){ v0 = *(const float4*)(bsrc); v1 = *(const float4*)(bsrc + 4); }
      else { v0.x=0.f; v0.y=0.f; v0.z=0.f; v0.w=0.f; v1 = v0; }
      half8 h,l; split8(v0,v1,h,l);
      *(half8*)&Bhs[0][bwr] = h; *(half8*)&Bls[0][bwr] = l;
    }
    __syncthreads();
    f32x4 acc = {0.f,0.f,0.f,0.f};
    const int col_l = (w<<4) + lr;
    const int ba = (lg<<9) + ((col_l ^ (lg<<2))<<3);
    for (int kc=0; kc<16; ++kc){
      float4 p0, p1;
      if (kc+1<16){
        if (bval){
          const float* s = bsrc + ((kc+1)<<5);
          p0 = *(const float4*)s; p1 = *(const float4*)(s + 4);
        } else { p0.x=0.f; p0.y=0.f; p0.z=0.f; p0.w=0.f; p1 = p0; }
      }
      const int aa = ((kc<<2)+lg)*136 + (lr<<3);
      half8 ah = *(const half8*)&Ahs[aa];
      half8 al = *(const half8*)&Als[aa];
      half8 bh = *(const half8*)&Bhs[kc&1][ba];
      half8 bl = *(const half8*)&Bls[kc&1][ba];
      acc = MF(ah,bh,acc);
      acc = MF(al,bh,acc);
      acc = MF(ah,bl,acc);
      if (kc+1<16){
        half8 h,l; split8(p0,p1,h,l);
        *(half8*)&Bhs[(kc+1)&1][bwr] = h; *(half8*)&Bls[(kc+1)&1][bwr] = l;
      }
      __syncthreads();
    }
    const int col = cbase + col_l;
    if (col < c2_32){
      half4_t t1h, t1l;
      #pragma unroll
      for (int qq=0;qq<4;++qq){
        int r = (rt<<4) + (lg<<2) + qq;
        float t = (r < c1 && col < c2) ? ftanh(acc[qq]) : 0.f;
        _Float16 hh = (_Float16)t;
        _Float16 ll = (_Float16)(t - (float)hh);
        T0h[(r<<7) + col] = hh;
        T0l[(r<<7) + col] = ll;
        t1h[qq] = hh; t1l[qq] = ll;
      }
      const int r0 = (rt<<4) + (lg<<2);
      *(half4_t*)&T1h[(col<<7) + r0] = t1h;
      *(half4_t*)&T1l[(col<<7) + r0] = t1l;
    }
  }
}

// ------- k_apply: own'[r][f] = sum_o T[r][o]*oth[o][f] via MFMA.
__global__ __launch_bounds__(256)
void k_apply(const _Float16* __restrict__ Th, const _Float16* __restrict__ Tl,
             const _Float16* __restrict__ p1h, const _Float16* __restrict__ p1l,
             const _Float16* __restrict__ p2h, const _Float16* __restrict__ p2l,
             const int* __restrict__ go1, const int* __restrict__ go2,
             const int* __restrict__ pb1, const int* __restrict__ pb2,
             float* __restrict__ sf, float* __restrict__ vf, int B)
{
  const int side = blockIdx.x, g = blockIdx.y, ft = blockIdx.z;
  const int* goR = side ? go2 : go1;
  const int* goO = side ? go1 : go2;
  const int* pbO = side ? pb1 : pb2;
  const _Float16* oph = side ? p1h : p2h;
  const _Float16* opl = side ? p1l : p2l;
  float* outp = side ? vf : sf;
  int gR = goR[g]; int cR = goR[g+1]-gR; if (cR>128) cR=128;
  int gO = goO[g]; int cO = goO[g+1]-gO; if (cO>128) cO=128;
  if (cR <= 0) return;
  const int pO = pbO[g];
  const int cO32 = (cO+31)&~31;
  const int MR = ((cR+15)&~15)>>4;
  const _Float16* Tph = Th + ((size_t)(side*B + g)<<14);
  const _Float16* Tpl = Tl + ((size_t)(side*B + g)<<14);
  const int tid = threadIdx.x, w = tid>>6, lane = tid&63;
  const int lr = lane&15, lg = lane>>4;
  const int f0 = (ft<<8) + (w<<6);
  for (int rc = 0; rc < MR; rc += 4){
    f32x4 acc[4][4];
    #pragma unroll
    for (int a_=0;a_<4;++a_)
      #pragma unroll
      for (int b_=0;b_<4;++b_) acc[a_][b_] = (f32x4){0.f,0.f,0.f,0.f};
    for (int k0=0; k0<cO32; k0+=32){
      half8 bh[4], bl[4];
      #pragma unroll
      for (int nj=0;nj<4;++nj){
        size_t a = ((size_t)((pO + k0)>>3) + lg)*4096 + (size_t)(f0 + (nj<<4) + lr)*8;
        bh[nj] = *(const half8*)(oph + a);
        bl[nj] = *(const half8*)(opl + a);
      }
      #pragma unroll
      for (int mi=0;mi<4;++mi){
        if (rc + mi < MR){
          int a = ((((rc+mi)<<4) + lr)<<7) + k0 + (lg<<3);
          half8 th_ = *(const half8*)&Tph[a];
          half8 tl_ = *(const half8*)&Tpl[a];
          #pragma unroll
          for (int nj=0;nj<4;++nj){
            acc[mi][nj] = MF(th_, bh[nj], acc[mi][nj]);
            acc[mi][nj] = MF(tl_, bh[nj], acc[mi][nj]);
            acc[mi][nj] = MF(th_, bl[nj], acc[mi][nj]);
          }
        }
      }
    }
    #pragma unroll
    for (int mi=0;mi<4;++mi){
      if (rc + mi < MR){
        #pragma unroll
        for (int nj=0;nj<4;++nj){
          #pragma unroll
          for (int qq=0;qq<4;++qq){
            int r = (((rc+mi)<<4)) + (lg<<2) + qq;
            if (r < cR)
              outp[(size_t)(gR + r)*1024 + 512 + f0 + (nj<<4) + lr] = acc[mi][nj][qq];
          }
        }
      }
    }
  }
}

// ------- k_gemmsk: fp32 skinny NT GEMM (kept for fc2 only).
__global__ __launch_bounds__(256)
void k_gemmsk(const float* __restrict__ Ab, size_t AsideOff, int lda,
              const float* __restrict__ Bm, int ldb,
              float* __restrict__ P, int M, int N, int kchunk)
{
  __shared__ float As[2][16][132];
  __shared__ float Bs[2][16][68];
  const int tid = threadIdx.x;
  const int col0 = (int)blockIdx.x << 6;
  const int kbeg = (int)blockIdx.z * kchunk;
  const float* A = Ab + (size_t)blockIdx.y * AsideOff;
  const int ar = tid >> 1, ak = (tid & 1) << 3;
  const int br = tid >> 2, bk = (tid & 3) << 2;
  const int tx = tid & 15, ty = tid >> 4;
  const float* Arow = A + (size_t)ar * lda + kbeg + ak;
  const float* Brow = Bm + (size_t)(col0 + br) * ldb + kbeg + bk;
  float acc[8][4] = {};
  float4 a0 = *(const float4*)(Arow);
  float4 a1 = *(const float4*)(Arow + 4);
  float4 b0 = *(const float4*)(Brow);
  As[0][ak+0][ar]=a0.x; As[0][ak+1][ar]=a0.y; As[0][ak+2][ar]=a0.z; As[0][ak+3][ar]=a0.w;
  As[0][ak+4][ar]=a1.x; As[0][ak+5][ar]=a1.y; As[0][ak+6][ar]=a1.z; As[0][ak+7][ar]=a1.w;
  Bs[0][bk+0][br]=b0.x; Bs[0][bk+1][br]=b0.y; Bs[0][bk+2][br]=b0.z; Bs[0][bk+3][br]=b0.w;
  __syncthreads();
  const int nt = kchunk >> 4;
  for (int t = 0; t < nt; ++t){
    const int cb = t & 1;
    if (t + 1 < nt){
      int k0 = (t + 1) << 4;
      a0 = *(const float4*)(Arow + k0);
      a1 = *(const float4*)(Arow + k0 + 4);
      b0 = *(const float4*)(Brow + k0);
    }
    #pragma unroll
    for (int kk = 0; kk < 16; ++kk){
      float4 b4 = *(const float4*)&Bs[cb][kk][tx << 2];
      float4 a4 = *(const float4*)&As[cb][kk][ty << 3];
      float4 a5 = *(const float4*)&As[cb][kk][(ty << 3) + 4];
      acc[0][0]+=a4.x*b4.x; acc[0][1]+=a4.x*b4.y; acc[0][2]+=a4.x*b4.z; acc[0][3]+=a4.x*b4.w;
      acc[1][0]+=a4.y*b4.x; acc[1][1]+=a4.y*b4.y; acc[1][2]+=a4.y*b4.z; acc[1][3]+=a4.y*b4.w;
      acc[2][0]+=a4.z*b4.x; acc[2][1]+=a4.z*b4.y; acc[2][2]+=a4.z*b4.z; acc[2][3]+=a4.z*b4.w;
      acc[3][0]+=a4.w*b4.x; acc[3][1]+=a4.w*b4.y; acc[3][2]+=a4.w*b4.z; acc[3][3]+=a4.w*b4.w;
      acc[4][0]+=a5.x*b4.x; acc[4][1]+=a5.x*b4.y; acc[4][2]+=a5.x*b4.z; acc[4][3]+=a5.x*b4.w;
      acc[5][0]+=a5.y*b4.x; acc[5][1]+=a5.y*b4.y; acc[5][2]+=a5.y*b4.z; acc[5][3]+=a5.y*b4.w;
      acc[6][0]+=a5.z*b4.x; acc[6][1]+=a5.z*b4.y; acc[6][2]+=a5.z*b4.z; acc[6][3]+=a5.z*b4.w;
      acc[7][0]+=a5.w*b4.x; acc[7][1]+=a5.w*b4.y; acc[7][2]+=a5.w*b4.z; acc[7][3]+=a5.w*b4.w;
    }
    if (t + 1 < nt){
      const int nb = cb ^ 1;
      As[nb][ak+0][ar]=a0.x; As[nb][ak+1][ar]=a0.y; As[nb][ak+2][ar]=a0.z; As[nb][ak+3][ar]=a0.w;
      As[nb][ak+4][ar]=a1.x; As[nb][ak+5][ar]=a1.y; As[nb][ak+6][ar]=a1.z; As[nb][ak+7][ar]=a1.w;
      Bs[nb][bk+0][br]=b0.x; Bs[nb][bk+1][br]=b0.y; Bs[nb][bk+2][br]=b0.z; Bs[nb][bk+3][br]=b0.w;
    }
    __syncthreads();
  }
  float* Pz = P + (size_t)(blockIdx.y*gridDim.z + blockIdx.z) * M * N;
  #pragma unroll
  for (int i = 0; i < 8; ++i){
    int rr = (ty << 3) + i;
    float4 v = {acc[i][0], acc[i][1], acc[i][2], acc[i][3]};
    *(float4*)(Pz + (size_t)rr*N + col0 + (tx<<2)) = v;
  }
}

// ------- k_gemmsk_h: split-f16 MFMA skinny GEMM (A fp32 staged, B packed planes).
__global__ __launch_bounds__(256)
void k_gemmsk_h(const float* __restrict__ Ab, size_t AsideOff, int lda,
                const _Float16* __restrict__ Bhp, const _Float16* __restrict__ Blp,
                float* __restrict__ P, int N, int kchunk)
{
  __shared__ __align__(16) _Float16 Ahs[2][4096];   // [kb(4)][m(128)][8]
  __shared__ __align__(16) _Float16 Als[2][4096];
  const int tid = threadIdx.x;
  const int col0 = (int)blockIdx.x << 7;
  const int kbeg = (int)blockIdx.z * kchunk;
  const float* A = Ab + (size_t)blockIdx.y * AsideOff;
  const int ar = tid >> 1, aq = (tid & 1) << 4;     // row, k-offset {0,16}
  const int wid = tid>>6, lane = tid&63;
  const int wr = wid>>1, wc = wid&1;
  const int lr = lane&15, lg = lane>>4;
  const float* Arow = A + (size_t)ar*lda + kbeg + aq;
  const int akb = aq>>3;                            // 0 or 2
  f32x4 acc[4][4] = {};
  const int nc = kchunk >> 5;
  float4 g0,g1,g2,g3;
  g0 = *(const float4*)(Arow);     g1 = *(const float4*)(Arow+4);
  g2 = *(const float4*)(Arow+8);   g3 = *(const float4*)(Arow+12);
  {
    half8 h,l;
    split8(g0,g1,h,l);
    *(half8*)&Ahs[0][(akb*128+ar)*8] = h;     *(half8*)&Als[0][(akb*128+ar)*8] = l;
    split8(g2,g3,h,l);
    *(half8*)&Ahs[0][((akb+1)*128+ar)*8] = h; *(half8*)&Als[0][((akb+1)*128+ar)*8] = l;
  }
  __syncthreads();
  for (int c=0;c<nc;++c){
    const int cb = c&1;
    if (c+1<nc){
      const float* p = Arow + ((c+1)<<5);
      g0 = *(const float4*)(p);    g1 = *(const float4*)(p+4);
      g2 = *(const float4*)(p+8);  g3 = *(const float4*)(p+12);
    }
    const size_t kb0 = (size_t)((kbeg + (c<<5)) >> 3) + lg;
    half8 bh[4], bl[4];
    #pragma unroll
    for (int ni=0;ni<4;++ni){
      size_t a = (kb0*N + col0 + (wc<<6) + (ni<<4) + lr)*8;
      bh[ni] = *(const half8*)(Bhp + a);
      bl[ni] = *(const half8*)(Blp + a);
    }
    #pragma unroll
    for (int mi=0;mi<4;++mi){
      int aa = ((lg<<7) + (wr<<6) + (mi<<4) + lr)<<3;
      half8 ah = *(const half8*)&Ahs[cb][aa];
      half8 al = *(const half8*)&Als[cb][aa];
      #pragma unroll
      for (int ni=0;ni<4;++ni){
        acc[mi][ni] = MF(ah,bh[ni],acc[mi][ni]);
        acc[mi][ni] = MF(al,bh[ni],acc[mi][ni]);
        acc[mi][ni] = MF(ah,bl[ni],acc[mi][ni]);
      }
    }
    if (c+1<nc){
      const int nb = cb^1;
      half8 h,l;
      split8(g0,g1,h,l);
      *(half8*)&Ahs[nb][(akb*128+ar)*8] = h;     *(half8*)&Als[nb][(akb*128+ar)*8] = l;
      split8(g2,g3,h,l);
      *(half8*)&Ahs[nb][((akb+1)*128+ar)*8] = h; *(half8*)&Als[nb][((akb+1)*128+ar)*8] = l;
    }
    __syncthreads();
  }
  float* Pz = P + (size_t)(blockIdx.y*gridDim.z + blockIdx.z)*128*N;
  #pragma unroll
  for (int mi=0;mi<4;++mi){
    #pragma unroll
    for (int ni=0;ni<4;++ni){
      int cc2 = col0 + (wc<<6) + (ni<<4) + lr;
      #pragma unroll
      for (int j=0;j<4;++j){
        int rr2 = (wr<<6) + (mi<<4) + (lg<<2) + j;
        Pz[(size_t)rr2*N + cc2] = acc[mi][ni][j];
      }
    }
  }
}

// sum split partials + bias (+relu)
__global__ void k_red_bias(const float* __restrict__ P, int split, int MN, int N,
                           const float* __restrict__ bias, float* __restrict__ C, int relu){
  int i = blockIdx.x*256 + threadIdx.x;
  if (i >= MN) return;
  float v = bias[i & (N-1)];
  for (int s=0;s<split;++s) v += P[(size_t)s*MN + i];
  if (relu) v = fmaxf(v, 0.f);
  C[i] = v;
}

// ---------------- Set2Set ----------------
__global__ void k_gemv_u(const float* __restrict__ Wih, const float* __restrict__ Whh,
                         const float* __restrict__ bih, const float* __restrict__ bhh,
                         float* __restrict__ h1, float* __restrict__ u){
  __shared__ float hsv[1024];
  int t = threadIdx.x;
  #pragma unroll
  for (int j=t; j<1024; j+=256){
    float gi = bih[j]        + bhh[j];
    float gg = bih[j+2048]   + bhh[j+2048];
    float go = bih[j+3072]   + bhh[j+3072];
    float cc = fsigm(gi)*ftanh(gg);
    float hv = fsigm(go)*ftanh(cc);
    hsv[j] = hv;
    if (blockIdx.x==0) h1[j] = hv;
  }
  __syncthreads();
  int w = (blockIdx.x*256 + t)>>6;
  int lane = t & 63;
  if (w >= 4096) return;
  const float* wi = Wih + (size_t)w*2048;
  const float* wh = Whh + (size_t)w*1024;
  float acc = 0.f;
  #pragma unroll
  for (int qq=0;qq<4;++qq){
    int o = qq*256 + (lane<<2);
    float4 hv = *(const float4*)&hsv[o];
    float4 a  = *(const float4*)(wi + o);
    float4 b  = *(const float4*)(wh + o);
    acc += hv.x*(a.x+b.x) + hv.y*(a.y+b.y) + hv.z*(a.z+b.z) + hv.w*(a.w+b.w);
  }
  acc = wredsum(acc);
  if (lane==0) u[w] = acc + bih[w] + bhh[w];
}

// fused attention, dual-side: SINGLE-PASS online segment softmax (see R7 notes).
__global__ __launch_bounds__(256)
void k_attn(const float* __restrict__ sf, const float* __restrict__ vf,
            const int* __restrict__ go1, const int* __restrict__ go2,
            const float* __restrict__ hbase, size_t hSideOff, int hstride,
            float* __restrict__ outbase, size_t oSideOff, int ldout)
{
  __shared__ float hs[1024];
  __shared__ float part[4][1024];
  __shared__ float redm[4], reds[4];
  int side = blockIdx.y;
  const float* x = side? vf : sf;
  const int* goff = side? go2 : go1;
  const float* hsrc = hbase + (size_t)side*hSideOff;
  float* outp = outbase + (size_t)side*oSideOff;
  int b = blockIdx.x, t = threadIdx.x;
  int i0 = goff[b], i1 = goff[b+1];
  int lane = t & 63, wv = t >> 6;
  { float4 hv = *(const float4*)(hsrc + (size_t)b*hstride + (t<<2));
    *(float4*)&hs[t<<2] = hv; }
  __syncthreads();
  float m = -3.0e38f, s = 0.f;
  float4 acc[4];
  #pragma unroll
  for (int qq=0;qq<4;++qq){ acc[qq].x=0.f; acc[qq].y=0.f; acc[qq].z=0.f; acc[qq].w=0.f; }
  for (int i = i0 + wv; i < i1; i += 4){
    const float* xr = x + (size_t)i*1024;
    float4 xv[4];
    float d = 0.f;
    #pragma unroll
    for (int qq=0;qq<4;++qq){
      int o = qq*256 + (lane<<2);
      xv[qq] = *(const float4*)(xr+o);
      float4 h4 = *(const float4*)&hs[o];
      d += xv[qq].x*h4.x + xv[qq].y*h4.y + xv[qq].z*h4.z + xv[qq].w*h4.w;
    }
    d = wredsum(d);
    if (d > m){
      float sc = __expf(m - d);
      s = s*sc + 1.f;
      #pragma unroll
      for (int qq=0;qq<4;++qq){
        acc[qq].x = acc[qq].x*sc + xv[qq].x;
        acc[qq].y = acc[qq].y*sc + xv[qq].y;
        acc[qq].z = acc[qq].z*sc + xv[qq].z;
        acc[qq].w = acc[qq].w*sc + xv[qq].w;
      }
      m = d;
    } else {
      float ww = __expf(d - m);
      s += ww;
      #pragma unroll
      for (int qq=0;qq<4;++qq){
        acc[qq].x += ww*xv[qq].x;
        acc[qq].y += ww*xv[qq].y;
        acc[qq].z += ww*xv[qq].z;
        acc[qq].w += ww*xv[qq].w;
      }
    }
  }
  if (lane==0){ redm[wv]=m; reds[wv]=s; }
  __syncthreads();
  float gm = fmaxf(fmaxf(redm[0],redm[1]), fmaxf(redm[2],redm[3]));
  float gs = reds[0]*__expf(redm[0]-gm) + reds[1]*__expf(redm[1]-gm)
           + reds[2]*__expf(redm[2]-gm) + reds[3]*__expf(redm[3]-gm);
  float wsc = __expf(m - gm);
  #pragma unroll
  for (int qq=0;qq<4;++qq){
    float4 v = acc[qq];
    v.x*=wsc; v.y*=wsc; v.z*=wsc; v.w*=wsc;
    *(float4*)&part[wv][qq*256 + (lane<<2)] = v;
  }
  __syncthreads();
  float inv = (i1>i0 && gs>0.f) ? 1.f/gs : 0.f;
  int col = t<<2;
  float4 p0 = *(float4*)&part[0][col];
  float4 p1 = *(float4*)&part[1][col];
  float4 p2 = *(float4*)&part[2][col];
  float4 p3 = *(float4*)&part[3][col];
  float4 o;
  o.x = (p0.x+p1.x+p2.x+p3.x)*inv;
  o.y = (p0.y+p1.y+p2.y+p3.y)*inv;
  o.z = (p0.z+p1.z+p2.z+p3.z)*inv;
  o.w = (p0.w+p1.w+p2.w+p3.w)*inv;
  *(float4*)(outp + (size_t)b*ldout + col) = o;
}

// LSTM iter2 (dual-side): sum split gate partials + u; c1 recomputed inline from biases.
__global__ void k_lstm2_red(const float* __restrict__ Pb, size_t PsideOff, int split,
                            const float* __restrict__ u,
                            const float* __restrict__ bih, const float* __restrict__ bhh,
                            float* __restrict__ z, int B){
  int idx = blockIdx.x*256 + threadIdx.x;
  if (idx >= B*1024) return;
  int side = blockIdx.y;
  const float* P = Pb + (size_t)side*PsideOff;
  int b = idx >> 10, j = idx & 1023;
  float gi=u[j], gf=u[j+1024], gg=u[j+2048], go=u[j+3072];
  const float* g = P + (size_t)b*4096;
  for (int s=0;s<split;++s){
    const float* gs = g + (size_t)s*B*4096;
    gi += gs[j]; gf += gs[j+1024]; gg += gs[j+2048]; go += gs[j+3072];
  }
  float b_i = bih[j] + bhh[j];
  float b_g = bih[j+2048] + bhh[j+2048];
  float c1v = fsigm(b_i)*ftanh(b_g);
  float cc = fsigm(gf)*c1v + fsigm(gi)*ftanh(gg);
  z[(size_t)b*4096 + side*2048 + j] = fsigm(go)*ftanh(cc);
}

// fused fc2-partials reduce + relu + fc3 dot; one block per graph row.
__global__ __launch_bounds__(256)
void k_fc23(const float* __restrict__ P, int split,
            const float* __restrict__ bf2, const float* __restrict__ w3,
            const float* __restrict__ b3, float* __restrict__ out, int B)
{
  __shared__ float zrow[512];
  __shared__ float red[4];
  const int b = blockIdx.x, t = threadIdx.x;
  const int MN = B*512;
  #pragma unroll
  for (int col = t; col < 512; col += 256){
    float v = bf2[col];
    for (int s=0;s<split;++s) v += P[(size_t)s*MN + (size_t)b*512 + col];
    zrow[col] = fmaxf(v, 0.f);
  }
  __syncthreads();
  int c2 = t<<1;
  float acc = zrow[c2]*w3[c2] + zrow[c2+1]*w3[c2+1];
  acc = wredsum(acc);
  int lane = t & 63, wv = t >> 6;
  if (lane==0) red[wv] = acc;
  __syncthreads();
  if (t==0) out[b] = red[0]+red[1]+red[2]+red[3] + b3[0];
}

// ---------------- driver ----------------
extern "C" void kernel_launch(void* const* d_in, const int* in_sizes, int n_in,
                              void* d_out, int out_size, void* d_ws, size_t ws_size,
                              hipStream_t stream)
{
  const float* x1  = (const float*)d_in[0];
  const float* x2  = (const float*)d_in[1];
  const int* src1  = (const int*)d_in[2];
  const int* dst1  = (const int*)d_in[3];
  const int* src2  = (const int*)d_in[4];
  const int* dst2  = (const int*)d_in[5];
  const int* gid1  = (const int*)d_in[6];
  const int* gid2  = (const int*)d_in[7];
  const float* Wg1 = (const float*)d_in[8];  const float* bg1 = (const float*)d_in[9];
  const float* Wg2 = (const float*)d_in[10]; const float* bg2 = (const float*)d_in[11];
  const float* Wg3 = (const float*)d_in[12]; const float* bg3 = (const float*)d_in[13];
  const float* Wg4 = (const float*)d_in[14]; const float* bg4 = (const float*)d_in[15];
  const float* Wih = (const float*)d_in[16]; const float* Whh = (const float*)d_in[17];
  const float* bih = (const float*)d_in[18]; const float* bhh = (const float*)d_in[19];
  const float* Wf1 = (const float*)d_in[20]; const float* bf1 = (const float*)d_in[21];
  const float* Wf2 = (const float*)d_in[22]; const float* bf2 = (const float*)d_in[23];
  const float* Wf3 = (const float*)d_in[24]; const float* bf3 = (const float*)d_in[25];
  float* out = (float*)d_out;

  const int N1 = in_sizes[0]/128;
  const int N2 = in_sizes[1]/128;
  const int E1 = in_sizes[2];
  const int E2 = in_sizes[4];
  const int B  = out_size;            // 128
  const int NM = N1>N2?N1:N2;

  char* base = (char*)d_ws; size_t off=0;
  auto alloc = [&](size_t bytes)->void*{ void* p = base+off; off += (bytes+255)&~(size_t)255; return p; };

  int* zr   = (int*)alloc(sizeof(int)*(size_t)(3*N1+3*N2));
  int* co1=zr, *ci1=zr+N1, *cur1=zr+2*N1;
  int* co2=zr+3*N1, *ci2=zr+3*N1+N2, *cur2=zr+3*N1+2*N2;
  int* row1 = (int*)alloc(sizeof(int)*(size_t)(N1+1));
  int* row2 = (int*)alloc(sizeof(int)*(size_t)(N2+1));
  int* csr1 = (int*)alloc(sizeof(int)*(size_t)E1);
  int* csr2 = (int*)alloc(sizeof(int)*(size_t)E2);
  int* go1  = (int*)alloc(sizeof(int)*(size_t)(B+1));
  int* go2  = (int*)alloc(sizeof(int)*(size_t)(B+1));
  int* pb1  = (int*)alloc(sizeof(int)*(size_t)(B+1));
  int* pb2  = (int*)alloc(sizeof(int)*(size_t)(B+1));
  int* gm1  = (int*)alloc(sizeof(int)*1024);
  int* gm2  = (int*)alloc(sizeof(int)*1024);
  float* os1 = (float*)alloc(sizeof(float)*(size_t)N1);
  float* is1 = (float*)alloc(sizeof(float)*(size_t)N1);
  float* os2 = (float*)alloc(sizeof(float)*(size_t)N2);
  float* is2 = (float*)alloc(sizeof(float)*(size_t)N2);
  _Float16* a1h = (_Float16*)alloc(sizeof(_Float16)*(size_t)(NM+128)*256);
  _Float16* a1l = (_Float16*)alloc(sizeof(_Float16)*(size_t)(NM+128)*256);
  _Float16* a2h = (_Float16*)alloc(sizeof(_Float16)*(size_t)(NM+128)*256);
  _Float16* a2l = (_Float16*)alloc(sizeof(_Float16)*(size_t)(NM+128)*256);
  _Float16* wg1h = (_Float16*)alloc(sizeof(_Float16)*32768);
  _Float16* wg1l = (_Float16*)alloc(sizeof(_Float16)*32768);
  _Float16* wg2h = (_Float16*)alloc(sizeof(_Float16)*131072);
  _Float16* wg2l = (_Float16*)alloc(sizeof(_Float16)*131072);
  _Float16* wg3h = (_Float16*)alloc(sizeof(_Float16)*32768);
  _Float16* wg3l = (_Float16*)alloc(sizeof(_Float16)*32768);
  _Float16* wg4h = (_Float16*)alloc(sizeof(_Float16)*131072);
  _Float16* wg4l = (_Float16*)alloc(sizeof(_Float16)*131072);
  _Float16* wihh = (_Float16*)alloc(sizeof(_Float16)*(size_t)4096*1024);
  _Float16* wihl = (_Float16*)alloc(sizeof(_Float16)*(size_t)4096*1024);
  _Float16* wf1h = (_Float16*)alloc(sizeof(_Float16)*(size_t)1024*4096);
  _Float16* wf1l = (_Float16*)alloc(sizeof(_Float16)*(size_t)1024*4096);
  float* sf  = (float*)alloc(sizeof(float)*(size_t)(N1+128)*1024);
  float* vf  = (float*)alloc(sizeof(float)*(size_t)(N2+128)*1024);
  float* h1 = (float*)alloc(sizeof(float)*1024);
  float* u  = (float*)alloc(sizeof(float)*4096);
  float* r1 = (float*)alloc(sizeof(float)*(size_t)2*B*1024);
  float* z1 = (float*)alloc(sizeof(float)*(size_t)B*1024);
  float* z  = (float*)alloc(sizeof(float)*(size_t)B*4096);
  // T planes: [2 sides][B][128][128] split-f16 (16.8 MB total)
  _Float16* Tqh = (_Float16*)alloc(sizeof(_Float16)*(size_t)2*B*16384);
  _Float16* Tql = (_Float16*)alloc(sizeof(_Float16)*(size_t)2*B*16384);
  // union region: node-packed split-f16 planes / Pbuf partials
  const int PN = ((NM + 32*B + 63)&~63) + 64;
  const size_t PE = (size_t)PN*512;
  size_t packedBytes = 4*PE*sizeof(_Float16);
  size_t pbufBytes   = sizeof(float)*(size_t)32*B*1024*4;
  char* uni = (char*)alloc(packedBytes > pbufBytes ? packedBytes : pbufBytes);
  _Float16* p1h = (_Float16*)uni;
  _Float16* p1l = p1h + PE;
  _Float16* p2h = p1l + PE;
  _Float16* p2l = p2h + PE;
  float* Pbuf = (float*)uni;
  if (off > ws_size) return;

  // hbuf regions live inside sf/vf cols [512,768) (stride 1024), overwritten later by apply
  float* hb1 = sf + 512;
  float* hb2 = vf + 512;

  dim3 blk(256);

  // --- fused pre-pass: zero counters + all weight packs (one launch) ---
  k_pre<<<dim3(512,7),blk,0,stream>>>(Wg1,Wg2,Wg3,Wg4,
                                      wg1h,wg1l, wg2h,wg2l, wg3h,wg3l, wg4h,wg4l,
                                      Wih+1024, wihh,wihl, Wf1, wf1h,wf1l,
                                      zr, 3*N1+3*N2);

  // --- prep ---
  k_hist2<<<(E1+E2+255)/256, blk, 0, stream>>>(src1,dst1,E1,co1,ci1, src2,dst2,E2,co2,ci2);
  k_prep2<<<3 + (N1+N2+1023)/1024, 1024, 0, stream>>>(ci1,N1,row1, ci2,N2,row2,
                                                      co1,os1,is1, co2,os2,is2,
                                                      gid1,go1, gid2,go2, B,
                                                      pb1,gm1, pb2,gm2);
  k_scatter2<<<(E1+E2+255)/256,blk,0,stream>>>(src1,dst1,E1,row1,cur1,csr1, src2,dst2,E2,row2,cur2,csr2);

  // --- GraphConv ---
  int gy = (NM+127)/128;
  k_agg_h<<<(N1+7)/8,blk,0,stream>>>(x1,128, os1,row1,csr1, a1h,a1l, N1,5);
  k_agg_h<<<(N2+7)/8,blk,0,stream>>>(x2,128, os2,row2,csr2, a2h,a2l, N2,5);
  k_gconv_mfma<<<dim3(2,gy,2),blk,0,stream>>>(a1h,a1l, a2h,a2l,
                                              wg1h,wg1l, wg3h,wg3l,
                                              hb1,hb2,1024, N1,N2, 256,128,
                                              is1,is2, bg1,bg3, 1, os1,os2);
  k_agg_h<<<(N1+3)/4,blk,0,stream>>>(hb1,1024, nullptr,row1,csr1, a1h,a1l, N1,6);
  k_agg_h<<<(N2+3)/4,blk,0,stream>>>(hb2,1024, nullptr,row2,csr2, a2h,a2l, N2,6);
  k_gconv_mfma<<<dim3(4,gy,2),blk,0,stream>>>(a1h,a1l, a2h,a2l,
                                              wg2h,wg2l, wg4h,wg4l,
                                              sf,vf,1024, N1,N2, 512,256,
                                              is1,is2, bg2,bg4, 0, nullptr,nullptr);

  // --- block-diagonal interaction ---
  const int GMAX = NM/32 + B + 2;
  k_pack<<<dim3(GMAX,2),blk,0,stream>>>(sf,vf, go1,go2, pb1,pb2, gm1,gm2,
                                        p1h,p1l, p2h,p2l, B);
  k_T<<<dim3(B,8),blk,0,stream>>>(sf,vf, go1,go2, Tqh,Tql, B);
  k_apply<<<dim3(2,B,2),blk,0,stream>>>(Tqh,Tql, p1h,p1l, p2h,p2l,
                                        go1,go2, pb1,pb2, sf,vf, B);

  // --- Set2Set ---
  k_gemv_u<<<1024,blk,0,stream>>>(Wih,Whh,bih,bhh,h1,u);
  k_attn<<<dim3(B,2),blk,0,stream>>>(sf,vf,go1,go2, h1,0,0, r1,(size_t)B*1024,1024);
  k_gemmsk_h<<<dim3(32,2,4),blk,0,stream>>>(r1,(size_t)B*1024,1024, wihh,wihl, Pbuf, 4096,256);
  k_lstm2_red<<<dim3((B*1024+255)/256,2),blk,0,stream>>>(Pbuf,(size_t)4*B*4096,4, u, bih,bhh, z,B);
  k_attn<<<dim3(B,2),blk,0,stream>>>(sf,vf,go1,go2, z,2048,4096, z+1024,2048,4096);

  // --- MLP head ---
  k_gemmsk_h<<<dim3(8,1,32),blk,0,stream>>>(z,0,4096, wf1h,wf1l, Pbuf, 1024,128);
  k_red_bias<<<(B*1024+255)/256,blk,0,stream>>>(Pbuf,32,B*1024,1024,bf1,z1,1);
  k_gemmsk<<<dim3(8,1,8),blk,0,stream>>>(z1,0,1024, Wf2,1024, Pbuf, 128,512,128);
  k_fc23<<<B,blk,0,stream>>>(Pbuf,8, bf2, Wf3, bf3, out, B);
}

// Round 10
// 339.968 us; speedup vs baseline: 1.3802x; 1.0387x over previous
//
#include <hip/hip_runtime.h>

#define DEV __device__ __forceinline__

typedef _Float16 half8 __attribute__((ext_vector_type(8)));
typedef _Float16 half4_t __attribute__((ext_vector_type(4)));
typedef float f32x4 __attribute__((ext_vector_type(4)));

DEV float ftanh(float x){
  float ax = fabsf(x);
  float e = __expf(-2.f*ax);
  float t = (1.f - e)/(1.f + e);
  return x < 0.f ? -t : t;
}
DEV float fsigm(float x){ return 1.f/(1.f + expf(-x)); }
DEV float wredsum(float v){
  #pragma unroll
  for (int o=32;o;o>>=1) v += __shfl_xor(v,o,64);
  return v;
}
DEV f32x4 MF(half8 a, half8 b, f32x4 c){
  return __builtin_amdgcn_mfma_f32_16x16x32_f16(a,b,c,0,0,0);
}
DEV void split8(float4 a0, float4 a1, half8& h, half8& l){
  float f[8] = {a0.x,a0.y,a0.z,a0.w,a1.x,a1.y,a1.z,a1.w};
  #pragma unroll
  for (int e=0;e<8;++e){
    _Float16 hh = (_Float16)f[e];
    h[e] = hh;
    l[e] = (_Float16)(f[e] - (float)hh);
  }
}

// ---------------- fused pre-pass ----------------
// blockIdx.y: 0..3 wpack4 | 4 zero counters | 5 wpackT gates | 6 wpackT fc1 |
//             7,8 gemv_u (input-only LSTM iter1 h + u gemv; runs concurrent with prep)
__global__ __launch_bounds__(256)
void k_pre(const float* __restrict__ W0, const float* __restrict__ W1,
           const float* __restrict__ W2, const float* __restrict__ W3,
           _Float16* __restrict__ h0, _Float16* __restrict__ l0,
           _Float16* __restrict__ h1p, _Float16* __restrict__ l1p,
           _Float16* __restrict__ h2, _Float16* __restrict__ l2,
           _Float16* __restrict__ h3, _Float16* __restrict__ l3,
           const float* __restrict__ Wg, _Float16* __restrict__ gh, _Float16* __restrict__ gl,
           const float* __restrict__ Wf, _Float16* __restrict__ fh, _Float16* __restrict__ fl,
           int* __restrict__ zr, int nz,
           const float* __restrict__ Wih, const float* __restrict__ Whh,
           const float* __restrict__ bih, const float* __restrict__ bhh,
           float* __restrict__ h1, float* __restrict__ u)
{
  __shared__ float st[32][260];
  const int y = blockIdx.y, t = threadIdx.x;
  if (y < 4){
    const float* W = (y==0)?W0:(y==1)?W1:(y==2)?W2:W3;
    _Float16* oh = (y==0)?h0:(y==1)?h1p:(y==2)?h2:h3;
    _Float16* ol = (y==0)?l0:(y==1)?l1p:(y==2)?l2:l3;
    int K   = (y&1)? 256 : 128;
    int nsh = (y&1)? 9 : 8;
    int i = blockIdx.x*256 + t;
    if (i >= (K<<nsh)) return;
    int k = i >> nsh, n = i & ((1<<nsh)-1);
    float v = W[i];
    _Float16 h = (_Float16)v;
    _Float16 l = (_Float16)(v - (float)h);
    size_t p = (((size_t)(k>>3)<<nsh) + n)*8 + (k&7);
    oh[p] = h; ol[p] = l;
    return;
  }
  if (y == 4){
    int i = blockIdx.x*256 + t;
    if (i < nz) zr[i] = 0;
    return;
  }
  if (y >= 7){
    // gemv_u: compute h1 from biases in LDS, then u = [Wih|Whh] h1 + biases
    float* hsv = &st[0][0];   // 1024 floats fit in st
    #pragma unroll
    for (int j=t; j<1024; j+=256){
      float gi = bih[j]        + bhh[j];
      float gg = bih[j+2048]   + bhh[j+2048];
      float go = bih[j+3072]   + bhh[j+3072];
      float cc = fsigm(gi)*ftanh(gg);
      float hv = fsigm(go)*ftanh(cc);
      hsv[j] = hv;
    }
    __syncthreads();
    const int gb = (y-7)*512 + blockIdx.x;      // 0..1023
    if (gb == 0 && t < 256){
      #pragma unroll
      for (int j=t; j<1024; j+=256) h1[j] = hsv[j];
    }
    int w = (gb<<2) + (t>>6);
    int lane = t & 63;
    if (w >= 4096) return;
    const float* wi = Wih + (size_t)w*2048;
    const float* wh = Whh + (size_t)w*1024;
    float acc = 0.f;
    #pragma unroll
    for (int qq=0;qq<4;++qq){
      int o = qq*256 + (lane<<2);
      float4 hv = *(const float4*)&hsv[o];
      float4 a  = *(const float4*)(wi + o);
      float4 b  = *(const float4*)(wh + o);
      acc += hv.x*(a.x+b.x) + hv.y*(a.y+b.y) + hv.z*(a.z+b.z) + hv.w*(a.w+b.w);
    }
    acc = wredsum(acc);
    if (lane==0) u[w] = acc + bih[w] + bhh[w];
    return;
  }
  // wpackT (y==5 gates, y==6 fc1)
  const float* W; _Float16* Bh; _Float16* Bl; int ldw, N, k0, n0;
  if (y == 5){
    int tile = blockIdx.x; if (tile >= 512) return;
    W = Wg; Bh = gh; Bl = gl; ldw = 2048; N = 4096;
    k0 = (tile & 3) << 8; n0 = (tile >> 2) << 5;
  } else {
    int tile = blockIdx.x; if (tile >= 512) return;
    W = Wf; Bh = fh; Bl = fl; ldw = 4096; N = 1024;
    k0 = (tile & 15) << 8; n0 = (tile >> 4) << 5;
  }
  const int r = t >> 3, la = t & 7;
  const float* src = W + (size_t)(n0 + r)*ldw + k0;
  #pragma unroll
  for (int q=0;q<8;++q){
    int f = (la<<2) + (q<<5);
    *(float4*)&st[r][f] = *(const float4*)(src + f);
  }
  __syncthreads();
  const int nl = t & 31;
  #pragma unroll
  for (int j=0;j<4;++j){
    int kbl = (t>>5) + (j<<3);
    half8 h8, l8;
    #pragma unroll
    for (int e=0;e<8;++e){
      float v = st[nl][(kbl<<3)+e];
      _Float16 hh = (_Float16)v;
      h8[e]=hh; l8[e]=(_Float16)(v-(float)hh);
    }
    size_t a = ((size_t)((k0>>3)+kbl)*N + n0 + nl)*8;
    *(half8*)(Bh + a) = h8;
    *(half8*)(Bl + a) = l8;
  }
}

// ---------------- graph prep ----------------
__global__ void k_hist2(const int* __restrict__ s1, const int* __restrict__ d1, int E1,
                        int* __restrict__ co1, int* __restrict__ ci1,
                        const int* __restrict__ s2, const int* __restrict__ d2, int E2,
                        int* __restrict__ co2, int* __restrict__ ci2){
  int e = blockIdx.x*256 + threadIdx.x;
  if (e < E1){ atomicAdd(&co1[s1[e]],1); atomicAdd(&ci1[d1[e]],1); }
  int f = e - E1;
  if (f >= 0 && f < E2){ atomicAdd(&co2[s2[f]],1); atomicAdd(&ci2[d2[f]],1); }
}

// fused: blocks 0,1 = CSR row scans; block 2 = goff+pb+gm; blocks 3+ = degree scales.
__global__ __launch_bounds__(1024)
void k_prep2(const int* __restrict__ ci1, int n1, int* __restrict__ row1,
             const int* __restrict__ ci2, int n2, int* __restrict__ row2,
             const int* __restrict__ co1, float* __restrict__ os1, float* __restrict__ is1,
             const int* __restrict__ co2, float* __restrict__ os2, float* __restrict__ is2,
             const int* __restrict__ g1, int* __restrict__ o1,
             const int* __restrict__ g2, int* __restrict__ o2, int B,
             int* __restrict__ pb1, int* __restrict__ gm1,
             int* __restrict__ pb2, int* __restrict__ gm2)
{
  const int bid = blockIdx.x, t = threadIdx.x;
  if (bid < 2){
    __shared__ int sm[1024];
    const int* cnt = bid ? ci2 : ci1;
    int*       row = bid ? row2 : row1;
    int n          = bid ? n2 : n1;
    int per = n/1024 + 1;
    int st = t*per;
    int s = 0;
    for (int i=st;i<st+per;++i) if (i<n) s += cnt[i];
    sm[t]=s; __syncthreads();
    for (int o=1;o<1024;o<<=1){
      int v = (t>=o)? sm[t-o]:0;
      __syncthreads();
      sm[t] += v;
      __syncthreads();
    }
    int base = sm[t]-s;
    for (int i=st;i<st+per;++i){
      if (i<=n) row[i]=base;
      if (i<n) base += cnt[i];
    }
    return;
  }
  if (bid == 2){
    __shared__ int sc[2][256];
    const bool act = t < 512;
    const int side = (t>>8)&1, q = t & 255;
    if (act && q<=B){
      const int* gid = side ? g2 : g1;
      int n = side ? n2 : n1;
      int lo=0, hi=n;
      while (lo<hi){ int mid=(lo+hi)>>1; if (gid[mid]<q) lo=mid+1; else hi=mid; }
      (side ? o2 : o1)[q]=lo;
    }
    __syncthreads();
    int pc = 0;
    if (act && q < B){
      const int* go = side ? o2 : o1;
      int c = go[q+1]-go[q]; if (c>128) c=128;
      pc = (c+31)&~31;
    }
    if (act) sc[side][q] = pc;
    __syncthreads();
    for (int o=1;o<B;o<<=1){
      int v = (act && q>=o && q<B) ? sc[side][q-o] : 0;
      __syncthreads();
      if (act && q<B) sc[side][q] += v;
      __syncthreads();
    }
    if (act && q < B){
      int incl = sc[side][q];
      int pbv  = incl - pc;
      int* pb = side ? pb2 : pb1;
      int* gm = side ? gm2 : gm1;
      pb[q] = pbv;
      if (q == B-1) pb[B] = incl;
      int nb = pc>>5, b0 = pbv>>5;
      for (int k=0;k<nb;++k) gm[b0+k] = q;
    }
    return;
  }
  int i = (bid-3)*1024 + t;
  if (i<n1){
    int a = co1[i] > 1 ? co1[i] : 1;
    int b = ci1[i] > 1 ? ci1[i] : 1;
    os1[i] = 1.f/sqrtf((float)a);
    is1[i] = 1.f/sqrtf((float)b);
  }
  int j = i - n1;
  if (j>=0 && j<n2){
    int a = co2[j] > 1 ? co2[j] : 1;
    int b = ci2[j] > 1 ? ci2[j] : 1;
    os2[j] = 1.f/sqrtf((float)a);
    is2[j] = 1.f/sqrtf((float)b);
  }
}

__global__ void k_scatter2(const int* __restrict__ s1, const int* __restrict__ d1, int E1,
                           const int* __restrict__ row1, int* __restrict__ cur1, int* __restrict__ csr1,
                           const int* __restrict__ s2, const int* __restrict__ d2, int E2,
                           const int* __restrict__ row2, int* __restrict__ cur2, int* __restrict__ csr2){
  int e = blockIdx.x*256+threadIdx.x;
  if (e<E1){ int d=d1[e]; int p=atomicAdd(&cur1[d],1); csr1[row1[d]+p]=s1[e]; }
  int f = e - E1;
  if (f>=0 && f<E2){ int d=d2[f]; int p=atomicAdd(&cur2[d],1); csr2[row2[d]+p]=s2[f]; }
}

// gather aggregation, DUAL-SIDE via blockIdx.y, split-f16 output planes
__global__ void k_agg2(const float* __restrict__ xa, const float* __restrict__ xb, int ldx,
                       const float* __restrict__ osca, const float* __restrict__ oscb,
                       const int* __restrict__ rowa, const int* __restrict__ csra,
                       const int* __restrict__ rowb, const int* __restrict__ csrb,
                       _Float16* __restrict__ oha, _Float16* __restrict__ ola,
                       _Float16* __restrict__ ohb, _Float16* __restrict__ olb,
                       int na, int nb, int f4shift){
  const int side = blockIdx.y;
  const float* x = side ? xb : xa;
  const float* osc = side ? oscb : osca;
  const int* row = side ? rowb : rowa;
  const int* csr = side ? csrb : csra;
  _Float16* oh = side ? ohb : oha;
  _Float16* ol = side ? olb : ola;
  const int n = side ? nb : na;
  int F4 = 1<<f4shift;
  int node = blockIdx.x*(256>>f4shift) + (threadIdx.x>>f4shift);
  if (node>=n) return;
  int fc = threadIdx.x & (F4-1);
  int F = F4<<2;
  int rs=row[node], re=row[node+1];
  float ax=0, ay=0, az=0, aw=0;
  if (osc){
    for (int e=rs;e<re;++e){
      int s = csr[e];
      float sc = osc[s];
      const float4 v = *(const float4*)(x + (size_t)s*ldx + (fc<<2));
      ax += sc*v.x; ay += sc*v.y; az += sc*v.z; aw += sc*v.w;
    }
  } else {
    int e = rs;
    for (; e+1<re; e+=2){
      int s0 = csr[e], s1 = csr[e+1];
      const float4 v0 = *(const float4*)(x + (size_t)s0*ldx + (fc<<2));
      const float4 v1 = *(const float4*)(x + (size_t)s1*ldx + (fc<<2));
      ax += v0.x+v1.x; ay += v0.y+v1.y; az += v0.z+v1.z; aw += v0.w+v1.w;
    }
    if (e<re){
      int s0 = csr[e];
      const float4 v0 = *(const float4*)(x + (size_t)s0*ldx + (fc<<2));
      ax += v0.x; ay += v0.y; az += v0.z; aw += v0.w;
    }
  }
  half4_t hv, lv;
  hv.x = (_Float16)ax; lv.x = (_Float16)(ax - (float)hv.x);
  hv.y = (_Float16)ay; lv.y = (_Float16)(ay - (float)hv.y);
  hv.z = (_Float16)az; lv.z = (_Float16)(az - (float)hv.z);
  hv.w = (_Float16)aw; lv.w = (_Float16)(aw - (float)hv.w);
  size_t o = (size_t)node*F + (fc<<2);
  *(half4_t*)(oh + o) = hv;
  *(half4_t*)(ol + o) = lv;
}

// ------- k_gconv_mfma v2: dual-side split-f16 MFMA GEMM, gemmsk_h-style.
__global__ __launch_bounds__(256)
void k_gconv_mfma(const _Float16* __restrict__ Ah0, const _Float16* __restrict__ Al0,
                  const _Float16* __restrict__ Ah1, const _Float16* __restrict__ Al1,
                  const _Float16* __restrict__ Bh0, const _Float16* __restrict__ Bl0,
                  const _Float16* __restrict__ Bh1, const _Float16* __restrict__ Bl1,
                  float* __restrict__ C0, float* __restrict__ C1, int ldc,
                  int M0, int M1, int N, int K,
                  const float* __restrict__ rs0, const float* __restrict__ rs1,
                  const float* __restrict__ bi0, const float* __restrict__ bi1, int relu,
                  const float* __restrict__ po0, const float* __restrict__ po1)
{
  __shared__ __align__(16) _Float16 Ahs[2][4096];   // [kb(4)][m(128)][8]
  __shared__ __align__(16) _Float16 Als[2][4096];

  const int gx = gridDim.x, gxy = gridDim.x*gridDim.y;
  const int nwg = gxy*2;
  int fid = blockIdx.x + gx*blockIdx.y + gxy*blockIdx.z;
  int q = nwg>>3, r = nwg&7;
  int xcd = fid & 7, idx = fid >> 3;
  int sid = (xcd<r ? xcd*(q+1) : r*(q+1)+(xcd-r)*q) + idx;
  const int z  = sid / gxy;  int rem = sid - z*gxy;
  const int by = rem / gx,  bx = rem - by*gx;

  const _Float16* Ah = z ? Ah1 : Ah0;
  const _Float16* Al = z ? Al1 : Al0;
  const _Float16* Bh = z ? Bh1 : Bh0;
  const _Float16* Bl = z ? Bl1 : Bl0;
  float*       C  = z ? C1 : C0;
  const float* rsc = z ? rs1 : rs0;
  const float* bia = z ? bi1 : bi0;
  const float* po  = z ? po1 : po0;
  const int M = z ? M1 : M0;

  const int row0 = by << 7;
  const int col0 = bx << 7;
  if (row0 >= ((M+127)&~127)) return;

  const int tid = threadIdx.x;
  const int am  = tid >> 2;
  const int akb = tid & 3;
  const int wid = tid >> 6, lane = tid & 63;
  const int wr = wid >> 1, wc = wid & 1;
  const int lr = lane & 15, lg = lane >> 4;

  f32x4 acc[4][4] = {};
  const int nt = K >> 5;
  const size_t rowK64 = (size_t)64 * K;
  const _Float16* Aph = Ah + (size_t)(row0 + am) * K + (akb<<3);
  const _Float16* Apl = Al + (size_t)(row0 + am) * K + (akb<<3);

  half8 gh0 = *(const half8*)(Aph);
  half8 gh1 = *(const half8*)(Aph + rowK64);
  half8 gl0 = *(const half8*)(Apl);
  half8 gl1 = *(const half8*)(Apl + rowK64);
  *(half8*)&Ahs[0][(akb*128 + am)*8]      = gh0;
  *(half8*)&Ahs[0][(akb*128 + am + 64)*8] = gh1;
  *(half8*)&Als[0][(akb*128 + am)*8]      = gl0;
  *(half8*)&Als[0][(akb*128 + am + 64)*8] = gl1;
  __syncthreads();

  for (int c = 0; c < nt; ++c){
    const int cb = c & 1;
    if (c + 1 < nt){
      const int k0 = (c + 1) << 5;
      gh0 = *(const half8*)(Aph + k0);
      gh1 = *(const half8*)(Aph + k0 + rowK64);
      gl0 = *(const half8*)(Apl + k0);
      gl1 = *(const half8*)(Apl + k0 + rowK64);
    }
    const size_t kb0 = (size_t)(c<<2) + lg;
    half8 bh[4], bl[4];
    #pragma unroll
    for (int ni=0;ni<4;++ni){
      size_t a = (kb0*N + col0 + (wc<<6) + (ni<<4) + lr)*8;
      bh[ni] = *(const half8*)(Bh + a);
      bl[ni] = *(const half8*)(Bl + a);
    }
    #pragma unroll
    for (int mi=0;mi<4;++mi){
      const int aa = ((lg<<7) + (wr<<6) + (mi<<4) + lr)<<3;
      half8 ah = *(const half8*)&Ahs[cb][aa];
      half8 al = *(const half8*)&Als[cb][aa];
      #pragma unroll
      for (int ni=0;ni<4;++ni){
        acc[mi][ni] = MF(ah, bh[ni], acc[mi][ni]);
        acc[mi][ni] = MF(al, bh[ni], acc[mi][ni]);
        acc[mi][ni] = MF(ah, bl[ni], acc[mi][ni]);
      }
    }
    if (c + 1 < nt){
      const int nb_ = cb ^ 1;
      *(half8*)&Ahs[nb_][(akb*128 + am)*8]      = gh0;
      *(half8*)&Ahs[nb_][(akb*128 + am + 64)*8] = gh1;
      *(half8*)&Als[nb_][(akb*128 + am)*8]      = gl0;
      *(half8*)&Als[nb_][(akb*128 + am + 64)*8] = gl1;
    }
    __syncthreads();
  }

  #pragma unroll
  for (int ni = 0; ni < 4; ++ni){
    int cc = col0 + (wc<<6) + (ni<<4) + lr;
    float bv = bia ? bia[cc] : 0.f;
    #pragma unroll
    for (int mi = 0; mi < 4; ++mi){
      int rbase = row0 + (wr<<6) + (mi<<4) + (lg<<2);
      #pragma unroll
      for (int j = 0; j < 4; ++j){
        int rr = rbase + j;
        if (rr < M){
          float rs_ = rsc ? rsc[rr] : 1.f;
          float v = acc[mi][ni][j]*rs_ + bv;
          if (relu) v = fmaxf(v, 0.f);
          if (po) v *= po[rr];
          C[(size_t)rr*ldc + cc] = v;
        }
      }
    }
  }
}

// ------- k_pack: repack sf/vf[:, 0:512) into per-graph 32-aligned node-packed
// split-f16 planes; padding nodes written as ZERO.
__global__ __launch_bounds__(256)
void k_pack(const float* __restrict__ sf, const float* __restrict__ vf,
            const int* __restrict__ go1, const int* __restrict__ go2,
            const int* __restrict__ pb1, const int* __restrict__ pb2,
            const int* __restrict__ gm1, const int* __restrict__ gm2,
            _Float16* __restrict__ p1h, _Float16* __restrict__ p1l,
            _Float16* __restrict__ p2h, _Float16* __restrict__ p2l, int B)
{
  __shared__ float st[32][516];
  const int side = blockIdx.y;
  const float* x = side ? vf : sf;
  const int* go = side ? go2 : go1;
  const int* pb = side ? pb2 : pb1;
  const int* gm = side ? gm2 : gm1;
  _Float16* ph = side ? p2h : p1h;
  _Float16* pl = side ? p2l : p1l;
  const int u = blockIdx.x;
  if (u*32 >= pb[B]) return;
  const int g = gm[u];
  const int j0 = u*32 - pb[g];
  const int base = go[g];
  int cnt = go[g+1]-base; if (cnt>128) cnt=128;
  const int t = threadIdx.x;
  const int r = t>>3, f0 = (t&7)<<2;
  const bool valid = (j0 + r) < cnt;
  const float* src = x + (size_t)(base + j0 + r)*1024;
  #pragma unroll
  for (int q=0;q<16;++q){
    int f = f0 + (q<<5);
    float4 vv;
    if (valid) vv = *(const float4*)(src + f);
    else { vv.x=0.f; vv.y=0.f; vv.z=0.f; vv.w=0.f; }
    *(float4*)&st[r][f] = vv;
  }
  __syncthreads();
  #pragma unroll
  for (int q=0;q<8;++q){
    int u2 = t + (q<<8);
    int jg = u2>>9, f = u2&511;
    half8 h8, l8;
    #pragma unroll
    for (int e=0;e<8;++e){
      float vvv = st[(jg<<3)+e][f];
      _Float16 hh = (_Float16)vvv;
      h8[e]=hh; l8[e]=(_Float16)(vvv-(float)hh);
    }
    size_t a = ((size_t)((u<<2)+jg)<<12) + ((size_t)f<<3);
    *(half8*)(ph + a) = h8;
    *(half8*)(pl + a) = l8;
  }
}

// ------- k_T: LDS-staged split-f16 MFMA interaction tiles (see R3 notes).
__global__ __launch_bounds__(256)
void k_T(const float* __restrict__ sf, const float* __restrict__ vf,
         const int* __restrict__ go1, const int* __restrict__ go2,
         _Float16* __restrict__ Th, _Float16* __restrict__ Tl, int B)
{
  __shared__ __align__(16) _Float16 Ahs[64*136 + 8];   // [fg64][r16][8], fg stride 136
  __shared__ __align__(16) _Float16 Als[64*136 + 8];
  __shared__ __align__(16) _Float16 Bhs[2][2048];      // [buf][fg4][c64][8], c XOR-swizzled
  __shared__ __align__(16) _Float16 Bls[2][2048];
  const int g = blockIdx.x, rt = blockIdx.y;
  int gR = go1[g]; int c1 = go1[g+1]-gR; if (c1>128) c1=128;
  int gO = go2[g]; int c2 = go2[g+1]-gO; if (c2>128) c2=128;
  const int c1_32 = (c1+31)&~31, c2_32 = (c2+31)&~31;
  if ((rt<<4) >= c1_32 || c2_32 == 0) return;
  const int tid = threadIdx.x;
  {
    const int r = tid >> 4;
    const int f0 = (tid & 15) << 5;
    const int row = (rt<<4) + r;
    const bool val = row < c1;
    const float* src = sf + (size_t)(gR + row)*1024 + f0;
    #pragma unroll
    for (int q=0;q<4;++q){
      float4 v0, v1;
      if (val){
        v0 = *(const float4*)(src + (q<<3));
        v1 = *(const float4*)(src + (q<<3) + 4);
      } else {
        v0.x=0.f; v0.y=0.f; v0.z=0.f; v0.w=0.f; v1 = v0;
      }
      half8 h,l; split8(v0,v1,h,l);
      const int a = ((f0>>3) + q)*136 + (r<<3);
      *(half8*)&Ahs[a] = h; *(half8*)&Als[a] = l;
    }
  }
  const int w = tid>>6, lane = tid&63, lr = lane&15, lg = lane>>4;
  const int bc = tid>>2, bfg = tid&3, bf = bfg<<3;
  const int bwr = (bfg<<9) + ((bc ^ (bfg<<2))<<3);
  const int ncc = (c2_32 + 63) >> 6;
  _Float16* T0h = Th + ((size_t)g<<14);
  _Float16* T0l = Tl + ((size_t)g<<14);
  _Float16* T1h = Th + ((size_t)(B + g)<<14);
  _Float16* T1l = Tl + ((size_t)(B + g)<<14);
  for (int cc=0; cc<ncc; ++cc){
    const int cbase = cc<<6;
    const int colr = cbase + bc;
    const bool bval = colr < c2;
    const float* bsrc = vf + (size_t)(gO + colr)*1024 + bf;
    {
      float4 v0, v1;
      if (bval){ v0 = *(const float4*)(bsrc); v1 = *(const float4*)(bsrc + 4); }
      else { v0.x=0.f; v0.y=0.f; v0.z=0.f; v0.w=0.f; v1 = v0; }
      half8 h,l; split8(v0,v1,h,l);
      *(half8*)&Bhs[0][bwr] = h; *(half8*)&Bls[0][bwr] = l;
    }
    __syncthreads();
    f32x4 acc = {0.f,0.f,0.f,0.f};
    const int col_l = (w<<4) + lr;
    const int ba = (lg<<9) + ((col_l ^ (lg<<2))<<3);
    for (int kc=0; kc<16; ++kc){
      float4 p0, p1;
      if (kc+1<16){
        if (bval){
          const float* s = bsrc + ((kc+1)<<5);
          p0 = *(const float4*)s; p1 = *(const float4*)(s + 4);
        } else { p0.x=0.f; p0.y=0.f; p0.z=0.f; p0.w=0.f; p1 = p0; }
      }
      const int aa = ((kc<<2)+lg)*136 + (lr<<3);
      half8 ah = *(const half8*)&Ahs[aa];
      half8 al = *(const half8*)&Als[aa];
      half8 bh = *(const half8*)&Bhs[kc&1][ba];
      half8 bl = *(const half8*)&Bls[kc&1][ba];
      acc = MF(ah,bh,acc);
      acc = MF(al,bh,acc);
      acc = MF(ah,bl,acc);
      if (kc+1<16){
        half8 h,l; split8(p0,p1,h,l);
        *(half8*)&Bhs[(kc+1)&1][bwr] = h; *(half8*)&Bls[(kc+1)&1][bwr] = l;
      }
      __syncthreads();
    }
    const int col = cbase + col_l;
    if (col < c2_32){
      half4_t t1h, t1l;
      #pragma unroll
      for (int qq=0;qq<4;++qq){
        int r = (rt<<4) + (lg<<2) + qq;
        float t = (r < c1 && col < c2) ? ftanh(acc[qq]) : 0.f;
        _Float16 hh = (_Float16)t;
        _Float16 ll = (_Float16)(t - (float)hh);
        T0h[(r<<7) + col] = hh;
        T0l[(r<<7) + col] = ll;
        t1h[qq] = hh; t1l[qq] = ll;
      }
      const int r0 = (rt<<4) + (lg<<2);
      *(half4_t*)&T1h[(col<<7) + r0] = t1h;
      *(half4_t*)&T1l[(col<<7) + r0] = t1l;
    }
  }
}

// ------- k_apply: own'[r][f] = sum_o T[r][o]*oth[o][f] via MFMA.
__global__ __launch_bounds__(256)
void k_apply(const _Float16* __restrict__ Th, const _Float16* __restrict__ Tl,
             const _Float16* __restrict__ p1h, const _Float16* __restrict__ p1l,
             const _Float16* __restrict__ p2h, const _Float16* __restrict__ p2l,
             const int* __restrict__ go1, const int* __restrict__ go2,
             const int* __restrict__ pb1, const int* __restrict__ pb2,
             float* __restrict__ sf, float* __restrict__ vf, int B)
{
  const int side = blockIdx.x, g = blockIdx.y, ft = blockIdx.z;
  const int* goR = side ? go2 : go1;
  const int* goO = side ? go1 : go2;
  const int* pbO = side ? pb1 : pb2;
  const _Float16* oph = side ? p1h : p2h;
  const _Float16* opl = side ? p1l : p2l;
  float* outp = side ? vf : sf;
  int gR = goR[g]; int cR = goR[g+1]-gR; if (cR>128) cR=128;
  int gO = goO[g]; int cO = goO[g+1]-gO; if (cO>128) cO=128;
  if (cR <= 0) return;
  const int pO = pbO[g];
  const int cO32 = (cO+31)&~31;
  const int MR = ((cR+15)&~15)>>4;
  const _Float16* Tph = Th + ((size_t)(side*B + g)<<14);
  const _Float16* Tpl = Tl + ((size_t)(side*B + g)<<14);
  const int tid = threadIdx.x, w = tid>>6, lane = tid&63;
  const int lr = lane&15, lg = lane>>4;
  const int f0 = (ft<<8) + (w<<6);
  for (int rc = 0; rc < MR; rc += 4){
    f32x4 acc[4][4];
    #pragma unroll
    for (int a_=0;a_<4;++a_)
      #pragma unroll
      for (int b_=0;b_<4;++b_) acc[a_][b_] = (f32x4){0.f,0.f,0.f,0.f};
    for (int k0=0; k0<cO32; k0+=32){
      half8 bh[4], bl[4];
      #pragma unroll
      for (int nj=0;nj<4;++nj){
        size_t a = ((size_t)((pO + k0)>>3) + lg)*4096 + (size_t)(f0 + (nj<<4) + lr)*8;
        bh[nj] = *(const half8*)(oph + a);
        bl[nj] = *(const half8*)(opl + a);
      }
      #pragma unroll
      for (int mi=0;mi<4;++mi){
        if (rc + mi < MR){
          int a = ((((rc+mi)<<4) + lr)<<7) + k0 + (lg<<3);
          half8 th_ = *(const half8*)&Tph[a];
          half8 tl_ = *(const half8*)&Tpl[a];
          #pragma unroll
          for (int nj=0;nj<4;++nj){
            acc[mi][nj] = MF(th_, bh[nj], acc[mi][nj]);
            acc[mi][nj] = MF(tl_, bh[nj], acc[mi][nj]);
            acc[mi][nj] = MF(th_, bl[nj], acc[mi][nj]);
          }
        }
      }
    }
    #pragma unroll
    for (int mi=0;mi<4;++mi){
      if (rc + mi < MR){
        #pragma unroll
        for (int nj=0;nj<4;++nj){
          #pragma unroll
          for (int qq=0;qq<4;++qq){
            int r = (((rc+mi)<<4)) + (lg<<2) + qq;
            if (r < cR)
              outp[(size_t)(gR + r)*1024 + 512 + f0 + (nj<<4) + lr] = acc[mi][nj][qq];
          }
        }
      }
    }
  }
}

// ------- k_gemmsk: fp32 skinny NT GEMM (kept for fc2 only).
__global__ __launch_bounds__(256)
void k_gemmsk(const float* __restrict__ Ab, size_t AsideOff, int lda,
              const float* __restrict__ Bm, int ldb,
              float* __restrict__ P, int M, int N, int kchunk)
{
  __shared__ float As[2][16][132];
  __shared__ float Bs[2][16][68];
  const int tid = threadIdx.x;
  const int col0 = (int)blockIdx.x << 6;
  const int kbeg = (int)blockIdx.z * kchunk;
  const float* A = Ab + (size_t)blockIdx.y * AsideOff;
  const int ar = tid >> 1, ak = (tid & 1) << 3;
  const int br = tid >> 2, bk = (tid & 3) << 2;
  const int tx = tid & 15, ty = tid >> 4;
  const float* Arow = A + (size_t)ar * lda + kbeg + ak;
  const float* Brow = Bm + (size_t)(col0 + br) * ldb + kbeg + bk;
  float acc[8][4] = {};
  float4 a0 = *(const float4*)(Arow);
  float4 a1 = *(const float4*)(Arow + 4);
  float4 b0 = *(const float4*)(Brow);
  As[0][ak+0][ar]=a0.x; As[0][ak+1][ar]=a0.y; As[0][ak+2][ar]=a0.z; As[0][ak+3][ar]=a0.w;
  As[0][ak+4][ar]=a1.x; As[0][ak+5][ar]=a1.y; As[0][ak+6][ar]=a1.z; As[0][ak+7][ar]=a1.w;
  Bs[0][bk+0][br]=b0.x; Bs[0][bk+1][br]=b0.y; Bs[0][bk+2][br]=b0.z; Bs[0][bk+3][br]=b0.w;
  __syncthreads();
  const int nt = kchunk >> 4;
  for (int t = 0; t < nt; ++t){
    const int cb = t & 1;
    if (t + 1 < nt){
      int k0 = (t + 1) << 4;
      a0 = *(const float4*)(Arow + k0);
      a1 = *(const float4*)(Arow + k0 + 4);
      b0 = *(const float4*)(Brow + k0);
    }
    #pragma unroll
    for (int kk = 0; kk < 16; ++kk){
      float4 b4 = *(const float4*)&Bs[cb][kk][tx << 2];
      float4 a4 = *(const float4*)&As[cb][kk][ty << 3];
      float4 a5 = *(const float4*)&As[cb][kk][(ty << 3) + 4];
      acc[0][0]+=a4.x*b4.x; acc[0][1]+=a4.x*b4.y; acc[0][2]+=a4.x*b4.z; acc[0][3]+=a4.x*b4.w;
      acc[1][0]+=a4.y*b4.x; acc[1][1]+=a4.y*b4.y; acc[1][2]+=a4.y*b4.z; acc[1][3]+=a4.y*b4.w;
      acc[2][0]+=a4.z*b4.x; acc[2][1]+=a4.z*b4.y; acc[2][2]+=a4.z*b4.z; acc[2][3]+=a4.z*b4.w;
      acc[3][0]+=a4.w*b4.x; acc[3][1]+=a4.w*b4.y; acc[3][2]+=a4.w*b4.z; acc[3][3]+=a4.w*b4.w;
      acc[4][0]+=a5.x*b4.x; acc[4][1]+=a5.x*b4.y; acc[4][2]+=a5.x*b4.z; acc[4][3]+=a5.x*b4.w;
      acc[5][0]+=a5.y*b4.x; acc[5][1]+=a5.y*b4.y; acc[5][2]+=a5.y*b4.z; acc[5][3]+=a5.y*b4.w;
      acc[6][0]+=a5.z*b4.x; acc[6][1]+=a5.z*b4.y; acc[6][2]+=a5.z*b4.z; acc[6][3]+=a5.z*b4.w;
      acc[7][0]+=a5.w*b4.x; acc[7][1]+=a5.w*b4.y; acc[7][2]+=a5.w*b4.z; acc[7][3]+=a5.w*b4.w;
    }
    if (t + 1 < nt){
      const int nb = cb ^ 1;
      As[nb][ak+0][ar]=a0.x; As[nb][ak+1][ar]=a0.y; As[nb][ak+2][ar]=a0.z; As[nb][ak+3][ar]=a0.w;
      As[nb][ak+4][ar]=a1.x; As[nb][ak+5][ar]=a1.y; As[nb][ak+6][ar]=a1.z; As[nb][ak+7][ar]=a1.w;
      Bs[nb][bk+0][br]=b0.x; Bs[nb][bk+1][br]=b0.y; Bs[nb][bk+2][br]=b0.z; Bs[nb][bk+3][br]=b0.w;
    }
    __syncthreads();
  }
  float* Pz = P + (size_t)(blockIdx.y*gridDim.z + blockIdx.z) * M * N;
  #pragma unroll
  for (int i = 0; i < 8; ++i){
    int rr = (ty << 3) + i;
    float4 v = {acc[i][0], acc[i][1], acc[i][2], acc[i][3]};
    *(float4*)(Pz + (size_t)rr*N + col0 + (tx<<2)) = v;
  }
}

// ------- k_gemmsk_h: split-f16 MFMA skinny GEMM (A fp32 staged, B packed planes).
__global__ __launch_bounds__(256)
void k_gemmsk_h(const float* __restrict__ Ab, size_t AsideOff, int lda,
                const _Float16* __restrict__ Bhp, const _Float16* __restrict__ Blp,
                float* __restrict__ P, int N, int kchunk)
{
  __shared__ __align__(16) _Float16 Ahs[2][4096];   // [kb(4)][m(128)][8]
  __shared__ __align__(16) _Float16 Als[2][4096];
  const int tid = threadIdx.x;
  const int col0 = (int)blockIdx.x << 7;
  const int kbeg = (int)blockIdx.z * kchunk;
  const float* A = Ab + (size_t)blockIdx.y * AsideOff;
  const int ar = tid >> 1, aq = (tid & 1) << 4;     // row, k-offset {0,16}
  const int wid = tid>>6, lane = tid&63;
  const int wr = wid>>1, wc = wid&1;
  const int lr = lane&15, lg = lane>>4;
  const float* Arow = A + (size_t)ar*lda + kbeg + aq;
  const int akb = aq>>3;                            // 0 or 2
  f32x4 acc[4][4] = {};
  const int nc = kchunk >> 5;
  float4 g0,g1,g2,g3;
  g0 = *(const float4*)(Arow);     g1 = *(const float4*)(Arow+4);
  g2 = *(const float4*)(Arow+8);   g3 = *(const float4*)(Arow+12);
  {
    half8 h,l;
    split8(g0,g1,h,l);
    *(half8*)&Ahs[0][(akb*128+ar)*8] = h;     *(half8*)&Als[0][(akb*128+ar)*8] = l;
    split8(g2,g3,h,l);
    *(half8*)&Ahs[0][((akb+1)*128+ar)*8] = h; *(half8*)&Als[0][((akb+1)*128+ar)*8] = l;
  }
  __syncthreads();
  for (int c=0;c<nc;++c){
    const int cb = c&1;
    if (c+1<nc){
      const float* p = Arow + ((c+1)<<5);
      g0 = *(const float4*)(p);    g1 = *(const float4*)(p+4);
      g2 = *(const float4*)(p+8);  g3 = *(const float4*)(p+12);
    }
    const size_t kb0 = (size_t)((kbeg + (c<<5)) >> 3) + lg;
    half8 bh[4], bl[4];
    #pragma unroll
    for (int ni=0;ni<4;++ni){
      size_t a = (kb0*N + col0 + (wc<<6) + (ni<<4) + lr)*8;
      bh[ni] = *(const half8*)(Bhp + a);
      bl[ni] = *(const half8*)(Blp + a);
    }
    #pragma unroll
    for (int mi=0;mi<4;++mi){
      int aa = ((lg<<7) + (wr<<6) + (mi<<4) + lr)<<3;
      half8 ah = *(const half8*)&Ahs[cb][aa];
      half8 al = *(const half8*)&Als[cb][aa];
      #pragma unroll
      for (int ni=0;ni<4;++ni){
        acc[mi][ni] = MF(ah,bh[ni],acc[mi][ni]);
        acc[mi][ni] = MF(al,bh[ni],acc[mi][ni]);
        acc[mi][ni] = MF(ah,bl[ni],acc[mi][ni]);
      }
    }
    if (c+1<nc){
      const int nb = cb^1;
      half8 h,l;
      split8(g0,g1,h,l);
      *(half8*)&Ahs[nb][(akb*128+ar)*8] = h;     *(half8*)&Als[nb][(akb*128+ar)*8] = l;
      split8(g2,g3,h,l);
      *(half8*)&Ahs[nb][((akb+1)*128+ar)*8] = h; *(half8*)&Als[nb][((akb+1)*128+ar)*8] = l;
    }
    __syncthreads();
  }
  float* Pz = P + (size_t)(blockIdx.y*gridDim.z + blockIdx.z)*128*N;
  #pragma unroll
  for (int mi=0;mi<4;++mi){
    #pragma unroll
    for (int ni=0;ni<4;++ni){
      int cc2 = col0 + (wc<<6) + (ni<<4) + lr;
      #pragma unroll
      for (int j=0;j<4;++j){
        int rr2 = (wr<<6) + (mi<<4) + (lg<<2) + j;
        Pz[(size_t)rr2*N + cc2] = acc[mi][ni][j];
      }
    }
  }
}

// sum split partials + bias (+relu)
__global__ void k_red_bias(const float* __restrict__ P, int split, int MN, int N,
                           const float* __restrict__ bias, float* __restrict__ C, int relu){
  int i = blockIdx.x*256 + threadIdx.x;
  if (i >= MN) return;
  float v = bias[i & (N-1)];
  for (int s=0;s<split;++s) v += P[(size_t)s*MN + i];
  if (relu) v = fmaxf(v, 0.f);
  C[i] = v;
}

// fused attention, dual-side: SINGLE-PASS online segment softmax (see R7 notes).
__global__ __launch_bounds__(256)
void k_attn(const float* __restrict__ sf, const float* __restrict__ vf,
            const int* __restrict__ go1, const int* __restrict__ go2,
            const float* __restrict__ hbase, size_t hSideOff, int hstride,
            float* __restrict__ outbase, size_t oSideOff, int ldout)
{
  __shared__ float hs[1024];
  __shared__ float part[4][1024];
  __shared__ float redm[4], reds[4];
  int side = blockIdx.y;
  const float* x = side? vf : sf;
  const int* goff = side? go2 : go1;
  const float* hsrc = hbase + (size_t)side*hSideOff;
  float* outp = outbase + (size_t)side*oSideOff;
  int b = blockIdx.x, t = threadIdx.x;
  int i0 = goff[b], i1 = goff[b+1];
  int lane = t & 63, wv = t >> 6;
  { float4 hv = *(const float4*)(hsrc + (size_t)b*hstride + (t<<2));
    *(float4*)&hs[t<<2] = hv; }
  __syncthreads();
  float m = -3.0e38f, s = 0.f;
  float4 acc[4];
  #pragma unroll
  for (int qq=0;qq<4;++qq){ acc[qq].x=0.f; acc[qq].y=0.f; acc[qq].z=0.f; acc[qq].w=0.f; }
  for (int i = i0 + wv; i < i1; i += 4){
    const float* xr = x + (size_t)i*1024;
    float4 xv[4];
    float d = 0.f;
    #pragma unroll
    for (int qq=0;qq<4;++qq){
      int o = qq*256 + (lane<<2);
      xv[qq] = *(const float4*)(xr+o);
      float4 h4 = *(const float4*)&hs[o];
      d += xv[qq].x*h4.x + xv[qq].y*h4.y + xv[qq].z*h4.z + xv[qq].w*h4.w;
    }
    d = wredsum(d);
    if (d > m){
      float sc = __expf(m - d);
      s = s*sc + 1.f;
      #pragma unroll
      for (int qq=0;qq<4;++qq){
        acc[qq].x = acc[qq].x*sc + xv[qq].x;
        acc[qq].y = acc[qq].y*sc + xv[qq].y;
        acc[qq].z = acc[qq].z*sc + xv[qq].z;
        acc[qq].w = acc[qq].w*sc + xv[qq].w;
      }
      m = d;
    } else {
      float ww = __expf(d - m);
      s += ww;
      #pragma unroll
      for (int qq=0;qq<4;++qq){
        acc[qq].x += ww*xv[qq].x;
        acc[qq].y += ww*xv[qq].y;
        acc[qq].z += ww*xv[qq].z;
        acc[qq].w += ww*xv[qq].w;
      }
    }
  }
  if (lane==0){ redm[wv]=m; reds[wv]=s; }
  __syncthreads();
  float gm = fmaxf(fmaxf(redm[0],redm[1]), fmaxf(redm[2],redm[3]));
  float gs = reds[0]*__expf(redm[0]-gm) + reds[1]*__expf(redm[1]-gm)
           + reds[2]*__expf(redm[2]-gm) + reds[3]*__expf(redm[3]-gm);
  float wsc = __expf(m - gm);
  #pragma unroll
  for (int qq=0;qq<4;++qq){
    float4 v = acc[qq];
    v.x*=wsc; v.y*=wsc; v.z*=wsc; v.w*=wsc;
    *(float4*)&part[wv][qq*256 + (lane<<2)] = v;
  }
  __syncthreads();
  float inv = (i1>i0 && gs>0.f) ? 1.f/gs : 0.f;
  int col = t<<2;
  float4 p0 = *(float4*)&part[0][col];
  float4 p1 = *(float4*)&part[1][col];
  float4 p2 = *(float4*)&part[2][col];
  float4 p3 = *(float4*)&part[3][col];
  float4 o;
  o.x = (p0.x+p1.x+p2.x+p3.x)*inv;
  o.y = (p0.y+p1.y+p2.y+p3.y)*inv;
  o.z = (p0.z+p1.z+p2.z+p3.z)*inv;
  o.w = (p0.w+p1.w+p2.w+p3.w)*inv;
  *(float4*)(outp + (size_t)b*ldout + col) = o;
}

// LSTM iter2 (dual-side): sum split gate partials + u; c1 recomputed inline from biases.
__global__ void k_lstm2_red(const float* __restrict__ Pb, size_t PsideOff, int split,
                            const float* __restrict__ u,
                            const float* __restrict__ bih, const float* __restrict__ bhh,
                            float* __restrict__ z, int B){
  int idx = blockIdx.x*256 + threadIdx.x;
  if (idx >= B*1024) return;
  int side = blockIdx.y;
  const float* P = Pb + (size_t)side*PsideOff;
  int b = idx >> 10, j = idx & 1023;
  float gi=u[j], gf=u[j+1024], gg=u[j+2048], go=u[j+3072];
  const float* g = P + (size_t)b*4096;
  for (int s=0;s<split;++s){
    const float* gs = g + (size_t)s*B*4096;
    gi += gs[j]; gf += gs[j+1024]; gg += gs[j+2048]; go += gs[j+3072];
  }
  float b_i = bih[j] + bhh[j];
  float b_g = bih[j+2048] + bhh[j+2048];
  float c1v = fsigm(b_i)*ftanh(b_g);
  float cc = fsigm(gf)*c1v + fsigm(gi)*ftanh(gg);
  z[(size_t)b*4096 + side*2048 + j] = fsigm(go)*ftanh(cc);
}

// fused fc2-partials reduce + relu + fc3 dot; one block per graph row.
__global__ __launch_bounds__(256)
void k_fc23(const float* __restrict__ P, int split,
            const float* __restrict__ bf2, const float* __restrict__ w3,
            const float* __restrict__ b3, float* __restrict__ out, int B)
{
  __shared__ float zrow[512];
  __shared__ float red[4];
  const int b = blockIdx.x, t = threadIdx.x;
  const int MN = B*512;
  #pragma unroll
  for (int col = t; col < 512; col += 256){
    float v = bf2[col];
    for (int s=0;s<split;++s) v += P[(size_t)s*MN + (size_t)b*512 + col];
    zrow[col] = fmaxf(v, 0.f);
  }
  __syncthreads();
  int c2 = t<<1;
  float acc = zrow[c2]*w3[c2] + zrow[c2+1]*w3[c2+1];
  acc = wredsum(acc);
  int lane = t & 63, wv = t >> 6;
  if (lane==0) red[wv] = acc;
  __syncthreads();
  if (t==0) out[b] = red[0]+red[1]+red[2]+red[3] + b3[0];
}

// ---------------- driver ----------------
extern "C" void kernel_launch(void* const* d_in, const int* in_sizes, int n_in,
                              void* d_out, int out_size, void* d_ws, size_t ws_size,
                              hipStream_t stream)
{
  const float* x1  = (const float*)d_in[0];
  const float* x2  = (const float*)d_in[1];
  const int* src1  = (const int*)d_in[2];
  const int* dst1  = (const int*)d_in[3];
  const int* src2  = (const int*)d_in[4];
  const int* dst2  = (const int*)d_in[5];
  const int* gid1  = (const int*)d_in[6];
  const int* gid2  = (const int*)d_in[7];
  const float* Wg1 = (const float*)d_in[8];  const float* bg1 = (const float*)d_in[9];
  const float* Wg2 = (const float*)d_in[10]; const float* bg2 = (const float*)d_in[11];
  const float* Wg3 = (const float*)d_in[12]; const float* bg3 = (const float*)d_in[13];
  const float* Wg4 = (const float*)d_in[14]; const float* bg4 = (const float*)d_in[15];
  const float* Wih = (const float*)d_in[16]; const float* Whh = (const float*)d_in[17];
  const float* bih = (const float*)d_in[18]; const float* bhh = (const float*)d_in[19];
  const float* Wf1 = (const float*)d_in[20]; const float* bf1 = (const float*)d_in[21];
  const float* Wf2 = (const float*)d_in[22]; const float* bf2 = (const float*)d_in[23];
  const float* Wf3 = (const float*)d_in[24]; const float* bf3 = (const float*)d_in[25];
  float* out = (float*)d_out;

  const int N1 = in_sizes[0]/128;
  const int N2 = in_sizes[1]/128;
  const int E1 = in_sizes[2];
  const int E2 = in_sizes[4];
  const int B  = out_size;            // 128
  const int NM = N1>N2?N1:N2;

  char* base = (char*)d_ws; size_t off=0;
  auto alloc = [&](size_t bytes)->void*{ void* p = base+off; off += (bytes+255)&~(size_t)255; return p; };

  int* zr   = (int*)alloc(sizeof(int)*(size_t)(3*N1+3*N2));
  int* co1=zr, *ci1=zr+N1, *cur1=zr+2*N1;
  int* co2=zr+3*N1, *ci2=zr+3*N1+N2, *cur2=zr+3*N1+2*N2;
  int* row1 = (int*)alloc(sizeof(int)*(size_t)(N1+1));
  int* row2 = (int*)alloc(sizeof(int)*(size_t)(N2+1));
  int* csr1 = (int*)alloc(sizeof(int)*(size_t)E1);
  int* csr2 = (int*)alloc(sizeof(int)*(size_t)E2);
  int* go1  = (int*)alloc(sizeof(int)*(size_t)(B+1));
  int* go2  = (int*)alloc(sizeof(int)*(size_t)(B+1));
  int* pb1  = (int*)alloc(sizeof(int)*(size_t)(B+1));
  int* pb2  = (int*)alloc(sizeof(int)*(size_t)(B+1));
  int* gm1  = (int*)alloc(sizeof(int)*1024);
  int* gm2  = (int*)alloc(sizeof(int)*1024);
  float* os1 = (float*)alloc(sizeof(float)*(size_t)N1);
  float* is1 = (float*)alloc(sizeof(float)*(size_t)N1);
  float* os2 = (float*)alloc(sizeof(float)*(size_t)N2);
  float* is2 = (float*)alloc(sizeof(float)*(size_t)N2);
  _Float16* a1h = (_Float16*)alloc(sizeof(_Float16)*(size_t)(NM+128)*256);
  _Float16* a1l = (_Float16*)alloc(sizeof(_Float16)*(size_t)(NM+128)*256);
  _Float16* a2h = (_Float16*)alloc(sizeof(_Float16)*(size_t)(NM+128)*256);
  _Float16* a2l = (_Float16*)alloc(sizeof(_Float16)*(size_t)(NM+128)*256);
  _Float16* wg1h = (_Float16*)alloc(sizeof(_Float16)*32768);
  _Float16* wg1l = (_Float16*)alloc(sizeof(_Float16)*32768);
  _Float16* wg2h = (_Float16*)alloc(sizeof(_Float16)*131072);
  _Float16* wg2l = (_Float16*)alloc(sizeof(_Float16)*131072);
  _Float16* wg3h = (_Float16*)alloc(sizeof(_Float16)*32768);
  _Float16* wg3l = (_Float16*)alloc(sizeof(_Float16)*32768);
  _Float16* wg4h = (_Float16*)alloc(sizeof(_Float16)*131072);
  _Float16* wg4l = (_Float16*)alloc(sizeof(_Float16)*131072);
  _Float16* wihh = (_Float16*)alloc(sizeof(_Float16)*(size_t)4096*1024);
  _Float16* wihl = (_Float16*)alloc(sizeof(_Float16)*(size_t)4096*1024);
  _Float16* wf1h = (_Float16*)alloc(sizeof(_Float16)*(size_t)1024*4096);
  _Float16* wf1l = (_Float16*)alloc(sizeof(_Float16)*(size_t)1024*4096);
  float* sf  = (float*)alloc(sizeof(float)*(size_t)(N1+128)*1024);
  float* vf  = (float*)alloc(sizeof(float)*(size_t)(N2+128)*1024);
  float* h1 = (float*)alloc(sizeof(float)*1024);
  float* u  = (float*)alloc(sizeof(float)*4096);
  float* r1 = (float*)alloc(sizeof(float)*(size_t)2*B*1024);
  float* z1 = (float*)alloc(sizeof(float)*(size_t)B*1024);
  float* z  = (float*)alloc(sizeof(float)*(size_t)B*4096);
  // T planes: [2 sides][B][128][128] split-f16 (16.8 MB total)
  _Float16* Tqh = (_Float16*)alloc(sizeof(_Float16)*(size_t)2*B*16384);
  _Float16* Tql = (_Float16*)alloc(sizeof(_Float16)*(size_t)2*B*16384);
  // union region: node-packed split-f16 planes / Pbuf partials
  const int PN = ((NM + 32*B + 63)&~63) + 64;
  const size_t PE = (size_t)PN*512;
  size_t packedBytes = 4*PE*sizeof(_Float16);
  size_t pbufBytes   = sizeof(float)*(size_t)32*B*1024*4;
  char* uni = (char*)alloc(packedBytes > pbufBytes ? packedBytes : pbufBytes);
  _Float16* p1h = (_Float16*)uni;
  _Float16* p1l = p1h + PE;
  _Float16* p2h = p1l + PE;
  _Float16* p2l = p2h + PE;
  float* Pbuf = (float*)uni;
  if (off > ws_size) return;

  // hbuf regions live inside sf/vf cols [512,768) (stride 1024), overwritten later by apply
  float* hb1 = sf + 512;
  float* hb2 = vf + 512;

  dim3 blk(256);

  // --- fused pre-pass: zero + weight packs + gemv_u (one launch, input-only) ---
  k_pre<<<dim3(512,9),blk,0,stream>>>(Wg1,Wg2,Wg3,Wg4,
                                      wg1h,wg1l, wg2h,wg2l, wg3h,wg3l, wg4h,wg4l,
                                      Wih+1024, wihh,wihl, Wf1, wf1h,wf1l,
                                      zr, 3*N1+3*N2,
                                      Wih, Whh, bih, bhh, h1, u);

  // --- prep ---
  k_hist2<<<(E1+E2+255)/256, blk, 0, stream>>>(src1,dst1,E1,co1,ci1, src2,dst2,E2,co2,ci2);
  k_prep2<<<3 + (N1+N2+1023)/1024, 1024, 0, stream>>>(ci1,N1,row1, ci2,N2,row2,
                                                      co1,os1,is1, co2,os2,is2,
                                                      gid1,go1, gid2,go2, B,
                                                      pb1,gm1, pb2,gm2);
  k_scatter2<<<(E1+E2+255)/256,blk,0,stream>>>(src1,dst1,E1,row1,cur1,csr1, src2,dst2,E2,row2,cur2,csr2);

  // --- GraphConv (agg both sides in ONE launch per round) ---
  int gy = (NM+127)/128;
  k_agg2<<<dim3((NM+7)/8,2),blk,0,stream>>>(x1,x2,128, os1,os2, row1,csr1, row2,csr2,
                                            a1h,a1l, a2h,a2l, N1,N2, 5);
  k_gconv_mfma<<<dim3(2,gy,2),blk,0,stream>>>(a1h,a1l, a2h,a2l,
                                              wg1h,wg1l, wg3h,wg3l,
                                              hb1,hb2,1024, N1,N2, 256,128,
                                              is1,is2, bg1,bg3, 1, os1,os2);
  k_agg2<<<dim3((NM+3)/4,2),blk,0,stream>>>(hb1,hb2,1024, nullptr,nullptr, row1,csr1, row2,csr2,
                                            a1h,a1l, a2h,a2l, N1,N2, 6);
  k_gconv_mfma<<<dim3(4,gy,2),blk,0,stream>>>(a1h,a1l, a2h,a2l,
                                              wg2h,wg2l, wg4h,wg4l,
                                              sf,vf,1024, N1,N2, 512,256,
                                              is1,is2, bg2,bg4, 0, nullptr,nullptr);

  // --- block-diagonal interaction ---
  const int GMAX = NM/32 + B + 2;
  k_pack<<<dim3(GMAX,2),blk,0,stream>>>(sf,vf, go1,go2, pb1,pb2, gm1,gm2,
                                        p1h,p1l, p2h,p2l, B);
  k_T<<<dim3(B,8),blk,0,stream>>>(sf,vf, go1,go2, Tqh,Tql, B);
  k_apply<<<dim3(2,B,2),blk,0,stream>>>(Tqh,Tql, p1h,p1l, p2h,p2l,
                                        go1,go2, pb1,pb2, sf,vf, B);

  // --- Set2Set (u/h1 already computed by k_pre) ---
  k_attn<<<dim3(B,2),blk,0,stream>>>(sf,vf,go1,go2, h1,0,0, r1,(size_t)B*1024,1024);
  k_gemmsk_h<<<dim3(32,2,4),blk,0,stream>>>(r1,(size_t)B*1024,1024, wihh,wihl, Pbuf, 4096,256);
  k_lstm2_red<<<dim3((B*1024+255)/256,2),blk,0,stream>>>(Pbuf,(size_t)4*B*4096,4, u, bih,bhh, z,B);
  k_attn<<<dim3(B,2),blk,0,stream>>>(sf,vf,go1,go2, z,2048,4096, z+1024,2048,4096);

  // --- MLP head (fc1 split-K 16 x chunk 256) ---
  k_gemmsk_h<<<dim3(8,1,16),blk,0,stream>>>(z,0,4096, wf1h,wf1l, Pbuf, 1024,256);
  k_red_bias<<<(B*1024+255)/256,blk,0,stream>>>(Pbuf,16,B*1024,1024,bf1,z1,1);
  k_gemmsk<<<dim3(8,1,8),blk,0,stream>>>(z1,0,1024, Wf2,1024, Pbuf, 128,512,128);
  k_fc23<<<B,blk,0,stream>>>(Pbuf,8, bf2, Wf3, bf3, out, B);
}